// Round 5
// baseline (899.400 us; speedup 1.0000x reference)
//
#include <hip/hip_runtime.h>
#include <hip/hip_fp16.h>
#include <math.h>

// Problem constants
// B=8, T=16, IMG=128, CF=32, WO=HO=32, N=1024, M=32, DH=256
// conv SAME stride2: pad_lo=0, pad_hi=1  ->  in_idx = 2*out + k

#define TWOPI_32 0.19634954084936207f  // 2*pi/32

// ---------------- conv1: [img][3][128][128] -> [img][32][64][64], stride2 SAME, ReLU
__global__ __launch_bounds__(256) void conv1_kernel(const float* __restrict__ in,
                                                    const float* __restrict__ w,
                                                    const float* __restrict__ bias,
                                                    float* __restrict__ out)
{
    const int strip = blockIdx.x;   // 4 strips of 16 output rows
    const int img   = blockIdx.y;   // 128 images
    const int tid   = threadIdx.x;
    __shared__ float sIn[3*33*130];
    const int iy0 = strip * 32;
    for (int idx = tid; idx < 3*33*130; idx += 256) {
        int ic  = idx / (33*130);
        int rem = idx - ic*(33*130);
        int li  = rem / 130;
        int col = rem - li*130;
        int iy  = iy0 + li;
        float v = 0.f;
        if (iy < 128 && col < 128)
            v = in[(((size_t)img*3 + ic)*128 + iy)*128 + col];
        sIn[idx] = v;
    }
    __syncthreads();
    const int oy0 = strip*16;
    #pragma unroll
    for (int p = 0; p < 4; ++p) {
        int pos = p*256 + tid;       // 1024 positions: 16 rows x 64 cols
        int ly = pos >> 6;
        int ox = pos & 63;
        float r[27];
        #pragma unroll
        for (int ic = 0; ic < 3; ++ic)
            #pragma unroll
            for (int dy = 0; dy < 3; ++dy)
                #pragma unroll
                for (int dx = 0; dx < 3; ++dx)
                    r[(ic*3+dy)*3+dx] = sIn[ic*(33*130) + (2*ly+dy)*130 + 2*ox + dx];
        for (int oc = 0; oc < 32; ++oc) {
            float acc = bias[oc];
            #pragma unroll
            for (int q = 0; q < 27; ++q)
                acc += r[q] * w[oc*27 + q];
            out[(((size_t)img*32 + oc)*64 + (oy0+ly))*64 + ox] = fmaxf(acc, 0.f);
        }
    }
}

// ---------------- conv2: [img][32][64][64] -> [img][32][32][32], stride2 SAME, ReLU
__global__ __launch_bounds__(256) void conv2_kernel(const float* __restrict__ in,
                                                    const float* __restrict__ w,
                                                    const float* __restrict__ bias,
                                                    float* __restrict__ out)
{
    const int strip = blockIdx.x;   // 8 strips of 4 output rows
    const int img   = blockIdx.y;
    const int tid   = threadIdx.x;
    __shared__ float sIn[32*9*66];
    const int iy0 = strip*8;
    for (int idx = tid; idx < 32*9*66; idx += 256) {
        int ic  = idx / (9*66);
        int rem = idx - ic*(9*66);
        int li  = rem / 66;
        int col = rem - li*66;
        int iy  = iy0 + li;
        float v = 0.f;
        if (iy < 64 && col < 64)
            v = in[(((size_t)img*32 + ic)*64 + iy)*64 + col];
        sIn[idx] = v;
    }
    __syncthreads();
    const int posl = tid & 127;     // 128 positions: 4 rows x 32 cols
    const int half = tid >> 7;      // 2 halves of 16 out-channels
    const int ly = posl >> 5;
    const int ox = posl & 31;
    float acc[16];
    #pragma unroll
    for (int j = 0; j < 16; ++j) acc[j] = 0.f;
    for (int ic = 0; ic < 32; ++ic) {
        float r[9];
        #pragma unroll
        for (int dy = 0; dy < 3; ++dy)
            #pragma unroll
            for (int dx = 0; dx < 3; ++dx)
                r[dy*3+dx] = sIn[ic*(9*66) + (2*ly+dy)*66 + 2*ox + dx];
        #pragma unroll
        for (int j = 0; j < 16; ++j) {
            int oc = half*16 + j;
            const float* wp = &w[(oc*32 + ic)*9];
            float a = acc[j];
            #pragma unroll
            for (int q = 0; q < 9; ++q) a += r[q]*wp[q];
            acc[j] = a;
        }
    }
    const int oy = strip*4 + ly;
    #pragma unroll
    for (int j = 0; j < 16; ++j) {
        int oc = half*16 + j;
        out[(((size_t)img*32 + oc)*32 + oy)*32 + ox] = fmaxf(acc[j] + bias[oc], 0.f);
    }
}

// ---------------- pack: f16 weight layouts + DFT twiddle table
// whhP [32 chunks][256 rows][8 halves]  <- Wh cols 0..255
// whrxP[256][64]                        <- Wh cols 256..319
// wkP/weP/waP [(m*16+j)*16+jj]          <- W[m][j+16*jj]
// twg [w][k][2] = (cos(2pi wk/32), -sin(2pi wk/32))
__global__ __launch_bounds__(256) void pack_kernel(const float* __restrict__ Wh,
    const float* __restrict__ Wk, const float* __restrict__ We, const float* __restrict__ Wa,
    __half* __restrict__ whhP, __half* __restrict__ whrxP,
    __half* __restrict__ wkP, __half* __restrict__ weP, __half* __restrict__ waP,
    float* __restrict__ twg)
{
    int idx = blockIdx.x*256 + threadIdx.x;
    if (idx < 65536) {
        int e = idx & 7, i = (idx >> 3) & 255, c = idx >> 11;
        int q = c >> 4, k = c & 15;
        whhP[idx] = __float2half(Wh[i*320 + q*128 + k*8 + e]);
    }
    if (idx < 16384) {
        int i = idx >> 6, s2 = idx & 63;
        whrxP[idx] = __float2half(Wh[i*320 + 256 + s2]);
    }
    if (idx < 8192) {
        int m = idx >> 8, j = (idx >> 4) & 15, jj = idx & 15;
        wkP[idx] = __float2half(Wk[m*256 + j + 16*jj]);
        weP[idx] = __float2half(We[m*256 + j + 16*jj]);
        waP[idx] = __float2half(Wa[m*256 + j + 16*jj]);
    }
    if (idx < 1024) {
        int w = idx >> 5, k = idx & 31;
        float sv, cv;
        sincosf(TWOPI_32 * (float)((w*k) & 31), &sv, &cv);
        twg[idx*2]     = cv;
        twg[idx*2 + 1] = -sv;
    }
}

// ---------------- xhalf: transpose xfeat [bt][m][n] f32 -> xh [bt][n][m] f16
__global__ __launch_bounds__(256) void xhalf_kernel(const float* __restrict__ xf,
                                                    __half* __restrict__ xh)
{
    const int bt  = blockIdx.x;
    const int tid = threadIdx.x;
    __shared__ float sT[32][257];
    const float* src = xf + (size_t)bt*32768;
    __half* dst = xh + (size_t)bt*32768;
    for (int tt = 0; tt < 4; ++tt) {
        #pragma unroll
        for (int m = 0; m < 32; ++m)
            sT[m][tid] = src[m*1024 + tt*256 + tid];
        __syncthreads();
        uint4 o[4];
        unsigned int* ou = (unsigned int*)o;
        #pragma unroll
        for (int k = 0; k < 16; ++k) {
            __half2 h2 = __floats2half2_rn(sT[2*k][tid], sT[2*k+1][tid]);
            ou[k] = *(unsigned int*)&h2;
        }
        uint4* dp = (uint4*)(dst + (size_t)(tt*256 + tid)*32);
        dp[0] = o[0]; dp[1] = o[1]; dp[2] = o[2]; dp[3] = o[3];
        __syncthreads();
    }
}

// ---------------- xmean: mean over n of xfeat rows [(bt*32+m)][1024]
__global__ __launch_bounds__(256) void xmean_kernel(const float* __restrict__ xfeat,
                                                    float* __restrict__ xmean)
{
    const int row  = blockIdx.x*4 + (threadIdx.x >> 6);   // 4096 rows
    const int lane = threadIdx.x & 63;
    const float* p = xfeat + (size_t)row*1024;
    float s = 0.f;
    #pragma unroll
    for (int jj = 0; jj < 16; ++jj) s += p[lane + 64*jj];
    #pragma unroll
    for (int d = 32; d > 0; d >>= 1) s += __shfl_xor(s, d, 64);
    if (lane == 0) xmean[row] = s * (1.f/1024.f);
}

// ---------------- NTM scalar recurrence: one block per batch, 512 threads.
__global__ __launch_bounds__(512, 2) void ntm_scal_kernel(
    const float* __restrict__ xfeat, const __half* __restrict__ xh,
    const float* __restrict__ xmean,
    const __half* __restrict__ whhP, const __half* __restrict__ whrxP,
    const __half* __restrict__ wkP, const __half* __restrict__ weP,
    const __half* __restrict__ waP,
    const float* __restrict__ bk, const float* __restrict__ Wbeta,
    const float* __restrict__ bbeta, const float* __restrict__ bh,
    const float* __restrict__ Wg,
    float* __restrict__ wbuf, float* __restrict__ eag, float* __restrict__ lnst)
{
    const int b    = blockIdx.x;
    const int tid  = threadIdx.x;
    const int lane = tid & 63;
    const int wid  = tid >> 6;

    __shared__ __align__(16) __half sWhh[65536];   // 128 KB
    __shared__ __align__(16) float sHbuf[2][256];
    __shared__ __align__(16) float sK[32];
    __shared__ __align__(16) float sXm[512];
    __shared__ float sRedC[256];
    __shared__ float sRedD[8];
    __shared__ float sRedL[16];
    __shared__ __align__(16) float sR32[32];
    __shared__ __align__(16) float sE[32];
    __shared__ __align__(16) float sA[32];
    __shared__ float sBk[32];
    __shared__ float sBh[256];

    // stage Wh h-part into LDS (one-time, 131072 B)
    {
        const uint4* src = (const uint4*)whhP;
        uint4* dst = (uint4*)sWhh;
        for (int i2 = tid; i2 < 8192; i2 += 512) dst[i2] = src[i2];
    }
    if (tid < 256) { sBh[tid] = bh[tid]; sHbuf[0][tid] = 0.f; }
    if (tid < 32)  sBk[tid] = bk[tid];
    if (tid < 512) sXm[tid] = xmean[b*512 + tid];
    float4 wbeta4 = *(const float4*)&Wbeta[(size_t)lane*4];
    float4 wg4    = *(const float4*)&Wg[(size_t)lane*4];
    float bb = bbeta[0];

    const int n0 = 2*tid;
    float c0[32], c1[32];

    // ---- init: c = layernorm(x0) over (N,M); publish stats for replay
    {
        const float* x0 = xfeat + (size_t)(b*16)*32768;
        float sum = 0.f, ss = 0.f;
        #pragma unroll
        for (int m = 0; m < 32; ++m) {
            float2 v = *(const float2*)&x0[m*1024 + n0];
            c0[m] = v.x; c1[m] = v.y;
            sum += v.x + v.y; ss += v.x*v.x + v.y*v.y;
        }
        #pragma unroll
        for (int d = 32; d > 0; d >>= 1) { sum += __shfl_xor(sum, d, 64); ss += __shfl_xor(ss, d, 64); }
        if (lane == 0) { sRedL[wid] = sum; sRedL[8+wid] = ss; }
        __syncthreads();
        float S = 0.f, SS = 0.f;
        #pragma unroll
        for (int i = 0; i < 8; ++i) { S += sRedL[i]; SS += sRedL[8+i]; }
        float mu = S * (1.f/32768.f);
        float var = SS * (1.f/32768.f) - mu*mu;
        float rs = rsqrtf(var + 1e-5f);
        if (tid == 0) { lnst[b*2] = mu; lnst[b*2+1] = rs; }
        #pragma unroll
        for (int m = 0; m < 32; ++m) { c0[m] = (c0[m]-mu)*rs; c1[m] = (c1[m]-mu)*rs; }
    }

    // prefetch x_0 (f16, transposed rows n0,n0+1 -> 128 contiguous bytes)
    uint4 xb[8];
    {
        const uint4* xrow = (const uint4*)(xh + (size_t)(b*16)*32768) + 8*tid;
        #pragma unroll
        for (int i = 0; i < 8; ++i) xb[i] = xrow[i];
    }
    __syncthreads();   // covers sWhh staging, sHbuf[0] zeros, sXm, sBk, sBh

    float ex0 = 0.f, ex1 = 0.f, w0 = 0.f, w1 = 0.f;
    const int rm = ((lane&1)<<4)|((lane&2)<<2)|(lane&4)|((lane&8)>>2)|((lane&16)>>4); // rev5(lane&31)

    #pragma unroll 1
    for (int t = 0; t < 16; ++t) {
        const int cur = t & 1, nxt = cur ^ 1;
        const float* hold = &sHbuf[cur][0];
        float betav;

        // ---- P1: k = tanh(Wk h + bk) (distributed, f16 weights streamed); beta per-wave redundant
        {
            const int m = tid >> 4, j = tid & 15;
            const uint4* wkp = (const uint4*)(wkP + (size_t)(m*16 + j)*16);
            uint4 wk0 = wkp[0], wk1 = wkp[1];
            float s = 0.f;
            const __half2* a2 = (const __half2*)&wk0;
            const __half2* b2 = (const __half2*)&wk1;
            #pragma unroll
            for (int d = 0; d < 4; ++d) {
                float2 p = __half22float2(a2[d]);
                s += p.x * hold[j + 16*(2*d)] + p.y * hold[j + 16*(2*d+1)];
            }
            #pragma unroll
            for (int d = 0; d < 4; ++d) {
                float2 p = __half22float2(b2[d]);
                s += p.x * hold[j + 16*(8+2*d)] + p.y * hold[j + 16*(8+2*d+1)];
            }
            s += __shfl_down(s, 8, 16); s += __shfl_down(s, 4, 16);
            s += __shfl_down(s, 2, 16); s += __shfl_down(s, 1, 16);
            if (j == 0) sK[m] = tanhf(s + sBk[m]);
            // beta (redundant per wave)
            float4 h4 = *(const float4*)&hold[lane*4];
            float p = wbeta4.x*h4.x + wbeta4.y*h4.y + wbeta4.z*h4.z + wbeta4.w*h4.w;
            #pragma unroll
            for (int d = 32; d > 0; d >>= 1) p += __shfl_xor(p, d, 64);
            float x = p + bb;
            betav = (x > 20.f) ? x : log1pf(expf(x));
        }
        __syncthreads();   // bar1: sK ready

        // ---- P2: cosine sims, exp weights, denom partials, r partials (vector butterfly)
        {
            float beta = betav;
            float dot0 = 0.f, dot1 = 0.f, cn20 = 0.f, cn21 = 0.f, kn2 = 0.f;
            #pragma unroll
            for (int q = 0; q < 8; ++q) {
                float4 k4 = *(const float4*)&sK[4*q];
                dot0 += c0[4*q]*k4.x + c0[4*q+1]*k4.y + c0[4*q+2]*k4.z + c0[4*q+3]*k4.w;
                dot1 += c1[4*q]*k4.x + c1[4*q+1]*k4.y + c1[4*q+2]*k4.z + c1[4*q+3]*k4.w;
                cn20 += c0[4*q]*c0[4*q] + c0[4*q+1]*c0[4*q+1] + c0[4*q+2]*c0[4*q+2] + c0[4*q+3]*c0[4*q+3];
                cn21 += c1[4*q]*c1[4*q] + c1[4*q+1]*c1[4*q+1] + c1[4*q+2]*c1[4*q+2] + c1[4*q+3]*c1[4*q+3];
                kn2  += k4.x*k4.x + k4.y*k4.y + k4.z*k4.z + k4.w*k4.w;
            }
            float kinv = 1.f / (sqrtf(kn2) + 1e-8f);
            float s0 = dot0 * kinv / (sqrtf(cn20) + 1e-8f);
            float s1 = dot1 * kinv / (sqrtf(cn21) + 1e-8f);
            ex0 = expf(beta * s0);
            ex1 = expf(beta * s1);
            float es = ex0 + ex1;
            #pragma unroll
            for (int d = 32; d > 0; d >>= 1) es += __shfl_xor(es, d, 64);
            if (lane == 0) sRedD[wid] = es;
            // vector butterfly: reduce v[32] across the wave, one component per lane
            float v[32];
            #pragma unroll
            for (int m = 0; m < 32; ++m) v[m] = ex0*c0[m] + ex1*c1[m];
            #pragma unroll
            for (int i = 0; i < 16; ++i) { float sd = (lane&1)? v[i] : v[i+16]; float rc = __shfl_xor(sd, 1, 64); v[i] = ((lane&1)? v[i+16] : v[i]) + rc; }
            #pragma unroll
            for (int i = 0; i < 8; ++i)  { float sd = (lane&2)? v[i] : v[i+8];  float rc = __shfl_xor(sd, 2, 64); v[i] = ((lane&2)? v[i+8]  : v[i]) + rc; }
            #pragma unroll
            for (int i = 0; i < 4; ++i)  { float sd = (lane&4)? v[i] : v[i+4];  float rc = __shfl_xor(sd, 4, 64); v[i] = ((lane&4)? v[i+4]  : v[i]) + rc; }
            #pragma unroll
            for (int i = 0; i < 2; ++i)  { float sd = (lane&8)? v[i] : v[i+2];  float rc = __shfl_xor(sd, 8, 64); v[i] = ((lane&8)? v[i+2]  : v[i]) + rc; }
            { float sd = (lane&16)? v[0] : v[1]; float rc = __shfl_xor(sd, 16, 64); v[0] = ((lane&16)? v[1] : v[0]) + rc; }
            v[0] += __shfl_xor(v[0], 32, 64);
            if (lane < 32) sRedC[wid*32 + rm] = v[0];
        }
        __syncthreads();   // bar2: sRedC/sRedD ready

        // ---- P3: r-combine (per-wave redundant), wbuf write, D-dot -> h_new
        {
            float den = sRedD[0]+sRedD[1]+sRedD[2]+sRedD[3]+sRedD[4]+sRedD[5]+sRedD[6]+sRedD[7];
            float inv = 1.f / den;
            w0 = ex0 * inv; w1 = ex1 * inv;
            *(float2*)&wbuf[(size_t)(b*16 + t)*1024 + n0] = make_float2(w0, w1);
            if (lane < 32) {
                float r = 0.f;
                #pragma unroll
                for (int w = 0; w < 8; ++w) r += sRedC[w*32 + lane];
                sR32[lane] = r * inv;
            }
            // D-dot: thread (i = tid>>1, q = tid&1) handles half of row i
            const int i = tid >> 1, q = tid & 1;
            const uint4* wrp = (const uint4*)(whrxP + (size_t)i*64 + q*32);
            float s = 0.f;
            #pragma unroll
            for (int k = 0; k < 16; ++k) {
                uint4 wv = *(const uint4*)&sWhh[(size_t)(((q*16 + k)*256 + i))*8];
                float4 h4a = *(const float4*)&hold[q*128 + k*8];
                float4 h4b = *(const float4*)&hold[q*128 + k*8 + 4];
                const __half2* w2 = (const __half2*)&wv;
                float2 p0 = __half22float2(w2[0]); s += p0.x*h4a.x + p0.y*h4a.y;
                float2 p1 = __half22float2(w2[1]); s += p1.x*h4a.z + p1.y*h4a.w;
                float2 p2 = __half22float2(w2[2]); s += p2.x*h4b.x + p2.y*h4b.y;
                float2 p3 = __half22float2(w2[3]); s += p3.x*h4b.z + p3.y*h4b.w;
            }
            // rx part: q=0 -> r[0..31], q=1 -> xmean[0..31]
            const float* rxsrc = q ? &sXm[t*32] : sR32;
            #pragma unroll
            for (int c4 = 0; c4 < 4; ++c4) {
                uint4 wvx = wrp[c4];
                float4 va = *(const float4*)&rxsrc[c4*8];
                float4 vb = *(const float4*)&rxsrc[c4*8 + 4];
                const __half2* w2 = (const __half2*)&wvx;
                float2 p0 = __half22float2(w2[0]); s += p0.x*va.x + p0.y*va.y;
                float2 p1 = __half22float2(w2[1]); s += p1.x*va.z + p1.y*va.w;
                float2 p2 = __half22float2(w2[2]); s += p2.x*vb.x + p2.y*vb.y;
                float2 p3 = __half22float2(w2[3]); s += p3.x*vb.z + p3.y*vb.w;
            }
            s += __shfl_down(s, 1, 2);
            if (q == 0) sHbuf[nxt][i] = tanhf(s + sBh[i]);
        }
        __syncthreads();   // bar3: h_new ready

        // ---- P4a: e = sig(We h), a = tanh(Wa h) (distributed); g per-wave redundant
        float gg;
        {
            const float* hnew = &sHbuf[nxt][0];
            const int m = tid >> 4, j = tid & 15;
            const uint4* wep = (const uint4*)(weP + (size_t)(m*16 + j)*16);
            const uint4* wap = (const uint4*)(waP + (size_t)(m*16 + j)*16);
            uint4 we0 = wep[0], we1 = wep[1];
            uint4 wa0 = wap[0], wa1 = wap[1];
            float se = 0.f, sa = 0.f;
            const __half2* e2a = (const __half2*)&we0;
            const __half2* e2b = (const __half2*)&we1;
            const __half2* a2a = (const __half2*)&wa0;
            const __half2* a2b = (const __half2*)&wa1;
            #pragma unroll
            for (int d = 0; d < 4; ++d) {
                float h0v = hnew[j + 16*(2*d)], h1v = hnew[j + 16*(2*d+1)];
                float2 pe = __half22float2(e2a[d]);
                float2 pa = __half22float2(a2a[d]);
                se += pe.x*h0v + pe.y*h1v;
                sa += pa.x*h0v + pa.y*h1v;
            }
            #pragma unroll
            for (int d = 0; d < 4; ++d) {
                float h0v = hnew[j + 16*(8+2*d)], h1v = hnew[j + 16*(8+2*d+1)];
                float2 pe = __half22float2(e2b[d]);
                float2 pa = __half22float2(a2b[d]);
                se += pe.x*h0v + pe.y*h1v;
                sa += pa.x*h0v + pa.y*h1v;
            }
            se += __shfl_down(se, 8, 16); sa += __shfl_down(sa, 8, 16);
            se += __shfl_down(se, 4, 16); sa += __shfl_down(sa, 4, 16);
            se += __shfl_down(se, 2, 16); sa += __shfl_down(sa, 2, 16);
            se += __shfl_down(se, 1, 16); sa += __shfl_down(sa, 1, 16);
            if (j == 0) {
                float e = 1.f/(1.f + expf(-se));
                float a = tanhf(sa);
                sE[m] = e; sA[m] = a;
                eag[(size_t)(b*16 + t)*80 + m]      = e;
                eag[(size_t)(b*16 + t)*80 + 32 + m] = a;
            }
            // g (redundant per wave)
            float4 h4 = *(const float4*)&hnew[lane*4];
            float p = wg4.x*h4.x + wg4.y*h4.y + wg4.z*h4.z + wg4.w*h4.w;
            #pragma unroll
            for (int d = 32; d > 0; d >>= 1) p += __shfl_xor(p, d, 64);
            gg = 1.f/(1.f + expf(-p));
            if (tid == 0) eag[(size_t)(b*16 + t)*80 + 64] = gg;
        }
        __syncthreads();   // bar4: sE/sA ready

        // ---- P4b: c update in registers (x prefetched in xb); then prefetch x(t+1)
        {
            float omg = 1.f - gg;
            const __half* xp = (const __half*)xb;
            #pragma unroll
            for (int q = 0; q < 8; ++q) {
                float4 e4 = *(const float4*)&sE[4*q];
                float4 a4 = *(const float4*)&sA[4*q];
                #pragma unroll
                for (int r = 0; r < 4; ++r) {
                    int m = 4*q + r;
                    float e = (r==0)?e4.x:(r==1)?e4.y:(r==2)?e4.z:e4.w;
                    float a = (r==0)?a4.x:(r==1)?a4.y:(r==2)?a4.z:a4.w;
                    float x0v = __half2float(xp[m]);
                    float x1v = __half2float(xp[32 + m]);
                    c0[m] = omg*(c0[m]*(1.f - w0*e) + w0*a) + gg*x0v;
                    c1[m] = omg*(c1[m]*(1.f - w1*e) + w1*a) + gg*x1v;
                }
            }
            if (t < 15) {
                const uint4* xrow = (const uint4*)(xh + (size_t)(b*16 + t + 1)*32768) + 8*tid;
                #pragma unroll
                for (int i = 0; i < 8; ++i) xb[i] = xrow[i];
            }
        }
    }
}

// ---------------- replay: reconstruct cseq from scalars, fully parallel
__global__ __launch_bounds__(256) void ntm_replay_kernel(
    const float* __restrict__ xfeat, const float* __restrict__ wbuf,
    const float* __restrict__ eag, const float* __restrict__ lnst,
    float* __restrict__ cseq)
{
    const int slab = blockIdx.x;    // 16 slabs of 64 n
    const int b    = blockIdx.y;    // 8
    const int tid  = threadIdx.x;
    const int m    = tid >> 3;      // 32
    const int ns   = tid & 7;       // 8 subgroups of 8 n
    const int n0   = slab*64 + ns*8;
    const float mu = lnst[b*2], rs = lnst[b*2+1];

    float c[8];
    {
        const float* x0 = xfeat + (size_t)(b*16)*32768 + m*1024 + n0;
        float4 a = *(const float4*)x0;
        float4 bv = *(const float4*)(x0 + 4);
        c[0]=(a.x-mu)*rs; c[1]=(a.y-mu)*rs; c[2]=(a.z-mu)*rs; c[3]=(a.w-mu)*rs;
        c[4]=(bv.x-mu)*rs; c[5]=(bv.y-mu)*rs; c[6]=(bv.z-mu)*rs; c[7]=(bv.w-mu)*rs;
    }
    for (int t = 0; t < 16; ++t) {
        const size_t bt = (size_t)(b*16 + t);
        const float* wp = &wbuf[bt*1024 + n0];
        float4 wA = *(const float4*)wp;
        float4 wB = *(const float4*)(wp + 4);
        float e = eag[bt*80 + m];
        float a = eag[bt*80 + 32 + m];
        float g = eag[bt*80 + 64];
        float omg = 1.f - g;
        const float* xp = &xfeat[bt*32768 + m*1024 + n0];
        float4 xA = *(const float4*)xp;
        float4 xB = *(const float4*)(xp + 4);
        c[0] = omg*(c[0]*(1.f - wA.x*e) + wA.x*a) + g*xA.x;
        c[1] = omg*(c[1]*(1.f - wA.y*e) + wA.y*a) + g*xA.y;
        c[2] = omg*(c[2]*(1.f - wA.z*e) + wA.z*a) + g*xA.z;
        c[3] = omg*(c[3]*(1.f - wA.w*e) + wA.w*a) + g*xA.w;
        c[4] = omg*(c[4]*(1.f - wB.x*e) + wB.x*a) + g*xB.x;
        c[5] = omg*(c[5]*(1.f - wB.y*e) + wB.y*a) + g*xB.y;
        c[6] = omg*(c[6]*(1.f - wB.z*e) + wB.z*a) + g*xB.z;
        c[7] = omg*(c[7]*(1.f - wB.w*e) + wB.w*a) + g*xB.w;
        float* op = &cseq[bt*32768 + m*1024 + n0];
        *(float4*)op       = make_float4(c[0], c[1], c[2], c[3]);
        *(float4*)(op + 4) = make_float4(c[4], c[5], c[6], c[7]);
    }
}

// ---------------- rfft2 v2: table-driven DFT, float4 LDS reads, 1 image per 256-thr block
__global__ __launch_bounds__(256) void fft_fwd_kernel(const float* __restrict__ src,
                                                      const float* __restrict__ cosw,
                                                      const float* __restrict__ twg,
                                                      float* __restrict__ dst)
{
    const int img = blockIdx.x;
    const int tid = threadIdx.x;
    __shared__ __align__(16) float sY[32*36];    // padded rows (stride 36)
    __shared__ __align__(16) float sT[2048];     // tw[w][k][2]
    __shared__ __align__(16) float sR[2048];     // R[h][k][2]

    // stage twiddle table (L2-hot, 8 KB)
    {
        const float4* s4 = (const float4*)twg;
        float4* d4 = (float4*)sT;
        d4[tid]       = s4[tid];
        d4[256 + tid] = s4[256 + tid];
    }
    // load + window: pos = tid*4 -> h = tid>>3, w0 = (tid&7)*4
    {
        float4 v = *(const float4*)&src[(size_t)img*1024 + tid*4];
        float4 c = *(const float4*)&cosw[tid*4];
        *(float4*)&sY[(tid>>3)*36 + (tid&7)*4] = make_float4(v.x*c.x, v.y*c.y, v.z*c.z, v.w*c.w);
    }
    __syncthreads();

    const int hj = tid >> 3;           // h (stage1) / j (stage2)
    const int k0 = (tid & 7) * 4;      // 4 consecutive k

    // stage1: R[h][k] = sum_w y[h][w] * tw[w][k]
    float r0=0.f,i0=0.f,r1=0.f,i1=0.f,r2=0.f,i2=0.f,r3=0.f,i3=0.f;
    #pragma unroll
    for (int w = 0; w < 32; ++w) {
        float y = sY[hj*36 + w];
        float4 ta = *(const float4*)&sT[(w*32 + k0)*2];
        float4 tb = *(const float4*)&sT[(w*32 + k0)*2 + 4];
        r0 += y*ta.x; i0 += y*ta.y;
        r1 += y*ta.z; i1 += y*ta.w;
        r2 += y*tb.x; i2 += y*tb.y;
        r3 += y*tb.z; i3 += y*tb.w;
    }
    *(float4*)&sR[(hj*32 + k0)*2]     = make_float4(r0,i0,r1,i1);
    *(float4*)&sR[(hj*32 + k0)*2 + 4] = make_float4(r2,i2,r3,i3);
    __syncthreads();

    // stage2: F[j][k] = sum_h R[h][k] * tw[h][j]
    float fr0=0.f,fi0=0.f,fr1=0.f,fi1=0.f,fr2=0.f,fi2=0.f,fr3=0.f,fi3=0.f;
    #pragma unroll
    for (int h = 0; h < 32; ++h) {
        float2 wj = *(const float2*)&sT[(h*32 + hj)*2];
        float4 Ra = *(const float4*)&sR[(h*32 + k0)*2];
        float4 Rb = *(const float4*)&sR[(h*32 + k0)*2 + 4];
        fr0 += Ra.x*wj.x - Ra.y*wj.y;  fi0 += Ra.x*wj.y + Ra.y*wj.x;
        fr1 += Ra.z*wj.x - Ra.w*wj.y;  fi1 += Ra.z*wj.y + Ra.w*wj.x;
        fr2 += Rb.x*wj.x - Rb.y*wj.y;  fi2 += Rb.x*wj.y + Rb.y*wj.x;
        fr3 += Rb.z*wj.x - Rb.w*wj.y;  fi3 += Rb.z*wj.y + Rb.w*wj.x;
    }
    // store only k <= 16 in [img][j*17+k][2] layout
    float* dp = dst + ((size_t)img*544 + hj*17 + k0)*2;
    if (k0 < 16) {
        *(float2*)&dp[0] = make_float2(fr0, fi0);
        *(float2*)&dp[2] = make_float2(fr1, fi1);
        *(float2*)&dp[4] = make_float2(fr2, fi2);
        *(float2*)&dp[6] = make_float2(fr3, fi3);
    } else if (k0 == 16) {
        *(float2*)&dp[0] = make_float2(fr0, fi0);
    }
}

// ---------------- channel-sum DCF combine (parallel: 1 thread per (bt,idx))
__global__ __launch_bounds__(256) void combine_kernel(const float* __restrict__ cfft,
                                                      const float* __restrict__ zfft,
                                                      const float* __restrict__ yf,
                                                      float* __restrict__ rfreq)
{
    int gid = blockIdx.x*256 + threadIdx.x;
    if (gid >= 128*544) return;
    int bt  = gid / 544;
    int idx = gid - bt*544;
    float kzz = 0.f, kxr = 0.f, kxi = 0.f;
    #pragma unroll 4
    for (int m = 0; m < 32; ++m) {
        size_t base = ((size_t)(bt*32 + m)*544 + idx)*2;
        float2 c = *(const float2*)&cfft[base];
        float2 z = *(const float2*)&zfft[base];
        kzz += c.x*c.x + c.y*c.y;
        kxr += z.x*c.x + z.y*c.y;   // z * conj(c)
        kxi += z.y*c.x - z.x*c.y;
    }
    float den = 1.f / (kzz + 1e-4f);
    float2 y = *(const float2*)&yf[idx*2];
    float ar = y.x*den, ai = y.y*den;
    *(float2*)&rfreq[(size_t)gid*2] = make_float2(kxr*ar - kxi*ai, kxr*ai + kxi*ar);
}

// ---------------- irfft2 back to 32x32 real response; one block per bt
__global__ __launch_bounds__(256) void ifft_kernel(const float* __restrict__ rfreq,
                                                   float* __restrict__ out)
{
    const int bt  = blockIdx.x;
    const int tid = threadIdx.x;
    __shared__ float sG[544*2];
    __shared__ float sS[544*2];
    __shared__ float ct[32], st[32];
    if (tid < 32) {
        float sv, cv;
        sincosf(TWOPI_32 * (float)tid, &sv, &cv);
        ct[tid] = cv; st[tid] = sv;
    }
    for (int i = tid; i < 1088; i += 256) sG[i] = rfreq[(size_t)bt*1088 + i];
    __syncthreads();
    // stage 1: inverse fft along j
    for (int idx = tid; idx < 544; idx += 256) {
        int h = idx / 17;
        int k = idx - h*17;
        float re = 0.f, im = 0.f;
        #pragma unroll
        for (int j = 0; j < 32; ++j) {
            float gr = sG[(j*17+k)*2], gi = sG[(j*17+k)*2+1];
            int a = (h*j) & 31;
            float c = ct[a], s = st[a];
            re += gr*c - gi*s;
            im += gr*s + gi*c;
        }
        sS[(h*17+k)*2] = re; sS[(h*17+k)*2+1] = im;
    }
    __syncthreads();
    // stage 2: inverse rfft along w with hermitian extension; scale 1/1024
    #pragma unroll
    for (int p = 0; p < 4; ++p) {
        int pos = p*256 + tid;
        int h = pos >> 5, wq = pos & 31;
        float acc = sS[(h*17)*2];
        #pragma unroll
        for (int k = 1; k < 16; ++k) {
            int a = (wq*k) & 31;
            acc += 2.f*(sS[(h*17+k)*2]*ct[a] - sS[(h*17+k)*2+1]*st[a]);
        }
        acc += sS[(h*17+16)*2] * ((wq & 1) ? -1.f : 1.f);
        out[(size_t)bt*1024 + pos] = acc * (1.f/1024.f);
    }
}

extern "C" void kernel_launch(void* const* d_in, const int* in_sizes, int n_in,
                              void* d_out, int out_size, void* d_ws, size_t ws_size,
                              hipStream_t stream)
{
    const float* x_i   = (const float*)d_in[0];
    const float* z_i   = (const float*)d_in[1];
    const float* c1w   = (const float*)d_in[2];
    const float* c1b   = (const float*)d_in[3];
    const float* c2w   = (const float*)d_in[4];
    const float* c2b   = (const float*)d_in[5];
    const float* Wk    = (const float*)d_in[6];
    const float* bk    = (const float*)d_in[7];
    const float* Wbeta = (const float*)d_in[8];
    const float* bbeta = (const float*)d_in[9];
    const float* Wh    = (const float*)d_in[10];
    const float* bh    = (const float*)d_in[11];
    const float* We    = (const float*)d_in[12];
    const float* Wa    = (const float*)d_in[13];
    const float* Wg    = (const float*)d_in[14];
    const float* cosw  = (const float*)d_in[15];
    const float* yf    = (const float*)d_in[16];
    float* out = (float*)d_out;
    float* ws  = (float*)d_ws;

    // workspace layout (floats); peak ~118 MB (unchanged footprint)
    float*  buf1  = ws;                 // conv1 out (16,777,216 f); reused after convs
    float*  xfeat = ws + 16777216;      // 4,194,304
    float*  zfeat = ws + 20971520;      // 4,194,304
    float*  cseq  = ws + 25165824;      // 4,194,304
    float*  rfreq = ws + 29360128;      // 139,264
    float*  xmb   = ws + 29499392;      // 4,096
    // regions inside buf1, valid after conv stage completes:
    float*  cfft  = buf1;               // 4,456,448 f
    float*  zfft  = buf1 + 4456448;     // 4,456,448 f (ends 8,912,896)
    __half* xhb   = (__half*)(ws + 9000000);    // 4,194,304 halfs
    float*  wbuf  = ws + 11100000;      // 131,072 f
    float*  eag   = ws + 11240000;      // 10,240 f
    float*  lnstp = ws + 11251000;      // 16 f
    __half* whhP  = (__half*)(ws + 11300000);   // 65,536 halfs
    __half* whrxP = (__half*)(ws + 11332768);   // 16,384 halfs
    __half* wkP   = (__half*)(ws + 11340960);   // 8,192 halfs
    __half* weP   = (__half*)(ws + 11345056);   // 8,192 halfs
    __half* waP   = (__half*)(ws + 11349152);   // 8,192 halfs (ends 11,353,248)
    float*  twg   = ws + 11360000;      // 2,048 f

    dim3 b256(256);
    conv1_kernel<<<dim3(4,128), b256, 0, stream>>>(x_i, c1w, c1b, buf1);
    conv2_kernel<<<dim3(8,128), b256, 0, stream>>>(buf1, c2w, c2b, xfeat);
    conv1_kernel<<<dim3(4,128), b256, 0, stream>>>(z_i, c1w, c1b, buf1);
    conv2_kernel<<<dim3(8,128), b256, 0, stream>>>(buf1, c2w, c2b, zfeat);
    pack_kernel<<<256, b256, 0, stream>>>(Wh, Wk, We, Wa, whhP, whrxP, wkP, weP, waP, twg);
    xhalf_kernel<<<128, b256, 0, stream>>>(xfeat, xhb);
    xmean_kernel<<<1024, b256, 0, stream>>>(xfeat, xmb);
    ntm_scal_kernel<<<8, 512, 0, stream>>>(xfeat, xhb, xmb, whhP, whrxP, wkP, weP, waP,
                                           bk, Wbeta, bbeta, bh, Wg, wbuf, eag, lnstp);
    ntm_replay_kernel<<<dim3(16,8), b256, 0, stream>>>(xfeat, wbuf, eag, lnstp, cseq);
    fft_fwd_kernel<<<4096, b256, 0, stream>>>(cseq, cosw, twg, cfft);
    fft_fwd_kernel<<<4096, b256, 0, stream>>>(zfeat, cosw, twg, zfft);
    combine_kernel<<<272, b256, 0, stream>>>(cfft, zfft, yf, rfreq);
    ifft_kernel<<<128, b256, 0, stream>>>(rfreq, out);
}

// Round 6
// 874.640 us; speedup vs baseline: 1.0283x; 1.0283x over previous
//
#include <hip/hip_runtime.h>
#include <hip/hip_fp16.h>
#include <math.h>

// Problem constants
// B=8, T=16, IMG=128, CF=32, WO=HO=32, N=1024, M=32, DH=256
// conv SAME stride2: pad_lo=0, pad_hi=1  ->  in_idx = 2*out + k

#define TWOPI_32 0.19634954084936207f  // 2*pi/32

typedef _Float16 __h2 __attribute__((ext_vector_type(2)));
__device__ __forceinline__ float fdot2(unsigned int w, unsigned int h, float acc) {
    union { unsigned int u; __h2 v; } a, b;
    a.u = w; b.u = h;
    return __builtin_amdgcn_fdot2(a.v, b.v, acc, false);
}

// ---------------- conv1: [img][3][128][128] -> [img][32][64][64], stride2 SAME, ReLU
__global__ __launch_bounds__(256) void conv1_kernel(const float* __restrict__ in,
                                                    const float* __restrict__ w,
                                                    const float* __restrict__ bias,
                                                    float* __restrict__ out)
{
    const int strip = blockIdx.x;   // 4 strips of 16 output rows
    const int img   = blockIdx.y;   // 128 images
    const int tid   = threadIdx.x;
    __shared__ float sIn[3*33*130];
    const int iy0 = strip * 32;
    for (int idx = tid; idx < 3*33*130; idx += 256) {
        int ic  = idx / (33*130);
        int rem = idx - ic*(33*130);
        int li  = rem / 130;
        int col = rem - li*130;
        int iy  = iy0 + li;
        float v = 0.f;
        if (iy < 128 && col < 128)
            v = in[(((size_t)img*3 + ic)*128 + iy)*128 + col];
        sIn[idx] = v;
    }
    __syncthreads();
    const int oy0 = strip*16;
    #pragma unroll
    for (int p = 0; p < 4; ++p) {
        int pos = p*256 + tid;       // 1024 positions: 16 rows x 64 cols
        int ly = pos >> 6;
        int ox = pos & 63;
        float r[27];
        #pragma unroll
        for (int ic = 0; ic < 3; ++ic)
            #pragma unroll
            for (int dy = 0; dy < 3; ++dy)
                #pragma unroll
                for (int dx = 0; dx < 3; ++dx)
                    r[(ic*3+dy)*3+dx] = sIn[ic*(33*130) + (2*ly+dy)*130 + 2*ox + dx];
        for (int oc = 0; oc < 32; ++oc) {
            float acc = bias[oc];
            #pragma unroll
            for (int q = 0; q < 27; ++q)
                acc += r[q] * w[oc*27 + q];
            out[(((size_t)img*32 + oc)*64 + (oy0+ly))*64 + ox] = fmaxf(acc, 0.f);
        }
    }
}

// ---------------- conv2: [img][32][64][64] -> [img][32][32][32], stride2 SAME, ReLU
__global__ __launch_bounds__(256) void conv2_kernel(const float* __restrict__ in,
                                                    const float* __restrict__ w,
                                                    const float* __restrict__ bias,
                                                    float* __restrict__ out)
{
    const int strip = blockIdx.x;   // 8 strips of 4 output rows
    const int img   = blockIdx.y;
    const int tid   = threadIdx.x;
    __shared__ float sIn[32*9*66];
    const int iy0 = strip*8;
    for (int idx = tid; idx < 32*9*66; idx += 256) {
        int ic  = idx / (9*66);
        int rem = idx - ic*(9*66);
        int li  = rem / 66;
        int col = rem - li*66;
        int iy  = iy0 + li;
        float v = 0.f;
        if (iy < 64 && col < 64)
            v = in[(((size_t)img*32 + ic)*64 + iy)*64 + col];
        sIn[idx] = v;
    }
    __syncthreads();
    const int posl = tid & 127;     // 128 positions: 4 rows x 32 cols
    const int half = tid >> 7;      // 2 halves of 16 out-channels
    const int ly = posl >> 5;
    const int ox = posl & 31;
    float acc[16];
    #pragma unroll
    for (int j = 0; j < 16; ++j) acc[j] = 0.f;
    for (int ic = 0; ic < 32; ++ic) {
        float r[9];
        #pragma unroll
        for (int dy = 0; dy < 3; ++dy)
            #pragma unroll
            for (int dx = 0; dx < 3; ++dx)
                r[dy*3+dx] = sIn[ic*(9*66) + (2*ly+dy)*66 + 2*ox + dx];
        #pragma unroll
        for (int j = 0; j < 16; ++j) {
            int oc = half*16 + j;
            const float* wp = &w[(oc*32 + ic)*9];
            float a = acc[j];
            #pragma unroll
            for (int q = 0; q < 9; ++q) a += r[q]*wp[q];
            acc[j] = a;
        }
    }
    const int oy = strip*4 + ly;
    #pragma unroll
    for (int j = 0; j < 16; ++j) {
        int oc = half*16 + j;
        out[(((size_t)img*32 + oc)*32 + oy)*32 + ox] = fmaxf(acc[j] + bias[oc], 0.f);
    }
}

// ---------------- prep: fused xhalf-transpose + xmean + weight pack + twiddle
// blocks 0..127: per-bt transpose xfeat->xh (f16) and xmean
// blocks 128..159: pack whhP/whrxP/wkP/weP/waP (dot2-friendly layouts) + twg
__global__ __launch_bounds__(256) void prep_kernel(
    const float* __restrict__ xf, __half* __restrict__ xh, float* __restrict__ xmean,
    const float* __restrict__ Wh, const float* __restrict__ Wk,
    const float* __restrict__ We, const float* __restrict__ Wa,
    __half* __restrict__ whhP, __half* __restrict__ whrxP,
    __half* __restrict__ wkP, __half* __restrict__ weP, __half* __restrict__ waP,
    float* __restrict__ twg)
{
    const int tid = threadIdx.x;
    if (blockIdx.x < 128) {
        const int bt = blockIdx.x;
        __shared__ float sT[32][257];
        const float* src = xf + (size_t)bt*32768;
        __half* dst = xh + (size_t)bt*32768;
        for (int tt = 0; tt < 4; ++tt) {
            #pragma unroll
            for (int m = 0; m < 32; ++m)
                sT[m][tid] = src[m*1024 + tt*256 + tid];
            __syncthreads();
            uint4 o[4];
            unsigned int* ou = (unsigned int*)o;
            #pragma unroll
            for (int k = 0; k < 16; ++k) {
                __half2 h2 = __floats2half2_rn(sT[2*k][tid], sT[2*k+1][tid]);
                ou[k] = *(unsigned int*)&h2;
            }
            uint4* dp = (uint4*)(dst + (size_t)(tt*256 + tid)*32);
            dp[0] = o[0]; dp[1] = o[1]; dp[2] = o[2]; dp[3] = o[3];
            __syncthreads();
        }
        // xmean: 8 threads per m
        const int m = tid >> 3, s8 = tid & 7;
        float sm = 0.f;
        #pragma unroll 16
        for (int k = 0; k < 128; ++k) sm += src[m*1024 + s8 + 8*k];
        sm += __shfl_down(sm, 4, 8); sm += __shfl_down(sm, 2, 8); sm += __shfl_down(sm, 1, 8);
        if (s8 == 0) xmean[bt*32 + m] = sm * (1.f/1024.f);
    } else {
        const int base = (blockIdx.x - 128)*256 + tid;   // 0..8191
        // whhP [chunk c=q*16+k][row i][e] <- Wh[i][q*128+k*8+e]
        #pragma unroll
        for (int r = 0; r < 8; ++r) {
            int idx = base*8 + r;
            int e = idx & 7, i = (idx >> 3) & 255, c = idx >> 11;
            int q = c >> 4, k = c & 15;
            whhP[idx] = __float2half(Wh[i*320 + q*128 + k*8 + e]);
        }
        // whrxP [i][64] <- Wh[i][256+..]
        #pragma unroll
        for (int r = 0; r < 2; ++r) {
            int idx = base*2 + r;
            int i = idx >> 6, s2 = idx & 63;
            whrxP[idx] = __float2half(Wh[i*320 + 256 + s2]);
        }
        // wkP/weP/waP: [(m*16+j)*16 + e]: e<8 -> col 8j+e; e>=8 -> col 128+8j+(e-8)
        {
            int idx = base;
            int m = idx >> 8, j = (idx >> 4) & 15, e = idx & 15;
            int col = (e < 8) ? (8*j + e) : (128 + 8*j + (e - 8));
            wkP[idx] = __float2half(Wk[m*256 + col]);
            weP[idx] = __float2half(We[m*256 + col]);
            waP[idx] = __float2half(Wa[m*256 + col]);
        }
        if (base < 1024) {
            int w = base >> 5, k = base & 31;
            float sv, cv;
            sincosf(TWOPI_32 * (float)((w*k) & 31), &sv, &cv);
            twg[base*2]     = cv;
            twg[base*2 + 1] = -sv;
        }
    }
}

// ---------------- NTM scalar recurrence: one block per batch, 512 threads, dot2 GEMVs
__global__ __launch_bounds__(512, 2) void ntm_scal_kernel(
    const float* __restrict__ xfeat, const __half* __restrict__ xh,
    const float* __restrict__ xmean,
    const __half* __restrict__ whhP, const __half* __restrict__ whrxP,
    const __half* __restrict__ wkP, const __half* __restrict__ weP,
    const __half* __restrict__ waP,
    const float* __restrict__ bk, const float* __restrict__ Wbeta,
    const float* __restrict__ bbeta, const float* __restrict__ bh,
    const float* __restrict__ Wg,
    float* __restrict__ wbuf, float* __restrict__ eag, float* __restrict__ lnst)
{
    const int b    = blockIdx.x;
    const int tid  = threadIdx.x;
    const int lane = tid & 63;
    const int wid  = tid >> 6;

    __shared__ __align__(16) __half sWhh[65536];   // 128 KB
    __shared__ __align__(16) float sHbuf[2][256];  // h f32 (beta/g/rx uses)
    __shared__ __align__(16) __half sHh[2][256];   // h f16 (dot2 operand)
    __shared__ __align__(16) float sK[32];
    __shared__ __align__(16) float sXm[512];
    __shared__ float sRedC[256];
    __shared__ float sRedD[8];
    __shared__ float sRedL[16];
    __shared__ __align__(16) float sR32[32];
    __shared__ __align__(16) float sE[32];
    __shared__ __align__(16) float sA[32];
    __shared__ float sBk[32];
    __shared__ float sBh[256];

    // stage Wh h-part into LDS (one-time, 131072 B)
    {
        const uint4* src = (const uint4*)whhP;
        uint4* dst = (uint4*)sWhh;
        for (int i2 = tid; i2 < 8192; i2 += 512) dst[i2] = src[i2];
    }
    if (tid < 256) { sBh[tid] = bh[tid]; sHbuf[0][tid] = 0.f; sHh[0][tid] = __float2half(0.f); }
    if (tid < 32)  sBk[tid] = bk[tid];
    if (tid < 512) sXm[tid] = xmean[b*512 + tid];
    float4 wbeta4 = *(const float4*)&Wbeta[(size_t)lane*4];
    float4 wg4    = *(const float4*)&Wg[(size_t)lane*4];
    float bb = bbeta[0];

    const int n0 = 2*tid;
    float c0[32], c1[32];

    // ---- init: c = layernorm(x0) over (N,M); publish stats for replay
    {
        const float* x0 = xfeat + (size_t)(b*16)*32768;
        float sum = 0.f, ss = 0.f;
        #pragma unroll
        for (int m = 0; m < 32; ++m) {
            float2 v = *(const float2*)&x0[m*1024 + n0];
            c0[m] = v.x; c1[m] = v.y;
            sum += v.x + v.y; ss += v.x*v.x + v.y*v.y;
        }
        #pragma unroll
        for (int d = 32; d > 0; d >>= 1) { sum += __shfl_xor(sum, d, 64); ss += __shfl_xor(ss, d, 64); }
        if (lane == 0) { sRedL[wid] = sum; sRedL[8+wid] = ss; }
        __syncthreads();
        float S = 0.f, SS = 0.f;
        #pragma unroll
        for (int i = 0; i < 8; ++i) { S += sRedL[i]; SS += sRedL[8+i]; }
        float mu = S * (1.f/32768.f);
        float var = SS * (1.f/32768.f) - mu*mu;
        float rs = rsqrtf(var + 1e-5f);
        if (tid == 0) { lnst[b*2] = mu; lnst[b*2+1] = rs; }
        #pragma unroll
        for (int m = 0; m < 32; ++m) { c0[m] = (c0[m]-mu)*rs; c1[m] = (c1[m]-mu)*rs; }
    }

    // prefetch x_0 (f16, transposed rows n0,n0+1 -> 128 contiguous bytes)
    uint4 xb[8];
    {
        const uint4* xrow = (const uint4*)(xh + (size_t)(b*16)*32768) + 8*tid;
        #pragma unroll
        for (int i = 0; i < 8; ++i) xb[i] = xrow[i];
    }
    __syncthreads();   // covers sWhh staging, h zeros, sXm, sBk, sBh

    float ex0 = 0.f, ex1 = 0.f, w0 = 0.f, w1 = 0.f;
    const int rm = ((lane&1)<<4)|((lane&2)<<2)|(lane&4)|((lane&8)>>2)|((lane&16)>>4); // rev5(lane&31)

    #pragma unroll 1
    for (int t = 0; t < 16; ++t) {
        const int cur = t & 1, nxt = cur ^ 1;
        const float* hold = &sHbuf[cur][0];
        float betav;

        // ---- P1: k = tanh(Wk h + bk) via dot2; beta per-wave redundant
        {
            const int m = tid >> 4, j = tid & 15;
            const uint4* wkp = (const uint4*)(wkP + (size_t)(m*16 + j)*16);
            uint4 wk0 = wkp[0], wk1 = wkp[1];
            uint4 h0 = *(const uint4*)&sHh[cur][8*j];
            uint4 h1 = *(const uint4*)&sHh[cur][128 + 8*j];
            float s = 0.f;
            s = fdot2(wk0.x, h0.x, s); s = fdot2(wk0.y, h0.y, s);
            s = fdot2(wk0.z, h0.z, s); s = fdot2(wk0.w, h0.w, s);
            s = fdot2(wk1.x, h1.x, s); s = fdot2(wk1.y, h1.y, s);
            s = fdot2(wk1.z, h1.z, s); s = fdot2(wk1.w, h1.w, s);
            s += __shfl_down(s, 8, 16); s += __shfl_down(s, 4, 16);
            s += __shfl_down(s, 2, 16); s += __shfl_down(s, 1, 16);
            if (j == 0) sK[m] = tanhf(s + sBk[m]);
            // beta (redundant per wave, f32 h)
            float4 h4 = *(const float4*)&hold[lane*4];
            float p = wbeta4.x*h4.x + wbeta4.y*h4.y + wbeta4.z*h4.z + wbeta4.w*h4.w;
            #pragma unroll
            for (int d = 32; d > 0; d >>= 1) p += __shfl_xor(p, d, 64);
            float x = p + bb;
            betav = (x > 20.f) ? x : log1pf(expf(x));
        }
        __syncthreads();   // bar1: sK ready

        // ---- P2: cosine sims, exp weights, denom partials, r partials (vector butterfly)
        {
            float beta = betav;
            float dot0 = 0.f, dot1 = 0.f, cn20 = 0.f, cn21 = 0.f, kn2 = 0.f;
            #pragma unroll
            for (int q = 0; q < 8; ++q) {
                float4 k4 = *(const float4*)&sK[4*q];
                dot0 += c0[4*q]*k4.x + c0[4*q+1]*k4.y + c0[4*q+2]*k4.z + c0[4*q+3]*k4.w;
                dot1 += c1[4*q]*k4.x + c1[4*q+1]*k4.y + c1[4*q+2]*k4.z + c1[4*q+3]*k4.w;
                cn20 += c0[4*q]*c0[4*q] + c0[4*q+1]*c0[4*q+1] + c0[4*q+2]*c0[4*q+2] + c0[4*q+3]*c0[4*q+3];
                cn21 += c1[4*q]*c1[4*q] + c1[4*q+1]*c1[4*q+1] + c1[4*q+2]*c1[4*q+2] + c1[4*q+3]*c1[4*q+3];
                kn2  += k4.x*k4.x + k4.y*k4.y + k4.z*k4.z + k4.w*k4.w;
            }
            float kinv = 1.f / (sqrtf(kn2) + 1e-8f);
            float s0 = dot0 * kinv / (sqrtf(cn20) + 1e-8f);
            float s1 = dot1 * kinv / (sqrtf(cn21) + 1e-8f);
            ex0 = expf(beta * s0);
            ex1 = expf(beta * s1);
            float es = ex0 + ex1;
            #pragma unroll
            for (int d = 32; d > 0; d >>= 1) es += __shfl_xor(es, d, 64);
            if (lane == 0) sRedD[wid] = es;
            float v[32];
            #pragma unroll
            for (int m = 0; m < 32; ++m) v[m] = ex0*c0[m] + ex1*c1[m];
            #pragma unroll
            for (int i = 0; i < 16; ++i) { float sd = (lane&1)? v[i] : v[i+16]; float rc = __shfl_xor(sd, 1, 64); v[i] = ((lane&1)? v[i+16] : v[i]) + rc; }
            #pragma unroll
            for (int i = 0; i < 8; ++i)  { float sd = (lane&2)? v[i] : v[i+8];  float rc = __shfl_xor(sd, 2, 64); v[i] = ((lane&2)? v[i+8]  : v[i]) + rc; }
            #pragma unroll
            for (int i = 0; i < 4; ++i)  { float sd = (lane&4)? v[i] : v[i+4];  float rc = __shfl_xor(sd, 4, 64); v[i] = ((lane&4)? v[i+4]  : v[i]) + rc; }
            #pragma unroll
            for (int i = 0; i < 2; ++i)  { float sd = (lane&8)? v[i] : v[i+2];  float rc = __shfl_xor(sd, 8, 64); v[i] = ((lane&8)? v[i+2]  : v[i]) + rc; }
            { float sd = (lane&16)? v[0] : v[1]; float rc = __shfl_xor(sd, 16, 64); v[0] = ((lane&16)? v[1] : v[0]) + rc; }
            v[0] += __shfl_xor(v[0], 32, 64);
            if (lane < 32) sRedC[wid*32 + rm] = v[0];
        }
        __syncthreads();   // bar2: sRedC/sRedD ready

        // ---- P3: r-combine, wbuf write, D-dot (dot2) -> h_new
        {
            float den = sRedD[0]+sRedD[1]+sRedD[2]+sRedD[3]+sRedD[4]+sRedD[5]+sRedD[6]+sRedD[7];
            float inv = 1.f / den;
            w0 = ex0 * inv; w1 = ex1 * inv;
            *(float2*)&wbuf[(size_t)(b*16 + t)*1024 + n0] = make_float2(w0, w1);
            if (lane < 32) {
                float r = 0.f;
                #pragma unroll
                for (int w = 0; w < 8; ++w) r += sRedC[w*32 + lane];
                sR32[lane] = r * inv;
            }
            // D-dot: thread (i = tid>>1, q = tid&1) handles half of row i
            const int i = tid >> 1, q = tid & 1;
            const uint4* wrp = (const uint4*)(whrxP + (size_t)i*64 + q*32);
            float s = 0.f;
            #pragma unroll
            for (int k = 0; k < 16; ++k) {
                uint4 wv = *(const uint4*)&sWhh[(size_t)(((q*16 + k)*256 + i))*8];
                uint4 hv = *(const uint4*)&sHh[cur][q*128 + k*8];
                s = fdot2(wv.x, hv.x, s); s = fdot2(wv.y, hv.y, s);
                s = fdot2(wv.z, hv.z, s); s = fdot2(wv.w, hv.w, s);
            }
            // rx part: q=0 -> r[0..31], q=1 -> xmean[0..31]  (f32 src, f16 weights)
            const float* rxsrc = q ? &sXm[t*32] : sR32;
            #pragma unroll
            for (int c4 = 0; c4 < 4; ++c4) {
                uint4 wvx = wrp[c4];
                float4 va = *(const float4*)&rxsrc[c4*8];
                float4 vb = *(const float4*)&rxsrc[c4*8 + 4];
                const __half2* w2 = (const __half2*)&wvx;
                float2 p0 = __half22float2(w2[0]); s += p0.x*va.x + p0.y*va.y;
                float2 p1 = __half22float2(w2[1]); s += p1.x*va.z + p1.y*va.w;
                float2 p2 = __half22float2(w2[2]); s += p2.x*vb.x + p2.y*vb.y;
                float2 p3 = __half22float2(w2[3]); s += p3.x*vb.z + p3.y*vb.w;
            }
            s += __shfl_down(s, 1, 2);
            if (q == 0) {
                float hn = tanhf(s + sBh[i]);
                sHbuf[nxt][i] = hn;
                sHh[nxt][i] = __float2half(hn);
            }
        }
        __syncthreads();   // bar3: h_new ready

        // ---- P4a: e = sig(We h), a = tanh(Wa h) via dot2; g per-wave redundant
        float gg;
        {
            const float* hnew = &sHbuf[nxt][0];
            const int m = tid >> 4, j = tid & 15;
            const uint4* wep = (const uint4*)(weP + (size_t)(m*16 + j)*16);
            const uint4* wap = (const uint4*)(waP + (size_t)(m*16 + j)*16);
            uint4 we0 = wep[0], we1 = wep[1];
            uint4 wa0 = wap[0], wa1 = wap[1];
            uint4 h0 = *(const uint4*)&sHh[nxt][8*j];
            uint4 h1 = *(const uint4*)&sHh[nxt][128 + 8*j];
            float se = 0.f, sa = 0.f;
            se = fdot2(we0.x, h0.x, se); se = fdot2(we0.y, h0.y, se);
            se = fdot2(we0.z, h0.z, se); se = fdot2(we0.w, h0.w, se);
            se = fdot2(we1.x, h1.x, se); se = fdot2(we1.y, h1.y, se);
            se = fdot2(we1.z, h1.z, se); se = fdot2(we1.w, h1.w, se);
            sa = fdot2(wa0.x, h0.x, sa); sa = fdot2(wa0.y, h0.y, sa);
            sa = fdot2(wa0.z, h0.z, sa); sa = fdot2(wa0.w, h0.w, sa);
            sa = fdot2(wa1.x, h1.x, sa); sa = fdot2(wa1.y, h1.y, sa);
            sa = fdot2(wa1.z, h1.z, sa); sa = fdot2(wa1.w, h1.w, sa);
            se += __shfl_down(se, 8, 16); sa += __shfl_down(sa, 8, 16);
            se += __shfl_down(se, 4, 16); sa += __shfl_down(sa, 4, 16);
            se += __shfl_down(se, 2, 16); sa += __shfl_down(sa, 2, 16);
            se += __shfl_down(se, 1, 16); sa += __shfl_down(sa, 1, 16);
            if (j == 0) {
                float e = 1.f/(1.f + expf(-se));
                float a = tanhf(sa);
                sE[m] = e; sA[m] = a;
                eag[(size_t)(b*16 + t)*80 + m]      = e;
                eag[(size_t)(b*16 + t)*80 + 32 + m] = a;
            }
            // g (redundant per wave, f32 h)
            float4 h4 = *(const float4*)&hnew[lane*4];
            float p = wg4.x*h4.x + wg4.y*h4.y + wg4.z*h4.z + wg4.w*h4.w;
            #pragma unroll
            for (int d = 32; d > 0; d >>= 1) p += __shfl_xor(p, d, 64);
            gg = 1.f/(1.f + expf(-p));
            if (tid == 0) eag[(size_t)(b*16 + t)*80 + 64] = gg;
        }
        __syncthreads();   // bar4: sE/sA ready

        // ---- P4b: c update in registers (x prefetched in xb); then prefetch x(t+1)
        {
            float omg = 1.f - gg;
            const __half* xp = (const __half*)xb;
            #pragma unroll
            for (int q = 0; q < 8; ++q) {
                float4 e4 = *(const float4*)&sE[4*q];
                float4 a4 = *(const float4*)&sA[4*q];
                #pragma unroll
                for (int r = 0; r < 4; ++r) {
                    int m = 4*q + r;
                    float e = (r==0)?e4.x:(r==1)?e4.y:(r==2)?e4.z:e4.w;
                    float a = (r==0)?a4.x:(r==1)?a4.y:(r==2)?a4.z:a4.w;
                    float x0v = __half2float(xp[m]);
                    float x1v = __half2float(xp[32 + m]);
                    c0[m] = omg*(c0[m]*(1.f - w0*e) + w0*a) + gg*x0v;
                    c1[m] = omg*(c1[m]*(1.f - w1*e) + w1*a) + gg*x1v;
                }
            }
            if (t < 15) {
                const uint4* xrow = (const uint4*)(xh + (size_t)(b*16 + t + 1)*32768) + 8*tid;
                #pragma unroll
                for (int i = 0; i < 8; ++i) xb[i] = xrow[i];
            }
        }
    }
}

// ---------------- replay: reconstruct cseq from scalars, fully parallel
__global__ __launch_bounds__(256) void ntm_replay_kernel(
    const float* __restrict__ xfeat, const float* __restrict__ wbuf,
    const float* __restrict__ eag, const float* __restrict__ lnst,
    float* __restrict__ cseq)
{
    const int slab = blockIdx.x;    // 16 slabs of 64 n
    const int b    = blockIdx.y;    // 8
    const int tid  = threadIdx.x;
    const int m    = tid >> 3;      // 32
    const int ns   = tid & 7;       // 8 subgroups of 8 n
    const int n0   = slab*64 + ns*8;
    const float mu = lnst[b*2], rs = lnst[b*2+1];

    float c[8];
    {
        const float* x0 = xfeat + (size_t)(b*16)*32768 + m*1024 + n0;
        float4 a = *(const float4*)x0;
        float4 bv = *(const float4*)(x0 + 4);
        c[0]=(a.x-mu)*rs; c[1]=(a.y-mu)*rs; c[2]=(a.z-mu)*rs; c[3]=(a.w-mu)*rs;
        c[4]=(bv.x-mu)*rs; c[5]=(bv.y-mu)*rs; c[6]=(bv.z-mu)*rs; c[7]=(bv.w-mu)*rs;
    }
    for (int t = 0; t < 16; ++t) {
        const size_t bt = (size_t)(b*16 + t);
        const float* wp = &wbuf[bt*1024 + n0];
        float4 wA = *(const float4*)wp;
        float4 wB = *(const float4*)(wp + 4);
        float e = eag[bt*80 + m];
        float a = eag[bt*80 + 32 + m];
        float g = eag[bt*80 + 64];
        float omg = 1.f - g;
        const float* xp = &xfeat[bt*32768 + m*1024 + n0];
        float4 xA = *(const float4*)xp;
        float4 xB = *(const float4*)(xp + 4);
        c[0] = omg*(c[0]*(1.f - wA.x*e) + wA.x*a) + g*xA.x;
        c[1] = omg*(c[1]*(1.f - wA.y*e) + wA.y*a) + g*xA.y;
        c[2] = omg*(c[2]*(1.f - wA.z*e) + wA.z*a) + g*xA.z;
        c[3] = omg*(c[3]*(1.f - wA.w*e) + wA.w*a) + g*xA.w;
        c[4] = omg*(c[4]*(1.f - wB.x*e) + wB.x*a) + g*xB.x;
        c[5] = omg*(c[5]*(1.f - wB.y*e) + wB.y*a) + g*xB.y;
        c[6] = omg*(c[6]*(1.f - wB.z*e) + wB.z*a) + g*xB.z;
        c[7] = omg*(c[7]*(1.f - wB.w*e) + wB.w*a) + g*xB.w;
        float* op = &cseq[bt*32768 + m*1024 + n0];
        *(float4*)op       = make_float4(c[0], c[1], c[2], c[3]);
        *(float4*)(op + 4) = make_float4(c[4], c[5], c[6], c[7]);
    }
}

// ---------------- rfft2: table-driven DFT, both inputs in ONE dispatch (8192 blocks)
__global__ __launch_bounds__(256) void fft_fwd_kernel(const float* __restrict__ srcA,
                                                      const float* __restrict__ srcB,
                                                      const float* __restrict__ cosw,
                                                      const float* __restrict__ twg,
                                                      float* __restrict__ dstA,
                                                      float* __restrict__ dstB)
{
    const int img = blockIdx.x;
    const int tid = threadIdx.x;
    const float* src; float* dst;
    if (img < 4096) { src = srcA + (size_t)img*1024;        dst = dstA + (size_t)img*1088; }
    else            { src = srcB + (size_t)(img-4096)*1024; dst = dstB + (size_t)(img-4096)*1088; }

    __shared__ __align__(16) float sY[32*36];    // padded rows (stride 36)
    __shared__ __align__(16) float sT[2048];     // tw[w][k][2]
    __shared__ __align__(16) float sR[2048];     // R[h][k][2]

    {
        const float4* s4 = (const float4*)twg;
        float4* d4 = (float4*)sT;
        d4[tid]       = s4[tid];
        d4[256 + tid] = s4[256 + tid];
    }
    {
        float4 v = *(const float4*)&src[tid*4];
        float4 c = *(const float4*)&cosw[tid*4];
        *(float4*)&sY[(tid>>3)*36 + (tid&7)*4] = make_float4(v.x*c.x, v.y*c.y, v.z*c.z, v.w*c.w);
    }
    __syncthreads();

    const int hj = tid >> 3;           // h (stage1) / j (stage2)
    const int k0 = (tid & 7) * 4;      // 4 consecutive k

    // stage1: R[h][k] = sum_w y[h][w] * tw[w][k]
    float r0=0.f,i0=0.f,r1=0.f,i1=0.f,r2=0.f,i2=0.f,r3=0.f,i3=0.f;
    #pragma unroll
    for (int w = 0; w < 32; ++w) {
        float y = sY[hj*36 + w];
        float4 ta = *(const float4*)&sT[(w*32 + k0)*2];
        float4 tb = *(const float4*)&sT[(w*32 + k0)*2 + 4];
        r0 += y*ta.x; i0 += y*ta.y;
        r1 += y*ta.z; i1 += y*ta.w;
        r2 += y*tb.x; i2 += y*tb.y;
        r3 += y*tb.z; i3 += y*tb.w;
    }
    *(float4*)&sR[(hj*32 + k0)*2]     = make_float4(r0,i0,r1,i1);
    *(float4*)&sR[(hj*32 + k0)*2 + 4] = make_float4(r2,i2,r3,i3);
    __syncthreads();

    // stage2: F[j][k] = sum_h R[h][k] * tw[h][j]
    float fr0=0.f,fi0=0.f,fr1=0.f,fi1=0.f,fr2=0.f,fi2=0.f,fr3=0.f,fi3=0.f;
    #pragma unroll
    for (int h = 0; h < 32; ++h) {
        float2 wj = *(const float2*)&sT[(h*32 + hj)*2];
        float4 Ra = *(const float4*)&sR[(h*32 + k0)*2];
        float4 Rb = *(const float4*)&sR[(h*32 + k0)*2 + 4];
        fr0 += Ra.x*wj.x - Ra.y*wj.y;  fi0 += Ra.x*wj.y + Ra.y*wj.x;
        fr1 += Ra.z*wj.x - Ra.w*wj.y;  fi1 += Ra.z*wj.y + Ra.w*wj.x;
        fr2 += Rb.x*wj.x - Rb.y*wj.y;  fi2 += Rb.x*wj.y + Rb.y*wj.x;
        fr3 += Rb.z*wj.x - Rb.w*wj.y;  fi3 += Rb.z*wj.y + Rb.w*wj.x;
    }
    float* dp = dst + (size_t)(hj*17 + k0)*2;
    if (k0 < 16) {
        *(float2*)&dp[0] = make_float2(fr0, fi0);
        *(float2*)&dp[2] = make_float2(fr1, fi1);
        *(float2*)&dp[4] = make_float2(fr2, fi2);
        *(float2*)&dp[6] = make_float2(fr3, fi3);
    } else if (k0 == 16) {
        *(float2*)&dp[0] = make_float2(fr0, fi0);
    }
}

// ---------------- fused combine + irfft2; one block per bt (128 blocks)
__global__ __launch_bounds__(256) void comb_ifft_kernel(const float* __restrict__ cfft,
                                                        const float* __restrict__ zfft,
                                                        const float* __restrict__ yf,
                                                        float* __restrict__ out)
{
    const int bt  = blockIdx.x;
    const int tid = threadIdx.x;
    __shared__ float sG[544*2];
    __shared__ float sS[544*2];
    __shared__ float ct[32], st[32];
    if (tid < 32) {
        float sv, cv;
        sincosf(TWOPI_32 * (float)tid, &sv, &cv);
        ct[tid] = cv; st[tid] = sv;
    }
    // combine directly into LDS
    for (int idx = tid; idx < 544; idx += 256) {
        float kzz = 0.f, kxr = 0.f, kxi = 0.f;
        #pragma unroll 4
        for (int m = 0; m < 32; ++m) {
            size_t base = ((size_t)(bt*32 + m)*544 + idx)*2;
            float2 c = *(const float2*)&cfft[base];
            float2 z = *(const float2*)&zfft[base];
            kzz += c.x*c.x + c.y*c.y;
            kxr += z.x*c.x + z.y*c.y;   // z * conj(c)
            kxi += z.y*c.x - z.x*c.y;
        }
        float den = 1.f / (kzz + 1e-4f);
        float2 y = *(const float2*)&yf[idx*2];
        float ar = y.x*den, ai = y.y*den;
        sG[idx*2]     = kxr*ar - kxi*ai;
        sG[idx*2 + 1] = kxr*ai + kxi*ar;
    }
    __syncthreads();
    // stage 1: inverse fft along j
    for (int idx = tid; idx < 544; idx += 256) {
        int h = idx / 17;
        int k = idx - h*17;
        float re = 0.f, im = 0.f;
        #pragma unroll
        for (int j = 0; j < 32; ++j) {
            float gr = sG[(j*17+k)*2], gi = sG[(j*17+k)*2+1];
            int a = (h*j) & 31;
            float c = ct[a], s = st[a];
            re += gr*c - gi*s;
            im += gr*s + gi*c;
        }
        sS[(h*17+k)*2] = re; sS[(h*17+k)*2+1] = im;
    }
    __syncthreads();
    // stage 2: inverse rfft along w with hermitian extension; scale 1/1024
    #pragma unroll
    for (int p = 0; p < 4; ++p) {
        int pos = p*256 + tid;
        int h = pos >> 5, wq = pos & 31;
        float acc = sS[(h*17)*2];
        #pragma unroll
        for (int k = 1; k < 16; ++k) {
            int a = (wq*k) & 31;
            acc += 2.f*(sS[(h*17+k)*2]*ct[a] - sS[(h*17+k)*2+1]*st[a]);
        }
        acc += sS[(h*17+16)*2] * ((wq & 1) ? -1.f : 1.f);
        out[(size_t)bt*1024 + pos] = acc * (1.f/1024.f);
    }
}

extern "C" void kernel_launch(void* const* d_in, const int* in_sizes, int n_in,
                              void* d_out, int out_size, void* d_ws, size_t ws_size,
                              hipStream_t stream)
{
    const float* x_i   = (const float*)d_in[0];
    const float* z_i   = (const float*)d_in[1];
    const float* c1w   = (const float*)d_in[2];
    const float* c1b   = (const float*)d_in[3];
    const float* c2w   = (const float*)d_in[4];
    const float* c2b   = (const float*)d_in[5];
    const float* Wk    = (const float*)d_in[6];
    const float* bk    = (const float*)d_in[7];
    const float* Wbeta = (const float*)d_in[8];
    const float* bbeta = (const float*)d_in[9];
    const float* Wh    = (const float*)d_in[10];
    const float* bh    = (const float*)d_in[11];
    const float* We    = (const float*)d_in[12];
    const float* Wa    = (const float*)d_in[13];
    const float* Wg    = (const float*)d_in[14];
    const float* cosw  = (const float*)d_in[15];
    const float* yf    = (const float*)d_in[16];
    float* out = (float*)d_out;
    float* ws  = (float*)d_ws;

    // workspace layout (floats); peak ~118 MB
    float*  buf1  = ws;                 // conv1 out (16,777,216 f); reused after convs
    float*  xfeat = ws + 16777216;      // 4,194,304
    float*  zfeat = ws + 20971520;      // 4,194,304
    float*  cseq  = ws + 25165824;      // 4,194,304
    float*  xmb   = ws + 29499392;      // 4,096
    // regions inside buf1, valid after conv stage completes:
    float*  cfft  = buf1;               // 4,456,448 f
    float*  zfft  = buf1 + 4456448;     // 4,456,448 f (ends 8,912,896)
    __half* xhb   = (__half*)(ws + 9000000);    // 4,194,304 halfs
    float*  wbuf  = ws + 11100000;      // 131,072 f
    float*  eag   = ws + 11240000;      // 10,240 f
    float*  lnstp = ws + 11251000;      // 16 f
    __half* whhP  = (__half*)(ws + 11300000);   // 65,536 halfs
    __half* whrxP = (__half*)(ws + 11332768);   // 16,384 halfs
    __half* wkP   = (__half*)(ws + 11340960);   // 8,192 halfs
    __half* weP   = (__half*)(ws + 11345056);   // 8,192 halfs
    __half* waP   = (__half*)(ws + 11349152);   // 8,192 halfs
    float*  twg   = ws + 11360000;      // 2,048 f

    dim3 b256(256);
    conv1_kernel<<<dim3(4,128), b256, 0, stream>>>(x_i, c1w, c1b, buf1);
    conv2_kernel<<<dim3(8,128), b256, 0, stream>>>(buf1, c2w, c2b, xfeat);
    conv1_kernel<<<dim3(4,128), b256, 0, stream>>>(z_i, c1w, c1b, buf1);
    conv2_kernel<<<dim3(8,128), b256, 0, stream>>>(buf1, c2w, c2b, zfeat);
    prep_kernel<<<160, b256, 0, stream>>>(xfeat, xhb, xmb, Wh, Wk, We, Wa,
                                          whhP, whrxP, wkP, weP, waP, twg);
    ntm_scal_kernel<<<8, 512, 0, stream>>>(xfeat, xhb, xmb, whhP, whrxP, wkP, weP, waP,
                                           bk, Wbeta, bbeta, bh, Wg, wbuf, eag, lnstp);
    ntm_replay_kernel<<<dim3(16,8), b256, 0, stream>>>(xfeat, wbuf, eag, lnstp, cseq);
    fft_fwd_kernel<<<8192, b256, 0, stream>>>(cseq, zfeat, cosw, twg, cfft, zfft);
    comb_ifft_kernel<<<128, b256, 0, stream>>>(cfft, zfft, yf, out);
}

// Round 8
// 637.121 us; speedup vs baseline: 1.4117x; 1.3728x over previous
//
#include <hip/hip_runtime.h>
#include <hip/hip_fp16.h>
#include <math.h>

// Problem constants
// B=8, T=16, IMG=128, CF=32, WO=HO=32, N=1024, M=32, DH=256
// conv SAME stride2: pad_lo=0, pad_hi=1  ->  in_idx = 2*out + k

#define TWOPI_32 0.19634954084936207f  // 2*pi/32

typedef _Float16 __h2 __attribute__((ext_vector_type(2)));
__device__ __forceinline__ float fdot2(unsigned int w, unsigned int h, float acc) {
    union { unsigned int u; __h2 v; } a, b;
    a.u = w; b.u = h;
    return __builtin_amdgcn_fdot2(a.v, b.v, acc, false);
}
__device__ __forceinline__ unsigned int packh2(float a, float b) {
    __half2 h2 = __floats2half2_rn(a, b);
    return *(unsigned int*)&h2;
}

// ---------------- prepack: all weight packs + twiddle (input-independent, runs first)
// NOTE: outputs MUST live outside buf1's range [0, 16,777,216) floats — conv1 overwrites it.
__global__ __launch_bounds__(256) void prepack_kernel(
    const float* __restrict__ Wh, const float* __restrict__ Wk,
    const float* __restrict__ We, const float* __restrict__ Wa,
    const float* __restrict__ c1w, const float* __restrict__ c2w,
    __half* __restrict__ whhP, __half* __restrict__ whrxP,
    __half* __restrict__ wkP, __half* __restrict__ weP, __half* __restrict__ waP,
    float* __restrict__ twg,
    unsigned int* __restrict__ c2wP, unsigned int* __restrict__ c1wP01,
    float* __restrict__ c1wP2)
{
    const int tid = threadIdx.x;
    if (blockIdx.x < 32) {
        const int base = blockIdx.x*256 + tid;   // 0..8191
        #pragma unroll
        for (int r = 0; r < 8; ++r) {
            int idx = base*8 + r;
            int e = idx & 7, i = (idx >> 3) & 255, c = idx >> 11;
            int q = c >> 4, k = c & 15;
            whhP[idx] = __float2half(Wh[i*320 + q*128 + k*8 + e]);
        }
        #pragma unroll
        for (int r = 0; r < 2; ++r) {
            int idx = base*2 + r;
            int i = idx >> 6, s2 = idx & 63;
            whrxP[idx] = __float2half(Wh[i*320 + 256 + s2]);
        }
        {
            int idx = base;
            int m = idx >> 8, j = (idx >> 4) & 15, e = idx & 15;
            int col = (e < 8) ? (8*j + e) : (128 + 8*j + (e - 8));
            wkP[idx] = __float2half(Wk[m*256 + col]);
            weP[idx] = __float2half(We[m*256 + col]);
            waP[idx] = __float2half(Wa[m*256 + col]);
        }
    } else {
        // conv2 weights: c2wP[half][ic2][q][j] = (w[oc][2ic2][q], w[oc][2ic2+1][q]), oc=half*16+j
        for (int idx = tid; idx < 4608; idx += 256) {
            int half = idx / 2304;
            int rem  = idx - half*2304;
            int ic2  = rem / 144;
            int r2   = rem - ic2*144;
            int q    = r2 >> 4, j = r2 & 15;
            int oc   = half*16 + j;
            c2wP[idx] = packh2(c2w[oc*288 + (2*ic2)*9 + q],
                               c2w[oc*288 + (2*ic2+1)*9 + q]);
        }
        // conv1 weights: pairs (dx0,dx1) + scalar dx2
        for (int idx = tid; idx < 288; idx += 256) {
            int oc = idx / 9, r = idx - oc*9;        // r = ic*3+dy
            c1wP01[idx] = packh2(c1w[oc*27 + r*3 + 0], c1w[oc*27 + r*3 + 1]);
            c1wP2[idx]  = c1w[oc*27 + r*3 + 2];
        }
        // twiddle
        for (int idx = tid; idx < 1024; idx += 256) {
            int w = idx >> 5, k = idx & 31;
            float sv, cv;
            sincosf(TWOPI_32 * (float)((w*k) & 31), &sv, &cv);
            twg[idx*2]     = cv;
            twg[idx*2 + 1] = -sv;
        }
    }
}

// ---------------- conv1 (dot2): [img][3][128][128] -> [img][32][64][64]
__global__ __launch_bounds__(256) void conv1_kernel(const float* __restrict__ in,
                                                    const unsigned int* __restrict__ w01,
                                                    const float* __restrict__ w2,
                                                    const float* __restrict__ bias,
                                                    float* __restrict__ out)
{
    const int strip = blockIdx.x;   // 4 strips of 16 output rows
    const int img   = blockIdx.y;
    const int tid   = threadIdx.x;
    // x-pair packed input: sIn2[ic][li][x2], x2 in 0..64 (cols 2x2,2x2+1), row stride 66
    __shared__ __align__(16) unsigned int sIn2[3*33*66];
    const int iy0 = strip * 32;
    for (int idx = tid; idx < 3*33*66; idx += 256) {
        int ic  = idx / (33*66);
        int rem = idx - ic*(33*66);
        int li  = rem / 66;
        int x2  = rem - li*66;
        int iy  = iy0 + li;
        unsigned int v = 0;
        if (iy < 128 && x2 < 64) {
            float2 p = *(const float2*)&in[(((size_t)img*3 + ic)*128 + iy)*128 + 2*x2];
            v = packh2(p.x, p.y);
        }
        sIn2[idx] = v;
    }
    __syncthreads();
    const int oy0 = strip*16;
    #pragma unroll
    for (int p = 0; p < 4; ++p) {
        int pos = p*256 + tid;       // 16 rows x 64 cols
        int ly = pos >> 6;
        int ox = pos & 63;
        unsigned int pa[9];
        float px[9];
        #pragma unroll
        for (int ic = 0; ic < 3; ++ic)
            #pragma unroll
            for (int dy = 0; dy < 3; ++dy) {
                int r = ic*3 + dy;
                int rowb = ic*(33*66) + (2*ly+dy)*66;
                pa[r] = sIn2[rowb + ox];
                unsigned int u = sIn2[rowb + ox + 1];
                px[r] = __half2float(((const __half2*)&u)->x);
            }
        for (int oc = 0; oc < 32; ++oc) {
            float acc = bias[oc];
            #pragma unroll
            for (int r = 0; r < 9; ++r) {
                acc = fdot2(w01[oc*9 + r], pa[r], acc);
                acc += w2[oc*9 + r] * px[r];
            }
            out[(((size_t)img*32 + oc)*64 + (oy0+ly))*64 + ox] = fmaxf(acc, 0.f);
        }
    }
}

// ---------------- conv2 (dot2): [img][32][64][64] -> [img][32][32][32]
__global__ __launch_bounds__(256) void conv2_kernel(const float* __restrict__ in,
                                                    const unsigned int* __restrict__ wP,
                                                    const float* __restrict__ bias,
                                                    float* __restrict__ out)
{
    const int strip = blockIdx.x;   // 8 strips of 4 output rows
    const int img   = blockIdx.y;
    const int tid   = threadIdx.x;
    // ic-pair packed input: sIn2[ic2][li][col], 16 x 9 x 66
    __shared__ __align__(16) unsigned int sIn2[16*9*66];
    const int iy0 = strip*8;
    for (int idx = tid; idx < 16*9*66; idx += 256) {
        int ic2 = idx / (9*66);
        int rem = idx - ic2*(9*66);
        int li  = rem / 66;
        int col = rem - li*66;
        int iy  = iy0 + li;
        unsigned int v = 0;
        if (iy < 64 && col < 64) {
            size_t base = (((size_t)img*32 + 2*ic2)*64 + iy)*64 + col;
            v = packh2(in[base], in[base + 4096]);
        }
        sIn2[idx] = v;
    }
    __syncthreads();
    const int posl = tid & 127;     // 4 rows x 32 cols
    const int half = tid >> 7;      // 2 halves of 16 out-channels
    const int ly = posl >> 5;
    const int ox = posl & 31;
    float acc[16];
    #pragma unroll
    for (int j = 0; j < 16; ++j) acc[j] = 0.f;
    for (int ic2 = 0; ic2 < 16; ++ic2) {
        unsigned int patch[9];
        #pragma unroll
        for (int dy = 0; dy < 3; ++dy)
            #pragma unroll
            for (int dx = 0; dx < 3; ++dx)
                patch[dy*3+dx] = sIn2[ic2*(9*66) + (2*ly+dy)*66 + 2*ox + dx];
        const unsigned int* wblk = wP + (half*16 + ic2)*144;
        #pragma unroll
        for (int j = 0; j < 16; ++j) {
            float a = acc[j];
            #pragma unroll
            for (int q = 0; q < 9; ++q)
                a = fdot2(wblk[q*16 + j], patch[q], a);
            acc[j] = a;
        }
    }
    const int oy = strip*4 + ly;
    #pragma unroll
    for (int j = 0; j < 16; ++j) {
        int oc = half*16 + j;
        out[(((size_t)img*32 + oc)*32 + oy)*32 + ox] = fmaxf(acc[j] + bias[oc], 0.f);
    }
}

// ---------------- prep2: xhalf-transpose + xmean (x-dependent, after convs)
__global__ __launch_bounds__(256) void prep2_kernel(
    const float* __restrict__ xf, __half* __restrict__ xh, float* __restrict__ xmean)
{
    const int tid = threadIdx.x;
    const int bt = blockIdx.x;
    __shared__ float sT[32][257];
    const float* src = xf + (size_t)bt*32768;
    __half* dst = xh + (size_t)bt*32768;
    for (int tt = 0; tt < 4; ++tt) {
        #pragma unroll
        for (int m = 0; m < 32; ++m)
            sT[m][tid] = src[m*1024 + tt*256 + tid];
        __syncthreads();
        uint4 o[4];
        unsigned int* ou = (unsigned int*)o;
        #pragma unroll
        for (int k = 0; k < 16; ++k)
            ou[k] = packh2(sT[2*k][tid], sT[2*k+1][tid]);
        uint4* dp = (uint4*)(dst + (size_t)(tt*256 + tid)*32);
        dp[0] = o[0]; dp[1] = o[1]; dp[2] = o[2]; dp[3] = o[3];
        __syncthreads();
    }
    const int m = tid >> 3, s8 = tid & 7;
    float sm = 0.f;
    #pragma unroll 16
    for (int k = 0; k < 128; ++k) sm += src[m*1024 + s8 + 8*k];
    sm += __shfl_down(sm, 4, 8); sm += __shfl_down(sm, 2, 8); sm += __shfl_down(sm, 1, 8);
    if (s8 == 0) xmean[bt*32 + m] = sm * (1.f/1024.f);
}

// ---------------- NTM scalar recurrence: one block per batch, 512 threads, dot2 GEMVs
__global__ __launch_bounds__(512, 2) void ntm_scal_kernel(
    const float* __restrict__ xfeat, const __half* __restrict__ xh,
    const float* __restrict__ xmean,
    const __half* __restrict__ whhP, const __half* __restrict__ whrxP,
    const __half* __restrict__ wkP, const __half* __restrict__ weP,
    const __half* __restrict__ waP,
    const float* __restrict__ bk, const float* __restrict__ Wbeta,
    const float* __restrict__ bbeta, const float* __restrict__ bh,
    const float* __restrict__ Wg,
    float* __restrict__ wbuf, float* __restrict__ eag, float* __restrict__ lnst)
{
    const int b    = blockIdx.x;
    const int tid  = threadIdx.x;
    const int lane = tid & 63;
    const int wid  = tid >> 6;

    __shared__ __align__(16) __half sWhh[65536];   // 128 KB
    __shared__ __align__(16) float sHbuf[2][256];  // h f32 (beta/g/rx uses)
    __shared__ __align__(16) __half sHh[2][256];   // h f16 (dot2 operand)
    __shared__ __align__(16) float sK[32];
    __shared__ __align__(16) float sXm[512];
    __shared__ float sRedC[256];
    __shared__ float sRedD[8];
    __shared__ float sRedL[16];
    __shared__ __align__(16) float sR32[32];
    __shared__ __align__(16) float sE[32];
    __shared__ __align__(16) float sA[32];
    __shared__ float sBk[32];
    __shared__ float sBh[256];

    {
        const uint4* src = (const uint4*)whhP;
        uint4* dst = (uint4*)sWhh;
        for (int i2 = tid; i2 < 8192; i2 += 512) dst[i2] = src[i2];
    }
    if (tid < 256) { sBh[tid] = bh[tid]; sHbuf[0][tid] = 0.f; sHh[0][tid] = __float2half(0.f); }
    if (tid < 32)  sBk[tid] = bk[tid];
    if (tid < 512) sXm[tid] = xmean[b*512 + tid];
    float4 wbeta4 = *(const float4*)&Wbeta[(size_t)lane*4];
    float4 wg4    = *(const float4*)&Wg[(size_t)lane*4];
    float bb = bbeta[0];

    const int n0 = 2*tid;
    float c0[32], c1[32];

    {
        const float* x0 = xfeat + (size_t)(b*16)*32768;
        float sum = 0.f, ss = 0.f;
        #pragma unroll
        for (int m = 0; m < 32; ++m) {
            float2 v = *(const float2*)&x0[m*1024 + n0];
            c0[m] = v.x; c1[m] = v.y;
            sum += v.x + v.y; ss += v.x*v.x + v.y*v.y;
        }
        #pragma unroll
        for (int d = 32; d > 0; d >>= 1) { sum += __shfl_xor(sum, d, 64); ss += __shfl_xor(ss, d, 64); }
        if (lane == 0) { sRedL[wid] = sum; sRedL[8+wid] = ss; }
        __syncthreads();
        float S = 0.f, SS = 0.f;
        #pragma unroll
        for (int i = 0; i < 8; ++i) { S += sRedL[i]; SS += sRedL[8+i]; }
        float mu = S * (1.f/32768.f);
        float var = SS * (1.f/32768.f) - mu*mu;
        float rs = rsqrtf(var + 1e-5f);
        if (tid == 0) { lnst[b*2] = mu; lnst[b*2+1] = rs; }
        #pragma unroll
        for (int m = 0; m < 32; ++m) { c0[m] = (c0[m]-mu)*rs; c1[m] = (c1[m]-mu)*rs; }
    }

    uint4 xb[8];
    {
        const uint4* xrow = (const uint4*)(xh + (size_t)(b*16)*32768) + 8*tid;
        #pragma unroll
        for (int i = 0; i < 8; ++i) xb[i] = xrow[i];
    }
    __syncthreads();

    float ex0 = 0.f, ex1 = 0.f, w0 = 0.f, w1 = 0.f;
    const int rm = ((lane&1)<<4)|((lane&2)<<2)|(lane&4)|((lane&8)>>2)|((lane&16)>>4); // rev5(lane&31)

    #pragma unroll 1
    for (int t = 0; t < 16; ++t) {
        const int cur = t & 1, nxt = cur ^ 1;
        const float* hold = &sHbuf[cur][0];
        float betav;

        // ---- P1
        {
            const int m = tid >> 4, j = tid & 15;
            const uint4* wkp = (const uint4*)(wkP + (size_t)(m*16 + j)*16);
            uint4 wk0 = wkp[0], wk1 = wkp[1];
            uint4 h0 = *(const uint4*)&sHh[cur][8*j];
            uint4 h1 = *(const uint4*)&sHh[cur][128 + 8*j];
            float s = 0.f;
            s = fdot2(wk0.x, h0.x, s); s = fdot2(wk0.y, h0.y, s);
            s = fdot2(wk0.z, h0.z, s); s = fdot2(wk0.w, h0.w, s);
            s = fdot2(wk1.x, h1.x, s); s = fdot2(wk1.y, h1.y, s);
            s = fdot2(wk1.z, h1.z, s); s = fdot2(wk1.w, h1.w, s);
            s += __shfl_down(s, 8, 16); s += __shfl_down(s, 4, 16);
            s += __shfl_down(s, 2, 16); s += __shfl_down(s, 1, 16);
            if (j == 0) sK[m] = tanhf(s + sBk[m]);
            float4 h4 = *(const float4*)&hold[lane*4];
            float p = wbeta4.x*h4.x + wbeta4.y*h4.y + wbeta4.z*h4.z + wbeta4.w*h4.w;
            #pragma unroll
            for (int d = 32; d > 0; d >>= 1) p += __shfl_xor(p, d, 64);
            float x = p + bb;
            betav = (x > 20.f) ? x : log1pf(expf(x));
        }
        __syncthreads();

        // ---- P2
        {
            float beta = betav;
            float dot0 = 0.f, dot1 = 0.f, cn20 = 0.f, cn21 = 0.f, kn2 = 0.f;
            #pragma unroll
            for (int q = 0; q < 8; ++q) {
                float4 k4 = *(const float4*)&sK[4*q];
                dot0 += c0[4*q]*k4.x + c0[4*q+1]*k4.y + c0[4*q+2]*k4.z + c0[4*q+3]*k4.w;
                dot1 += c1[4*q]*k4.x + c1[4*q+1]*k4.y + c1[4*q+2]*k4.z + c1[4*q+3]*k4.w;
                cn20 += c0[4*q]*c0[4*q] + c0[4*q+1]*c0[4*q+1] + c0[4*q+2]*c0[4*q+2] + c0[4*q+3]*c0[4*q+3];
                cn21 += c1[4*q]*c1[4*q] + c1[4*q+1]*c1[4*q+1] + c1[4*q+2]*c1[4*q+2] + c1[4*q+3]*c1[4*q+3];
                kn2  += k4.x*k4.x + k4.y*k4.y + k4.z*k4.z + k4.w*k4.w;
            }
            float kinv = 1.f / (sqrtf(kn2) + 1e-8f);
            float s0 = dot0 * kinv / (sqrtf(cn20) + 1e-8f);
            float s1 = dot1 * kinv / (sqrtf(cn21) + 1e-8f);
            ex0 = expf(beta * s0);
            ex1 = expf(beta * s1);
            float es = ex0 + ex1;
            #pragma unroll
            for (int d = 32; d > 0; d >>= 1) es += __shfl_xor(es, d, 64);
            if (lane == 0) sRedD[wid] = es;
            float v[32];
            #pragma unroll
            for (int m = 0; m < 32; ++m) v[m] = ex0*c0[m] + ex1*c1[m];
            #pragma unroll
            for (int i = 0; i < 16; ++i) { float sd = (lane&1)? v[i] : v[i+16]; float rc = __shfl_xor(sd, 1, 64); v[i] = ((lane&1)? v[i+16] : v[i]) + rc; }
            #pragma unroll
            for (int i = 0; i < 8; ++i)  { float sd = (lane&2)? v[i] : v[i+8];  float rc = __shfl_xor(sd, 2, 64); v[i] = ((lane&2)? v[i+8]  : v[i]) + rc; }
            #pragma unroll
            for (int i = 0; i < 4; ++i)  { float sd = (lane&4)? v[i] : v[i+4];  float rc = __shfl_xor(sd, 4, 64); v[i] = ((lane&4)? v[i+4]  : v[i]) + rc; }
            #pragma unroll
            for (int i = 0; i < 2; ++i)  { float sd = (lane&8)? v[i] : v[i+2];  float rc = __shfl_xor(sd, 8, 64); v[i] = ((lane&8)? v[i+2]  : v[i]) + rc; }
            { float sd = (lane&16)? v[0] : v[1]; float rc = __shfl_xor(sd, 16, 64); v[0] = ((lane&16)? v[1] : v[0]) + rc; }
            v[0] += __shfl_xor(v[0], 32, 64);
            if (lane < 32) sRedC[wid*32 + rm] = v[0];
        }
        __syncthreads();

        // ---- P3
        {
            float den = sRedD[0]+sRedD[1]+sRedD[2]+sRedD[3]+sRedD[4]+sRedD[5]+sRedD[6]+sRedD[7];
            float inv = 1.f / den;
            w0 = ex0 * inv; w1 = ex1 * inv;
            *(float2*)&wbuf[(size_t)(b*16 + t)*1024 + n0] = make_float2(w0, w1);
            if (lane < 32) {
                float r = 0.f;
                #pragma unroll
                for (int w = 0; w < 8; ++w) r += sRedC[w*32 + lane];
                sR32[lane] = r * inv;
            }
            const int i = tid >> 1, q = tid & 1;
            const uint4* wrp = (const uint4*)(whrxP + (size_t)i*64 + q*32);
            float s = 0.f;
            #pragma unroll
            for (int k = 0; k < 16; ++k) {
                uint4 wv = *(const uint4*)&sWhh[(size_t)(((q*16 + k)*256 + i))*8];
                uint4 hv = *(const uint4*)&sHh[cur][q*128 + k*8];
                s = fdot2(wv.x, hv.x, s); s = fdot2(wv.y, hv.y, s);
                s = fdot2(wv.z, hv.z, s); s = fdot2(wv.w, hv.w, s);
            }
            const float* rxsrc = q ? &sXm[t*32] : sR32;
            #pragma unroll
            for (int c4 = 0; c4 < 4; ++c4) {
                uint4 wvx = wrp[c4];
                float4 va = *(const float4*)&rxsrc[c4*8];
                float4 vb = *(const float4*)&rxsrc[c4*8 + 4];
                const __half2* w2 = (const __half2*)&wvx;
                float2 p0 = __half22float2(w2[0]); s += p0.x*va.x + p0.y*va.y;
                float2 p1 = __half22float2(w2[1]); s += p1.x*va.z + p1.y*va.w;
                float2 p2 = __half22float2(w2[2]); s += p2.x*vb.x + p2.y*vb.y;
                float2 p3 = __half22float2(w2[3]); s += p3.x*vb.z + p3.y*vb.w;
            }
            s += __shfl_down(s, 1, 2);
            if (q == 0) {
                float hn = tanhf(s + sBh[i]);
                sHbuf[nxt][i] = hn;
                sHh[nxt][i] = __float2half(hn);
            }
        }
        __syncthreads();

        // ---- P4a
        float gg;
        {
            const float* hnew = &sHbuf[nxt][0];
            const int m = tid >> 4, j = tid & 15;
            const uint4* wep = (const uint4*)(weP + (size_t)(m*16 + j)*16);
            const uint4* wap = (const uint4*)(waP + (size_t)(m*16 + j)*16);
            uint4 we0 = wep[0], we1 = wep[1];
            uint4 wa0 = wap[0], wa1 = wap[1];
            uint4 h0 = *(const uint4*)&sHh[nxt][8*j];
            uint4 h1 = *(const uint4*)&sHh[nxt][128 + 8*j];
            float se = 0.f, sa = 0.f;
            se = fdot2(we0.x, h0.x, se); se = fdot2(we0.y, h0.y, se);
            se = fdot2(we0.z, h0.z, se); se = fdot2(we0.w, h0.w, se);
            se = fdot2(we1.x, h1.x, se); se = fdot2(we1.y, h1.y, se);
            se = fdot2(we1.z, h1.z, se); se = fdot2(we1.w, h1.w, se);
            sa = fdot2(wa0.x, h0.x, sa); sa = fdot2(wa0.y, h0.y, sa);
            sa = fdot2(wa0.z, h0.z, sa); sa = fdot2(wa0.w, h0.w, sa);
            sa = fdot2(wa1.x, h1.x, sa); sa = fdot2(wa1.y, h1.y, sa);
            sa = fdot2(wa1.z, h1.z, sa); sa = fdot2(wa1.w, h1.w, sa);
            se += __shfl_down(se, 8, 16); sa += __shfl_down(sa, 8, 16);
            se += __shfl_down(se, 4, 16); sa += __shfl_down(sa, 4, 16);
            se += __shfl_down(se, 2, 16); sa += __shfl_down(sa, 2, 16);
            se += __shfl_down(se, 1, 16); sa += __shfl_down(sa, 1, 16);
            if (j == 0) {
                float e = 1.f/(1.f + expf(-se));
                float a = tanhf(sa);
                sE[m] = e; sA[m] = a;
                eag[(size_t)(b*16 + t)*80 + m]      = e;
                eag[(size_t)(b*16 + t)*80 + 32 + m] = a;
            }
            float4 h4 = *(const float4*)&hnew[lane*4];
            float p = wg4.x*h4.x + wg4.y*h4.y + wg4.z*h4.z + wg4.w*h4.w;
            #pragma unroll
            for (int d = 32; d > 0; d >>= 1) p += __shfl_xor(p, d, 64);
            gg = 1.f/(1.f + expf(-p));
            if (tid == 0) eag[(size_t)(b*16 + t)*80 + 64] = gg;
        }
        __syncthreads();

        // ---- P4b
        {
            float omg = 1.f - gg;
            const __half* xp = (const __half*)xb;
            #pragma unroll
            for (int q = 0; q < 8; ++q) {
                float4 e4 = *(const float4*)&sE[4*q];
                float4 a4 = *(const float4*)&sA[4*q];
                #pragma unroll
                for (int r = 0; r < 4; ++r) {
                    int m = 4*q + r;
                    float e = (r==0)?e4.x:(r==1)?e4.y:(r==2)?e4.z:e4.w;
                    float a = (r==0)?a4.x:(r==1)?a4.y:(r==2)?a4.z:a4.w;
                    float x0v = __half2float(xp[m]);
                    float x1v = __half2float(xp[32 + m]);
                    c0[m] = omg*(c0[m]*(1.f - w0*e) + w0*a) + gg*x0v;
                    c1[m] = omg*(c1[m]*(1.f - w1*e) + w1*a) + gg*x1v;
                }
            }
            if (t < 15) {
                const uint4* xrow = (const uint4*)(xh + (size_t)(b*16 + t + 1)*32768) + 8*tid;
                #pragma unroll
                for (int i = 0; i < 8; ++i) xb[i] = xrow[i];
            }
        }
    }
}

// ---------------- replay: reconstruct cseq from scalars, fully parallel
__global__ __launch_bounds__(256) void ntm_replay_kernel(
    const float* __restrict__ xfeat, const float* __restrict__ wbuf,
    const float* __restrict__ eag, const float* __restrict__ lnst,
    float* __restrict__ cseq)
{
    const int slab = blockIdx.x;    // 16 slabs of 64 n
    const int b    = blockIdx.y;    // 8
    const int tid  = threadIdx.x;
    const int m    = tid >> 3;      // 32
    const int ns   = tid & 7;       // 8 subgroups of 8 n
    const int n0   = slab*64 + ns*8;
    const float mu = lnst[b*2], rs = lnst[b*2+1];

    float c[8];
    {
        const float* x0 = xfeat + (size_t)(b*16)*32768 + m*1024 + n0;
        float4 a = *(const float4*)x0;
        float4 bv = *(const float4*)(x0 + 4);
        c[0]=(a.x-mu)*rs; c[1]=(a.y-mu)*rs; c[2]=(a.z-mu)*rs; c[3]=(a.w-mu)*rs;
        c[4]=(bv.x-mu)*rs; c[5]=(bv.y-mu)*rs; c[6]=(bv.z-mu)*rs; c[7]=(bv.w-mu)*rs;
    }
    for (int t = 0; t < 16; ++t) {
        const size_t bt = (size_t)(b*16 + t);
        const float* wp = &wbuf[bt*1024 + n0];
        float4 wA = *(const float4*)wp;
        float4 wB = *(const float4*)(wp + 4);
        float e = eag[bt*80 + m];
        float a = eag[bt*80 + 32 + m];
        float g = eag[bt*80 + 64];
        float omg = 1.f - g;
        const float* xp = &xfeat[bt*32768 + m*1024 + n0];
        float4 xA = *(const float4*)xp;
        float4 xB = *(const float4*)(xp + 4);
        c[0] = omg*(c[0]*(1.f - wA.x*e) + wA.x*a) + g*xA.x;
        c[1] = omg*(c[1]*(1.f - wA.y*e) + wA.y*a) + g*xA.y;
        c[2] = omg*(c[2]*(1.f - wA.z*e) + wA.z*a) + g*xA.z;
        c[3] = omg*(c[3]*(1.f - wA.w*e) + wA.w*a) + g*xA.w;
        c[4] = omg*(c[4]*(1.f - wB.x*e) + wB.x*a) + g*xB.x;
        c[5] = omg*(c[5]*(1.f - wB.y*e) + wB.y*a) + g*xB.y;
        c[6] = omg*(c[6]*(1.f - wB.z*e) + wB.z*a) + g*xB.z;
        c[7] = omg*(c[7]*(1.f - wB.w*e) + wB.w*a) + g*xB.w;
        float* op = &cseq[bt*32768 + m*1024 + n0];
        *(float4*)op       = make_float4(c[0], c[1], c[2], c[3]);
        *(float4*)(op + 4) = make_float4(c[4], c[5], c[6], c[7]);
    }
}

// ---------------- rfft2: table-driven DFT, both inputs in ONE dispatch
__global__ __launch_bounds__(256) void fft_fwd_kernel(const float* __restrict__ srcA,
                                                      const float* __restrict__ srcB,
                                                      const float* __restrict__ cosw,
                                                      const float* __restrict__ twg,
                                                      float* __restrict__ dstA,
                                                      float* __restrict__ dstB)
{
    const int img = blockIdx.x;
    const int tid = threadIdx.x;
    const float* src; float* dst;
    if (img < 4096) { src = srcA + (size_t)img*1024;        dst = dstA + (size_t)img*1088; }
    else            { src = srcB + (size_t)(img-4096)*1024; dst = dstB + (size_t)(img-4096)*1088; }

    __shared__ __align__(16) float sY[32*36];
    __shared__ __align__(16) float sT[2048];
    __shared__ __align__(16) float sR[2048];

    {
        const float4* s4 = (const float4*)twg;
        float4* d4 = (float4*)sT;
        d4[tid]       = s4[tid];
        d4[256 + tid] = s4[256 + tid];
    }
    {
        float4 v = *(const float4*)&src[tid*4];
        float4 c = *(const float4*)&cosw[tid*4];
        *(float4*)&sY[(tid>>3)*36 + (tid&7)*4] = make_float4(v.x*c.x, v.y*c.y, v.z*c.z, v.w*c.w);
    }
    __syncthreads();

    const int hj = tid >> 3;
    const int k0 = (tid & 7) * 4;

    float r0=0.f,i0=0.f,r1=0.f,i1=0.f,r2=0.f,i2=0.f,r3=0.f,i3=0.f;
    #pragma unroll
    for (int w = 0; w < 32; ++w) {
        float y = sY[hj*36 + w];
        float4 ta = *(const float4*)&sT[(w*32 + k0)*2];
        float4 tb = *(const float4*)&sT[(w*32 + k0)*2 + 4];
        r0 += y*ta.x; i0 += y*ta.y;
        r1 += y*ta.z; i1 += y*ta.w;
        r2 += y*tb.x; i2 += y*tb.y;
        r3 += y*tb.z; i3 += y*tb.w;
    }
    *(float4*)&sR[(hj*32 + k0)*2]     = make_float4(r0,i0,r1,i1);
    *(float4*)&sR[(hj*32 + k0)*2 + 4] = make_float4(r2,i2,r3,i3);
    __syncthreads();

    float fr0=0.f,fi0=0.f,fr1=0.f,fi1=0.f,fr2=0.f,fi2=0.f,fr3=0.f,fi3=0.f;
    #pragma unroll
    for (int h = 0; h < 32; ++h) {
        float2 wj = *(const float2*)&sT[(h*32 + hj)*2];
        float4 Ra = *(const float4*)&sR[(h*32 + k0)*2];
        float4 Rb = *(const float4*)&sR[(h*32 + k0)*2 + 4];
        fr0 += Ra.x*wj.x - Ra.y*wj.y;  fi0 += Ra.x*wj.y + Ra.y*wj.x;
        fr1 += Ra.z*wj.x - Ra.w*wj.y;  fi1 += Ra.z*wj.y + Ra.w*wj.x;
        fr2 += Rb.x*wj.x - Rb.y*wj.y;  fi2 += Rb.x*wj.y + Rb.y*wj.x;
        fr3 += Rb.z*wj.x - Rb.w*wj.y;  fi3 += Rb.z*wj.y + Rb.w*wj.x;
    }
    float* dp = dst + (size_t)(hj*17 + k0)*2;
    if (k0 < 16) {
        *(float2*)&dp[0] = make_float2(fr0, fi0);
        *(float2*)&dp[2] = make_float2(fr1, fi1);
        *(float2*)&dp[4] = make_float2(fr2, fi2);
        *(float2*)&dp[6] = make_float2(fr3, fi3);
    } else if (k0 == 16) {
        *(float2*)&dp[0] = make_float2(fr0, fi0);
    }
}

// ---------------- fused combine + irfft2; one block per bt
__global__ __launch_bounds__(256) void comb_ifft_kernel(const float* __restrict__ cfft,
                                                        const float* __restrict__ zfft,
                                                        const float* __restrict__ yf,
                                                        float* __restrict__ out)
{
    const int bt  = blockIdx.x;
    const int tid = threadIdx.x;
    __shared__ float sG[544*2];
    __shared__ float sS[544*2];
    __shared__ float ct[32], st[32];
    if (tid < 32) {
        float sv, cv;
        sincosf(TWOPI_32 * (float)tid, &sv, &cv);
        ct[tid] = cv; st[tid] = sv;
    }
    for (int idx = tid; idx < 544; idx += 256) {
        float kzz = 0.f, kxr = 0.f, kxi = 0.f;
        #pragma unroll 4
        for (int m = 0; m < 32; ++m) {
            size_t base = ((size_t)(bt*32 + m)*1088) + idx*2;
            float2 c = *(const float2*)&cfft[base];
            float2 z = *(const float2*)&zfft[base];
            kzz += c.x*c.x + c.y*c.y;
            kxr += z.x*c.x + z.y*c.y;
            kxi += z.y*c.x - z.x*c.y;
        }
        float den = 1.f / (kzz + 1e-4f);
        float2 y = *(const float2*)&yf[idx*2];
        float ar = y.x*den, ai = y.y*den;
        sG[idx*2]     = kxr*ar - kxi*ai;
        sG[idx*2 + 1] = kxr*ai + kxi*ar;
    }
    __syncthreads();
    for (int idx = tid; idx < 544; idx += 256) {
        int h = idx / 17;
        int k = idx - h*17;
        float re = 0.f, im = 0.f;
        #pragma unroll
        for (int j = 0; j < 32; ++j) {
            float gr = sG[(j*17+k)*2], gi = sG[(j*17+k)*2+1];
            int a = (h*j) & 31;
            float c = ct[a], s = st[a];
            re += gr*c - gi*s;
            im += gr*s + gi*c;
        }
        sS[(h*17+k)*2] = re; sS[(h*17+k)*2+1] = im;
    }
    __syncthreads();
    #pragma unroll
    for (int p = 0; p < 4; ++p) {
        int pos = p*256 + tid;
        int h = pos >> 5, wq = pos & 31;
        float acc = sS[(h*17)*2];
        #pragma unroll
        for (int k = 1; k < 16; ++k) {
            int a = (wq*k) & 31;
            acc += 2.f*(sS[(h*17+k)*2]*ct[a] - sS[(h*17+k)*2+1]*st[a]);
        }
        acc += sS[(h*17+16)*2] * ((wq & 1) ? -1.f : 1.f);
        out[(size_t)bt*1024 + pos] = acc * (1.f/1024.f);
    }
}

extern "C" void kernel_launch(void* const* d_in, const int* in_sizes, int n_in,
                              void* d_out, int out_size, void* d_ws, size_t ws_size,
                              hipStream_t stream)
{
    const float* x_i   = (const float*)d_in[0];
    const float* z_i   = (const float*)d_in[1];
    const float* c1w   = (const float*)d_in[2];
    const float* c1b   = (const float*)d_in[3];
    const float* c2w   = (const float*)d_in[4];
    const float* c2b   = (const float*)d_in[5];
    const float* Wk    = (const float*)d_in[6];
    const float* bk    = (const float*)d_in[7];
    const float* Wbeta = (const float*)d_in[8];
    const float* bbeta = (const float*)d_in[9];
    const float* Wh    = (const float*)d_in[10];
    const float* bh    = (const float*)d_in[11];
    const float* We    = (const float*)d_in[12];
    const float* Wa    = (const float*)d_in[13];
    const float* Wg    = (const float*)d_in[14];
    const float* cosw  = (const float*)d_in[15];
    const float* yf    = (const float*)d_in[16];
    float* out = (float*)d_out;
    float* ws  = (float*)d_ws;

    // workspace layout (floats)
    // buf1 spans [0, 16,777,216): anything written BEFORE the convs must live above that.
    float*  buf1  = ws;                 // conv1 out (16,777,216 f); reused after convs
    float*  xfeat = ws + 16777216;      // 4,194,304
    float*  zfeat = ws + 20971520;      // 4,194,304
    float*  cseq  = ws + 25165824;      // 4,194,304 (ends 29,360,128)
    float*  xmb   = ws + 29499392;      // 4,096
    // regions inside buf1, valid only AFTER conv stage completes:
    float*  cfft  = buf1;               // 4,456,448 f
    float*  zfft  = buf1 + 4456448;     // 4,456,448 f (ends 8,912,896)
    __half* xhb   = (__half*)(ws + 9000000);    // 4,194,304 halfs (written post-conv by prep2)
    float*  wbuf  = ws + 11100000;      // 131,072 f (written post-conv by ntm)
    float*  eag   = ws + 11240000;      // 10,240 f
    float*  lnstp = ws + 11251000;      // 16 f
    // prepack outputs: OUTSIDE buf1, in the dead gap after cseq [29,360,128 .. 29,499,392)
    __half* whhP  = (__half*)(ws + 29360128);   // 65,536 halfs -> ends f 29,392,896
    __half* whrxP = (__half*)(ws + 29392896);   // 16,384 halfs -> ends f 29,401,088
    __half* wkP   = (__half*)(ws + 29401088);   // 8,192 halfs  -> ends f 29,405,184
    __half* weP   = (__half*)(ws + 29405184);   // 8,192 halfs  -> ends f 29,409,280
    __half* waP   = (__half*)(ws + 29409280);   // 8,192 halfs  -> ends f 29,413,376
    float*  twg   = ws + 29413376;      // 2,048 f -> ends 29,415,424
    unsigned int* c2wP   = (unsigned int*)(ws + 29415424);  // 4,608 u32 -> ends 29,420,032
    unsigned int* c1wP01 = (unsigned int*)(ws + 29420032);  // 288 u32
    float*  c1wP2 = ws + 29420320;      // 288 f -> ends 29,420,608 (< 29,499,392 OK)

    dim3 b256(256);
    prepack_kernel<<<33, b256, 0, stream>>>(Wh, Wk, We, Wa, c1w, c2w,
                                            whhP, whrxP, wkP, weP, waP, twg,
                                            c2wP, c1wP01, c1wP2);
    conv1_kernel<<<dim3(4,128), b256, 0, stream>>>(x_i, c1wP01, c1wP2, c1b, buf1);
    conv2_kernel<<<dim3(8,128), b256, 0, stream>>>(buf1, c2wP, c2b, xfeat);
    conv1_kernel<<<dim3(4,128), b256, 0, stream>>>(z_i, c1wP01, c1wP2, c1b, buf1);
    conv2_kernel<<<dim3(8,128), b256, 0, stream>>>(buf1, c2wP, c2b, zfeat);
    prep2_kernel<<<128, b256, 0, stream>>>(xfeat, xhb, xmb);
    ntm_scal_kernel<<<8, 512, 0, stream>>>(xfeat, xhb, xmb, whhP, whrxP, wkP, weP, waP,
                                           bk, Wbeta, bbeta, bh, Wg, wbuf, eag, lnstp);
    ntm_replay_kernel<<<dim3(16,8), b256, 0, stream>>>(xfeat, wbuf, eag, lnstp, cseq);
    fft_fwd_kernel<<<8192, b256, 0, stream>>>(cseq, zfeat, cosw, twg, cfft, zfft);
    comb_ifft_kernel<<<128, b256, 0, stream>>>(cfft, zfft, yf, out);
}

// Round 9
// 628.504 us; speedup vs baseline: 1.4310x; 1.0137x over previous
//
#include <hip/hip_runtime.h>
#include <hip/hip_fp16.h>
#include <math.h>

// Problem constants
// B=8, T=16, IMG=128, CF=32, WO=HO=32, N=1024, M=32, DH=256
// conv SAME stride2: pad_lo=0, pad_hi=1  ->  in_idx = 2*out + k

#define TWOPI_32 0.19634954084936207f  // 2*pi/32

typedef _Float16 __h2 __attribute__((ext_vector_type(2)));
__device__ __forceinline__ float fdot2(unsigned int w, unsigned int h, float acc) {
    union { unsigned int u; __h2 v; } a, b;
    a.u = w; b.u = h;
    return __builtin_amdgcn_fdot2(a.v, b.v, acc, false);
}
__device__ __forceinline__ unsigned int packh2(float a, float b) {
    __half2 h2 = __floats2half2_rn(a, b);
    return *(unsigned int*)&h2;
}

// ---------------- prepack: all weight packs + twiddle (input-independent, runs first)
// NOTE: outputs MUST live outside buf1's range — conv1 overwrites it.
__global__ __launch_bounds__(256) void prepack_kernel(
    const float* __restrict__ Wh, const float* __restrict__ Wk,
    const float* __restrict__ We, const float* __restrict__ Wa,
    const float* __restrict__ c1w, const float* __restrict__ c2w,
    __half* __restrict__ whhP, __half* __restrict__ whrxP,
    __half* __restrict__ wkP, __half* __restrict__ weP, __half* __restrict__ waP,
    float* __restrict__ twg,
    unsigned int* __restrict__ c2wP, unsigned int* __restrict__ c1wP01,
    float* __restrict__ c1wP2)
{
    const int tid = threadIdx.x;
    if (blockIdx.x < 32) {
        const int base = blockIdx.x*256 + tid;   // 0..8191
        #pragma unroll
        for (int r = 0; r < 8; ++r) {
            int idx = base*8 + r;
            int e = idx & 7, i = (idx >> 3) & 255, c = idx >> 11;
            int q = c >> 4, k = c & 15;
            whhP[idx] = __float2half(Wh[i*320 + q*128 + k*8 + e]);
        }
        #pragma unroll
        for (int r = 0; r < 2; ++r) {
            int idx = base*2 + r;
            int i = idx >> 6, s2 = idx & 63;
            whrxP[idx] = __float2half(Wh[i*320 + 256 + s2]);
        }
        {
            int idx = base;
            int m = idx >> 8, j = (idx >> 4) & 15, e = idx & 15;
            int col = (e < 8) ? (8*j + e) : (128 + 8*j + (e - 8));
            wkP[idx] = __float2half(Wk[m*256 + col]);
            weP[idx] = __float2half(We[m*256 + col]);
            waP[idx] = __float2half(Wa[m*256 + col]);
        }
    } else {
        // conv2 weights: c2wP[half][ic2][q][j] = (w[oc][2ic2][q], w[oc][2ic2+1][q]), oc=half*16+j
        for (int idx = tid; idx < 4608; idx += 256) {
            int half = idx / 2304;
            int rem  = idx - half*2304;
            int ic2  = rem / 144;
            int r2   = rem - ic2*144;
            int q    = r2 >> 4, j = r2 & 15;
            int oc   = half*16 + j;
            c2wP[idx] = packh2(c2w[oc*288 + (2*ic2)*9 + q],
                               c2w[oc*288 + (2*ic2+1)*9 + q]);
        }
        // conv1 weights: pairs (dx0,dx1) + scalar dx2
        for (int idx = tid; idx < 288; idx += 256) {
            int oc = idx / 9, r = idx - oc*9;        // r = ic*3+dy
            c1wP01[idx] = packh2(c1w[oc*27 + r*3 + 0], c1w[oc*27 + r*3 + 1]);
            c1wP2[idx]  = c1w[oc*27 + r*3 + 2];
        }
        // twiddle
        for (int idx = tid; idx < 1024; idx += 256) {
            int w = idx >> 5, k = idx & 31;
            float sv, cv;
            sincosf(TWOPI_32 * (float)((w*k) & 31), &sv, &cv);
            twg[idx*2]     = cv;
            twg[idx*2 + 1] = -sv;
        }
    }
}

// ---------------- conv1 (dot2): [img][3][128][128] -> packed u32 [img][16 oc2][64][64]
__global__ __launch_bounds__(256) void conv1_kernel(const float* __restrict__ in,
                                                    const unsigned int* __restrict__ w01,
                                                    const float* __restrict__ w2,
                                                    const float* __restrict__ bias,
                                                    unsigned int* __restrict__ out)
{
    const int strip = blockIdx.x;   // 4 strips of 16 output rows
    const int img   = blockIdx.y;
    const int tid   = threadIdx.x;
    // x-pair packed input: sIn2[ic][li][x2], x2 in 0..64 (cols 2x2,2x2+1), row stride 66
    __shared__ __align__(16) unsigned int sIn2[3*33*66];
    const int iy0 = strip * 32;
    for (int idx = tid; idx < 3*33*66; idx += 256) {
        int ic  = idx / (33*66);
        int rem = idx - ic*(33*66);
        int li  = rem / 66;
        int x2  = rem - li*66;
        int iy  = iy0 + li;
        unsigned int v = 0;
        if (iy < 128 && x2 < 64) {
            float2 p = *(const float2*)&in[(((size_t)img*3 + ic)*128 + iy)*128 + 2*x2];
            v = packh2(p.x, p.y);
        }
        sIn2[idx] = v;
    }
    __syncthreads();
    const int oy0 = strip*16;
    #pragma unroll
    for (int p = 0; p < 4; ++p) {
        int pos = p*256 + tid;       // 16 rows x 64 cols
        int ly = pos >> 6;
        int ox = pos & 63;
        unsigned int pa[9];
        float px[9];
        #pragma unroll
        for (int ic = 0; ic < 3; ++ic)
            #pragma unroll
            for (int dy = 0; dy < 3; ++dy) {
                int r = ic*3 + dy;
                int rowb = ic*(33*66) + (2*ly+dy)*66;
                pa[r] = sIn2[rowb + ox];
                unsigned int u = sIn2[rowb + ox + 1];
                px[r] = __half2float(((const __half2*)&u)->x);
            }
        for (int oc2 = 0; oc2 < 16; ++oc2) {
            const int oca = 2*oc2, ocb = 2*oc2 + 1;
            float acca = bias[oca], accb = bias[ocb];
            #pragma unroll
            for (int r = 0; r < 9; ++r) {
                acca = fdot2(w01[oca*9 + r], pa[r], acca);
                acca += w2[oca*9 + r] * px[r];
                accb = fdot2(w01[ocb*9 + r], pa[r], accb);
                accb += w2[ocb*9 + r] * px[r];
            }
            out[(((size_t)img*16 + oc2)*64 + (oy0+ly))*64 + ox] =
                packh2(fmaxf(acca, 0.f), fmaxf(accb, 0.f));
        }
    }
}

// ---------------- conv2 (dot2): packed u32 in [img][16 ic2][64][64] -> [img][32][32][32]
__global__ __launch_bounds__(256) void conv2_kernel(const unsigned int* __restrict__ in,
                                                    const unsigned int* __restrict__ wP,
                                                    const float* __restrict__ bias,
                                                    float* __restrict__ out)
{
    const int strip = blockIdx.x;   // 8 strips of 4 output rows
    const int img   = blockIdx.y;
    const int tid   = threadIdx.x;
    // ic-pair packed input: sIn2[ic2][li][col], 16 x 9 x 66
    __shared__ __align__(16) unsigned int sIn2[16*9*66];
    const int iy0 = strip*8;
    for (int idx = tid; idx < 16*9*66; idx += 256) {
        int ic2 = idx / (9*66);
        int rem = idx - ic2*(9*66);
        int li  = rem / 66;
        int col = rem - li*66;
        int iy  = iy0 + li;
        unsigned int v = 0;
        if (iy < 64 && col < 64)
            v = in[(((size_t)img*16 + ic2)*64 + iy)*64 + col];
        sIn2[idx] = v;
    }
    __syncthreads();
    const int posl = tid & 127;     // 4 rows x 32 cols
    const int half = tid >> 7;      // 2 halves of 16 out-channels
    const int ly = posl >> 5;
    const int ox = posl & 31;
    float acc[16];
    #pragma unroll
    for (int j = 0; j < 16; ++j) acc[j] = 0.f;
    for (int ic2 = 0; ic2 < 16; ++ic2) {
        unsigned int patch[9];
        #pragma unroll
        for (int dy = 0; dy < 3; ++dy)
            #pragma unroll
            for (int dx = 0; dx < 3; ++dx)
                patch[dy*3+dx] = sIn2[ic2*(9*66) + (2*ly+dy)*66 + 2*ox + dx];
        const unsigned int* wblk = wP + (half*16 + ic2)*144;
        #pragma unroll
        for (int j = 0; j < 16; ++j) {
            float a = acc[j];
            #pragma unroll
            for (int q = 0; q < 9; ++q)
                a = fdot2(wblk[q*16 + j], patch[q], a);
            acc[j] = a;
        }
    }
    const int oy = strip*4 + ly;
    #pragma unroll
    for (int j = 0; j < 16; ++j) {
        int oc = half*16 + j;
        out[(((size_t)img*32 + oc)*32 + oy)*32 + ox] = fmaxf(acc[j] + bias[oc], 0.f);
    }
}

// ---------------- prep2: xhalf-transpose + xmean (x-dependent, after convs)
__global__ __launch_bounds__(256) void prep2_kernel(
    const float* __restrict__ xf, __half* __restrict__ xh, float* __restrict__ xmean)
{
    const int tid = threadIdx.x;
    const int bt = blockIdx.x;
    __shared__ float sT[32][257];
    const float* src = xf + (size_t)bt*32768;
    __half* dst = xh + (size_t)bt*32768;
    for (int tt = 0; tt < 4; ++tt) {
        #pragma unroll
        for (int m = 0; m < 32; ++m)
            sT[m][tid] = src[m*1024 + tt*256 + tid];
        __syncthreads();
        uint4 o[4];
        unsigned int* ou = (unsigned int*)o;
        #pragma unroll
        for (int k = 0; k < 16; ++k)
            ou[k] = packh2(sT[2*k][tid], sT[2*k+1][tid]);
        uint4* dp = (uint4*)(dst + (size_t)(tt*256 + tid)*32);
        dp[0] = o[0]; dp[1] = o[1]; dp[2] = o[2]; dp[3] = o[3];
        __syncthreads();
    }
    const int m = tid >> 3, s8 = tid & 7;
    float sm = 0.f;
    #pragma unroll 16
    for (int k = 0; k < 128; ++k) sm += src[m*1024 + s8 + 8*k];
    sm += __shfl_down(sm, 4, 8); sm += __shfl_down(sm, 2, 8); sm += __shfl_down(sm, 1, 8);
    if (s8 == 0) xmean[bt*32 + m] = sm * (1.f/1024.f);
}

// ---------------- NTM scalar recurrence v3: 3 barriers/step, register-resident weights
__global__ __launch_bounds__(512, 2) void ntm_scal_kernel(
    const float* __restrict__ xfeat, const __half* __restrict__ xh,
    const float* __restrict__ xmean,
    const __half* __restrict__ whhP, const __half* __restrict__ whrxP,
    const __half* __restrict__ wkP, const __half* __restrict__ weP,
    const __half* __restrict__ waP,
    const float* __restrict__ bk, const float* __restrict__ Wbeta,
    const float* __restrict__ bbeta, const float* __restrict__ bh,
    const float* __restrict__ Wg,
    float* __restrict__ wbuf, float* __restrict__ eag, float* __restrict__ lnst)
{
    const int b    = blockIdx.x;
    const int tid  = threadIdx.x;
    const int lane = tid & 63;
    const int wid  = tid >> 6;

    __shared__ __align__(16) __half sWhh[65536];   // 128 KB
    __shared__ __align__(16) float sHbuf[2][256];  // h f32 (g/beta dots)
    __shared__ __align__(16) __half sHh[2][256];   // h f16 (dot2 operand)
    __shared__ __align__(16) float sK[32];
    __shared__ __align__(16) float sXm[512];
    __shared__ float sRedC[256];
    __shared__ float sRedD[8];
    __shared__ float sRedL[16];
    __shared__ __align__(16) float sR32[32];
    __shared__ __align__(16) float sE[32];
    __shared__ __align__(16) float sA[32];
    __shared__ float sBk[32];
    __shared__ float sBh[256];

    {
        const uint4* src = (const uint4*)whhP;
        uint4* dst = (uint4*)sWhh;
        for (int i2 = tid; i2 < 8192; i2 += 512) dst[i2] = src[i2];
    }
    if (tid < 256) { sBh[tid] = bh[tid]; sHbuf[0][tid] = 0.f; sHh[0][tid] = __float2half(0.f); }
    if (tid < 32)  { sBk[tid] = bk[tid]; sK[tid] = tanhf(bk[tid]); }   // k(0): h=0
    if (tid < 512) sXm[tid] = xmean[b*512 + tid];
    float4 wbeta4 = *(const float4*)&Wbeta[(size_t)lane*4];
    float4 wg4    = *(const float4*)&Wg[(size_t)lane*4];
    float bb = bbeta[0];

    // ---- step-invariant weight registers
    const int mg = tid >> 4, jg = tid & 15;      // PH_C groups
    uint4 wk0, wk1, we0, we1, wa0, wa1;
    {
        const uint4* p;
        p = (const uint4*)(wkP + (size_t)(mg*16 + jg)*16); wk0 = p[0]; wk1 = p[1];
        p = (const uint4*)(weP + (size_t)(mg*16 + jg)*16); we0 = p[0]; we1 = p[1];
        p = (const uint4*)(waP + (size_t)(mg*16 + jg)*16); wa0 = p[0]; wa1 = p[1];
    }
    const int iD = tid >> 1, qD = tid & 1;       // PH_B mapping
    uint4 wrx0, wrx1, wrx2, wrx3;
    {
        const uint4* p = (const uint4*)(whrxP + (size_t)iD*64 + qD*32);
        wrx0 = p[0]; wrx1 = p[1]; wrx2 = p[2]; wrx3 = p[3];
    }

    const int n0 = 2*tid;
    float c0[32], c1[32];

    // ---- init: c = layernorm(x0); publish stats for replay
    {
        const float* x0 = xfeat + (size_t)(b*16)*32768;
        float sum = 0.f, ss = 0.f;
        #pragma unroll
        for (int m = 0; m < 32; ++m) {
            float2 v = *(const float2*)&x0[m*1024 + n0];
            c0[m] = v.x; c1[m] = v.y;
            sum += v.x + v.y; ss += v.x*v.x + v.y*v.y;
        }
        #pragma unroll
        for (int d = 32; d > 0; d >>= 1) { sum += __shfl_xor(sum, d, 64); ss += __shfl_xor(ss, d, 64); }
        if (lane == 0) { sRedL[wid] = sum; sRedL[8+wid] = ss; }
        __syncthreads();
        float S = 0.f, SS = 0.f;
        #pragma unroll
        for (int i = 0; i < 8; ++i) { S += sRedL[i]; SS += sRedL[8+i]; }
        float mu = S * (1.f/32768.f);
        float var = SS * (1.f/32768.f) - mu*mu;
        float rs = rsqrtf(var + 1e-5f);
        if (tid == 0) { lnst[b*2] = mu; lnst[b*2+1] = rs; }
        #pragma unroll
        for (int m = 0; m < 32; ++m) { c0[m] = (c0[m]-mu)*rs; c1[m] = (c1[m]-mu)*rs; }
    }

    uint4 xb[8];
    {
        const uint4* xrow = (const uint4*)(xh + (size_t)(b*16)*32768) + 8*tid;
        #pragma unroll
        for (int i = 0; i < 8; ++i) xb[i] = xrow[i];
    }
    __syncthreads();

    float betav = (bb > 20.f) ? bb : log1pf(expf(bb));   // beta(0): h=0
    float ex0 = 0.f, ex1 = 0.f, w0 = 0.f, w1 = 0.f;
    const int rm = ((lane&1)<<4)|((lane&2)<<2)|(lane&4)|((lane&8)>>2)|((lane&16)>>4); // rev5(lane&31)

    #pragma unroll 1
    for (int t = 0; t < 16; ++t) {
        const int cur = t & 1, nxt = cur ^ 1;

        // ---- PH_A: cosine sims, exp weights, denom partials, r partials
        {
            float beta = betav;
            float dot0 = 0.f, dot1 = 0.f, cn20 = 0.f, cn21 = 0.f, kn2 = 0.f;
            #pragma unroll
            for (int q = 0; q < 8; ++q) {
                float4 k4 = *(const float4*)&sK[4*q];
                dot0 += c0[4*q]*k4.x + c0[4*q+1]*k4.y + c0[4*q+2]*k4.z + c0[4*q+3]*k4.w;
                dot1 += c1[4*q]*k4.x + c1[4*q+1]*k4.y + c1[4*q+2]*k4.z + c1[4*q+3]*k4.w;
                cn20 += c0[4*q]*c0[4*q] + c0[4*q+1]*c0[4*q+1] + c0[4*q+2]*c0[4*q+2] + c0[4*q+3]*c0[4*q+3];
                cn21 += c1[4*q]*c1[4*q] + c1[4*q+1]*c1[4*q+1] + c1[4*q+2]*c1[4*q+2] + c1[4*q+3]*c1[4*q+3];
                kn2  += k4.x*k4.x + k4.y*k4.y + k4.z*k4.z + k4.w*k4.w;
            }
            float kinv = 1.f / (sqrtf(kn2) + 1e-8f);
            float s0 = dot0 * kinv / (sqrtf(cn20) + 1e-8f);
            float s1 = dot1 * kinv / (sqrtf(cn21) + 1e-8f);
            ex0 = expf(beta * s0);
            ex1 = expf(beta * s1);
            float es = ex0 + ex1;
            #pragma unroll
            for (int d = 32; d > 0; d >>= 1) es += __shfl_xor(es, d, 64);
            if (lane == 0) sRedD[wid] = es;
            float v[32];
            #pragma unroll
            for (int m = 0; m < 32; ++m) v[m] = ex0*c0[m] + ex1*c1[m];
            #pragma unroll
            for (int i = 0; i < 16; ++i) { float sd = (lane&1)? v[i] : v[i+16]; float rc = __shfl_xor(sd, 1, 64); v[i] = ((lane&1)? v[i+16] : v[i]) + rc; }
            #pragma unroll
            for (int i = 0; i < 8; ++i)  { float sd = (lane&2)? v[i] : v[i+8];  float rc = __shfl_xor(sd, 2, 64); v[i] = ((lane&2)? v[i+8]  : v[i]) + rc; }
            #pragma unroll
            for (int i = 0; i < 4; ++i)  { float sd = (lane&4)? v[i] : v[i+4];  float rc = __shfl_xor(sd, 4, 64); v[i] = ((lane&4)? v[i+4]  : v[i]) + rc; }
            #pragma unroll
            for (int i = 0; i < 2; ++i)  { float sd = (lane&8)? v[i] : v[i+2];  float rc = __shfl_xor(sd, 8, 64); v[i] = ((lane&8)? v[i+2]  : v[i]) + rc; }
            { float sd = (lane&16)? v[0] : v[1]; float rc = __shfl_xor(sd, 16, 64); v[0] = ((lane&16)? v[1] : v[0]) + rc; }
            v[0] += __shfl_xor(v[0], 32, 64);
            if (lane < 32) sRedC[wid*32 + rm] = v[0];
        }
        __syncthreads();   // bar1

        // ---- PH_B: r-combine, wbuf write, Wh GEMV (ILP4) -> h_new
        {
            float den = sRedD[0]+sRedD[1]+sRedD[2]+sRedD[3]+sRedD[4]+sRedD[5]+sRedD[6]+sRedD[7];
            float inv = 1.f / den;
            w0 = ex0 * inv; w1 = ex1 * inv;
            *(float2*)&wbuf[(size_t)(b*16 + t)*1024 + n0] = make_float2(w0, w1);
            if (lane < 32) {
                float r = 0.f;
                #pragma unroll
                for (int w = 0; w < 8; ++w) r += sRedC[w*32 + lane];
                sR32[lane] = r * inv;
            }
            float s0 = 0.f, s1 = 0.f, s2 = 0.f, s3 = 0.f;
            #pragma unroll
            for (int k4 = 0; k4 < 4; ++k4) {
                const int kb = 4*k4;
                uint4 wv0 = *(const uint4*)&sWhh[(size_t)((qD*16 + kb+0)*256 + iD)*8];
                uint4 hv0 = *(const uint4*)&sHh[cur][qD*128 + (kb+0)*8];
                s0 = fdot2(wv0.x, hv0.x, s0); s0 = fdot2(wv0.y, hv0.y, s0);
                s0 = fdot2(wv0.z, hv0.z, s0); s0 = fdot2(wv0.w, hv0.w, s0);
                uint4 wv1 = *(const uint4*)&sWhh[(size_t)((qD*16 + kb+1)*256 + iD)*8];
                uint4 hv1 = *(const uint4*)&sHh[cur][qD*128 + (kb+1)*8];
                s1 = fdot2(wv1.x, hv1.x, s1); s1 = fdot2(wv1.y, hv1.y, s1);
                s1 = fdot2(wv1.z, hv1.z, s1); s1 = fdot2(wv1.w, hv1.w, s1);
                uint4 wv2 = *(const uint4*)&sWhh[(size_t)((qD*16 + kb+2)*256 + iD)*8];
                uint4 hv2 = *(const uint4*)&sHh[cur][qD*128 + (kb+2)*8];
                s2 = fdot2(wv2.x, hv2.x, s2); s2 = fdot2(wv2.y, hv2.y, s2);
                s2 = fdot2(wv2.z, hv2.z, s2); s2 = fdot2(wv2.w, hv2.w, s2);
                uint4 wv3 = *(const uint4*)&sWhh[(size_t)((qD*16 + kb+3)*256 + iD)*8];
                uint4 hv3 = *(const uint4*)&sHh[cur][qD*128 + (kb+3)*8];
                s3 = fdot2(wv3.x, hv3.x, s3); s3 = fdot2(wv3.y, hv3.y, s3);
                s3 = fdot2(wv3.z, hv3.z, s3); s3 = fdot2(wv3.w, hv3.w, s3);
            }
            const float* rxsrc = qD ? &sXm[t*32] : sR32;
            {
                const __half2* w2;
                float4 va, vb;
                va = *(const float4*)&rxsrc[0];  vb = *(const float4*)&rxsrc[4];
                w2 = (const __half2*)&wrx0;
                { float2 p0 = __half22float2(w2[0]); s0 += p0.x*va.x + p0.y*va.y;
                  float2 p1 = __half22float2(w2[1]); s0 += p1.x*va.z + p1.y*va.w;
                  float2 p2 = __half22float2(w2[2]); s0 += p2.x*vb.x + p2.y*vb.y;
                  float2 p3 = __half22float2(w2[3]); s0 += p3.x*vb.z + p3.y*vb.w; }
                va = *(const float4*)&rxsrc[8];  vb = *(const float4*)&rxsrc[12];
                w2 = (const __half2*)&wrx1;
                { float2 p0 = __half22float2(w2[0]); s1 += p0.x*va.x + p0.y*va.y;
                  float2 p1 = __half22float2(w2[1]); s1 += p1.x*va.z + p1.y*va.w;
                  float2 p2 = __half22float2(w2[2]); s1 += p2.x*vb.x + p2.y*vb.y;
                  float2 p3 = __half22float2(w2[3]); s1 += p3.x*vb.z + p3.y*vb.w; }
                va = *(const float4*)&rxsrc[16]; vb = *(const float4*)&rxsrc[20];
                w2 = (const __half2*)&wrx2;
                { float2 p0 = __half22float2(w2[0]); s2 += p0.x*va.x + p0.y*va.y;
                  float2 p1 = __half22float2(w2[1]); s2 += p1.x*va.z + p1.y*va.w;
                  float2 p2 = __half22float2(w2[2]); s2 += p2.x*vb.x + p2.y*vb.y;
                  float2 p3 = __half22float2(w2[3]); s2 += p3.x*vb.z + p3.y*vb.w; }
                va = *(const float4*)&rxsrc[24]; vb = *(const float4*)&rxsrc[28];
                w2 = (const __half2*)&wrx3;
                { float2 p0 = __half22float2(w2[0]); s3 += p0.x*va.x + p0.y*va.y;
                  float2 p1 = __half22float2(w2[1]); s3 += p1.x*va.z + p1.y*va.w;
                  float2 p2 = __half22float2(w2[2]); s3 += p2.x*vb.x + p2.y*vb.y;
                  float2 p3 = __half22float2(w2[3]); s3 += p3.x*vb.z + p3.y*vb.w; }
            }
            float s = (s0 + s1) + (s2 + s3);
            s += __shfl_down(s, 1, 2);
            if (qD == 0) {
                float hn = tanhf(s + sBh[iD]);
                sHbuf[nxt][iD] = hn;
                sHh[nxt][iD] = __float2half(hn);
            }
        }
        __syncthreads();   // bar2

        // ---- PH_C: e, a, k(t+1) (dot2 groups); g, beta(t+1) per-wave
        float gg;
        {
            uint4 h0 = *(const uint4*)&sHh[nxt][8*jg];
            uint4 h1 = *(const uint4*)&sHh[nxt][128 + 8*jg];
            float se0=0.f, se1=0.f, sa0=0.f, sa1=0.f, sk0=0.f, sk1=0.f;
            se0 = fdot2(we0.x, h0.x, se0); se1 = fdot2(we0.y, h0.y, se1);
            se0 = fdot2(we0.z, h0.z, se0); se1 = fdot2(we0.w, h0.w, se1);
            se0 = fdot2(we1.x, h1.x, se0); se1 = fdot2(we1.y, h1.y, se1);
            se0 = fdot2(we1.z, h1.z, se0); se1 = fdot2(we1.w, h1.w, se1);
            sa0 = fdot2(wa0.x, h0.x, sa0); sa1 = fdot2(wa0.y, h0.y, sa1);
            sa0 = fdot2(wa0.z, h0.z, sa0); sa1 = fdot2(wa0.w, h0.w, sa1);
            sa0 = fdot2(wa1.x, h1.x, sa0); sa1 = fdot2(wa1.y, h1.y, sa1);
            sa0 = fdot2(wa1.z, h1.z, sa0); sa1 = fdot2(wa1.w, h1.w, sa1);
            sk0 = fdot2(wk0.x, h0.x, sk0); sk1 = fdot2(wk0.y, h0.y, sk1);
            sk0 = fdot2(wk0.z, h0.z, sk0); sk1 = fdot2(wk0.w, h0.w, sk1);
            sk0 = fdot2(wk1.x, h1.x, sk0); sk1 = fdot2(wk1.y, h1.y, sk1);
            sk0 = fdot2(wk1.z, h1.z, sk0); sk1 = fdot2(wk1.w, h1.w, sk1);
            float se = se0 + se1, sa = sa0 + sa1, sk = sk0 + sk1;
            se += __shfl_down(se, 8, 16); sa += __shfl_down(sa, 8, 16); sk += __shfl_down(sk, 8, 16);
            se += __shfl_down(se, 4, 16); sa += __shfl_down(sa, 4, 16); sk += __shfl_down(sk, 4, 16);
            se += __shfl_down(se, 2, 16); sa += __shfl_down(sa, 2, 16); sk += __shfl_down(sk, 2, 16);
            se += __shfl_down(se, 1, 16); sa += __shfl_down(sa, 1, 16); sk += __shfl_down(sk, 1, 16);
            if (jg == 0) {
                float e = 1.f/(1.f + expf(-se));
                float a = tanhf(sa);
                sE[mg] = e; sA[mg] = a;
                sK[mg] = tanhf(sk + sBk[mg]);
                eag[(size_t)(b*16 + t)*80 + mg]      = e;
                eag[(size_t)(b*16 + t)*80 + 32 + mg] = a;
            }
            float4 h4 = *(const float4*)&sHbuf[nxt][lane*4];
            float pg = wg4.x*h4.x + wg4.y*h4.y + wg4.z*h4.z + wg4.w*h4.w;
            float pb = wbeta4.x*h4.x + wbeta4.y*h4.y + wbeta4.z*h4.z + wbeta4.w*h4.w;
            #pragma unroll
            for (int d = 32; d > 0; d >>= 1) {
                pg += __shfl_xor(pg, d, 64);
                pb += __shfl_xor(pb, d, 64);
            }
            gg = 1.f/(1.f + expf(-pg));
            float xbeta = pb + bb;
            betav = (xbeta > 20.f) ? xbeta : log1pf(expf(xbeta));
            if (tid == 0) eag[(size_t)(b*16 + t)*80 + 64] = gg;
        }
        __syncthreads();   // bar3

        // ---- PH_D: c update in registers; prefetch x(t+1); no trailing barrier
        {
            float omg = 1.f - gg;
            const __half* xp = (const __half*)xb;
            #pragma unroll
            for (int q = 0; q < 8; ++q) {
                float4 e4 = *(const float4*)&sE[4*q];
                float4 a4 = *(const float4*)&sA[4*q];
                #pragma unroll
                for (int r = 0; r < 4; ++r) {
                    int m = 4*q + r;
                    float e = (r==0)?e4.x:(r==1)?e4.y:(r==2)?e4.z:e4.w;
                    float a = (r==0)?a4.x:(r==1)?a4.y:(r==2)?a4.z:a4.w;
                    float x0v = __half2float(xp[m]);
                    float x1v = __half2float(xp[32 + m]);
                    c0[m] = omg*(c0[m]*(1.f - w0*e) + w0*a) + gg*x0v;
                    c1[m] = omg*(c1[m]*(1.f - w1*e) + w1*a) + gg*x1v;
                }
            }
            if (t < 15) {
                const uint4* xrow = (const uint4*)(xh + (size_t)(b*16 + t + 1)*32768) + 8*tid;
                #pragma unroll
                for (int i = 0; i < 8; ++i) xb[i] = xrow[i];
            }
        }
    }
}

// ---------------- replay: reconstruct cseq from scalars, fully parallel
__global__ __launch_bounds__(256) void ntm_replay_kernel(
    const float* __restrict__ xfeat, const float* __restrict__ wbuf,
    const float* __restrict__ eag, const float* __restrict__ lnst,
    float* __restrict__ cseq)
{
    const int slab = blockIdx.x;    // 16 slabs of 64 n
    const int b    = blockIdx.y;    // 8
    const int tid  = threadIdx.x;
    const int m    = tid >> 3;      // 32
    const int ns   = tid & 7;       // 8 subgroups of 8 n
    const int n0   = slab*64 + ns*8;
    const float mu = lnst[b*2], rs = lnst[b*2+1];

    float c[8];
    {
        const float* x0 = xfeat + (size_t)(b*16)*32768 + m*1024 + n0;
        float4 a = *(const float4*)x0;
        float4 bv = *(const float4*)(x0 + 4);
        c[0]=(a.x-mu)*rs; c[1]=(a.y-mu)*rs; c[2]=(a.z-mu)*rs; c[3]=(a.w-mu)*rs;
        c[4]=(bv.x-mu)*rs; c[5]=(bv.y-mu)*rs; c[6]=(bv.z-mu)*rs; c[7]=(bv.w-mu)*rs;
    }
    for (int t = 0; t < 16; ++t) {
        const size_t bt = (size_t)(b*16 + t);
        const float* wp = &wbuf[bt*1024 + n0];
        float4 wA = *(const float4*)wp;
        float4 wB = *(const float4*)(wp + 4);
        float e = eag[bt*80 + m];
        float a = eag[bt*80 + 32 + m];
        float g = eag[bt*80 + 64];
        float omg = 1.f - g;
        const float* xp = &xfeat[bt*32768 + m*1024 + n0];
        float4 xA = *(const float4*)xp;
        float4 xB = *(const float4*)(xp + 4);
        c[0] = omg*(c[0]*(1.f - wA.x*e) + wA.x*a) + g*xA.x;
        c[1] = omg*(c[1]*(1.f - wA.y*e) + wA.y*a) + g*xA.y;
        c[2] = omg*(c[2]*(1.f - wA.z*e) + wA.z*a) + g*xA.z;
        c[3] = omg*(c[3]*(1.f - wA.w*e) + wA.w*a) + g*xA.w;
        c[4] = omg*(c[4]*(1.f - wB.x*e) + wB.x*a) + g*xB.x;
        c[5] = omg*(c[5]*(1.f - wB.y*e) + wB.y*a) + g*xB.y;
        c[6] = omg*(c[6]*(1.f - wB.z*e) + wB.z*a) + g*xB.z;
        c[7] = omg*(c[7]*(1.f - wB.w*e) + wB.w*a) + g*xB.w;
        float* op = &cseq[bt*32768 + m*1024 + n0];
        *(float4*)op       = make_float4(c[0], c[1], c[2], c[3]);
        *(float4*)(op + 4) = make_float4(c[4], c[5], c[6], c[7]);
    }
}

// ---------------- rfft2: table-driven DFT, both inputs in ONE dispatch
__global__ __launch_bounds__(256) void fft_fwd_kernel(const float* __restrict__ srcA,
                                                      const float* __restrict__ srcB,
                                                      const float* __restrict__ cosw,
                                                      const float* __restrict__ twg,
                                                      float* __restrict__ dstA,
                                                      float* __restrict__ dstB)
{
    const int img = blockIdx.x;
    const int tid = threadIdx.x;
    const float* src; float* dst;
    if (img < 4096) { src = srcA + (size_t)img*1024;        dst = dstA + (size_t)img*1088; }
    else            { src = srcB + (size_t)(img-4096)*1024; dst = dstB + (size_t)(img-4096)*1088; }

    __shared__ __align__(16) float sY[32*36];
    __shared__ __align__(16) float sT[2048];
    __shared__ __align__(16) float sR[2048];

    {
        const float4* s4 = (const float4*)twg;
        float4* d4 = (float4*)sT;
        d4[tid]       = s4[tid];
        d4[256 + tid] = s4[256 + tid];
    }
    {
        float4 v = *(const float4*)&src[tid*4];
        float4 c = *(const float4*)&cosw[tid*4];
        *(float4*)&sY[(tid>>3)*36 + (tid&7)*4] = make_float4(v.x*c.x, v.y*c.y, v.z*c.z, v.w*c.w);
    }
    __syncthreads();

    const int hj = tid >> 3;
    const int k0 = (tid & 7) * 4;

    float r0=0.f,i0=0.f,r1=0.f,i1=0.f,r2=0.f,i2=0.f,r3=0.f,i3=0.f;
    #pragma unroll
    for (int w = 0; w < 32; ++w) {
        float y = sY[hj*36 + w];
        float4 ta = *(const float4*)&sT[(w*32 + k0)*2];
        float4 tb = *(const float4*)&sT[(w*32 + k0)*2 + 4];
        r0 += y*ta.x; i0 += y*ta.y;
        r1 += y*ta.z; i1 += y*ta.w;
        r2 += y*tb.x; i2 += y*tb.y;
        r3 += y*tb.z; i3 += y*tb.w;
    }
    *(float4*)&sR[(hj*32 + k0)*2]     = make_float4(r0,i0,r1,i1);
    *(float4*)&sR[(hj*32 + k0)*2 + 4] = make_float4(r2,i2,r3,i3);
    __syncthreads();

    float fr0=0.f,fi0=0.f,fr1=0.f,fi1=0.f,fr2=0.f,fi2=0.f,fr3=0.f,fi3=0.f;
    #pragma unroll
    for (int h = 0; h < 32; ++h) {
        float2 wj = *(const float2*)&sT[(h*32 + hj)*2];
        float4 Ra = *(const float4*)&sR[(h*32 + k0)*2];
        float4 Rb = *(const float4*)&sR[(h*32 + k0)*2 + 4];
        fr0 += Ra.x*wj.x - Ra.y*wj.y;  fi0 += Ra.x*wj.y + Ra.y*wj.x;
        fr1 += Ra.z*wj.x - Ra.w*wj.y;  fi1 += Ra.z*wj.y + Ra.w*wj.x;
        fr2 += Rb.x*wj.x - Rb.y*wj.y;  fi2 += Rb.x*wj.y + Rb.y*wj.x;
        fr3 += Rb.z*wj.x - Rb.w*wj.y;  fi3 += Rb.z*wj.y + Rb.w*wj.x;
    }
    float* dp = dst + (size_t)(hj*17 + k0)*2;
    if (k0 < 16) {
        *(float2*)&dp[0] = make_float2(fr0, fi0);
        *(float2*)&dp[2] = make_float2(fr1, fi1);
        *(float2*)&dp[4] = make_float2(fr2, fi2);
        *(float2*)&dp[6] = make_float2(fr3, fi3);
    } else if (k0 == 16) {
        *(float2*)&dp[0] = make_float2(fr0, fi0);
    }
}

// ---------------- fused combine + irfft2; one block per bt
__global__ __launch_bounds__(256) void comb_ifft_kernel(const float* __restrict__ cfft,
                                                        const float* __restrict__ zfft,
                                                        const float* __restrict__ yf,
                                                        float* __restrict__ out)
{
    const int bt  = blockIdx.x;
    const int tid = threadIdx.x;
    __shared__ float sG[544*2];
    __shared__ float sS[544*2];
    __shared__ float ct[32], st[32];
    if (tid < 32) {
        float sv, cv;
        sincosf(TWOPI_32 * (float)tid, &sv, &cv);
        ct[tid] = cv; st[tid] = sv;
    }
    for (int idx = tid; idx < 544; idx += 256) {
        float kzz = 0.f, kxr = 0.f, kxi = 0.f;
        #pragma unroll 4
        for (int m = 0; m < 32; ++m) {
            size_t base = ((size_t)(bt*32 + m)*1088) + idx*2;
            float2 c = *(const float2*)&cfft[base];
            float2 z = *(const float2*)&zfft[base];
            kzz += c.x*c.x + c.y*c.y;
            kxr += z.x*c.x + z.y*c.y;
            kxi += z.y*c.x - z.x*c.y;
        }
        float den = 1.f / (kzz + 1e-4f);
        float2 y = *(const float2*)&yf[idx*2];
        float ar = y.x*den, ai = y.y*den;
        sG[idx*2]     = kxr*ar - kxi*ai;
        sG[idx*2 + 1] = kxr*ai + kxi*ar;
    }
    __syncthreads();
    for (int idx = tid; idx < 544; idx += 256) {
        int h = idx / 17;
        int k = idx - h*17;
        float re = 0.f, im = 0.f;
        #pragma unroll
        for (int j = 0; j < 32; ++j) {
            float gr = sG[(j*17+k)*2], gi = sG[(j*17+k)*2+1];
            int a = (h*j) & 31;
            float c = ct[a], s = st[a];
            re += gr*c - gi*s;
            im += gr*s + gi*c;
        }
        sS[(h*17+k)*2] = re; sS[(h*17+k)*2+1] = im;
    }
    __syncthreads();
    #pragma unroll
    for (int p = 0; p < 4; ++p) {
        int pos = p*256 + tid;
        int h = pos >> 5, wq = pos & 31;
        float acc = sS[(h*17)*2];
        #pragma unroll
        for (int k = 1; k < 16; ++k) {
            int a = (wq*k) & 31;
            acc += 2.f*(sS[(h*17+k)*2]*ct[a] - sS[(h*17+k)*2+1]*st[a]);
        }
        acc += sS[(h*17+16)*2] * ((wq & 1) ? -1.f : 1.f);
        out[(size_t)bt*1024 + pos] = acc * (1.f/1024.f);
    }
}

extern "C" void kernel_launch(void* const* d_in, const int* in_sizes, int n_in,
                              void* d_out, int out_size, void* d_ws, size_t ws_size,
                              hipStream_t stream)
{
    const float* x_i   = (const float*)d_in[0];
    const float* z_i   = (const float*)d_in[1];
    const float* c1w   = (const float*)d_in[2];
    const float* c1b   = (const float*)d_in[3];
    const float* c2w   = (const float*)d_in[4];
    const float* c2b   = (const float*)d_in[5];
    const float* Wk    = (const float*)d_in[6];
    const float* bk    = (const float*)d_in[7];
    const float* Wbeta = (const float*)d_in[8];
    const float* bbeta = (const float*)d_in[9];
    const float* Wh    = (const float*)d_in[10];
    const float* bh    = (const float*)d_in[11];
    const float* We    = (const float*)d_in[12];
    const float* Wa    = (const float*)d_in[13];
    const float* Wg    = (const float*)d_in[14];
    const float* cosw  = (const float*)d_in[15];
    const float* yf    = (const float*)d_in[16];
    float* out = (float*)d_out;
    float* ws  = (float*)d_ws;

    // workspace layout (floats)
    // buf1 region spans [0, 16,777,216): anything written BEFORE the convs must live above.
    unsigned int* buf1p = (unsigned int*)ws;    // packed conv1 out: 8,388,608 u32
    float*  xfeat = ws + 16777216;      // 4,194,304
    float*  zfeat = ws + 20971520;      // 4,194,304
    float*  cseq  = ws + 25165824;      // 4,194,304 (ends 29,360,128)
    float*  xmb   = ws + 29499392;      // 4,096
    // regions inside buf1 region, valid only AFTER conv stage completes:
    float*  cfft  = ws;                 // 4,456,448 f
    float*  zfft  = ws + 4456448;       // 4,456,448 f (ends 8,912,896)
    __half* xhb   = (__half*)(ws + 9000000);    // 4,194,304 halfs (written post-conv)
    float*  wbuf  = ws + 11100000;      // 131,072 f
    float*  eag   = ws + 11240000;      // 10,240 f
    float*  lnstp = ws + 11251000;      // 16 f
    // prepack outputs: OUTSIDE buf1, in the dead gap [29,360,128 .. 29,499,392)
    __half* whhP  = (__half*)(ws + 29360128);   // 65,536 halfs
    __half* whrxP = (__half*)(ws + 29392896);   // 16,384 halfs
    __half* wkP   = (__half*)(ws + 29401088);   // 8,192 halfs
    __half* weP   = (__half*)(ws + 29405184);   // 8,192 halfs
    __half* waP   = (__half*)(ws + 29409280);   // 8,192 halfs
    float*  twg   = ws + 29413376;      // 2,048 f
    unsigned int* c2wP   = (unsigned int*)(ws + 29415424);  // 4,608 u32
    unsigned int* c1wP01 = (unsigned int*)(ws + 29420032);  // 288 u32
    float*  c1wP2 = ws + 29420320;      // 288 f (ends 29,420,608 < 29,499,392 OK)

    dim3 b256(256);
    prepack_kernel<<<33, b256, 0, stream>>>(Wh, Wk, We, Wa, c1w, c2w,
                                            whhP, whrxP, wkP, weP, waP, twg,
                                            c2wP, c1wP01, c1wP2);
    conv1_kernel<<<dim3(4,128), b256, 0, stream>>>(x_i, c1wP01, c1wP2, c1b, buf1p);
    conv2_kernel<<<dim3(8,128), b256, 0, stream>>>(buf1p, c2wP, c2b, xfeat);
    conv1_kernel<<<dim3(4,128), b256, 0, stream>>>(z_i, c1wP01, c1wP2, c1b, buf1p);
    conv2_kernel<<<dim3(8,128), b256, 0, stream>>>(buf1p, c2wP, c2b, zfeat);
    prep2_kernel<<<128, b256, 0, stream>>>(xfeat, xhb, xmb);
    ntm_scal_kernel<<<8, 512, 0, stream>>>(xfeat, xhb, xmb, whhP, whrxP, wkP, weP, waP,
                                           bk, Wbeta, bbeta, bh, Wg, wbuf, eag, lnstp);
    ntm_replay_kernel<<<dim3(16,8), b256, 0, stream>>>(xfeat, wbuf, eag, lnstp, cseq);
    fft_fwd_kernel<<<8192, b256, 0, stream>>>(cseq, zfeat, cosw, twg, cfft, zfft);
    comb_ifft_kernel<<<128, b256, 0, stream>>>(cfft, zfft, yf, out);
}

// Round 10
// 576.957 us; speedup vs baseline: 1.5589x; 1.0893x over previous
//
#include <hip/hip_runtime.h>
#include <hip/hip_fp16.h>
#include <math.h>

// B=8, T=16, IMG=128, CF=32, WO=HO=32, N=1024, M=32, DH=256
// conv SAME stride2: pad_lo=0, pad_hi=1 -> in_idx = 2*out + k

#define TWOPI_32 0.19634954084936207f  // 2*pi/32

typedef _Float16 __h2 __attribute__((ext_vector_type(2)));
__device__ __forceinline__ float fdot2(unsigned int w, unsigned int h, float acc) {
    union { unsigned int u; __h2 v; } a, b;
    a.u = w; b.u = h;
    return __builtin_amdgcn_fdot2(a.v, b.v, acc, false);
}
__device__ __forceinline__ unsigned int packh2(float a, float b) {
    __half2 h2 = __floats2half2_rn(a, b);
    return *(unsigned int*)&h2;
}

// ---------------- prepack: all weight packs + twiddle
__global__ __launch_bounds__(256) void prepack_kernel(
    const float* __restrict__ Wh, const float* __restrict__ Wk,
    const float* __restrict__ We, const float* __restrict__ Wa,
    const float* __restrict__ c1w, const float* __restrict__ c2w,
    __half* __restrict__ whhP, __half* __restrict__ whrxP,
    __half* __restrict__ wkP, __half* __restrict__ weP, __half* __restrict__ waP,
    float* __restrict__ twg,
    unsigned int* __restrict__ c2wP, unsigned int* __restrict__ c1wP01,
    float* __restrict__ c1wP2)
{
    const int tid = threadIdx.x;
    if (blockIdx.x < 32) {
        const int base = blockIdx.x*256 + tid;   // 0..8191
        #pragma unroll
        for (int r = 0; r < 8; ++r) {
            int idx = base*8 + r;
            int e = idx & 7, i = (idx >> 3) & 255, c = idx >> 11;
            int q = c >> 4, k = c & 15;
            whhP[idx] = __float2half(Wh[i*320 + q*128 + k*8 + e]);
        }
        #pragma unroll
        for (int r = 0; r < 2; ++r) {
            int idx = base*2 + r;
            int i = idx >> 6, s2 = idx & 63;
            whrxP[idx] = __float2half(Wh[i*320 + 256 + s2]);
        }
        {
            int idx = base;
            int m = idx >> 8, j = (idx >> 4) & 15, e = idx & 15;
            int col = (e < 8) ? (8*j + e) : (128 + 8*j + (e - 8));
            wkP[idx] = __float2half(Wk[m*256 + col]);
            weP[idx] = __float2half(We[m*256 + col]);
            waP[idx] = __float2half(Wa[m*256 + col]);
        }
    } else {
        for (int idx = tid; idx < 4608; idx += 256) {
            int half = idx / 2304;
            int rem  = idx - half*2304;
            int ic2  = rem / 144;
            int r2   = rem - ic2*144;
            int q    = r2 >> 4, j = r2 & 15;
            int oc   = half*16 + j;
            c2wP[idx] = packh2(c2w[oc*288 + (2*ic2)*9 + q],
                               c2w[oc*288 + (2*ic2+1)*9 + q]);
        }
        for (int idx = tid; idx < 288; idx += 256) {
            int oc = idx / 9, r = idx - oc*9;        // r = ic*3+dy
            c1wP01[idx] = packh2(c1w[oc*27 + r*3 + 0], c1w[oc*27 + r*3 + 1]);
            c1wP2[idx]  = c1w[oc*27 + r*3 + 2];
        }
        for (int idx = tid; idx < 1024; idx += 256) {
            int w = idx >> 5, k = idx & 31;
            float sv, cv;
            sincosf(TWOPI_32 * (float)((w*k) & 31), &sv, &cv);
            twg[idx*2]     = cv;
            twg[idx*2 + 1] = -sv;
        }
    }
}

// ---------------- conv1 (x path): [img][3][128][128] -> packed u32 [img][16 oc2][64][64]
__global__ __launch_bounds__(256) void conv1_kernel(const float* __restrict__ in,
                                                    const unsigned int* __restrict__ w01,
                                                    const float* __restrict__ w2,
                                                    const float* __restrict__ bias,
                                                    unsigned int* __restrict__ out)
{
    const int strip = blockIdx.x;   // 4 strips of 16 output rows
    const int img   = blockIdx.y;
    const int tid   = threadIdx.x;
    __shared__ __align__(16) unsigned int sIn2[3*33*66];
    const int iy0 = strip * 32;
    for (int idx = tid; idx < 3*33*66; idx += 256) {
        int ic  = idx / (33*66);
        int rem = idx - ic*(33*66);
        int li  = rem / 66;
        int x2  = rem - li*66;
        int iy  = iy0 + li;
        unsigned int v = 0;
        if (iy < 128 && x2 < 64) {
            float2 p = *(const float2*)&in[(((size_t)img*3 + ic)*128 + iy)*128 + 2*x2];
            v = packh2(p.x, p.y);
        }
        sIn2[idx] = v;
    }
    __syncthreads();
    const int oy0 = strip*16;
    #pragma unroll
    for (int p = 0; p < 4; ++p) {
        int pos = p*256 + tid;       // 16 rows x 64 cols
        int ly = pos >> 6;
        int ox = pos & 63;
        unsigned int pa[9];
        float px[9];
        #pragma unroll
        for (int ic = 0; ic < 3; ++ic)
            #pragma unroll
            for (int dy = 0; dy < 3; ++dy) {
                int r = ic*3 + dy;
                int rowb = ic*(33*66) + (2*ly+dy)*66;
                pa[r] = sIn2[rowb + ox];
                unsigned int u = sIn2[rowb + ox + 1];
                px[r] = __half2float(((const __half2*)&u)->x);
            }
        for (int oc2 = 0; oc2 < 16; ++oc2) {
            const int oca = 2*oc2, ocb = 2*oc2 + 1;
            float acca = bias[oca], accb = bias[ocb];
            #pragma unroll
            for (int r = 0; r < 9; ++r) {
                acca = fdot2(w01[oca*9 + r], pa[r], acca);
                acca += w2[oca*9 + r] * px[r];
                accb = fdot2(w01[ocb*9 + r], pa[r], accb);
                accb += w2[ocb*9 + r] * px[r];
            }
            out[(((size_t)img*16 + oc2)*64 + (oy0+ly))*64 + ox] =
                packh2(fmaxf(acca, 0.f), fmaxf(accb, 0.f));
        }
    }
}

// ---------------- conv2 (x path): packed u32 in [img][16 ic2][64][64] -> [img][32][32][32]
__global__ __launch_bounds__(256) void conv2_kernel(const unsigned int* __restrict__ in,
                                                    const unsigned int* __restrict__ wP,
                                                    const float* __restrict__ bias,
                                                    float* __restrict__ out)
{
    const int strip = blockIdx.x;   // 8 strips of 4 output rows
    const int img   = blockIdx.y;
    const int tid   = threadIdx.x;
    __shared__ __align__(16) unsigned int sIn2[16*9*66];
    const int iy0 = strip*8;
    for (int idx = tid; idx < 16*9*66; idx += 256) {
        int ic2 = idx / (9*66);
        int rem = idx - ic2*(9*66);
        int li  = rem / 66;
        int col = rem - li*66;
        int iy  = iy0 + li;
        unsigned int v = 0;
        if (iy < 64 && col < 64)
            v = in[(((size_t)img*16 + ic2)*64 + iy)*64 + col];
        sIn2[idx] = v;
    }
    __syncthreads();
    const int posl = tid & 127;
    const int half = tid >> 7;
    const int ly = posl >> 5;
    const int ox = posl & 31;
    float acc[16];
    #pragma unroll
    for (int j = 0; j < 16; ++j) acc[j] = 0.f;
    for (int ic2 = 0; ic2 < 16; ++ic2) {
        unsigned int patch[9];
        #pragma unroll
        for (int dy = 0; dy < 3; ++dy)
            #pragma unroll
            for (int dx = 0; dx < 3; ++dx)
                patch[dy*3+dx] = sIn2[ic2*(9*66) + (2*ly+dy)*66 + 2*ox + dx];
        const unsigned int* wblk = wP + (half*16 + ic2)*144;
        #pragma unroll
        for (int j = 0; j < 16; ++j) {
            float a = acc[j];
            #pragma unroll
            for (int q = 0; q < 9; ++q)
                a = fdot2(wblk[q*16 + j], patch[q], a);
            acc[j] = a;
        }
    }
    const int oy = strip*4 + ly;
    #pragma unroll
    for (int j = 0; j < 16; ++j) {
        int oc = half*16 + j;
        out[(((size_t)img*32 + oc)*32 + oy)*32 + ox] = fmaxf(acc[j] + bias[oc], 0.f);
    }
}

// ---------------- prep2: xhalf-transpose + xmean
__global__ __launch_bounds__(256) void prep2_kernel(
    const float* __restrict__ xf, __half* __restrict__ xh, float* __restrict__ xmean)
{
    const int tid = threadIdx.x;
    const int bt = blockIdx.x;
    __shared__ float sT[32][257];
    const float* src = xf + (size_t)bt*32768;
    __half* dst = xh + (size_t)bt*32768;
    for (int tt = 0; tt < 4; ++tt) {
        #pragma unroll
        for (int m = 0; m < 32; ++m)
            sT[m][tid] = src[m*1024 + tt*256 + tid];
        __syncthreads();
        uint4 o[4];
        unsigned int* ou = (unsigned int*)o;
        #pragma unroll
        for (int k = 0; k < 16; ++k)
            ou[k] = packh2(sT[2*k][tid], sT[2*k+1][tid]);
        uint4* dp = (uint4*)(dst + (size_t)(tt*256 + tid)*32);
        dp[0] = o[0]; dp[1] = o[1]; dp[2] = o[2]; dp[3] = o[3];
        __syncthreads();
    }
    const int m = tid >> 3, s8 = tid & 7;
    float sm = 0.f;
    #pragma unroll 16
    for (int k = 0; k < 128; ++k) sm += src[m*1024 + s8 + 8*k];
    sm += __shfl_down(sm, 4, 8); sm += __shfl_down(sm, 2, 8); sm += __shfl_down(sm, 1, 8);
    if (s8 == 0) xmean[bt*32 + m] = sm * (1.f/1024.f);
}

// ---------------- FAT: blocks 0..7 = NTM recurrence; blocks 8.. = fused conv1+conv2 (z)
__global__ __launch_bounds__(512, 2) void fat_kernel(
    const float* __restrict__ xfeat, const __half* __restrict__ xh,
    const float* __restrict__ xmean,
    const __half* __restrict__ whhP, const __half* __restrict__ whrxP,
    const __half* __restrict__ wkP, const __half* __restrict__ weP,
    const __half* __restrict__ waP,
    const float* __restrict__ bk, const float* __restrict__ Wbeta,
    const float* __restrict__ bbeta, const float* __restrict__ bh,
    const float* __restrict__ Wg,
    float* __restrict__ wbuf, float* __restrict__ eag, float* __restrict__ lnst,
    const float* __restrict__ z_i, const unsigned int* __restrict__ c1w01,
    const float* __restrict__ c1w2, const float* __restrict__ c1b,
    const unsigned int* __restrict__ c2wP, const float* __restrict__ c2b,
    float* __restrict__ zfeat)
{
    __shared__ __align__(16) char smem[139264];

    if (blockIdx.x < 8) {
        // ======== NTM branch (round-9 body, LDS aliased into smem) ========
        __half* sWhh = (__half*)(smem);                    // 131072 B
        float (*sHbuf)[256] = (float(*)[256])(smem + 131072);
        __half (*sHh)[256] = (__half(*)[256])(smem + 133120);
        float* sK    = (float*)(smem + 134144);
        float* sXm   = (float*)(smem + 134272);
        float* sRedC = (float*)(smem + 136320);
        float* sR32  = (float*)(smem + 137344);
        float* sE    = (float*)(smem + 137472);
        float* sA    = (float*)(smem + 137600);
        float* sBk   = (float*)(smem + 137728);
        float* sBh   = (float*)(smem + 137856);
        float* sRedD = (float*)(smem + 138880);
        float* sRedL = (float*)(smem + 138912);

        const int b    = blockIdx.x;
        const int tid  = threadIdx.x;
        const int lane = tid & 63;
        const int wid  = tid >> 6;

        {
            const uint4* src = (const uint4*)whhP;
            uint4* dst = (uint4*)sWhh;
            for (int i2 = tid; i2 < 8192; i2 += 512) dst[i2] = src[i2];
        }
        if (tid < 256) { sBh[tid] = bh[tid]; sHbuf[0][tid] = 0.f; sHh[0][tid] = __float2half(0.f); }
        if (tid < 32)  { sBk[tid] = bk[tid]; sK[tid] = tanhf(bk[tid]); }
        if (tid < 512) sXm[tid] = xmean[b*512 + tid];
        float4 wbeta4 = *(const float4*)&Wbeta[(size_t)lane*4];
        float4 wg4    = *(const float4*)&Wg[(size_t)lane*4];
        float bb = bbeta[0];

        const int mg = tid >> 4, jg = tid & 15;
        uint4 wk0, wk1, we0, we1, wa0, wa1;
        {
            const uint4* p;
            p = (const uint4*)(wkP + (size_t)(mg*16 + jg)*16); wk0 = p[0]; wk1 = p[1];
            p = (const uint4*)(weP + (size_t)(mg*16 + jg)*16); we0 = p[0]; we1 = p[1];
            p = (const uint4*)(waP + (size_t)(mg*16 + jg)*16); wa0 = p[0]; wa1 = p[1];
        }
        const int iD = tid >> 1, qD = tid & 1;
        uint4 wrx0, wrx1, wrx2, wrx3;
        {
            const uint4* p = (const uint4*)(whrxP + (size_t)iD*64 + qD*32);
            wrx0 = p[0]; wrx1 = p[1]; wrx2 = p[2]; wrx3 = p[3];
        }

        const int n0 = 2*tid;
        float c0[32], c1[32];

        {
            const float* x0 = xfeat + (size_t)(b*16)*32768;
            float sum = 0.f, ss = 0.f;
            #pragma unroll
            for (int m = 0; m < 32; ++m) {
                float2 v = *(const float2*)&x0[m*1024 + n0];
                c0[m] = v.x; c1[m] = v.y;
                sum += v.x + v.y; ss += v.x*v.x + v.y*v.y;
            }
            #pragma unroll
            for (int d = 32; d > 0; d >>= 1) { sum += __shfl_xor(sum, d, 64); ss += __shfl_xor(ss, d, 64); }
            if (lane == 0) { sRedL[wid] = sum; sRedL[8+wid] = ss; }
            __syncthreads();
            float S = 0.f, SS = 0.f;
            #pragma unroll
            for (int i = 0; i < 8; ++i) { S += sRedL[i]; SS += sRedL[8+i]; }
            float mu = S * (1.f/32768.f);
            float var = SS * (1.f/32768.f) - mu*mu;
            float rs = rsqrtf(var + 1e-5f);
            if (tid == 0) { lnst[b*2] = mu; lnst[b*2+1] = rs; }
            #pragma unroll
            for (int m = 0; m < 32; ++m) { c0[m] = (c0[m]-mu)*rs; c1[m] = (c1[m]-mu)*rs; }
        }

        uint4 xb[8];
        {
            const uint4* xrow = (const uint4*)(xh + (size_t)(b*16)*32768) + 8*tid;
            #pragma unroll
            for (int i = 0; i < 8; ++i) xb[i] = xrow[i];
        }
        __syncthreads();

        float betav = (bb > 20.f) ? bb : log1pf(expf(bb));
        float ex0 = 0.f, ex1 = 0.f, w0 = 0.f, w1 = 0.f;
        const int rm = ((lane&1)<<4)|((lane&2)<<2)|(lane&4)|((lane&8)>>2)|((lane&16)>>4);

        #pragma unroll 1
        for (int t = 0; t < 16; ++t) {
            const int cur = t & 1, nxt = cur ^ 1;

            // PH_A
            {
                float beta = betav;
                float dot0 = 0.f, dot1 = 0.f, cn20 = 0.f, cn21 = 0.f, kn2 = 0.f;
                #pragma unroll
                for (int q = 0; q < 8; ++q) {
                    float4 k4 = *(const float4*)&sK[4*q];
                    dot0 += c0[4*q]*k4.x + c0[4*q+1]*k4.y + c0[4*q+2]*k4.z + c0[4*q+3]*k4.w;
                    dot1 += c1[4*q]*k4.x + c1[4*q+1]*k4.y + c1[4*q+2]*k4.z + c1[4*q+3]*k4.w;
                    cn20 += c0[4*q]*c0[4*q] + c0[4*q+1]*c0[4*q+1] + c0[4*q+2]*c0[4*q+2] + c0[4*q+3]*c0[4*q+3];
                    cn21 += c1[4*q]*c1[4*q] + c1[4*q+1]*c1[4*q+1] + c1[4*q+2]*c1[4*q+2] + c1[4*q+3]*c1[4*q+3];
                    kn2  += k4.x*k4.x + k4.y*k4.y + k4.z*k4.z + k4.w*k4.w;
                }
                float kinv = 1.f / (sqrtf(kn2) + 1e-8f);
                float s0 = dot0 * kinv / (sqrtf(cn20) + 1e-8f);
                float s1 = dot1 * kinv / (sqrtf(cn21) + 1e-8f);
                ex0 = expf(beta * s0);
                ex1 = expf(beta * s1);
                float es = ex0 + ex1;
                #pragma unroll
                for (int d = 32; d > 0; d >>= 1) es += __shfl_xor(es, d, 64);
                if (lane == 0) sRedD[wid] = es;
                float v[32];
                #pragma unroll
                for (int m = 0; m < 32; ++m) v[m] = ex0*c0[m] + ex1*c1[m];
                #pragma unroll
                for (int i = 0; i < 16; ++i) { float sd = (lane&1)? v[i] : v[i+16]; float rc = __shfl_xor(sd, 1, 64); v[i] = ((lane&1)? v[i+16] : v[i]) + rc; }
                #pragma unroll
                for (int i = 0; i < 8; ++i)  { float sd = (lane&2)? v[i] : v[i+8];  float rc = __shfl_xor(sd, 2, 64); v[i] = ((lane&2)? v[i+8]  : v[i]) + rc; }
                #pragma unroll
                for (int i = 0; i < 4; ++i)  { float sd = (lane&4)? v[i] : v[i+4];  float rc = __shfl_xor(sd, 4, 64); v[i] = ((lane&4)? v[i+4]  : v[i]) + rc; }
                #pragma unroll
                for (int i = 0; i < 2; ++i)  { float sd = (lane&8)? v[i] : v[i+2];  float rc = __shfl_xor(sd, 8, 64); v[i] = ((lane&8)? v[i+2]  : v[i]) + rc; }
                { float sd = (lane&16)? v[0] : v[1]; float rc = __shfl_xor(sd, 16, 64); v[0] = ((lane&16)? v[1] : v[0]) + rc; }
                v[0] += __shfl_xor(v[0], 32, 64);
                if (lane < 32) sRedC[wid*32 + rm] = v[0];
            }
            __syncthreads();

            // PH_B
            {
                float den = sRedD[0]+sRedD[1]+sRedD[2]+sRedD[3]+sRedD[4]+sRedD[5]+sRedD[6]+sRedD[7];
                float inv = 1.f / den;
                w0 = ex0 * inv; w1 = ex1 * inv;
                *(float2*)&wbuf[(size_t)(b*16 + t)*1024 + n0] = make_float2(w0, w1);
                if (lane < 32) {
                    float r = 0.f;
                    #pragma unroll
                    for (int w = 0; w < 8; ++w) r += sRedC[w*32 + lane];
                    sR32[lane] = r * inv;
                }
                float s0 = 0.f, s1 = 0.f, s2 = 0.f, s3 = 0.f;
                #pragma unroll
                for (int k4 = 0; k4 < 4; ++k4) {
                    const int kb = 4*k4;
                    uint4 wv0 = *(const uint4*)&sWhh[(size_t)((qD*16 + kb+0)*256 + iD)*8];
                    uint4 hv0 = *(const uint4*)&sHh[cur][qD*128 + (kb+0)*8];
                    s0 = fdot2(wv0.x, hv0.x, s0); s0 = fdot2(wv0.y, hv0.y, s0);
                    s0 = fdot2(wv0.z, hv0.z, s0); s0 = fdot2(wv0.w, hv0.w, s0);
                    uint4 wv1 = *(const uint4*)&sWhh[(size_t)((qD*16 + kb+1)*256 + iD)*8];
                    uint4 hv1 = *(const uint4*)&sHh[cur][qD*128 + (kb+1)*8];
                    s1 = fdot2(wv1.x, hv1.x, s1); s1 = fdot2(wv1.y, hv1.y, s1);
                    s1 = fdot2(wv1.z, hv1.z, s1); s1 = fdot2(wv1.w, hv1.w, s1);
                    uint4 wv2 = *(const uint4*)&sWhh[(size_t)((qD*16 + kb+2)*256 + iD)*8];
                    uint4 hv2 = *(const uint4*)&sHh[cur][qD*128 + (kb+2)*8];
                    s2 = fdot2(wv2.x, hv2.x, s2); s2 = fdot2(wv2.y, hv2.y, s2);
                    s2 = fdot2(wv2.z, hv2.z, s2); s2 = fdot2(wv2.w, hv2.w, s2);
                    uint4 wv3 = *(const uint4*)&sWhh[(size_t)((qD*16 + kb+3)*256 + iD)*8];
                    uint4 hv3 = *(const uint4*)&sHh[cur][qD*128 + (kb+3)*8];
                    s3 = fdot2(wv3.x, hv3.x, s3); s3 = fdot2(wv3.y, hv3.y, s3);
                    s3 = fdot2(wv3.z, hv3.z, s3); s3 = fdot2(wv3.w, hv3.w, s3);
                }
                const float* rxsrc = qD ? &sXm[t*32] : sR32;
                {
                    const __half2* w2;
                    float4 va, vb;
                    va = *(const float4*)&rxsrc[0];  vb = *(const float4*)&rxsrc[4];
                    w2 = (const __half2*)&wrx0;
                    { float2 p0 = __half22float2(w2[0]); s0 += p0.x*va.x + p0.y*va.y;
                      float2 p1 = __half22float2(w2[1]); s0 += p1.x*va.z + p1.y*va.w;
                      float2 p2 = __half22float2(w2[2]); s0 += p2.x*vb.x + p2.y*vb.y;
                      float2 p3 = __half22float2(w2[3]); s0 += p3.x*vb.z + p3.y*vb.w; }
                    va = *(const float4*)&rxsrc[8];  vb = *(const float4*)&rxsrc[12];
                    w2 = (const __half2*)&wrx1;
                    { float2 p0 = __half22float2(w2[0]); s1 += p0.x*va.x + p0.y*va.y;
                      float2 p1 = __half22float2(w2[1]); s1 += p1.x*va.z + p1.y*va.w;
                      float2 p2 = __half22float2(w2[2]); s1 += p2.x*vb.x + p2.y*vb.y;
                      float2 p3 = __half22float2(w2[3]); s1 += p3.x*vb.z + p3.y*vb.w; }
                    va = *(const float4*)&rxsrc[16]; vb = *(const float4*)&rxsrc[20];
                    w2 = (const __half2*)&wrx2;
                    { float2 p0 = __half22float2(w2[0]); s2 += p0.x*va.x + p0.y*va.y;
                      float2 p1 = __half22float2(w2[1]); s2 += p1.x*va.z + p1.y*va.w;
                      float2 p2 = __half22float2(w2[2]); s2 += p2.x*vb.x + p2.y*vb.y;
                      float2 p3 = __half22float2(w2[3]); s2 += p3.x*vb.z + p3.y*vb.w; }
                    va = *(const float4*)&rxsrc[24]; vb = *(const float4*)&rxsrc[28];
                    w2 = (const __half2*)&wrx3;
                    { float2 p0 = __half22float2(w2[0]); s3 += p0.x*va.x + p0.y*va.y;
                      float2 p1 = __half22float2(w2[1]); s3 += p1.x*va.z + p1.y*va.w;
                      float2 p2 = __half22float2(w2[2]); s3 += p2.x*vb.x + p2.y*vb.y;
                      float2 p3 = __half22float2(w2[3]); s3 += p3.x*vb.z + p3.y*vb.w; }
                }
                float s = (s0 + s1) + (s2 + s3);
                s += __shfl_down(s, 1, 2);
                if (qD == 0) {
                    float hn = tanhf(s + sBh[iD]);
                    sHbuf[nxt][iD] = hn;
                    sHh[nxt][iD] = __float2half(hn);
                }
            }
            __syncthreads();

            // PH_C
            float gg;
            {
                uint4 h0 = *(const uint4*)&sHh[nxt][8*jg];
                uint4 h1 = *(const uint4*)&sHh[nxt][128 + 8*jg];
                float se0=0.f, se1=0.f, sa0=0.f, sa1=0.f, sk0=0.f, sk1=0.f;
                se0 = fdot2(we0.x, h0.x, se0); se1 = fdot2(we0.y, h0.y, se1);
                se0 = fdot2(we0.z, h0.z, se0); se1 = fdot2(we0.w, h0.w, se1);
                se0 = fdot2(we1.x, h1.x, se0); se1 = fdot2(we1.y, h1.y, se1);
                se0 = fdot2(we1.z, h1.z, se0); se1 = fdot2(we1.w, h1.w, se1);
                sa0 = fdot2(wa0.x, h0.x, sa0); sa1 = fdot2(wa0.y, h0.y, sa1);
                sa0 = fdot2(wa0.z, h0.z, sa0); sa1 = fdot2(wa0.w, h0.w, sa1);
                sa0 = fdot2(wa1.x, h1.x, sa0); sa1 = fdot2(wa1.y, h1.y, sa1);
                sa0 = fdot2(wa1.z, h1.z, sa0); sa1 = fdot2(wa1.w, h1.w, sa1);
                sk0 = fdot2(wk0.x, h0.x, sk0); sk1 = fdot2(wk0.y, h0.y, sk1);
                sk0 = fdot2(wk0.z, h0.z, sk0); sk1 = fdot2(wk0.w, h0.w, sk1);
                sk0 = fdot2(wk1.x, h1.x, sk0); sk1 = fdot2(wk1.y, h1.y, sk1);
                sk0 = fdot2(wk1.z, h1.z, sk0); sk1 = fdot2(wk1.w, h1.w, sk1);
                float se = se0 + se1, sa = sa0 + sa1, sk = sk0 + sk1;
                se += __shfl_down(se, 8, 16); sa += __shfl_down(sa, 8, 16); sk += __shfl_down(sk, 8, 16);
                se += __shfl_down(se, 4, 16); sa += __shfl_down(sa, 4, 16); sk += __shfl_down(sk, 4, 16);
                se += __shfl_down(se, 2, 16); sa += __shfl_down(sa, 2, 16); sk += __shfl_down(sk, 2, 16);
                se += __shfl_down(se, 1, 16); sa += __shfl_down(sa, 1, 16); sk += __shfl_down(sk, 1, 16);
                if (jg == 0) {
                    float e = 1.f/(1.f + expf(-se));
                    float a = tanhf(sa);
                    sE[mg] = e; sA[mg] = a;
                    sK[mg] = tanhf(sk + sBk[mg]);
                    eag[(size_t)(b*16 + t)*80 + mg]      = e;
                    eag[(size_t)(b*16 + t)*80 + 32 + mg] = a;
                }
                float4 h4 = *(const float4*)&sHbuf[nxt][lane*4];
                float pg = wg4.x*h4.x + wg4.y*h4.y + wg4.z*h4.z + wg4.w*h4.w;
                float pb = wbeta4.x*h4.x + wbeta4.y*h4.y + wbeta4.z*h4.z + wbeta4.w*h4.w;
                #pragma unroll
                for (int d = 32; d > 0; d >>= 1) {
                    pg += __shfl_xor(pg, d, 64);
                    pb += __shfl_xor(pb, d, 64);
                }
                gg = 1.f/(1.f + expf(-pg));
                float xbeta = pb + bb;
                betav = (xbeta > 20.f) ? xbeta : log1pf(expf(xbeta));
                if (tid == 0) eag[(size_t)(b*16 + t)*80 + 64] = gg;
            }
            __syncthreads();

            // PH_D
            {
                float omg = 1.f - gg;
                const __half* xp = (const __half*)xb;
                #pragma unroll
                for (int q = 0; q < 8; ++q) {
                    float4 e4 = *(const float4*)&sE[4*q];
                    float4 a4 = *(const float4*)&sA[4*q];
                    #pragma unroll
                    for (int r = 0; r < 4; ++r) {
                        int m = 4*q + r;
                        float e = (r==0)?e4.x:(r==1)?e4.y:(r==2)?e4.z:e4.w;
                        float a = (r==0)?a4.x:(r==1)?a4.y:(r==2)?a4.z:a4.w;
                        float x0v = __half2float(xp[m]);
                        float x1v = __half2float(xp[32 + m]);
                        c0[m] = omg*(c0[m]*(1.f - w0*e) + w0*a) + gg*x0v;
                        c1[m] = omg*(c1[m]*(1.f - w1*e) + w1*a) + gg*x1v;
                    }
                }
                if (t < 15) {
                    const uint4* xrow = (const uint4*)(xh + (size_t)(b*16 + t + 1)*32768) + 8*tid;
                    #pragma unroll
                    for (int i = 0; i < 8; ++i) xb[i] = xrow[i];
                }
            }
        }
    } else {
        // ======== fused conv1+conv2 (z) branch: 2 tiles per block (2x256 teams) ========
        const int team = threadIdx.x >> 8;
        const int t256 = threadIdx.x & 255;
        const int tile = (blockIdx.x - 8)*2 + team;   // 0..1023
        const int img  = tile >> 3;
        const int strip = tile & 7;
        unsigned int* sZ  = (unsigned int*)(smem + team*53072);           // [3][19][66]
        unsigned int* sC1 = (unsigned int*)(smem + team*53072 + 15048);   // [16][9][66]

        const int zrow0 = strip*16;
        for (int idx = t256; idx < 3762; idx += 256) {
            int ic = idx / (19*66);
            int rem = idx - ic*(19*66);
            int li = rem / 66;
            int x2 = rem - li*66;
            int iy = zrow0 + li;
            unsigned int v = 0;
            if (iy < 128 && x2 < 64) {
                float2 p = *(const float2*)&z_i[(((size_t)img*3 + ic)*128 + iy)*128 + 2*x2];
                v = packh2(p.x, p.y);
            }
            sZ[idx] = v;
        }
        // zero pad columns 64,65 of sC1
        for (int idx = t256; idx < 16*9*2; idx += 256) {
            int oc2 = idx / 18; int rem = idx - oc2*18; int li = rem >> 1; int c = 64 + (rem & 1);
            sC1[oc2*(9*66) + li*66 + c] = 0;
        }
        __syncthreads();
        // conv1: 9 rows x 64 cols -> sC1 (row 8*strip+li; phantom row 64 at strip 7 must be 0)
        for (int pos = t256; pos < 576; pos += 256) {
            int li = pos >> 6;
            int ox = pos & 63;
            unsigned int pa[9]; float px[9];
            #pragma unroll
            for (int ic = 0; ic < 3; ++ic)
                #pragma unroll
                for (int dy = 0; dy < 3; ++dy) {
                    int r = ic*3 + dy;
                    int rowb = ic*(19*66) + (2*li + dy)*66;
                    pa[r] = sZ[rowb + ox];
                    unsigned int u = sZ[rowb + ox + 1];
                    px[r] = __half2float(((const __half2*)&u)->x);
                }
            const bool phantom = (strip == 7) && (li == 8);
            #pragma unroll 4
            for (int oc2 = 0; oc2 < 16; ++oc2) {
                const int oca = 2*oc2, ocb = oca + 1;
                float acca = c1b[oca], accb = c1b[ocb];
                #pragma unroll
                for (int r = 0; r < 9; ++r) {
                    acca = fdot2(c1w01[oca*9 + r], pa[r], acca);
                    acca += c1w2[oca*9 + r] * px[r];
                    accb = fdot2(c1w01[ocb*9 + r], pa[r], accb);
                    accb += c1w2[ocb*9 + r] * px[r];
                }
                sC1[oc2*(9*66) + li*66 + ox] =
                    phantom ? 0u : packh2(fmaxf(acca, 0.f), fmaxf(accb, 0.f));
            }
        }
        __syncthreads();
        // conv2: 4 rows x 32 cols x 32 oc
        const int posl = t256 & 127;
        const int half = t256 >> 7;
        const int ly = posl >> 5;
        const int ox = posl & 31;
        float acc[16];
        #pragma unroll
        for (int j = 0; j < 16; ++j) acc[j] = 0.f;
        for (int ic2 = 0; ic2 < 16; ++ic2) {
            unsigned int patch[9];
            #pragma unroll
            for (int dy = 0; dy < 3; ++dy)
                #pragma unroll
                for (int dx = 0; dx < 3; ++dx)
                    patch[dy*3+dx] = sC1[ic2*(9*66) + (2*ly+dy)*66 + 2*ox + dx];
            const unsigned int* wblk = c2wP + (half*16 + ic2)*144;
            #pragma unroll
            for (int j = 0; j < 16; ++j) {
                float a = acc[j];
                #pragma unroll
                for (int q = 0; q < 9; ++q)
                    a = fdot2(wblk[q*16 + j], patch[q], a);
                acc[j] = a;
            }
        }
        const int oy = strip*4 + ly;
        #pragma unroll
        for (int j = 0; j < 16; ++j) {
            int oc = half*16 + j;
            zfeat[(((size_t)img*32 + oc)*32 + oy)*32 + ox] = fmaxf(acc[j] + c2b[oc], 0.f);
        }
    }
}

// ---------------- replay: reconstruct cseq from scalars, fully parallel
__global__ __launch_bounds__(256) void ntm_replay_kernel(
    const float* __restrict__ xfeat, const float* __restrict__ wbuf,
    const float* __restrict__ eag, const float* __restrict__ lnst,
    float* __restrict__ cseq)
{
    const int slab = blockIdx.x;
    const int b    = blockIdx.y;
    const int tid  = threadIdx.x;
    const int m    = tid >> 3;
    const int ns   = tid & 7;
    const int n0   = slab*64 + ns*8;
    const float mu = lnst[b*2], rs = lnst[b*2+1];

    float c[8];
    {
        const float* x0 = xfeat + (size_t)(b*16)*32768 + m*1024 + n0;
        float4 a = *(const float4*)x0;
        float4 bv = *(const float4*)(x0 + 4);
        c[0]=(a.x-mu)*rs; c[1]=(a.y-mu)*rs; c[2]=(a.z-mu)*rs; c[3]=(a.w-mu)*rs;
        c[4]=(bv.x-mu)*rs; c[5]=(bv.y-mu)*rs; c[6]=(bv.z-mu)*rs; c[7]=(bv.w-mu)*rs;
    }
    for (int t = 0; t < 16; ++t) {
        const size_t bt = (size_t)(b*16 + t);
        const float* wp = &wbuf[bt*1024 + n0];
        float4 wA = *(const float4*)wp;
        float4 wB = *(const float4*)(wp + 4);
        float e = eag[bt*80 + m];
        float a = eag[bt*80 + 32 + m];
        float g = eag[bt*80 + 64];
        float omg = 1.f - g;
        const float* xp = &xfeat[bt*32768 + m*1024 + n0];
        float4 xA = *(const float4*)xp;
        float4 xB = *(const float4*)(xp + 4);
        c[0] = omg*(c[0]*(1.f - wA.x*e) + wA.x*a) + g*xA.x;
        c[1] = omg*(c[1]*(1.f - wA.y*e) + wA.y*a) + g*xA.y;
        c[2] = omg*(c[2]*(1.f - wA.z*e) + wA.z*a) + g*xA.z;
        c[3] = omg*(c[3]*(1.f - wA.w*e) + wA.w*a) + g*xA.w;
        c[4] = omg*(c[4]*(1.f - wB.x*e) + wB.x*a) + g*xB.x;
        c[5] = omg*(c[5]*(1.f - wB.y*e) + wB.y*a) + g*xB.y;
        c[6] = omg*(c[6]*(1.f - wB.z*e) + wB.z*a) + g*xB.z;
        c[7] = omg*(c[7]*(1.f - wB.w*e) + wB.w*a) + g*xB.w;
        float* op = &cseq[bt*32768 + m*1024 + n0];
        *(float4*)op       = make_float4(c[0], c[1], c[2], c[3]);
        *(float4*)(op + 4) = make_float4(c[4], c[5], c[6], c[7]);
    }
}

// ---------------- rfft2: table-driven DFT, both inputs in ONE dispatch
__global__ __launch_bounds__(256) void fft_fwd_kernel(const float* __restrict__ srcA,
                                                      const float* __restrict__ srcB,
                                                      const float* __restrict__ cosw,
                                                      const float* __restrict__ twg,
                                                      float* __restrict__ dstA,
                                                      float* __restrict__ dstB)
{
    const int img = blockIdx.x;
    const int tid = threadIdx.x;
    const float* src; float* dst;
    if (img < 4096) { src = srcA + (size_t)img*1024;        dst = dstA + (size_t)img*1088; }
    else            { src = srcB + (size_t)(img-4096)*1024; dst = dstB + (size_t)(img-4096)*1088; }

    __shared__ __align__(16) float sY[32*36];
    __shared__ __align__(16) float sT[2048];
    __shared__ __align__(16) float sR[2048];

    {
        const float4* s4 = (const float4*)twg;
        float4* d4 = (float4*)sT;
        d4[tid]       = s4[tid];
        d4[256 + tid] = s4[256 + tid];
    }
    {
        float4 v = *(const float4*)&src[tid*4];
        float4 c = *(const float4*)&cosw[tid*4];
        *(float4*)&sY[(tid>>3)*36 + (tid&7)*4] = make_float4(v.x*c.x, v.y*c.y, v.z*c.z, v.w*c.w);
    }
    __syncthreads();

    const int hj = tid >> 3;
    const int k0 = (tid & 7) * 4;

    float r0=0.f,i0=0.f,r1=0.f,i1=0.f,r2=0.f,i2=0.f,r3=0.f,i3=0.f;
    #pragma unroll
    for (int w = 0; w < 32; ++w) {
        float y = sY[hj*36 + w];
        float4 ta = *(const float4*)&sT[(w*32 + k0)*2];
        float4 tb = *(const float4*)&sT[(w*32 + k0)*2 + 4];
        r0 += y*ta.x; i0 += y*ta.y;
        r1 += y*ta.z; i1 += y*ta.w;
        r2 += y*tb.x; i2 += y*tb.y;
        r3 += y*tb.z; i3 += y*tb.w;
    }
    *(float4*)&sR[(hj*32 + k0)*2]     = make_float4(r0,i0,r1,i1);
    *(float4*)&sR[(hj*32 + k0)*2 + 4] = make_float4(r2,i2,r3,i3);
    __syncthreads();

    float fr0=0.f,fi0=0.f,fr1=0.f,fi1=0.f,fr2=0.f,fi2=0.f,fr3=0.f,fi3=0.f;
    #pragma unroll
    for (int h = 0; h < 32; ++h) {
        float2 wj = *(const float2*)&sT[(h*32 + hj)*2];
        float4 Ra = *(const float4*)&sR[(h*32 + k0)*2];
        float4 Rb = *(const float4*)&sR[(h*32 + k0)*2 + 4];
        fr0 += Ra.x*wj.x - Ra.y*wj.y;  fi0 += Ra.x*wj.y + Ra.y*wj.x;
        fr1 += Ra.z*wj.x - Ra.w*wj.y;  fi1 += Ra.z*wj.y + Ra.w*wj.x;
        fr2 += Rb.x*wj.x - Rb.y*wj.y;  fi2 += Rb.x*wj.y + Rb.y*wj.x;
        fr3 += Rb.z*wj.x - Rb.w*wj.y;  fi3 += Rb.z*wj.y + Rb.w*wj.x;
    }
    float* dp = dst + (size_t)(hj*17 + k0)*2;
    if (k0 < 16) {
        *(float2*)&dp[0] = make_float2(fr0, fi0);
        *(float2*)&dp[2] = make_float2(fr1, fi1);
        *(float2*)&dp[4] = make_float2(fr2, fi2);
        *(float2*)&dp[6] = make_float2(fr3, fi3);
    } else if (k0 == 16) {
        *(float2*)&dp[0] = make_float2(fr0, fi0);
    }
}

// ---------------- fused combine + irfft2; one block per bt
__global__ __launch_bounds__(256) void comb_ifft_kernel(const float* __restrict__ cfft,
                                                        const float* __restrict__ zfft,
                                                        const float* __restrict__ yf,
                                                        float* __restrict__ out)
{
    const int bt  = blockIdx.x;
    const int tid = threadIdx.x;
    __shared__ float sG[544*2];
    __shared__ float sS[544*2];
    __shared__ float ct[32], st[32];
    if (tid < 32) {
        float sv, cv;
        sincosf(TWOPI_32 * (float)tid, &sv, &cv);
        ct[tid] = cv; st[tid] = sv;
    }
    for (int idx = tid; idx < 544; idx += 256) {
        float kzz = 0.f, kxr = 0.f, kxi = 0.f;
        #pragma unroll 4
        for (int m = 0; m < 32; ++m) {
            size_t base = ((size_t)(bt*32 + m)*1088) + idx*2;
            float2 c = *(const float2*)&cfft[base];
            float2 z = *(const float2*)&zfft[base];
            kzz += c.x*c.x + c.y*c.y;
            kxr += z.x*c.x + z.y*c.y;
            kxi += z.y*c.x - z.x*c.y;
        }
        float den = 1.f / (kzz + 1e-4f);
        float2 y = *(const float2*)&yf[idx*2];
        float ar = y.x*den, ai = y.y*den;
        sG[idx*2]     = kxr*ar - kxi*ai;
        sG[idx*2 + 1] = kxr*ai + kxi*ar;
    }
    __syncthreads();
    for (int idx = tid; idx < 544; idx += 256) {
        int h = idx / 17;
        int k = idx - h*17;
        float re = 0.f, im = 0.f;
        #pragma unroll
        for (int j = 0; j < 32; ++j) {
            float gr = sG[(j*17+k)*2], gi = sG[(j*17+k)*2+1];
            int a = (h*j) & 31;
            float c = ct[a], s = st[a];
            re += gr*c - gi*s;
            im += gr*s + gi*c;
        }
        sS[(h*17+k)*2] = re; sS[(h*17+k)*2+1] = im;
    }
    __syncthreads();
    #pragma unroll
    for (int p = 0; p < 4; ++p) {
        int pos = p*256 + tid;
        int h = pos >> 5, wq = pos & 31;
        float acc = sS[(h*17)*2];
        #pragma unroll
        for (int k = 1; k < 16; ++k) {
            int a = (wq*k) & 31;
            acc += 2.f*(sS[(h*17+k)*2]*ct[a] - sS[(h*17+k)*2+1]*st[a]);
        }
        acc += sS[(h*17+16)*2] * ((wq & 1) ? -1.f : 1.f);
        out[(size_t)bt*1024 + pos] = acc * (1.f/1024.f);
    }
}

extern "C" void kernel_launch(void* const* d_in, const int* in_sizes, int n_in,
                              void* d_out, int out_size, void* d_ws, size_t ws_size,
                              hipStream_t stream)
{
    const float* x_i   = (const float*)d_in[0];
    const float* z_i   = (const float*)d_in[1];
    const float* c1w   = (const float*)d_in[2];
    const float* c1b   = (const float*)d_in[3];
    const float* c2w   = (const float*)d_in[4];
    const float* c2b   = (const float*)d_in[5];
    const float* Wk    = (const float*)d_in[6];
    const float* bk    = (const float*)d_in[7];
    const float* Wbeta = (const float*)d_in[8];
    const float* bbeta = (const float*)d_in[9];
    const float* Wh    = (const float*)d_in[10];
    const float* bh    = (const float*)d_in[11];
    const float* We    = (const float*)d_in[12];
    const float* Wa    = (const float*)d_in[13];
    const float* Wg    = (const float*)d_in[14];
    const float* cosw  = (const float*)d_in[15];
    const float* yf    = (const float*)d_in[16];
    float* out = (float*)d_out;
    float* ws  = (float*)d_ws;

    // workspace layout (floats)
    unsigned int* buf1p = (unsigned int*)ws;    // packed conv1(x) out: 8,388,608 u32
    float*  xfeat = ws + 16777216;      // 4,194,304
    float*  zfeat = ws + 20971520;      // 4,194,304
    float*  cseq  = ws + 25165824;      // 4,194,304 (ends 29,360,128)
    float*  xmb   = ws + 29499392;      // 4,096
    float*  cfft  = ws;                 // 4,456,448 f (after convs)
    float*  zfft  = ws + 4456448;       // 4,456,448 f
    __half* xhb   = (__half*)(ws + 9000000);    // 4,194,304 halfs
    float*  wbuf  = ws + 11100000;      // 131,072 f
    float*  eag   = ws + 11240000;      // 10,240 f
    float*  lnstp = ws + 11251000;      // 16 f
    // prepack outputs in the dead gap [29,360,128 .. 29,499,392)
    __half* whhP  = (__half*)(ws + 29360128);
    __half* whrxP = (__half*)(ws + 29392896);
    __half* wkP   = (__half*)(ws + 29401088);
    __half* weP   = (__half*)(ws + 29405184);
    __half* waP   = (__half*)(ws + 29409280);
    float*  twg   = ws + 29413376;
    unsigned int* c2wP   = (unsigned int*)(ws + 29415424);
    unsigned int* c1wP01 = (unsigned int*)(ws + 29420032);
    float*  c1wP2 = ws + 29420320;      // ends 29,420,608

    dim3 b256(256);
    prepack_kernel<<<33, b256, 0, stream>>>(Wh, Wk, We, Wa, c1w, c2w,
                                            whhP, whrxP, wkP, weP, waP, twg,
                                            c2wP, c1wP01, c1wP2);
    conv1_kernel<<<dim3(4,128), b256, 0, stream>>>(x_i, c1wP01, c1wP2, c1b, buf1p);
    conv2_kernel<<<dim3(8,128), b256, 0, stream>>>(buf1p, c2wP, c2b, xfeat);
    prep2_kernel<<<128, b256, 0, stream>>>(xfeat, xhb, xmb);
    fat_kernel<<<520, 512, 0, stream>>>(xfeat, xhb, xmb, whhP, whrxP, wkP, weP, waP,
                                        bk, Wbeta, bbeta, bh, Wg, wbuf, eag, lnstp,
                                        z_i, c1wP01, c1wP2, c1b, c2wP, c2b, zfeat);
    ntm_replay_kernel<<<dim3(16,8), b256, 0, stream>>>(xfeat, wbuf, eag, lnstp, cseq);
    fft_fwd_kernel<<<8192, b256, 0, stream>>>(cseq, zfeat, cosw, twg, cfft, zfft);
    comb_ifft_kernel<<<128, b256, 0, stream>>>(cfft, zfft, yf, out);
}

// Round 12
// 445.660 us; speedup vs baseline: 2.0181x; 1.2946x over previous
//
#include <hip/hip_runtime.h>
#include <hip/hip_fp16.h>
#include <math.h>

// B=8, T=16, IMG=128, CF=32, WO=HO=32, N=1024, M=32, DH=256
// conv SAME stride2: pad_lo=0, pad_hi=1 -> in_idx = 2*out + k

#define TWOPI_32 0.19634954084936207f  // 2*pi/32

typedef _Float16 __h2 __attribute__((ext_vector_type(2)));
__device__ __forceinline__ float fdot2(unsigned int w, unsigned int h, float acc) {
    union { unsigned int u; __h2 v; } a, b;
    a.u = w; b.u = h;
    return __builtin_amdgcn_fdot2(a.v, b.v, acc, false);
}
__device__ __forceinline__ unsigned int packh2(float a, float b) {
    __half2 h2 = __floats2half2_rn(a, b);
    return *(unsigned int*)&h2;
}

// ---------------- prepack: all weight packs + twiddle
// c2wP padded layout: [half][ic2][j][12] u32, entries q=0..8 valid (pads unread)
__global__ __launch_bounds__(256) void prepack_kernel(
    const float* __restrict__ Wh, const float* __restrict__ Wk,
    const float* __restrict__ We, const float* __restrict__ Wa,
    const float* __restrict__ c1w, const float* __restrict__ c2w,
    __half* __restrict__ whhP, __half* __restrict__ whrxP,
    __half* __restrict__ wkP, __half* __restrict__ weP, __half* __restrict__ waP,
    float* __restrict__ twg,
    unsigned int* __restrict__ c2wP, unsigned int* __restrict__ c1wP01,
    float* __restrict__ c1wP2)
{
    const int tid = threadIdx.x;
    if (blockIdx.x < 32) {
        const int base = blockIdx.x*256 + tid;   // 0..8191
        #pragma unroll
        for (int r = 0; r < 8; ++r) {
            int idx = base*8 + r;
            int e = idx & 7, i = (idx >> 3) & 255, c = idx >> 11;
            int q = c >> 4, k = c & 15;
            whhP[idx] = __float2half(Wh[i*320 + q*128 + k*8 + e]);
        }
        #pragma unroll
        for (int r = 0; r < 2; ++r) {
            int idx = base*2 + r;
            int i = idx >> 6, s2 = idx & 63;
            whrxP[idx] = __float2half(Wh[i*320 + 256 + s2]);
        }
        {
            int idx = base;
            int m = idx >> 8, j = (idx >> 4) & 15, e = idx & 15;
            int col = (e < 8) ? (8*j + e) : (128 + 8*j + (e - 8));
            wkP[idx] = __float2half(Wk[m*256 + col]);
            weP[idx] = __float2half(We[m*256 + col]);
            waP[idx] = __float2half(Wa[m*256 + col]);
        }
    } else {
        // conv2 weights, padded [half][ic2][j][12]
        for (int idx = tid; idx < 4608; idx += 256) {
            int half = idx / 2304;
            int rem  = idx - half*2304;
            int ic2  = rem / 144;
            int r2   = rem - ic2*144;
            int j    = r2 / 9, q = r2 - j*9;
            int oc   = half*16 + j;
            c2wP[((half*16 + ic2)*16 + j)*12 + q] =
                packh2(c2w[oc*288 + (2*ic2)*9 + q],
                       c2w[oc*288 + (2*ic2+1)*9 + q]);
        }
        // conv1 weights: pairs (dx0,dx1) + scalar dx2
        for (int idx = tid; idx < 288; idx += 256) {
            int oc = idx / 9, r = idx - oc*9;        // r = ic*3+dy
            c1wP01[idx] = packh2(c1w[oc*27 + r*3 + 0], c1w[oc*27 + r*3 + 1]);
            c1wP2[idx]  = c1w[oc*27 + r*3 + 2];
        }
        for (int idx = tid; idx < 1024; idx += 256) {
            int w = idx >> 5, k = idx & 31;
            float sv, cv;
            sincosf(TWOPI_32 * (float)((w*k) & 31), &sv, &cv);
            twg[idx*2]     = cv;
            twg[idx*2 + 1] = -sv;
        }
    }
}

// ---------------- conv1 (x path): [img][3][128][128] -> packed u32 [img][16 oc2][64][64]
__global__ __launch_bounds__(256) void conv1_kernel(const float* __restrict__ in,
                                                    const unsigned int* __restrict__ w01,
                                                    const float* __restrict__ w2,
                                                    const float* __restrict__ bias,
                                                    unsigned int* __restrict__ out)
{
    const int strip = blockIdx.x;   // 4 strips of 16 output rows
    const int img   = blockIdx.y;
    const int tid   = threadIdx.x;
    __shared__ __align__(16) unsigned int sIn2[3*33*66];
    __shared__ unsigned int sw01[288];
    __shared__ float sw2[288];
    __shared__ float sb[32];
    for (int i = tid; i < 288; i += 256) { sw01[i] = w01[i]; sw2[i] = w2[i]; }   // FIX: strided
    if (tid < 32) sb[tid] = bias[tid];
    const int iy0 = strip * 32;
    for (int idx = tid; idx < 3*33*66; idx += 256) {
        int ic  = idx / (33*66);
        int rem = idx - ic*(33*66);
        int li  = rem / 66;
        int x2  = rem - li*66;
        int iy  = iy0 + li;
        unsigned int v = 0;
        if (iy < 128 && x2 < 64) {
            float2 p = *(const float2*)&in[(((size_t)img*3 + ic)*128 + iy)*128 + 2*x2];
            v = packh2(p.x, p.y);
        }
        sIn2[idx] = v;
    }
    __syncthreads();
    const int oy0 = strip*16;
    #pragma unroll
    for (int p = 0; p < 4; ++p) {
        int pos = p*256 + tid;       // 16 rows x 64 cols
        int ly = pos >> 6;
        int ox = pos & 63;
        unsigned int pa[9];
        float px[9];
        #pragma unroll
        for (int ic = 0; ic < 3; ++ic)
            #pragma unroll
            for (int dy = 0; dy < 3; ++dy) {
                int r = ic*3 + dy;
                int rowb = ic*(33*66) + (2*ly+dy)*66;
                pa[r] = sIn2[rowb + ox];
                unsigned int u = sIn2[rowb + ox + 1];
                px[r] = __half2float(((const __half2*)&u)->x);
            }
        for (int oc2 = 0; oc2 < 16; ++oc2) {
            const int oca = 2*oc2, ocb = 2*oc2 + 1;
            float acca = sb[oca], accb = sb[ocb];
            #pragma unroll
            for (int r = 0; r < 9; ++r) {
                acca = fdot2(sw01[oca*9 + r], pa[r], acca);
                acca += sw2[oca*9 + r] * px[r];
                accb = fdot2(sw01[ocb*9 + r], pa[r], accb);
                accb += sw2[ocb*9 + r] * px[r];
            }
            out[(((size_t)img*16 + oc2)*64 + (oy0+ly))*64 + ox] =
                packh2(fmaxf(acca, 0.f), fmaxf(accb, 0.f));
        }
    }
}

// ---------------- conv2 (x path): packed u32 in -> [img][32][32][32]; weights in LDS
__global__ __launch_bounds__(256) void conv2_kernel(const unsigned int* __restrict__ in,
                                                    const unsigned int* __restrict__ wP,
                                                    const float* __restrict__ bias,
                                                    float* __restrict__ out)
{
    const int strip = blockIdx.x;   // 8 strips of 4 output rows
    const int img   = blockIdx.y;
    const int tid   = threadIdx.x;
    __shared__ __align__(16) unsigned int sIn2[16*9*66];
    __shared__ __align__(16) unsigned int sW[6144];
    __shared__ float sb[32];
    for (int i = tid; i < 1536; i += 256) ((uint4*)sW)[i] = ((const uint4*)wP)[i];
    if (tid < 32) sb[tid] = bias[tid];
    const int iy0 = strip*8;
    for (int idx = tid; idx < 16*9*66; idx += 256) {
        int ic2 = idx / (9*66);
        int rem = idx - ic2*(9*66);
        int li  = rem / 66;
        int col = rem - li*66;
        int iy  = iy0 + li;
        unsigned int v = 0;
        if (iy < 64 && col < 64)
            v = in[(((size_t)img*16 + ic2)*64 + iy)*64 + col];
        sIn2[idx] = v;
    }
    __syncthreads();
    const int posl = tid & 127;
    const int half = tid >> 7;
    const int ly = posl >> 5;
    const int ox = posl & 31;
    float acc[16];
    #pragma unroll
    for (int j = 0; j < 16; ++j) acc[j] = 0.f;
    for (int ic2 = 0; ic2 < 16; ++ic2) {
        unsigned int patch[9];
        #pragma unroll
        for (int dy = 0; dy < 3; ++dy)
            #pragma unroll
            for (int dx = 0; dx < 3; ++dx)
                patch[dy*3+dx] = sIn2[ic2*(9*66) + (2*ly+dy)*66 + 2*ox + dx];
        const unsigned int* wbase = sW + (half*16 + ic2)*192;
        #pragma unroll
        for (int j = 0; j < 16; ++j) {
            const unsigned int* wr = wbase + j*12;
            uint4 wa = *(const uint4*)wr;
            uint4 wb = *(const uint4*)(wr + 4);
            unsigned int w8 = wr[8];
            float a = acc[j];
            a = fdot2(wa.x, patch[0], a); a = fdot2(wa.y, patch[1], a);
            a = fdot2(wa.z, patch[2], a); a = fdot2(wa.w, patch[3], a);
            a = fdot2(wb.x, patch[4], a); a = fdot2(wb.y, patch[5], a);
            a = fdot2(wb.z, patch[6], a); a = fdot2(wb.w, patch[7], a);
            a = fdot2(w8,  patch[8], a);
            acc[j] = a;
        }
    }
    const int oy = strip*4 + ly;
    #pragma unroll
    for (int j = 0; j < 16; ++j) {
        int oc = half*16 + j;
        out[(((size_t)img*32 + oc)*32 + oy)*32 + ox] = fmaxf(acc[j] + sb[oc], 0.f);
    }
}

// ---------------- prep2: xhalf-transpose + xmean
__global__ __launch_bounds__(256) void prep2_kernel(
    const float* __restrict__ xf, __half* __restrict__ xh, float* __restrict__ xmean)
{
    const int tid = threadIdx.x;
    const int bt = blockIdx.x;
    __shared__ float sT[32][257];
    const float* src = xf + (size_t)bt*32768;
    __half* dst = xh + (size_t)bt*32768;
    for (int tt = 0; tt < 4; ++tt) {
        #pragma unroll
        for (int m = 0; m < 32; ++m)
            sT[m][tid] = src[m*1024 + tt*256 + tid];
        __syncthreads();
        uint4 o[4];
        unsigned int* ou = (unsigned int*)o;
        #pragma unroll
        for (int k = 0; k < 16; ++k)
            ou[k] = packh2(sT[2*k][tid], sT[2*k+1][tid]);
        uint4* dp = (uint4*)(dst + (size_t)(tt*256 + tid)*32);
        dp[0] = o[0]; dp[1] = o[1]; dp[2] = o[2]; dp[3] = o[3];
        __syncthreads();
    }
    const int m = tid >> 3, s8 = tid & 7;
    float sm = 0.f;
    #pragma unroll 16
    for (int k = 0; k < 128; ++k) sm += src[m*1024 + s8 + 8*k];
    sm += __shfl_down(sm, 4, 8); sm += __shfl_down(sm, 2, 8); sm += __shfl_down(sm, 1, 8);
    if (s8 == 0) xmean[bt*32 + m] = sm * (1.f/1024.f);
}

// ---------------- FAT: blocks 0..7 = NTM recurrence; blocks 8.. = fused conv1+conv2 (z)
__global__ __launch_bounds__(512, 2) void fat_kernel(
    const float* __restrict__ xfeat, const __half* __restrict__ xh,
    const float* __restrict__ xmean,
    const __half* __restrict__ whhP, const __half* __restrict__ whrxP,
    const __half* __restrict__ wkP, const __half* __restrict__ weP,
    const __half* __restrict__ waP,
    const float* __restrict__ bk, const float* __restrict__ Wbeta,
    const float* __restrict__ bbeta, const float* __restrict__ bh,
    const float* __restrict__ Wg,
    float* __restrict__ wbuf, float* __restrict__ eag, float* __restrict__ lnst,
    const float* __restrict__ z_i, const unsigned int* __restrict__ c1w01,
    const float* __restrict__ c1w2, const float* __restrict__ c1b,
    const unsigned int* __restrict__ c2wP, const float* __restrict__ c2b,
    float* __restrict__ zfeat)
{
    __shared__ __align__(16) char smem[139264];

    if (blockIdx.x < 8) {
        // ======== NTM branch ========
        __half* sWhh = (__half*)(smem);                    // 131072 B
        float (*sHbuf)[256] = (float(*)[256])(smem + 131072);
        __half (*sHh)[256] = (__half(*)[256])(smem + 133120);
        float* sK    = (float*)(smem + 134144);
        float* sXm   = (float*)(smem + 134272);
        float* sRedC = (float*)(smem + 136320);
        float* sR32  = (float*)(smem + 137344);
        float* sE    = (float*)(smem + 137472);
        float* sA    = (float*)(smem + 137600);
        float* sBk   = (float*)(smem + 137728);
        float* sBh   = (float*)(smem + 137856);
        float* sRedD = (float*)(smem + 138880);
        float* sRedL = (float*)(smem + 138912);

        const int b    = blockIdx.x;
        const int tid  = threadIdx.x;
        const int lane = tid & 63;
        const int wid  = tid >> 6;

        {
            const uint4* src = (const uint4*)whhP;
            uint4* dst = (uint4*)sWhh;
            for (int i2 = tid; i2 < 8192; i2 += 512) dst[i2] = src[i2];
        }
        if (tid < 256) { sBh[tid] = bh[tid]; sHbuf[0][tid] = 0.f; sHh[0][tid] = __float2half(0.f); }
        if (tid < 32)  { sBk[tid] = bk[tid]; sK[tid] = tanhf(bk[tid]); }
        if (tid < 512) sXm[tid] = xmean[b*512 + tid];
        float4 wbeta4 = *(const float4*)&Wbeta[(size_t)lane*4];
        float4 wg4    = *(const float4*)&Wg[(size_t)lane*4];
        float bb = bbeta[0];

        const int mg = tid >> 4, jg = tid & 15;
        uint4 wk0, wk1, we0, we1, wa0, wa1;
        {
            const uint4* p;
            p = (const uint4*)(wkP + (size_t)(mg*16 + jg)*16); wk0 = p[0]; wk1 = p[1];
            p = (const uint4*)(weP + (size_t)(mg*16 + jg)*16); we0 = p[0]; we1 = p[1];
            p = (const uint4*)(waP + (size_t)(mg*16 + jg)*16); wa0 = p[0]; wa1 = p[1];
        }
        const int iD = tid >> 1, qD = tid & 1;
        uint4 wrx0, wrx1, wrx2, wrx3;
        {
            const uint4* p = (const uint4*)(whrxP + (size_t)iD*64 + qD*32);
            wrx0 = p[0]; wrx1 = p[1]; wrx2 = p[2]; wrx3 = p[3];
        }

        const int n0 = 2*tid;
        float c0[32], c1[32];

        {
            const float* x0 = xfeat + (size_t)(b*16)*32768;
            float sum = 0.f, ss = 0.f;
            #pragma unroll
            for (int m = 0; m < 32; ++m) {
                float2 v = *(const float2*)&x0[m*1024 + n0];
                c0[m] = v.x; c1[m] = v.y;
                sum += v.x + v.y; ss += v.x*v.x + v.y*v.y;
            }
            #pragma unroll
            for (int d = 32; d > 0; d >>= 1) { sum += __shfl_xor(sum, d, 64); ss += __shfl_xor(ss, d, 64); }
            if (lane == 0) { sRedL[wid] = sum; sRedL[8+wid] = ss; }
            __syncthreads();
            float S = 0.f, SS = 0.f;
            #pragma unroll
            for (int i = 0; i < 8; ++i) { S += sRedL[i]; SS += sRedL[8+i]; }
            float mu = S * (1.f/32768.f);
            float var = SS * (1.f/32768.f) - mu*mu;
            float rs = rsqrtf(var + 1e-5f);
            if (tid == 0) { lnst[b*2] = mu; lnst[b*2+1] = rs; }
            #pragma unroll
            for (int m = 0; m < 32; ++m) { c0[m] = (c0[m]-mu)*rs; c1[m] = (c1[m]-mu)*rs; }
        }

        uint4 xb[8];
        {
            const uint4* xrow = (const uint4*)(xh + (size_t)(b*16)*32768) + 8*tid;
            #pragma unroll
            for (int i = 0; i < 8; ++i) xb[i] = xrow[i];
        }
        __syncthreads();

        float betav = (bb > 20.f) ? bb : log1pf(expf(bb));
        float ex0 = 0.f, ex1 = 0.f, w0 = 0.f, w1 = 0.f;
        const int rm = ((lane&1)<<4)|((lane&2)<<2)|(lane&4)|((lane&8)>>2)|((lane&16)>>4);

        #pragma unroll 1
        for (int t = 0; t < 16; ++t) {
            const int cur = t & 1, nxt = cur ^ 1;

            // PH_A
            {
                float beta = betav;
                float dot0 = 0.f, dot1 = 0.f, cn20 = 0.f, cn21 = 0.f, kn2 = 0.f;
                #pragma unroll
                for (int q = 0; q < 8; ++q) {
                    float4 k4 = *(const float4*)&sK[4*q];
                    dot0 += c0[4*q]*k4.x + c0[4*q+1]*k4.y + c0[4*q+2]*k4.z + c0[4*q+3]*k4.w;
                    dot1 += c1[4*q]*k4.x + c1[4*q+1]*k4.y + c1[4*q+2]*k4.z + c1[4*q+3]*k4.w;
                    cn20 += c0[4*q]*c0[4*q] + c0[4*q+1]*c0[4*q+1] + c0[4*q+2]*c0[4*q+2] + c0[4*q+3]*c0[4*q+3];
                    cn21 += c1[4*q]*c1[4*q] + c1[4*q+1]*c1[4*q+1] + c1[4*q+2]*c1[4*q+2] + c1[4*q+3]*c1[4*q+3];
                    kn2  += k4.x*k4.x + k4.y*k4.y + k4.z*k4.z + k4.w*k4.w;
                }
                float kinv = 1.f / (sqrtf(kn2) + 1e-8f);
                float s0 = dot0 * kinv / (sqrtf(cn20) + 1e-8f);
                float s1 = dot1 * kinv / (sqrtf(cn21) + 1e-8f);
                ex0 = expf(beta * s0);
                ex1 = expf(beta * s1);
                float es = ex0 + ex1;
                #pragma unroll
                for (int d = 32; d > 0; d >>= 1) es += __shfl_xor(es, d, 64);
                if (lane == 0) sRedD[wid] = es;
                float v[32];
                #pragma unroll
                for (int m = 0; m < 32; ++m) v[m] = ex0*c0[m] + ex1*c1[m];
                #pragma unroll
                for (int i = 0; i < 16; ++i) { float sd = (lane&1)? v[i] : v[i+16]; float rc = __shfl_xor(sd, 1, 64); v[i] = ((lane&1)? v[i+16] : v[i]) + rc; }
                #pragma unroll
                for (int i = 0; i < 8; ++i)  { float sd = (lane&2)? v[i] : v[i+8];  float rc = __shfl_xor(sd, 2, 64); v[i] = ((lane&2)? v[i+8]  : v[i]) + rc; }
                #pragma unroll
                for (int i = 0; i < 4; ++i)  { float sd = (lane&4)? v[i] : v[i+4];  float rc = __shfl_xor(sd, 4, 64); v[i] = ((lane&4)? v[i+4]  : v[i]) + rc; }
                #pragma unroll
                for (int i = 0; i < 2; ++i)  { float sd = (lane&8)? v[i] : v[i+2];  float rc = __shfl_xor(sd, 8, 64); v[i] = ((lane&8)? v[i+2]  : v[i]) + rc; }
                { float sd = (lane&16)? v[0] : v[1]; float rc = __shfl_xor(sd, 16, 64); v[0] = ((lane&16)? v[1] : v[0]) + rc; }
                v[0] += __shfl_xor(v[0], 32, 64);
                if (lane < 32) sRedC[wid*32 + rm] = v[0];
            }
            __syncthreads();

            // PH_B
            {
                float den = sRedD[0]+sRedD[1]+sRedD[2]+sRedD[3]+sRedD[4]+sRedD[5]+sRedD[6]+sRedD[7];
                float inv = 1.f / den;
                w0 = ex0 * inv; w1 = ex1 * inv;
                *(float2*)&wbuf[(size_t)(b*16 + t)*1024 + n0] = make_float2(w0, w1);
                if (lane < 32) {
                    float r = 0.f;
                    #pragma unroll
                    for (int w = 0; w < 8; ++w) r += sRedC[w*32 + lane];
                    sR32[lane] = r * inv;
                }
                float s0 = 0.f, s1 = 0.f, s2 = 0.f, s3 = 0.f;
                #pragma unroll
                for (int k4 = 0; k4 < 4; ++k4) {
                    const int kb = 4*k4;
                    uint4 wv0 = *(const uint4*)&sWhh[(size_t)((qD*16 + kb+0)*256 + iD)*8];
                    uint4 hv0 = *(const uint4*)&sHh[cur][qD*128 + (kb+0)*8];
                    s0 = fdot2(wv0.x, hv0.x, s0); s0 = fdot2(wv0.y, hv0.y, s0);
                    s0 = fdot2(wv0.z, hv0.z, s0); s0 = fdot2(wv0.w, hv0.w, s0);
                    uint4 wv1 = *(const uint4*)&sWhh[(size_t)((qD*16 + kb+1)*256 + iD)*8];
                    uint4 hv1 = *(const uint4*)&sHh[cur][qD*128 + (kb+1)*8];
                    s1 = fdot2(wv1.x, hv1.x, s1); s1 = fdot2(wv1.y, hv1.y, s1);
                    s1 = fdot2(wv1.z, hv1.z, s1); s1 = fdot2(wv1.w, hv1.w, s1);
                    uint4 wv2 = *(const uint4*)&sWhh[(size_t)((qD*16 + kb+2)*256 + iD)*8];
                    uint4 hv2 = *(const uint4*)&sHh[cur][qD*128 + (kb+2)*8];
                    s2 = fdot2(wv2.x, hv2.x, s2); s2 = fdot2(wv2.y, hv2.y, s2);
                    s2 = fdot2(wv2.z, hv2.z, s2); s2 = fdot2(wv2.w, hv2.w, s2);
                    uint4 wv3 = *(const uint4*)&sWhh[(size_t)((qD*16 + kb+3)*256 + iD)*8];
                    uint4 hv3 = *(const uint4*)&sHh[cur][qD*128 + (kb+3)*8];
                    s3 = fdot2(wv3.x, hv3.x, s3); s3 = fdot2(wv3.y, hv3.y, s3);
                    s3 = fdot2(wv3.z, hv3.z, s3); s3 = fdot2(wv3.w, hv3.w, s3);
                }
                const float* rxsrc = qD ? &sXm[t*32] : sR32;
                {
                    const __half2* w2;
                    float4 va, vb;
                    va = *(const float4*)&rxsrc[0];  vb = *(const float4*)&rxsrc[4];
                    w2 = (const __half2*)&wrx0;
                    { float2 p0 = __half22float2(w2[0]); s0 += p0.x*va.x + p0.y*va.y;
                      float2 p1 = __half22float2(w2[1]); s0 += p1.x*va.z + p1.y*va.w;
                      float2 p2 = __half22float2(w2[2]); s0 += p2.x*vb.x + p2.y*vb.y;
                      float2 p3 = __half22float2(w2[3]); s0 += p3.x*vb.z + p3.y*vb.w; }
                    va = *(const float4*)&rxsrc[8];  vb = *(const float4*)&rxsrc[12];
                    w2 = (const __half2*)&wrx1;
                    { float2 p0 = __half22float2(w2[0]); s1 += p0.x*va.x + p0.y*va.y;
                      float2 p1 = __half22float2(w2[1]); s1 += p1.x*va.z + p1.y*va.w;
                      float2 p2 = __half22float2(w2[2]); s1 += p2.x*vb.x + p2.y*vb.y;
                      float2 p3 = __half22float2(w2[3]); s1 += p3.x*vb.z + p3.y*vb.w; }
                    va = *(const float4*)&rxsrc[16]; vb = *(const float4*)&rxsrc[20];
                    w2 = (const __half2*)&wrx2;
                    { float2 p0 = __half22float2(w2[0]); s2 += p0.x*va.x + p0.y*va.y;
                      float2 p1 = __half22float2(w2[1]); s2 += p1.x*va.z + p1.y*va.w;
                      float2 p2 = __half22float2(w2[2]); s2 += p2.x*vb.x + p2.y*vb.y;
                      float2 p3 = __half22float2(w2[3]); s2 += p3.x*vb.z + p3.y*vb.w; }
                    va = *(const float4*)&rxsrc[24]; vb = *(const float4*)&rxsrc[28];
                    w2 = (const __half2*)&wrx3;
                    { float2 p0 = __half22float2(w2[0]); s3 += p0.x*va.x + p0.y*va.y;
                      float2 p1 = __half22float2(w2[1]); s3 += p1.x*va.z + p1.y*va.w;
                      float2 p2 = __half22float2(w2[2]); s3 += p2.x*vb.x + p2.y*vb.y;
                      float2 p3 = __half22float2(w2[3]); s3 += p3.x*vb.z + p3.y*vb.w; }
                }
                float s = (s0 + s1) + (s2 + s3);
                s += __shfl_down(s, 1, 2);
                if (qD == 0) {
                    float hn = tanhf(s + sBh[iD]);
                    sHbuf[nxt][iD] = hn;
                    sHh[nxt][iD] = __float2half(hn);
                }
            }
            __syncthreads();

            // PH_C
            float gg;
            {
                uint4 h0 = *(const uint4*)&sHh[nxt][8*jg];
                uint4 h1 = *(const uint4*)&sHh[nxt][128 + 8*jg];
                float se0=0.f, se1=0.f, sa0=0.f, sa1=0.f, sk0=0.f, sk1=0.f;
                se0 = fdot2(we0.x, h0.x, se0); se1 = fdot2(we0.y, h0.y, se1);
                se0 = fdot2(we0.z, h0.z, se0); se1 = fdot2(we0.w, h0.w, se1);
                se0 = fdot2(we1.x, h1.x, se0); se1 = fdot2(we1.y, h1.y, se1);
                se0 = fdot2(we1.z, h1.z, se0); se1 = fdot2(we1.w, h1.w, se1);
                sa0 = fdot2(wa0.x, h0.x, sa0); sa1 = fdot2(wa0.y, h0.y, sa1);
                sa0 = fdot2(wa0.z, h0.z, sa0); sa1 = fdot2(wa0.w, h0.w, sa1);
                sa0 = fdot2(wa1.x, h1.x, sa0); sa1 = fdot2(wa1.y, h1.y, sa1);
                sa0 = fdot2(wa1.z, h1.z, sa0); sa1 = fdot2(wa1.w, h1.w, sa1);
                sk0 = fdot2(wk0.x, h0.x, sk0); sk1 = fdot2(wk0.y, h0.y, sk1);
                sk0 = fdot2(wk0.z, h0.z, sk0); sk1 = fdot2(wk0.w, h0.w, sk1);
                sk0 = fdot2(wk1.x, h1.x, sk0); sk1 = fdot2(wk1.y, h1.y, sk1);
                sk0 = fdot2(wk1.z, h1.z, sk0); sk1 = fdot2(wk1.w, h1.w, sk1);
                float se = se0 + se1, sa = sa0 + sa1, sk = sk0 + sk1;
                se += __shfl_down(se, 8, 16); sa += __shfl_down(sa, 8, 16); sk += __shfl_down(sk, 8, 16);
                se += __shfl_down(se, 4, 16); sa += __shfl_down(sa, 4, 16); sk += __shfl_down(sk, 4, 16);
                se += __shfl_down(se, 2, 16); sa += __shfl_down(sa, 2, 16); sk += __shfl_down(sk, 2, 16);
                se += __shfl_down(se, 1, 16); sa += __shfl_down(sa, 1, 16); sk += __shfl_down(sk, 1, 16);
                if (jg == 0) {
                    float e = 1.f/(1.f + expf(-se));
                    float a = tanhf(sa);
                    sE[mg] = e; sA[mg] = a;
                    sK[mg] = tanhf(sk + sBk[mg]);
                    eag[(size_t)(b*16 + t)*80 + mg]      = e;
                    eag[(size_t)(b*16 + t)*80 + 32 + mg] = a;
                }
                float4 h4 = *(const float4*)&sHbuf[nxt][lane*4];
                float pg = wg4.x*h4.x + wg4.y*h4.y + wg4.z*h4.z + wg4.w*h4.w;
                float pb = wbeta4.x*h4.x + wbeta4.y*h4.y + wbeta4.z*h4.z + wbeta4.w*h4.w;
                #pragma unroll
                for (int d = 32; d > 0; d >>= 1) {
                    pg += __shfl_xor(pg, d, 64);
                    pb += __shfl_xor(pb, d, 64);
                }
                gg = 1.f/(1.f + expf(-pg));
                float xbeta = pb + bb;
                betav = (xbeta > 20.f) ? xbeta : log1pf(expf(xbeta));
                if (tid == 0) eag[(size_t)(b*16 + t)*80 + 64] = gg;
            }
            __syncthreads();

            // PH_D
            {
                float omg = 1.f - gg;
                const __half* xp = (const __half*)xb;
                #pragma unroll
                for (int q = 0; q < 8; ++q) {
                    float4 e4 = *(const float4*)&sE[4*q];
                    float4 a4 = *(const float4*)&sA[4*q];
                    #pragma unroll
                    for (int r = 0; r < 4; ++r) {
                        int m = 4*q + r;
                        float e = (r==0)?e4.x:(r==1)?e4.y:(r==2)?e4.z:e4.w;
                        float a = (r==0)?a4.x:(r==1)?a4.y:(r==2)?a4.z:a4.w;
                        float x0v = __half2float(xp[m]);
                        float x1v = __half2float(xp[32 + m]);
                        c0[m] = omg*(c0[m]*(1.f - w0*e) + w0*a) + gg*x0v;
                        c1[m] = omg*(c1[m]*(1.f - w1*e) + w1*a) + gg*x1v;
                    }
                }
                if (t < 15) {
                    const uint4* xrow = (const uint4*)(xh + (size_t)(b*16 + t + 1)*32768) + 8*tid;
                    #pragma unroll
                    for (int i = 0; i < 8; ++i) xb[i] = xrow[i];
                }
            }
        }
    } else {
        // ======== fused conv1+conv2 (z): 2 tiles/block; weights staged in shared LDS ========
        const int team = threadIdx.x >> 8;
        const int t256 = threadIdx.x & 255;
        const int tile = (blockIdx.x - 8)*2 + team;   // 0..1023
        const int img  = tile >> 3;
        const int strip = tile & 7;
        unsigned int* sZ  = (unsigned int*)(smem + team*53072);           // [3][19][66]
        unsigned int* sC1 = (unsigned int*)(smem + team*53072 + 15048);   // [16][9][66]
        unsigned int* sW   = (unsigned int*)(smem + 106144);              // 6144 u32
        unsigned int* sw01 = (unsigned int*)(smem + 130720);              // 288
        float*        sw2  = (float*)(smem + 131872);                     // 288
        float*        sb2  = (float*)(smem + 133024);                     // 32
        float*        sb1  = (float*)(smem + 133152);                     // 32

        for (int i = threadIdx.x; i < 1536; i += 512)
            ((uint4*)sW)[i] = ((const uint4*)c2wP)[i];
        for (int i = threadIdx.x; i < 288; i += 512) { sw01[i] = c1w01[i]; sw2[i] = c1w2[i]; }
        if (threadIdx.x < 32) { sb2[threadIdx.x] = c2b[threadIdx.x]; sb1[threadIdx.x] = c1b[threadIdx.x]; }

        const int zrow0 = strip*16;
        for (int idx = t256; idx < 3762; idx += 256) {
            int ic = idx / (19*66);
            int rem = idx - ic*(19*66);
            int li = rem / 66;
            int x2 = rem - li*66;
            int iy = zrow0 + li;
            unsigned int v = 0;
            if (iy < 128 && x2 < 64) {
                float2 p = *(const float2*)&z_i[(((size_t)img*3 + ic)*128 + iy)*128 + 2*x2];
                v = packh2(p.x, p.y);
            }
            sZ[idx] = v;
        }
        for (int idx = t256; idx < 16*9*2; idx += 256) {
            int oc2 = idx / 18; int rem = idx - oc2*18; int li = rem >> 1; int c = 64 + (rem & 1);
            sC1[oc2*(9*66) + li*66 + c] = 0;
        }
        __syncthreads();
        // conv1: 9 rows x 64 cols (phantom row 64 at strip 7 -> 0)
        for (int pos = t256; pos < 576; pos += 256) {
            int li = pos >> 6;
            int ox = pos & 63;
            unsigned int pa[9]; float px[9];
            #pragma unroll
            for (int ic = 0; ic < 3; ++ic)
                #pragma unroll
                for (int dy = 0; dy < 3; ++dy) {
                    int r = ic*3 + dy;
                    int rowb = ic*(19*66) + (2*li + dy)*66;
                    pa[r] = sZ[rowb + ox];
                    unsigned int u = sZ[rowb + ox + 1];
                    px[r] = __half2float(((const __half2*)&u)->x);
                }
            const bool phantom = (strip == 7) && (li == 8);
            #pragma unroll 4
            for (int oc2 = 0; oc2 < 16; ++oc2) {
                const int oca = 2*oc2, ocb = oca + 1;
                float acca = sb1[oca], accb = sb1[ocb];
                #pragma unroll
                for (int r = 0; r < 9; ++r) {
                    acca = fdot2(sw01[oca*9 + r], pa[r], acca);
                    acca += sw2[oca*9 + r] * px[r];
                    accb = fdot2(sw01[ocb*9 + r], pa[r], accb);
                    accb += sw2[ocb*9 + r] * px[r];
                }
                sC1[oc2*(9*66) + li*66 + ox] =
                    phantom ? 0u : packh2(fmaxf(acca, 0.f), fmaxf(accb, 0.f));
            }
        }
        __syncthreads();
        // conv2: 4 rows x 32 cols x 32 oc; weights from LDS (b128 reads)
        const int posl = t256 & 127;
        const int half = t256 >> 7;
        const int ly = posl >> 5;
        const int ox = posl & 31;
        float acc[16];
        #pragma unroll
        for (int j = 0; j < 16; ++j) acc[j] = 0.f;
        for (int ic2 = 0; ic2 < 16; ++ic2) {
            unsigned int patch[9];
            #pragma unroll
            for (int dy = 0; dy < 3; ++dy)
                #pragma unroll
                for (int dx = 0; dx < 3; ++dx)
                    patch[dy*3+dx] = sC1[ic2*(9*66) + (2*ly+dy)*66 + 2*ox + dx];
            const unsigned int* wbase = sW + (half*16 + ic2)*192;
            #pragma unroll
            for (int j = 0; j < 16; ++j) {
                const unsigned int* wr = wbase + j*12;
                uint4 wa = *(const uint4*)wr;
                uint4 wb = *(const uint4*)(wr + 4);
                unsigned int w8 = wr[8];
                float a = acc[j];
                a = fdot2(wa.x, patch[0], a); a = fdot2(wa.y, patch[1], a);
                a = fdot2(wa.z, patch[2], a); a = fdot2(wa.w, patch[3], a);
                a = fdot2(wb.x, patch[4], a); a = fdot2(wb.y, patch[5], a);
                a = fdot2(wb.z, patch[6], a); a = fdot2(wb.w, patch[7], a);
                a = fdot2(w8,  patch[8], a);
                acc[j] = a;
            }
        }
        const int oy = strip*4 + ly;
        #pragma unroll
        for (int j = 0; j < 16; ++j) {
            int oc = half*16 + j;
            zfeat[(((size_t)img*32 + oc)*32 + oy)*32 + ox] = fmaxf(acc[j] + sb2[oc], 0.f);
        }
    }
}

// ---------------- replay: reconstruct cseq from scalars, fully parallel
__global__ __launch_bounds__(256) void ntm_replay_kernel(
    const float* __restrict__ xfeat, const float* __restrict__ wbuf,
    const float* __restrict__ eag, const float* __restrict__ lnst,
    float* __restrict__ cseq)
{
    const int slab = blockIdx.x;
    const int b    = blockIdx.y;
    const int tid  = threadIdx.x;
    const int m    = tid >> 3;
    const int ns   = tid & 7;
    const int n0   = slab*64 + ns*8;
    const float mu = lnst[b*2], rs = lnst[b*2+1];

    float c[8];
    {
        const float* x0 = xfeat + (size_t)(b*16)*32768 + m*1024 + n0;
        float4 a = *(const float4*)x0;
        float4 bv = *(const float4*)(x0 + 4);
        c[0]=(a.x-mu)*rs; c[1]=(a.y-mu)*rs; c[2]=(a.z-mu)*rs; c[3]=(a.w-mu)*rs;
        c[4]=(bv.x-mu)*rs; c[5]=(bv.y-mu)*rs; c[6]=(bv.z-mu)*rs; c[7]=(bv.w-mu)*rs;
    }
    for (int t = 0; t < 16; ++t) {
        const size_t bt = (size_t)(b*16 + t);
        const float* wp = &wbuf[bt*1024 + n0];
        float4 wA = *(const float4*)wp;
        float4 wB = *(const float4*)(wp + 4);
        float e = eag[bt*80 + m];
        float a = eag[bt*80 + 32 + m];
        float g = eag[bt*80 + 64];
        float omg = 1.f - g;
        const float* xp = &xfeat[bt*32768 + m*1024 + n0];
        float4 xA = *(const float4*)xp;
        float4 xB = *(const float4*)(xp + 4);
        c[0] = omg*(c[0]*(1.f - wA.x*e) + wA.x*a) + g*xA.x;
        c[1] = omg*(c[1]*(1.f - wA.y*e) + wA.y*a) + g*xA.y;
        c[2] = omg*(c[2]*(1.f - wA.z*e) + wA.z*a) + g*xA.z;
        c[3] = omg*(c[3]*(1.f - wA.w*e) + wA.w*a) + g*xA.w;
        c[4] = omg*(c[4]*(1.f - wB.x*e) + wB.x*a) + g*xB.x;
        c[5] = omg*(c[5]*(1.f - wB.y*e) + wB.y*a) + g*xB.y;
        c[6] = omg*(c[6]*(1.f - wB.z*e) + wB.z*a) + g*xB.z;
        c[7] = omg*(c[7]*(1.f - wB.w*e) + wB.w*a) + g*xB.w;
        float* op = &cseq[bt*32768 + m*1024 + n0];
        *(float4*)op       = make_float4(c[0], c[1], c[2], c[3]);
        *(float4*)(op + 4) = make_float4(c[4], c[5], c[6], c[7]);
    }
}

// ---------------- rfft2: table-driven DFT, both inputs in ONE dispatch
__global__ __launch_bounds__(256) void fft_fwd_kernel(const float* __restrict__ srcA,
                                                      const float* __restrict__ srcB,
                                                      const float* __restrict__ cosw,
                                                      const float* __restrict__ twg,
                                                      float* __restrict__ dstA,
                                                      float* __restrict__ dstB)
{
    const int img = blockIdx.x;
    const int tid = threadIdx.x;
    const float* src; float* dst;
    if (img < 4096) { src = srcA + (size_t)img*1024;        dst = dstA + (size_t)img*1088; }
    else            { src = srcB + (size_t)(img-4096)*1024; dst = dstB + (size_t)(img-4096)*1088; }

    __shared__ __align__(16) float sY[32*36];
    __shared__ __align__(16) float sT[2048];
    __shared__ __align__(16) float sR[2048];

    {
        const float4* s4 = (const float4*)twg;
        float4* d4 = (float4*)sT;
        d4[tid]       = s4[tid];
        d4[256 + tid] = s4[256 + tid];
    }
    {
        float4 v = *(const float4*)&src[tid*4];
        float4 c = *(const float4*)&cosw[tid*4];
        *(float4*)&sY[(tid>>3)*36 + (tid&7)*4] = make_float4(v.x*c.x, v.y*c.y, v.z*c.z, v.w*c.w);
    }
    __syncthreads();

    const int hj = tid >> 3;
    const int k0 = (tid & 7) * 4;

    float r0=0.f,i0=0.f,r1=0.f,i1=0.f,r2=0.f,i2=0.f,r3=0.f,i3=0.f;
    #pragma unroll
    for (int w = 0; w < 32; ++w) {
        float y = sY[hj*36 + w];
        float4 ta = *(const float4*)&sT[(w*32 + k0)*2];
        float4 tb = *(const float4*)&sT[(w*32 + k0)*2 + 4];
        r0 += y*ta.x; i0 += y*ta.y;
        r1 += y*ta.z; i1 += y*ta.w;
        r2 += y*tb.x; i2 += y*tb.y;
        r3 += y*tb.z; i3 += y*tb.w;
    }
    *(float4*)&sR[(hj*32 + k0)*2]     = make_float4(r0,i0,r1,i1);
    *(float4*)&sR[(hj*32 + k0)*2 + 4] = make_float4(r2,i2,r3,i3);
    __syncthreads();

    float fr0=0.f,fi0=0.f,fr1=0.f,fi1=0.f,fr2=0.f,fi2=0.f,fr3=0.f,fi3=0.f;
    #pragma unroll
    for (int h = 0; h < 32; ++h) {
        float2 wj = *(const float2*)&sT[(h*32 + hj)*2];
        float4 Ra = *(const float4*)&sR[(h*32 + k0)*2];
        float4 Rb = *(const float4*)&sR[(h*32 + k0)*2 + 4];
        fr0 += Ra.x*wj.x - Ra.y*wj.y;  fi0 += Ra.x*wj.y + Ra.y*wj.x;
        fr1 += Ra.z*wj.x - Ra.w*wj.y;  fi1 += Ra.z*wj.y + Ra.w*wj.x;
        fr2 += Rb.x*wj.x - Rb.y*wj.y;  fi2 += Rb.x*wj.y + Rb.y*wj.x;
        fr3 += Rb.z*wj.x - Rb.w*wj.y;  fi3 += Rb.z*wj.y + Rb.w*wj.x;
    }
    float* dp = dst + (size_t)(hj*17 + k0)*2;
    if (k0 < 16) {
        *(float2*)&dp[0] = make_float2(fr0, fi0);
        *(float2*)&dp[2] = make_float2(fr1, fi1);
        *(float2*)&dp[4] = make_float2(fr2, fi2);
        *(float2*)&dp[6] = make_float2(fr3, fi3);
    } else if (k0 == 16) {
        *(float2*)&dp[0] = make_float2(fr0, fi0);
    }
}

// ---------------- fused combine + irfft2; one block per bt
__global__ __launch_bounds__(256) void comb_ifft_kernel(const float* __restrict__ cfft,
                                                        const float* __restrict__ zfft,
                                                        const float* __restrict__ yf,
                                                        float* __restrict__ out)
{
    const int bt  = blockIdx.x;
    const int tid = threadIdx.x;
    __shared__ float sG[544*2];
    __shared__ float sS[544*2];
    __shared__ float ct[32], st[32];
    if (tid < 32) {
        float sv, cv;
        sincosf(TWOPI_32 * (float)tid, &sv, &cv);
        ct[tid] = cv; st[tid] = sv;
    }
    for (int idx = tid; idx < 544; idx += 256) {
        float kzz = 0.f, kxr = 0.f, kxi = 0.f;
        #pragma unroll 4
        for (int m = 0; m < 32; ++m) {
            size_t base = ((size_t)(bt*32 + m)*1088) + idx*2;
            float2 c = *(const float2*)&cfft[base];
            float2 z = *(const float2*)&zfft[base];
            kzz += c.x*c.x + c.y*c.y;
            kxr += z.x*c.x + z.y*c.y;
            kxi += z.y*c.x - z.x*c.y;
        }
        float den = 1.f / (kzz + 1e-4f);
        float2 y = *(const float2*)&yf[idx*2];
        float ar = y.x*den, ai = y.y*den;
        sG[idx*2]     = kxr*ar - kxi*ai;
        sG[idx*2 + 1] = kxr*ai + kxi*ar;
    }
    __syncthreads();
    for (int idx = tid; idx < 544; idx += 256) {
        int h = idx / 17;
        int k = idx - h*17;
        float re = 0.f, im = 0.f;
        #pragma unroll
        for (int j = 0; j < 32; ++j) {
            float gr = sG[(j*17+k)*2], gi = sG[(j*17+k)*2+1];
            int a = (h*j) & 31;
            float c = ct[a], s = st[a];
            re += gr*c - gi*s;
            im += gr*s + gi*c;
        }
        sS[(h*17+k)*2] = re; sS[(h*17+k)*2+1] = im;
    }
    __syncthreads();
    #pragma unroll
    for (int p = 0; p < 4; ++p) {
        int pos = p*256 + tid;
        int h = pos >> 5, wq = pos & 31;
        float acc = sS[(h*17)*2];
        #pragma unroll
        for (int k = 1; k < 16; ++k) {
            int a = (wq*k) & 31;
            acc += 2.f*(sS[(h*17+k)*2]*ct[a] - sS[(h*17+k)*2+1]*st[a]);
        }
        acc += sS[(h*17+16)*2] * ((wq & 1) ? -1.f : 1.f);
        out[(size_t)bt*1024 + pos] = acc * (1.f/1024.f);
    }
}

extern "C" void kernel_launch(void* const* d_in, const int* in_sizes, int n_in,
                              void* d_out, int out_size, void* d_ws, size_t ws_size,
                              hipStream_t stream)
{
    const float* x_i   = (const float*)d_in[0];
    const float* z_i   = (const float*)d_in[1];
    const float* c1w   = (const float*)d_in[2];
    const float* c1b   = (const float*)d_in[3];
    const float* c2w   = (const float*)d_in[4];
    const float* c2b   = (const float*)d_in[5];
    const float* Wk    = (const float*)d_in[6];
    const float* bk    = (const float*)d_in[7];
    const float* Wbeta = (const float*)d_in[8];
    const float* bbeta = (const float*)d_in[9];
    const float* Wh    = (const float*)d_in[10];
    const float* bh    = (const float*)d_in[11];
    const float* We    = (const float*)d_in[12];
    const float* Wa    = (const float*)d_in[13];
    const float* Wg    = (const float*)d_in[14];
    const float* cosw  = (const float*)d_in[15];
    const float* yf    = (const float*)d_in[16];
    float* out = (float*)d_out;
    float* ws  = (float*)d_ws;

    // workspace layout (floats)
    unsigned int* buf1p = (unsigned int*)ws;    // packed conv1(x) out: 8,388,608 u32
    float*  xfeat = ws + 16777216;      // 4,194,304
    float*  zfeat = ws + 20971520;      // 4,194,304
    float*  cseq  = ws + 25165824;      // 4,194,304 (ends 29,360,128)
    float*  xmb   = ws + 29499392;      // 4,096
    float*  cfft  = ws;                 // 4,456,448 f (after convs)
    float*  zfft  = ws + 4456448;       // 4,456,448 f
    __half* xhb   = (__half*)(ws + 9000000);    // 4,194,304 halfs
    float*  wbuf  = ws + 11100000;      // 131,072 f
    float*  eag   = ws + 11240000;      // 10,240 f
    float*  lnstp = ws + 11251000;      // 16 f
    // prepack outputs in the dead gap [29,360,128 .. 29,499,392)
    __half* whhP  = (__half*)(ws + 29360128);
    __half* whrxP = (__half*)(ws + 29392896);
    __half* wkP   = (__half*)(ws + 29401088);
    __half* weP   = (__half*)(ws + 29405184);
    __half* waP   = (__half*)(ws + 29409280);
    float*  twg   = ws + 29413376;
    unsigned int* c2wP   = (unsigned int*)(ws + 29415424);  // 6,144 u32 -> ends 29,421,568
    unsigned int* c1wP01 = (unsigned int*)(ws + 29421568);  // 288 u32
    float*  c1wP2 = ws + 29421856;      // 288 f -> ends 29,422,144 (< 29,499,392 OK)

    dim3 b256(256);
    prepack_kernel<<<33, b256, 0, stream>>>(Wh, Wk, We, Wa, c1w, c2w,
                                            whhP, whrxP, wkP, weP, waP, twg,
                                            c2wP, c1wP01, c1wP2);
    conv1_kernel<<<dim3(4,128), b256, 0, stream>>>(x_i, c1wP01, c1wP2, c1b, buf1p);
    conv2_kernel<<<dim3(8,128), b256, 0, stream>>>(buf1p, c2wP, c2b, xfeat);
    prep2_kernel<<<128, b256, 0, stream>>>(xfeat, xhb, xmb);
    fat_kernel<<<520, 512, 0, stream>>>(xfeat, xhb, xmb, whhP, whrxP, wkP, weP, waP,
                                        bk, Wbeta, bbeta, bh, Wg, wbuf, eag, lnstp,
                                        z_i, c1wP01, c1wP2, c1b, c2wP, c2b, zfeat);
    ntm_replay_kernel<<<dim3(16,8), b256, 0, stream>>>(xfeat, wbuf, eag, lnstp, cseq);
    fft_fwd_kernel<<<8192, b256, 0, stream>>>(cseq, zfeat, cosw, twg, cfft, zfft);
    comb_ifft_kernel<<<128, b256, 0, stream>>>(cfft, zfft, yf, out);
}

// Round 13
// 427.918 us; speedup vs baseline: 2.1018x; 1.0415x over previous
//
#include <hip/hip_runtime.h>
#include <hip/hip_fp16.h>
#include <math.h>

// B=8, T=16, IMG=128, CF=32, WO=HO=32, N=1024, M=32, DH=256
// conv SAME stride2: pad_lo=0, pad_hi=1 -> in_idx = 2*out + k

#define TWOPI_32 0.19634954084936207f  // 2*pi/32

typedef _Float16 __h2 __attribute__((ext_vector_type(2)));
__device__ __forceinline__ float fdot2(unsigned int w, unsigned int h, float acc) {
    union { unsigned int u; __h2 v; } a, b;
    a.u = w; b.u = h;
    return __builtin_amdgcn_fdot2(a.v, b.v, acc, false);
}
__device__ __forceinline__ unsigned int packh2(float a, float b) {
    __half2 h2 = __floats2half2_rn(a, b);
    return *(unsigned int*)&h2;
}

// ---------------- prepack: all weight packs + twiddle
// c2wP padded layout: [half][ic2][j][12] u32, entries q=0..8 valid
__global__ __launch_bounds__(256) void prepack_kernel(
    const float* __restrict__ Wh, const float* __restrict__ Wk,
    const float* __restrict__ We, const float* __restrict__ Wa,
    const float* __restrict__ c1w, const float* __restrict__ c2w,
    __half* __restrict__ whhP, __half* __restrict__ whrxP,
    __half* __restrict__ wkP, __half* __restrict__ weP, __half* __restrict__ waP,
    float* __restrict__ twg,
    unsigned int* __restrict__ c2wP, unsigned int* __restrict__ c1wP01,
    float* __restrict__ c1wP2)
{
    const int tid = threadIdx.x;
    if (blockIdx.x < 32) {
        const int base = blockIdx.x*256 + tid;   // 0..8191
        #pragma unroll
        for (int r = 0; r < 8; ++r) {
            int idx = base*8 + r;
            int e = idx & 7, i = (idx >> 3) & 255, c = idx >> 11;
            int q = c >> 4, k = c & 15;
            whhP[idx] = __float2half(Wh[i*320 + q*128 + k*8 + e]);
        }
        #pragma unroll
        for (int r = 0; r < 2; ++r) {
            int idx = base*2 + r;
            int i = idx >> 6, s2 = idx & 63;
            whrxP[idx] = __float2half(Wh[i*320 + 256 + s2]);
        }
        {
            int idx = base;
            int m = idx >> 8, j = (idx >> 4) & 15, e = idx & 15;
            int col = (e < 8) ? (8*j + e) : (128 + 8*j + (e - 8));
            wkP[idx] = __float2half(Wk[m*256 + col]);
            weP[idx] = __float2half(We[m*256 + col]);
            waP[idx] = __float2half(Wa[m*256 + col]);
        }
    } else {
        for (int idx = tid; idx < 4608; idx += 256) {
            int half = idx / 2304;
            int rem  = idx - half*2304;
            int ic2  = rem / 144;
            int r2   = rem - ic2*144;
            int j    = r2 / 9, q = r2 - j*9;
            int oc   = half*16 + j;
            c2wP[((half*16 + ic2)*16 + j)*12 + q] =
                packh2(c2w[oc*288 + (2*ic2)*9 + q],
                       c2w[oc*288 + (2*ic2+1)*9 + q]);
        }
        for (int idx = tid; idx < 288; idx += 256) {
            int oc = idx / 9, r = idx - oc*9;        // r = ic*3+dy
            c1wP01[idx] = packh2(c1w[oc*27 + r*3 + 0], c1w[oc*27 + r*3 + 1]);
            c1wP2[idx]  = c1w[oc*27 + r*3 + 2];
        }
        for (int idx = tid; idx < 1024; idx += 256) {
            int w = idx >> 5, k = idx & 31;
            float sv, cv;
            sincosf(TWOPI_32 * (float)((w*k) & 31), &sv, &cv);
            twg[idx*2]     = cv;
            twg[idx*2 + 1] = -sv;
        }
    }
}

// ---------------- convx: fused conv1+conv2 (x path); writes xfeat + xh(f16,T) + xmp partials
// 512 blocks x 512 thr, 2 tiles/block (tile = img*8 + strip)
__global__ __launch_bounds__(512, 2) void convx_kernel(
    const float* __restrict__ x_i, const unsigned int* __restrict__ c1w01,
    const float* __restrict__ c1w2, const float* __restrict__ c1b,
    const unsigned int* __restrict__ c2wP, const float* __restrict__ c2b,
    float* __restrict__ xfeat, __half* __restrict__ xh, float* __restrict__ xmp)
{
    __shared__ __align__(16) char smem[139264];
    const int team = threadIdx.x >> 8;
    const int t256 = threadIdx.x & 255;
    const int tile = blockIdx.x*2 + team;   // 0..1023
    const int img  = tile >> 3;
    const int strip = tile & 7;
    unsigned int* sZ  = (unsigned int*)(smem + team*53072);           // [3][19][66]
    unsigned int* sC1 = (unsigned int*)(smem + team*53072 + 15048);   // [16][9][66]
    unsigned int* sW   = (unsigned int*)(smem + 106144);              // 6144 u32
    unsigned int* sw01 = (unsigned int*)(smem + 130720);              // 288
    float*        sw2  = (float*)(smem + 131872);                     // 288
    float*        sb2  = (float*)(smem + 133024);                     // 32
    float*        sb1  = (float*)(smem + 133152);                     // 32

    for (int i = threadIdx.x; i < 1536; i += 512)
        ((uint4*)sW)[i] = ((const uint4*)c2wP)[i];
    for (int i = threadIdx.x; i < 288; i += 512) { sw01[i] = c1w01[i]; sw2[i] = c1w2[i]; }
    if (threadIdx.x < 32) { sb2[threadIdx.x] = c2b[threadIdx.x]; sb1[threadIdx.x] = c1b[threadIdx.x]; }

    const int zrow0 = strip*16;
    for (int idx = t256; idx < 3762; idx += 256) {
        int ic = idx / (19*66);
        int rem = idx - ic*(19*66);
        int li = rem / 66;
        int x2 = rem - li*66;
        int iy = zrow0 + li;
        unsigned int v = 0;
        if (iy < 128 && x2 < 64) {
            float2 p = *(const float2*)&x_i[(((size_t)img*3 + ic)*128 + iy)*128 + 2*x2];
            v = packh2(p.x, p.y);
        }
        sZ[idx] = v;
    }
    for (int idx = t256; idx < 16*9*2; idx += 256) {
        int oc2 = idx / 18; int rem = idx - oc2*18; int li = rem >> 1; int c = 64 + (rem & 1);
        sC1[oc2*(9*66) + li*66 + c] = 0;
    }
    __syncthreads();
    // conv1: 9 rows x 64 cols (phantom row 64 at strip 7 -> 0)
    for (int pos = t256; pos < 576; pos += 256) {
        int li = pos >> 6;
        int ox = pos & 63;
        unsigned int pa[9]; float px[9];
        #pragma unroll
        for (int ic = 0; ic < 3; ++ic)
            #pragma unroll
            for (int dy = 0; dy < 3; ++dy) {
                int r = ic*3 + dy;
                int rowb = ic*(19*66) + (2*li + dy)*66;
                pa[r] = sZ[rowb + ox];
                unsigned int u = sZ[rowb + ox + 1];
                px[r] = __half2float(((const __half2*)&u)->x);
            }
        const bool phantom = (strip == 7) && (li == 8);
        #pragma unroll 4
        for (int oc2 = 0; oc2 < 16; ++oc2) {
            const int oca = 2*oc2, ocb = oca + 1;
            float acca = sb1[oca], accb = sb1[ocb];
            #pragma unroll
            for (int r = 0; r < 9; ++r) {
                acca = fdot2(sw01[oca*9 + r], pa[r], acca);
                acca += sw2[oca*9 + r] * px[r];
                accb = fdot2(sw01[ocb*9 + r], pa[r], accb);
                accb += sw2[ocb*9 + r] * px[r];
            }
            sC1[oc2*(9*66) + li*66 + ox] =
                phantom ? 0u : packh2(fmaxf(acca, 0.f), fmaxf(accb, 0.f));
        }
    }
    __syncthreads();
    // conv2: 4 rows x 32 cols x 32 oc; then emit xfeat/xh/xmp
    const int posl = t256 & 127;
    const int half = t256 >> 7;
    const int ly = posl >> 5;
    const int ox = posl & 31;
    float acc[16];
    #pragma unroll
    for (int j = 0; j < 16; ++j) acc[j] = 0.f;
    for (int ic2 = 0; ic2 < 16; ++ic2) {
        unsigned int patch[9];
        #pragma unroll
        for (int dy = 0; dy < 3; ++dy)
            #pragma unroll
            for (int dx = 0; dx < 3; ++dx)
                patch[dy*3+dx] = sC1[ic2*(9*66) + (2*ly+dy)*66 + 2*ox + dx];
        const unsigned int* wbase = sW + (half*16 + ic2)*192;
        #pragma unroll
        for (int j = 0; j < 16; ++j) {
            const unsigned int* wr = wbase + j*12;
            uint4 wa = *(const uint4*)wr;
            uint4 wb = *(const uint4*)(wr + 4);
            unsigned int w8 = wr[8];
            float a = acc[j];
            a = fdot2(wa.x, patch[0], a); a = fdot2(wa.y, patch[1], a);
            a = fdot2(wa.z, patch[2], a); a = fdot2(wa.w, patch[3], a);
            a = fdot2(wb.x, patch[4], a); a = fdot2(wb.y, patch[5], a);
            a = fdot2(wb.z, patch[6], a); a = fdot2(wb.w, patch[7], a);
            a = fdot2(w8,  patch[8], a);
            acc[j] = a;
        }
    }
    const int oy = strip*4 + ly;
    const int n  = oy*32 + ox;
    float vals[16];
    #pragma unroll
    for (int j = 0; j < 16; ++j) {
        int oc = half*16 + j;
        float v = fmaxf(acc[j] + sb2[oc], 0.f);
        vals[j] = v;
        xfeat[(((size_t)img*32 + oc)*32 + oy)*32 + ox] = v;
    }
    // xh: 16 halfs at [img][n][half*16..]
    {
        unsigned int hp[8];
        #pragma unroll
        for (int k = 0; k < 8; ++k) hp[k] = packh2(vals[2*k], vals[2*k+1]);
        uint4* dp = (uint4*)(xh + (size_t)img*32768 + (size_t)n*32 + half*16);
        dp[0] = *(uint4*)&hp[0];
        dp[1] = *(uint4*)&hp[4];
    }
    // xmp partials: wave-reduce each of 16 vals over 64 lanes, lane0 writes
    {
        const int lane = threadIdx.x & 63;
        const int wsub = (t256 >> 6) & 1;
        #pragma unroll
        for (int j = 0; j < 16; ++j) {
            float v = vals[j];
            #pragma unroll
            for (int d = 32; d > 0; d >>= 1) v += __shfl_xor(v, d, 64);
            if (lane == 0)
                xmp[(((size_t)img*8 + strip)*2 + wsub)*32 + half*16 + j] = v * (1.f/1024.f);
        }
    }
}

// ---------------- FAT: blocks 0..7 = NTM recurrence; blocks 8.. = fused conv1+conv2 (z)
__global__ __launch_bounds__(512, 2) void fat_kernel(
    const float* __restrict__ xfeat, const __half* __restrict__ xh,
    const float* __restrict__ xmp,
    const __half* __restrict__ whhP, const __half* __restrict__ whrxP,
    const __half* __restrict__ wkP, const __half* __restrict__ weP,
    const __half* __restrict__ waP,
    const float* __restrict__ bk, const float* __restrict__ Wbeta,
    const float* __restrict__ bbeta, const float* __restrict__ bh,
    const float* __restrict__ Wg,
    float* __restrict__ wbuf, float* __restrict__ eag, float* __restrict__ lnst,
    const float* __restrict__ z_i, const unsigned int* __restrict__ c1w01,
    const float* __restrict__ c1w2, const float* __restrict__ c1b,
    const unsigned int* __restrict__ c2wP, const float* __restrict__ c2b,
    float* __restrict__ zfeat)
{
    __shared__ __align__(16) char smem[139264];

    if (blockIdx.x < 8) {
        // ======== NTM branch ========
        __builtin_amdgcn_s_setprio(1);
        __half* sWhh = (__half*)(smem);                    // 131072 B
        float (*sHbuf)[256] = (float(*)[256])(smem + 131072);
        __half (*sHh)[256] = (__half(*)[256])(smem + 133120);
        float* sK    = (float*)(smem + 134144);
        float* sXm   = (float*)(smem + 134272);
        float* sRedC = (float*)(smem + 136320);
        float* sR32  = (float*)(smem + 137344);
        float* sE    = (float*)(smem + 137472);
        float* sA    = (float*)(smem + 137600);
        float* sBk   = (float*)(smem + 137728);
        float* sBh   = (float*)(smem + 137856);
        float* sRedD = (float*)(smem + 138880);
        float* sRedL = (float*)(smem + 138912);

        const int b    = blockIdx.x;
        const int tid  = threadIdx.x;
        const int lane = tid & 63;
        const int wid  = tid >> 6;

        {
            const uint4* src = (const uint4*)whhP;
            uint4* dst = (uint4*)sWhh;
            for (int i2 = tid; i2 < 8192; i2 += 512) dst[i2] = src[i2];
        }
        if (tid < 256) { sBh[tid] = bh[tid]; sHbuf[0][tid] = 0.f; sHh[0][tid] = __float2half(0.f); }
        if (tid < 32)  { sBk[tid] = bk[tid]; sK[tid] = tanhf(bk[tid]); }
        if (tid < 512) {
            const int tt = tid >> 5, m = tid & 31;
            const float* pp = xmp + ((size_t)(b*16 + tt)*16)*32 + m;
            float s = 0.f;
            #pragma unroll
            for (int q = 0; q < 16; ++q) s += pp[q*32];
            sXm[tid] = s;
        }
        float4 wbeta4 = *(const float4*)&Wbeta[(size_t)lane*4];
        float4 wg4    = *(const float4*)&Wg[(size_t)lane*4];
        float bb = bbeta[0];

        const int mg = tid >> 4, jg = tid & 15;
        uint4 wk0, wk1, we0, we1, wa0, wa1;
        {
            const uint4* p;
            p = (const uint4*)(wkP + (size_t)(mg*16 + jg)*16); wk0 = p[0]; wk1 = p[1];
            p = (const uint4*)(weP + (size_t)(mg*16 + jg)*16); we0 = p[0]; we1 = p[1];
            p = (const uint4*)(waP + (size_t)(mg*16 + jg)*16); wa0 = p[0]; wa1 = p[1];
        }
        const int iD = tid >> 1, qD = tid & 1;
        uint4 wrx0, wrx1, wrx2, wrx3;
        {
            const uint4* p = (const uint4*)(whrxP + (size_t)iD*64 + qD*32);
            wrx0 = p[0]; wrx1 = p[1]; wrx2 = p[2]; wrx3 = p[3];
        }

        const int n0 = 2*tid;
        float c0[32], c1[32];

        {
            const float* x0 = xfeat + (size_t)(b*16)*32768;
            float sum = 0.f, ss = 0.f;
            #pragma unroll
            for (int m = 0; m < 32; ++m) {
                float2 v = *(const float2*)&x0[m*1024 + n0];
                c0[m] = v.x; c1[m] = v.y;
                sum += v.x + v.y; ss += v.x*v.x + v.y*v.y;
            }
            #pragma unroll
            for (int d = 32; d > 0; d >>= 1) { sum += __shfl_xor(sum, d, 64); ss += __shfl_xor(ss, d, 64); }
            if (lane == 0) { sRedL[wid] = sum; sRedL[8+wid] = ss; }
            __syncthreads();
            float S = 0.f, SS = 0.f;
            #pragma unroll
            for (int i = 0; i < 8; ++i) { S += sRedL[i]; SS += sRedL[8+i]; }
            float mu = S * (1.f/32768.f);
            float var = SS * (1.f/32768.f) - mu*mu;
            float rs = rsqrtf(var + 1e-5f);
            if (tid == 0) { lnst[b*2] = mu; lnst[b*2+1] = rs; }
            #pragma unroll
            for (int m = 0; m < 32; ++m) { c0[m] = (c0[m]-mu)*rs; c1[m] = (c1[m]-mu)*rs; }
        }

        uint4 xb[8];
        {
            const uint4* xrow = (const uint4*)(xh + (size_t)(b*16)*32768) + 8*tid;
            #pragma unroll
            for (int i = 0; i < 8; ++i) xb[i] = xrow[i];
        }
        __syncthreads();

        float betav = (bb > 20.f) ? bb : log1pf(expf(bb));
        float ex0 = 0.f, ex1 = 0.f, w0 = 0.f, w1 = 0.f;
        const int rm = ((lane&1)<<4)|((lane&2)<<2)|(lane&4)|((lane&8)>>2)|((lane&16)>>4);

        #pragma unroll 1
        for (int t = 0; t < 16; ++t) {
            const int cur = t & 1, nxt = cur ^ 1;

            // PH_A
            {
                float beta = betav;
                float dot0 = 0.f, dot1 = 0.f, cn20 = 0.f, cn21 = 0.f, kn2 = 0.f;
                #pragma unroll
                for (int q = 0; q < 8; ++q) {
                    float4 k4 = *(const float4*)&sK[4*q];
                    dot0 += c0[4*q]*k4.x + c0[4*q+1]*k4.y + c0[4*q+2]*k4.z + c0[4*q+3]*k4.w;
                    dot1 += c1[4*q]*k4.x + c1[4*q+1]*k4.y + c1[4*q+2]*k4.z + c1[4*q+3]*k4.w;
                    cn20 += c0[4*q]*c0[4*q] + c0[4*q+1]*c0[4*q+1] + c0[4*q+2]*c0[4*q+2] + c0[4*q+3]*c0[4*q+3];
                    cn21 += c1[4*q]*c1[4*q] + c1[4*q+1]*c1[4*q+1] + c1[4*q+2]*c1[4*q+2] + c1[4*q+3]*c1[4*q+3];
                    kn2  += k4.x*k4.x + k4.y*k4.y + k4.z*k4.z + k4.w*k4.w;
                }
                float kinv = 1.f / (sqrtf(kn2) + 1e-8f);
                float s0 = dot0 * kinv / (sqrtf(cn20) + 1e-8f);
                float s1 = dot1 * kinv / (sqrtf(cn21) + 1e-8f);
                ex0 = expf(beta * s0);
                ex1 = expf(beta * s1);
                float es = ex0 + ex1;
                #pragma unroll
                for (int d = 32; d > 0; d >>= 1) es += __shfl_xor(es, d, 64);
                if (lane == 0) sRedD[wid] = es;
                float v[32];
                #pragma unroll
                for (int m = 0; m < 32; ++m) v[m] = ex0*c0[m] + ex1*c1[m];
                #pragma unroll
                for (int i = 0; i < 16; ++i) { float sd = (lane&1)? v[i] : v[i+16]; float rc = __shfl_xor(sd, 1, 64); v[i] = ((lane&1)? v[i+16] : v[i]) + rc; }
                #pragma unroll
                for (int i = 0; i < 8; ++i)  { float sd = (lane&2)? v[i] : v[i+8];  float rc = __shfl_xor(sd, 2, 64); v[i] = ((lane&2)? v[i+8]  : v[i]) + rc; }
                #pragma unroll
                for (int i = 0; i < 4; ++i)  { float sd = (lane&4)? v[i] : v[i+4];  float rc = __shfl_xor(sd, 4, 64); v[i] = ((lane&4)? v[i+4]  : v[i]) + rc; }
                #pragma unroll
                for (int i = 0; i < 2; ++i)  { float sd = (lane&8)? v[i] : v[i+2];  float rc = __shfl_xor(sd, 8, 64); v[i] = ((lane&8)? v[i+2]  : v[i]) + rc; }
                { float sd = (lane&16)? v[0] : v[1]; float rc = __shfl_xor(sd, 16, 64); v[0] = ((lane&16)? v[1] : v[0]) + rc; }
                v[0] += __shfl_xor(v[0], 32, 64);
                if (lane < 32) sRedC[wid*32 + rm] = v[0];
            }
            __syncthreads();

            // PH_B
            {
                float den = sRedD[0]+sRedD[1]+sRedD[2]+sRedD[3]+sRedD[4]+sRedD[5]+sRedD[6]+sRedD[7];
                float inv = 1.f / den;
                w0 = ex0 * inv; w1 = ex1 * inv;
                *(float2*)&wbuf[(size_t)(b*16 + t)*1024 + n0] = make_float2(w0, w1);
                if (lane < 32) {
                    float r = 0.f;
                    #pragma unroll
                    for (int w = 0; w < 8; ++w) r += sRedC[w*32 + lane];
                    sR32[lane] = r * inv;
                }
                float s0 = 0.f, s1 = 0.f, s2 = 0.f, s3 = 0.f;
                #pragma unroll
                for (int k4 = 0; k4 < 4; ++k4) {
                    const int kb = 4*k4;
                    uint4 wv0 = *(const uint4*)&sWhh[(size_t)((qD*16 + kb+0)*256 + iD)*8];
                    uint4 hv0 = *(const uint4*)&sHh[cur][qD*128 + (kb+0)*8];
                    s0 = fdot2(wv0.x, hv0.x, s0); s0 = fdot2(wv0.y, hv0.y, s0);
                    s0 = fdot2(wv0.z, hv0.z, s0); s0 = fdot2(wv0.w, hv0.w, s0);
                    uint4 wv1 = *(const uint4*)&sWhh[(size_t)((qD*16 + kb+1)*256 + iD)*8];
                    uint4 hv1 = *(const uint4*)&sHh[cur][qD*128 + (kb+1)*8];
                    s1 = fdot2(wv1.x, hv1.x, s1); s1 = fdot2(wv1.y, hv1.y, s1);
                    s1 = fdot2(wv1.z, hv1.z, s1); s1 = fdot2(wv1.w, hv1.w, s1);
                    uint4 wv2 = *(const uint4*)&sWhh[(size_t)((qD*16 + kb+2)*256 + iD)*8];
                    uint4 hv2 = *(const uint4*)&sHh[cur][qD*128 + (kb+2)*8];
                    s2 = fdot2(wv2.x, hv2.x, s2); s2 = fdot2(wv2.y, hv2.y, s2);
                    s2 = fdot2(wv2.z, hv2.z, s2); s2 = fdot2(wv2.w, hv2.w, s2);
                    uint4 wv3 = *(const uint4*)&sWhh[(size_t)((qD*16 + kb+3)*256 + iD)*8];
                    uint4 hv3 = *(const uint4*)&sHh[cur][qD*128 + (kb+3)*8];
                    s3 = fdot2(wv3.x, hv3.x, s3); s3 = fdot2(wv3.y, hv3.y, s3);
                    s3 = fdot2(wv3.w, hv3.w, s3); s3 = fdot2(wv3.z, hv3.z, s3);
                }
                const float* rxsrc = qD ? &sXm[t*32] : sR32;
                {
                    const __half2* w2;
                    float4 va, vb;
                    va = *(const float4*)&rxsrc[0];  vb = *(const float4*)&rxsrc[4];
                    w2 = (const __half2*)&wrx0;
                    { float2 p0 = __half22float2(w2[0]); s0 += p0.x*va.x + p0.y*va.y;
                      float2 p1 = __half22float2(w2[1]); s0 += p1.x*va.z + p1.y*va.w;
                      float2 p2 = __half22float2(w2[2]); s0 += p2.x*vb.x + p2.y*vb.y;
                      float2 p3 = __half22float2(w2[3]); s0 += p3.x*vb.z + p3.y*vb.w; }
                    va = *(const float4*)&rxsrc[8];  vb = *(const float4*)&rxsrc[12];
                    w2 = (const __half2*)&wrx1;
                    { float2 p0 = __half22float2(w2[0]); s1 += p0.x*va.x + p0.y*va.y;
                      float2 p1 = __half22float2(w2[1]); s1 += p1.x*va.z + p1.y*va.w;
                      float2 p2 = __half22float2(w2[2]); s1 += p2.x*vb.x + p2.y*vb.y;
                      float2 p3 = __half22float2(w2[3]); s1 += p3.x*vb.z + p3.y*vb.w; }
                    va = *(const float4*)&rxsrc[16]; vb = *(const float4*)&rxsrc[20];
                    w2 = (const __half2*)&wrx2;
                    { float2 p0 = __half22float2(w2[0]); s2 += p0.x*va.x + p0.y*va.y;
                      float2 p1 = __half22float2(w2[1]); s2 += p1.x*va.z + p1.y*va.w;
                      float2 p2 = __half22float2(w2[2]); s2 += p2.x*vb.x + p2.y*vb.y;
                      float2 p3 = __half22float2(w2[3]); s2 += p3.x*vb.z + p3.y*vb.w; }
                    va = *(const float4*)&rxsrc[24]; vb = *(const float4*)&rxsrc[28];
                    w2 = (const __half2*)&wrx3;
                    { float2 p0 = __half22float2(w2[0]); s3 += p0.x*va.x + p0.y*va.y;
                      float2 p1 = __half22float2(w2[1]); s3 += p1.x*va.z + p1.y*va.w;
                      float2 p2 = __half22float2(w2[2]); s3 += p2.x*vb.x + p2.y*vb.y;
                      float2 p3 = __half22float2(w2[3]); s3 += p3.x*vb.z + p3.y*vb.w; }
                }
                float s = (s0 + s1) + (s2 + s3);
                s += __shfl_down(s, 1, 2);
                if (qD == 0) {
                    float hn = tanhf(s + sBh[iD]);
                    sHbuf[nxt][iD] = hn;
                    sHh[nxt][iD] = __float2half(hn);
                }
            }
            __syncthreads();

            // PH_C
            float gg;
            {
                uint4 h0 = *(const uint4*)&sHh[nxt][8*jg];
                uint4 h1 = *(const uint4*)&sHh[nxt][128 + 8*jg];
                float se0=0.f, se1=0.f, sa0=0.f, sa1=0.f, sk0=0.f, sk1=0.f;
                se0 = fdot2(we0.x, h0.x, se0); se1 = fdot2(we0.y, h0.y, se1);
                se0 = fdot2(we0.z, h0.z, se0); se1 = fdot2(we0.w, h0.w, se1);
                se0 = fdot2(we1.x, h1.x, se0); se1 = fdot2(we1.y, h1.y, se1);
                se0 = fdot2(we1.z, h1.z, se0); se1 = fdot2(we1.w, h1.w, se1);
                sa0 = fdot2(wa0.x, h0.x, sa0); sa1 = fdot2(wa0.y, h0.y, sa1);
                sa0 = fdot2(wa0.z, h0.z, sa0); sa1 = fdot2(wa0.w, h0.w, sa1);
                sa0 = fdot2(wa1.x, h1.x, sa0); sa1 = fdot2(wa1.y, h1.y, sa1);
                sa0 = fdot2(wa1.z, h1.z, sa0); sa1 = fdot2(wa1.w, h1.w, sa1);
                sk0 = fdot2(wk0.x, h0.x, sk0); sk1 = fdot2(wk0.y, h0.y, sk1);
                sk0 = fdot2(wk0.z, h0.z, sk0); sk1 = fdot2(wk0.w, h0.w, sk1);
                sk0 = fdot2(wk1.x, h1.x, sk0); sk1 = fdot2(wk1.y, h1.y, sk1);
                sk0 = fdot2(wk1.z, h1.z, sk0); sk1 = fdot2(wk1.w, h1.w, sk1);
                float se = se0 + se1, sa = sa0 + sa1, sk = sk0 + sk1;
                se += __shfl_down(se, 8, 16); sa += __shfl_down(sa, 8, 16); sk += __shfl_down(sk, 8, 16);
                se += __shfl_down(se, 4, 16); sa += __shfl_down(sa, 4, 16); sk += __shfl_down(sk, 4, 16);
                se += __shfl_down(se, 2, 16); sa += __shfl_down(sa, 2, 16); sk += __shfl_down(sk, 2, 16);
                se += __shfl_down(se, 1, 16); sa += __shfl_down(sa, 1, 16); sk += __shfl_down(sk, 1, 16);
                if (jg == 0) {
                    float e = 1.f/(1.f + expf(-se));
                    float a = tanhf(sa);
                    sE[mg] = e; sA[mg] = a;
                    sK[mg] = tanhf(sk + sBk[mg]);
                    eag[(size_t)(b*16 + t)*80 + mg]      = e;
                    eag[(size_t)(b*16 + t)*80 + 32 + mg] = a;
                }
                float4 h4 = *(const float4*)&sHbuf[nxt][lane*4];
                float pg = wg4.x*h4.x + wg4.y*h4.y + wg4.z*h4.z + wg4.w*h4.w;
                float pb = wbeta4.x*h4.x + wbeta4.y*h4.y + wbeta4.z*h4.z + wbeta4.w*h4.w;
                #pragma unroll
                for (int d = 32; d > 0; d >>= 1) {
                    pg += __shfl_xor(pg, d, 64);
                    pb += __shfl_xor(pb, d, 64);
                }
                gg = 1.f/(1.f + expf(-pg));
                float xbeta = pb + bb;
                betav = (xbeta > 20.f) ? xbeta : log1pf(expf(xbeta));
                if (tid == 0) eag[(size_t)(b*16 + t)*80 + 64] = gg;
            }
            __syncthreads();

            // PH_D
            {
                float omg = 1.f - gg;
                const __half* xp = (const __half*)xb;
                #pragma unroll
                for (int q = 0; q < 8; ++q) {
                    float4 e4 = *(const float4*)&sE[4*q];
                    float4 a4 = *(const float4*)&sA[4*q];
                    #pragma unroll
                    for (int r = 0; r < 4; ++r) {
                        int m = 4*q + r;
                        float e = (r==0)?e4.x:(r==1)?e4.y:(r==2)?e4.z:e4.w;
                        float a = (r==0)?a4.x:(r==1)?a4.y:(r==2)?a4.z:a4.w;
                        float x0v = __half2float(xp[m]);
                        float x1v = __half2float(xp[32 + m]);
                        c0[m] = omg*(c0[m]*(1.f - w0*e) + w0*a) + gg*x0v;
                        c1[m] = omg*(c1[m]*(1.f - w1*e) + w1*a) + gg*x1v;
                    }
                }
                if (t < 15) {
                    const uint4* xrow = (const uint4*)(xh + (size_t)(b*16 + t + 1)*32768) + 8*tid;
                    #pragma unroll
                    for (int i = 0; i < 8; ++i) xb[i] = xrow[i];
                }
            }
        }
    } else {
        // ======== fused conv1+conv2 (z): 2 tiles/block; weights staged in shared LDS ========
        const int team = threadIdx.x >> 8;
        const int t256 = threadIdx.x & 255;
        const int tile = (blockIdx.x - 8)*2 + team;   // 0..1023
        const int img  = tile >> 3;
        const int strip = tile & 7;
        unsigned int* sZ  = (unsigned int*)(smem + team*53072);           // [3][19][66]
        unsigned int* sC1 = (unsigned int*)(smem + team*53072 + 15048);   // [16][9][66]
        unsigned int* sW   = (unsigned int*)(smem + 106144);              // 6144 u32
        unsigned int* sw01 = (unsigned int*)(smem + 130720);              // 288
        float*        sw2  = (float*)(smem + 131872);                     // 288
        float*        sb2  = (float*)(smem + 133024);                     // 32
        float*        sb1  = (float*)(smem + 133152);                     // 32

        for (int i = threadIdx.x; i < 1536; i += 512)
            ((uint4*)sW)[i] = ((const uint4*)c2wP)[i];
        for (int i = threadIdx.x; i < 288; i += 512) { sw01[i] = c1w01[i]; sw2[i] = c1w2[i]; }
        if (threadIdx.x < 32) { sb2[threadIdx.x] = c2b[threadIdx.x]; sb1[threadIdx.x] = c1b[threadIdx.x]; }

        const int zrow0 = strip*16;
        for (int idx = t256; idx < 3762; idx += 256) {
            int ic = idx / (19*66);
            int rem = idx - ic*(19*66);
            int li = rem / 66;
            int x2 = rem - li*66;
            int iy = zrow0 + li;
            unsigned int v = 0;
            if (iy < 128 && x2 < 64) {
                float2 p = *(const float2*)&z_i[(((size_t)img*3 + ic)*128 + iy)*128 + 2*x2];
                v = packh2(p.x, p.y);
            }
            sZ[idx] = v;
        }
        for (int idx = t256; idx < 16*9*2; idx += 256) {
            int oc2 = idx / 18; int rem = idx - oc2*18; int li = rem >> 1; int c = 64 + (rem & 1);
            sC1[oc2*(9*66) + li*66 + c] = 0;
        }
        __syncthreads();
        for (int pos = t256; pos < 576; pos += 256) {
            int li = pos >> 6;
            int ox = pos & 63;
            unsigned int pa[9]; float px[9];
            #pragma unroll
            for (int ic = 0; ic < 3; ++ic)
                #pragma unroll
                for (int dy = 0; dy < 3; ++dy) {
                    int r = ic*3 + dy;
                    int rowb = ic*(19*66) + (2*li + dy)*66;
                    pa[r] = sZ[rowb + ox];
                    unsigned int u = sZ[rowb + ox + 1];
                    px[r] = __half2float(((const __half2*)&u)->x);
                }
            const bool phantom = (strip == 7) && (li == 8);
            #pragma unroll 4
            for (int oc2 = 0; oc2 < 16; ++oc2) {
                const int oca = 2*oc2, ocb = oca + 1;
                float acca = sb1[oca], accb = sb1[ocb];
                #pragma unroll
                for (int r = 0; r < 9; ++r) {
                    acca = fdot2(sw01[oca*9 + r], pa[r], acca);
                    acca += sw2[oca*9 + r] * px[r];
                    accb = fdot2(sw01[ocb*9 + r], pa[r], accb);
                    accb += sw2[ocb*9 + r] * px[r];
                }
                sC1[oc2*(9*66) + li*66 + ox] =
                    phantom ? 0u : packh2(fmaxf(acca, 0.f), fmaxf(accb, 0.f));
            }
        }
        __syncthreads();
        const int posl = t256 & 127;
        const int half = t256 >> 7;
        const int ly = posl >> 5;
        const int ox = posl & 31;
        float acc[16];
        #pragma unroll
        for (int j = 0; j < 16; ++j) acc[j] = 0.f;
        for (int ic2 = 0; ic2 < 16; ++ic2) {
            unsigned int patch[9];
            #pragma unroll
            for (int dy = 0; dy < 3; ++dy)
                #pragma unroll
                for (int dx = 0; dx < 3; ++dx)
                    patch[dy*3+dx] = sC1[ic2*(9*66) + (2*ly+dy)*66 + 2*ox + dx];
            const unsigned int* wbase = sW + (half*16 + ic2)*192;
            #pragma unroll
            for (int j = 0; j < 16; ++j) {
                const unsigned int* wr = wbase + j*12;
                uint4 wa = *(const uint4*)wr;
                uint4 wb = *(const uint4*)(wr + 4);
                unsigned int w8 = wr[8];
                float a = acc[j];
                a = fdot2(wa.x, patch[0], a); a = fdot2(wa.y, patch[1], a);
                a = fdot2(wa.z, patch[2], a); a = fdot2(wa.w, patch[3], a);
                a = fdot2(wb.x, patch[4], a); a = fdot2(wb.y, patch[5], a);
                a = fdot2(wb.z, patch[6], a); a = fdot2(wb.w, patch[7], a);
                a = fdot2(w8,  patch[8], a);
                acc[j] = a;
            }
        }
        const int oy = strip*4 + ly;
        #pragma unroll
        for (int j = 0; j < 16; ++j) {
            int oc = half*16 + j;
            zfeat[(((size_t)img*32 + oc)*32 + oy)*32 + ox] = fmaxf(acc[j] + sb2[oc], 0.f);
        }
    }
}

// ---------------- replay: reconstruct cseq from scalars, fully parallel
__global__ __launch_bounds__(256) void ntm_replay_kernel(
    const float* __restrict__ xfeat, const float* __restrict__ wbuf,
    const float* __restrict__ eag, const float* __restrict__ lnst,
    float* __restrict__ cseq)
{
    const int slab = blockIdx.x;
    const int b    = blockIdx.y;
    const int tid  = threadIdx.x;
    const int m    = tid >> 3;
    const int ns   = tid & 7;
    const int n0   = slab*64 + ns*8;
    const float mu = lnst[b*2], rs = lnst[b*2+1];

    float c[8];
    {
        const float* x0 = xfeat + (size_t)(b*16)*32768 + m*1024 + n0;
        float4 a = *(const float4*)x0;
        float4 bv = *(const float4*)(x0 + 4);
        c[0]=(a.x-mu)*rs; c[1]=(a.y-mu)*rs; c[2]=(a.z-mu)*rs; c[3]=(a.w-mu)*rs;
        c[4]=(bv.x-mu)*rs; c[5]=(bv.y-mu)*rs; c[6]=(bv.z-mu)*rs; c[7]=(bv.w-mu)*rs;
    }
    for (int t = 0; t < 16; ++t) {
        const size_t bt = (size_t)(b*16 + t);
        const float* wp = &wbuf[bt*1024 + n0];
        float4 wA = *(const float4*)wp;
        float4 wB = *(const float4*)(wp + 4);
        float e = eag[bt*80 + m];
        float a = eag[bt*80 + 32 + m];
        float g = eag[bt*80 + 64];
        float omg = 1.f - g;
        const float* xp = &xfeat[bt*32768 + m*1024 + n0];
        float4 xA = *(const float4*)xp;
        float4 xB = *(const float4*)(xp + 4);
        c[0] = omg*(c[0]*(1.f - wA.x*e) + wA.x*a) + g*xA.x;
        c[1] = omg*(c[1]*(1.f - wA.y*e) + wA.y*a) + g*xA.y;
        c[2] = omg*(c[2]*(1.f - wA.z*e) + wA.z*a) + g*xA.z;
        c[3] = omg*(c[3]*(1.f - wA.w*e) + wA.w*a) + g*xA.w;
        c[4] = omg*(c[4]*(1.f - wB.x*e) + wB.x*a) + g*xB.x;
        c[5] = omg*(c[5]*(1.f - wB.y*e) + wB.y*a) + g*xB.y;
        c[6] = omg*(c[6]*(1.f - wB.z*e) + wB.z*a) + g*xB.z;
        c[7] = omg*(c[7]*(1.f - wB.w*e) + wB.w*a) + g*xB.w;
        float* op = &cseq[bt*32768 + m*1024 + n0];
        *(float4*)op       = make_float4(c[0], c[1], c[2], c[3]);
        *(float4*)(op + 4) = make_float4(c[4], c[5], c[6], c[7]);
    }
}

// ---------------- rfft2: table-driven DFT, both inputs in ONE dispatch
__global__ __launch_bounds__(256) void fft_fwd_kernel(const float* __restrict__ srcA,
                                                      const float* __restrict__ srcB,
                                                      const float* __restrict__ cosw,
                                                      const float* __restrict__ twg,
                                                      float* __restrict__ dstA,
                                                      float* __restrict__ dstB)
{
    const int img = blockIdx.x;
    const int tid = threadIdx.x;
    const float* src; float* dst;
    if (img < 4096) { src = srcA + (size_t)img*1024;        dst = dstA + (size_t)img*1088; }
    else            { src = srcB + (size_t)(img-4096)*1024; dst = dstB + (size_t)(img-4096)*1088; }

    __shared__ __align__(16) float sY[32*36];
    __shared__ __align__(16) float sT[2048];
    __shared__ __align__(16) float sR[2048];

    {
        const float4* s4 = (const float4*)twg;
        float4* d4 = (float4*)sT;
        d4[tid]       = s4[tid];
        d4[256 + tid] = s4[256 + tid];
    }
    {
        float4 v = *(const float4*)&src[tid*4];
        float4 c = *(const float4*)&cosw[tid*4];
        *(float4*)&sY[(tid>>3)*36 + (tid&7)*4] = make_float4(v.x*c.x, v.y*c.y, v.z*c.z, v.w*c.w);
    }
    __syncthreads();

    const int hj = tid >> 3;
    const int k0 = (tid & 7) * 4;

    float r0=0.f,i0=0.f,r1=0.f,i1=0.f,r2=0.f,i2=0.f,r3=0.f,i3=0.f;
    #pragma unroll
    for (int w = 0; w < 32; ++w) {
        float y = sY[hj*36 + w];
        float4 ta = *(const float4*)&sT[(w*32 + k0)*2];
        float4 tb = *(const float4*)&sT[(w*32 + k0)*2 + 4];
        r0 += y*ta.x; i0 += y*ta.y;
        r1 += y*ta.z; i1 += y*ta.w;
        r2 += y*tb.x; i2 += y*tb.y;
        r3 += y*tb.z; i3 += y*tb.w;
    }
    *(float4*)&sR[(hj*32 + k0)*2]     = make_float4(r0,i0,r1,i1);
    *(float4*)&sR[(hj*32 + k0)*2 + 4] = make_float4(r2,i2,r3,i3);
    __syncthreads();

    float fr0=0.f,fi0=0.f,fr1=0.f,fi1=0.f,fr2=0.f,fi2=0.f,fr3=0.f,fi3=0.f;
    #pragma unroll
    for (int h = 0; h < 32; ++h) {
        float2 wj = *(const float2*)&sT[(h*32 + hj)*2];
        float4 Ra = *(const float4*)&sR[(h*32 + k0)*2];
        float4 Rb = *(const float4*)&sR[(h*32 + k0)*2 + 4];
        fr0 += Ra.x*wj.x - Ra.y*wj.y;  fi0 += Ra.x*wj.y + Ra.y*wj.x;
        fr1 += Ra.z*wj.x - Ra.w*wj.y;  fi1 += Ra.z*wj.y + Ra.w*wj.x;
        fr2 += Rb.x*wj.x - Rb.y*wj.y;  fi2 += Rb.x*wj.y + Rb.y*wj.x;
        fr3 += Rb.z*wj.x - Rb.w*wj.y;  fi3 += Rb.z*wj.y + Rb.w*wj.x;
    }
    float* dp = dst + (size_t)(hj*17 + k0)*2;
    if (k0 < 16) {
        *(float2*)&dp[0] = make_float2(fr0, fi0);
        *(float2*)&dp[2] = make_float2(fr1, fi1);
        *(float2*)&dp[4] = make_float2(fr2, fi2);
        *(float2*)&dp[6] = make_float2(fr3, fi3);
    } else if (k0 == 16) {
        *(float2*)&dp[0] = make_float2(fr0, fi0);
    }
}

// ---------------- fused combine + irfft2; one block per bt
__global__ __launch_bounds__(256) void comb_ifft_kernel(const float* __restrict__ cfft,
                                                        const float* __restrict__ zfft,
                                                        const float* __restrict__ yf,
                                                        float* __restrict__ out)
{
    const int bt  = blockIdx.x;
    const int tid = threadIdx.x;
    __shared__ float sG[544*2];
    __shared__ float sS[544*2];
    __shared__ float ct[32], st[32];
    if (tid < 32) {
        float sv, cv;
        sincosf(TWOPI_32 * (float)tid, &sv, &cv);
        ct[tid] = cv; st[tid] = sv;
    }
    for (int idx = tid; idx < 544; idx += 256) {
        float kzz = 0.f, kxr = 0.f, kxi = 0.f;
        #pragma unroll 4
        for (int m = 0; m < 32; ++m) {
            size_t base = ((size_t)(bt*32 + m)*1088) + idx*2;
            float2 c = *(const float2*)&cfft[base];
            float2 z = *(const float2*)&zfft[base];
            kzz += c.x*c.x + c.y*c.y;
            kxr += z.x*c.x + z.y*c.y;
            kxi += z.y*c.x - z.x*c.y;
        }
        float den = 1.f / (kzz + 1e-4f);
        float2 y = *(const float2*)&yf[idx*2];
        float ar = y.x*den, ai = y.y*den;
        sG[idx*2]     = kxr*ar - kxi*ai;
        sG[idx*2 + 1] = kxr*ai + kxi*ar;
    }
    __syncthreads();
    for (int idx = tid; idx < 544; idx += 256) {
        int h = idx / 17;
        int k = idx - h*17;
        float re = 0.f, im = 0.f;
        #pragma unroll
        for (int j = 0; j < 32; ++j) {
            float gr = sG[(j*17+k)*2], gi = sG[(j*17+k)*2+1];
            int a = (h*j) & 31;
            float c = ct[a], s = st[a];
            re += gr*c - gi*s;
            im += gr*s + gi*c;
        }
        sS[(h*17+k)*2] = re; sS[(h*17+k)*2+1] = im;
    }
    __syncthreads();
    #pragma unroll
    for (int p = 0; p < 4; ++p) {
        int pos = p*256 + tid;
        int h = pos >> 5, wq = pos & 31;
        float acc = sS[(h*17)*2];
        #pragma unroll
        for (int k = 1; k < 16; ++k) {
            int a = (wq*k) & 31;
            acc += 2.f*(sS[(h*17+k)*2]*ct[a] - sS[(h*17+k)*2+1]*st[a]);
        }
        acc += sS[(h*17+16)*2] * ((wq & 1) ? -1.f : 1.f);
        out[(size_t)bt*1024 + pos] = acc * (1.f/1024.f);
    }
}

extern "C" void kernel_launch(void* const* d_in, const int* in_sizes, int n_in,
                              void* d_out, int out_size, void* d_ws, size_t ws_size,
                              hipStream_t stream)
{
    const float* x_i   = (const float*)d_in[0];
    const float* z_i   = (const float*)d_in[1];
    const float* c1w   = (const float*)d_in[2];
    const float* c1b   = (const float*)d_in[3];
    const float* c2w   = (const float*)d_in[4];
    const float* c2b   = (const float*)d_in[5];
    const float* Wk    = (const float*)d_in[6];
    const float* bk    = (const float*)d_in[7];
    const float* Wbeta = (const float*)d_in[8];
    const float* bbeta = (const float*)d_in[9];
    const float* Wh    = (const float*)d_in[10];
    const float* bh    = (const float*)d_in[11];
    const float* We    = (const float*)d_in[12];
    const float* Wa    = (const float*)d_in[13];
    const float* Wg    = (const float*)d_in[14];
    const float* cosw  = (const float*)d_in[15];
    const float* yf    = (const float*)d_in[16];
    float* out = (float*)d_out;
    float* ws  = (float*)d_ws;

    // workspace layout (floats)
    float*  xfeat = ws + 16777216;      // 4,194,304
    float*  zfeat = ws + 20971520;      // 4,194,304
    float*  cseq  = ws + 25165824;      // 4,194,304 (ends 29,360,128)
    float*  cfft  = ws;                 // 4,456,448 f (written after fat)
    float*  zfft  = ws + 4456448;       // 4,456,448 f
    __half* xhb   = (__half*)(ws + 9000000);    // 4,194,304 halfs
    float*  wbuf  = ws + 11100000;      // 131,072 f
    float*  eag   = ws + 11240000;      // 10,240 f
    float*  lnstp = ws + 11251000;      // 16 f
    // prepack outputs + xmp in the dead gap [29,360,128 .. 29,499,392)
    __half* whhP  = (__half*)(ws + 29360128);
    __half* whrxP = (__half*)(ws + 29392896);
    __half* wkP   = (__half*)(ws + 29401088);
    __half* weP   = (__half*)(ws + 29405184);
    __half* waP   = (__half*)(ws + 29409280);
    float*  twg   = ws + 29413376;
    unsigned int* c2wP   = (unsigned int*)(ws + 29415424);  // 6,144 u32
    unsigned int* c1wP01 = (unsigned int*)(ws + 29421568);  // 288 u32
    float*  c1wP2 = ws + 29421856;      // 288 f -> ends 29,422,144
    float*  xmp   = ws + 29422144;      // 65,536 f -> ends 29,487,680 (< 29,499,392 OK)

    dim3 b256(256);
    prepack_kernel<<<33, b256, 0, stream>>>(Wh, Wk, We, Wa, c1w, c2w,
                                            whhP, whrxP, wkP, weP, waP, twg,
                                            c2wP, c1wP01, c1wP2);
    convx_kernel<<<512, 512, 0, stream>>>(x_i, c1wP01, c1wP2, c1b, c2wP, c2b,
                                          xfeat, xhb, xmp);
    fat_kernel<<<520, 512, 0, stream>>>(xfeat, xhb, xmp, whhP, whrxP, wkP, weP, waP,
                                        bk, Wbeta, bbeta, bh, Wg, wbuf, eag, lnstp,
                                        z_i, c1wP01, c1wP2, c1b, c2wP, c2b, zfeat);
    ntm_replay_kernel<<<dim3(16,8), b256, 0, stream>>>(xfeat, wbuf, eag, lnstp, cseq);
    fft_fwd_kernel<<<8192, b256, 0, stream>>>(cseq, zfeat, cosw, twg, cfft, zfft);
    comb_ifft_kernel<<<128, b256, 0, stream>>>(cfft, zfft, yf, out);
}

// Round 14
// 418.215 us; speedup vs baseline: 2.1506x; 1.0232x over previous
//
#include <hip/hip_runtime.h>
#include <hip/hip_fp16.h>
#include <math.h>

// B=8, T=16, IMG=128, CF=32, WO=HO=32, N=1024, M=32, DH=256
// conv SAME stride2: pad_lo=0, pad_hi=1 -> in_idx = 2*out + k

#define TWOPI_32 0.19634954084936207f  // 2*pi/32

typedef _Float16 __h2 __attribute__((ext_vector_type(2)));
__device__ __forceinline__ float fdot2(unsigned int w, unsigned int h, float acc) {
    union { unsigned int u; __h2 v; } a, b;
    a.u = w; b.u = h;
    return __builtin_amdgcn_fdot2(a.v, b.v, acc, false);
}
__device__ __forceinline__ unsigned int packh2(float a, float b) {
    __half2 h2 = __floats2half2_rn(a, b);
    return *(unsigned int*)&h2;
}

// ---------------- prepack: all weight packs + twiddle
// c2wP padded layout: [half][ic2][j][12] u32, entries q=0..8 valid
__global__ __launch_bounds__(256) void prepack_kernel(
    const float* __restrict__ Wh, const float* __restrict__ Wk,
    const float* __restrict__ We, const float* __restrict__ Wa,
    const float* __restrict__ c1w, const float* __restrict__ c2w,
    __half* __restrict__ whhP, __half* __restrict__ whrxP,
    __half* __restrict__ wkP, __half* __restrict__ weP, __half* __restrict__ waP,
    float* __restrict__ twg,
    unsigned int* __restrict__ c2wP, unsigned int* __restrict__ c1wP01,
    float* __restrict__ c1wP2)
{
    const int tid = threadIdx.x;
    if (blockIdx.x < 32) {
        const int base = blockIdx.x*256 + tid;   // 0..8191
        #pragma unroll
        for (int r = 0; r < 8; ++r) {
            int idx = base*8 + r;
            int e = idx & 7, i = (idx >> 3) & 255, c = idx >> 11;
            int q = c >> 4, k = c & 15;
            whhP[idx] = __float2half(Wh[i*320 + q*128 + k*8 + e]);
        }
        #pragma unroll
        for (int r = 0; r < 2; ++r) {
            int idx = base*2 + r;
            int i = idx >> 6, s2 = idx & 63;
            whrxP[idx] = __float2half(Wh[i*320 + 256 + s2]);
        }
        {
            int idx = base;
            int m = idx >> 8, j = (idx >> 4) & 15, e = idx & 15;
            int col = (e < 8) ? (8*j + e) : (128 + 8*j + (e - 8));
            wkP[idx] = __float2half(Wk[m*256 + col]);
            weP[idx] = __float2half(We[m*256 + col]);
            waP[idx] = __float2half(Wa[m*256 + col]);
        }
    } else {
        for (int idx = tid; idx < 4608; idx += 256) {
            int half = idx / 2304;
            int rem  = idx - half*2304;
            int ic2  = rem / 144;
            int r2   = rem - ic2*144;
            int j    = r2 / 9, q = r2 - j*9;
            int oc   = half*16 + j;
            c2wP[((half*16 + ic2)*16 + j)*12 + q] =
                packh2(c2w[oc*288 + (2*ic2)*9 + q],
                       c2w[oc*288 + (2*ic2+1)*9 + q]);
        }
        for (int idx = tid; idx < 288; idx += 256) {
            int oc = idx / 9, r = idx - oc*9;        // r = ic*3+dy
            c1wP01[idx] = packh2(c1w[oc*27 + r*3 + 0], c1w[oc*27 + r*3 + 1]);
            c1wP2[idx]  = c1w[oc*27 + r*3 + 2];
        }
        for (int idx = tid; idx < 1024; idx += 256) {
            int w = idx >> 5, k = idx & 31;
            float sv, cv;
            sincosf(TWOPI_32 * (float)((w*k) & 31), &sv, &cv);
            twg[idx*2]     = cv;
            twg[idx*2 + 1] = -sv;
        }
    }
}

// ---------------- convx: fused conv1+conv2 (x path); writes xfeat + xh(f16,T) + xmp partials
__global__ __launch_bounds__(512, 1) void convx_kernel(
    const float* __restrict__ x_i, const unsigned int* __restrict__ c1w01,
    const float* __restrict__ c1w2, const float* __restrict__ c1b,
    const unsigned int* __restrict__ c2wP, const float* __restrict__ c2b,
    float* __restrict__ xfeat, __half* __restrict__ xh, float* __restrict__ xmp)
{
    __shared__ __align__(16) char smem[139264];
    const int team = threadIdx.x >> 8;
    const int t256 = threadIdx.x & 255;
    const int tile = blockIdx.x*2 + team;   // 0..1023
    const int img  = tile >> 3;
    const int strip = tile & 7;
    unsigned int* sZ  = (unsigned int*)(smem + team*53072);           // [3][19][66]
    unsigned int* sC1 = (unsigned int*)(smem + team*53072 + 15048);   // [16][9][66]
    unsigned int* sW   = (unsigned int*)(smem + 106144);              // 6144 u32
    unsigned int* sw01 = (unsigned int*)(smem + 130720);              // 288
    float*        sw2  = (float*)(smem + 131872);                     // 288
    float*        sb2  = (float*)(smem + 133024);                     // 32
    float*        sb1  = (float*)(smem + 133152);                     // 32

    for (int i = threadIdx.x; i < 1536; i += 512)
        ((uint4*)sW)[i] = ((const uint4*)c2wP)[i];
    for (int i = threadIdx.x; i < 288; i += 512) { sw01[i] = c1w01[i]; sw2[i] = c1w2[i]; }
    if (threadIdx.x < 32) { sb2[threadIdx.x] = c2b[threadIdx.x]; sb1[threadIdx.x] = c1b[threadIdx.x]; }

    const int zrow0 = strip*16;
    for (int idx = t256; idx < 3762; idx += 256) {
        int ic = idx / (19*66);
        int rem = idx - ic*(19*66);
        int li = rem / 66;
        int x2 = rem - li*66;
        int iy = zrow0 + li;
        unsigned int v = 0;
        if (iy < 128 && x2 < 64) {
            float2 p = *(const float2*)&x_i[(((size_t)img*3 + ic)*128 + iy)*128 + 2*x2];
            v = packh2(p.x, p.y);
        }
        sZ[idx] = v;
    }
    for (int idx = t256; idx < 16*9*2; idx += 256) {
        int oc2 = idx / 18; int rem = idx - oc2*18; int li = rem >> 1; int c = 64 + (rem & 1);
        sC1[oc2*(9*66) + li*66 + c] = 0;
    }
    __syncthreads();
    // conv1: 9 rows x 64 cols (phantom row 64 at strip 7 -> 0)
    for (int pos = t256; pos < 576; pos += 256) {
        int li = pos >> 6;
        int ox = pos & 63;
        unsigned int pa[9]; float px[9];
        #pragma unroll
        for (int ic = 0; ic < 3; ++ic)
            #pragma unroll
            for (int dy = 0; dy < 3; ++dy) {
                int r = ic*3 + dy;
                int rowb = ic*(19*66) + (2*li + dy)*66;
                pa[r] = sZ[rowb + ox];
                unsigned int u = sZ[rowb + ox + 1];
                px[r] = __half2float(((const __half2*)&u)->x);
            }
        const bool phantom = (strip == 7) && (li == 8);
        #pragma unroll 4
        for (int oc2 = 0; oc2 < 16; ++oc2) {
            const int oca = 2*oc2, ocb = oca + 1;
            float acca = sb1[oca], accb = sb1[ocb];
            #pragma unroll
            for (int r = 0; r < 9; ++r) {
                acca = fdot2(sw01[oca*9 + r], pa[r], acca);
                acca += sw2[oca*9 + r] * px[r];
                accb = fdot2(sw01[ocb*9 + r], pa[r], accb);
                accb += sw2[ocb*9 + r] * px[r];
            }
            sC1[oc2*(9*66) + li*66 + ox] =
                phantom ? 0u : packh2(fmaxf(acca, 0.f), fmaxf(accb, 0.f));
        }
    }
    __syncthreads();
    // conv2: 4 rows x 32 cols x 32 oc; then emit xfeat/xh/xmp
    const int posl = t256 & 127;
    const int half = t256 >> 7;
    const int ly = posl >> 5;
    const int ox = posl & 31;
    float acc[16];
    #pragma unroll
    for (int j = 0; j < 16; ++j) acc[j] = 0.f;
    for (int ic2 = 0; ic2 < 16; ++ic2) {
        unsigned int patch[9];
        #pragma unroll
        for (int dy = 0; dy < 3; ++dy)
            #pragma unroll
            for (int dx = 0; dx < 3; ++dx)
                patch[dy*3+dx] = sC1[ic2*(9*66) + (2*ly+dy)*66 + 2*ox + dx];
        const unsigned int* wbase = sW + (half*16 + ic2)*192;
        #pragma unroll
        for (int j = 0; j < 16; ++j) {
            const unsigned int* wr = wbase + j*12;
            uint4 wa = *(const uint4*)wr;
            uint4 wb = *(const uint4*)(wr + 4);
            unsigned int w8 = wr[8];
            float a = acc[j];
            a = fdot2(wa.x, patch[0], a); a = fdot2(wa.y, patch[1], a);
            a = fdot2(wa.z, patch[2], a); a = fdot2(wa.w, patch[3], a);
            a = fdot2(wb.x, patch[4], a); a = fdot2(wb.y, patch[5], a);
            a = fdot2(wb.z, patch[6], a); a = fdot2(wb.w, patch[7], a);
            a = fdot2(w8,  patch[8], a);
            acc[j] = a;
        }
    }
    const int oy = strip*4 + ly;
    const int n  = oy*32 + ox;
    float vals[16];
    #pragma unroll
    for (int j = 0; j < 16; ++j) {
        int oc = half*16 + j;
        float v = fmaxf(acc[j] + sb2[oc], 0.f);
        vals[j] = v;
        xfeat[(((size_t)img*32 + oc)*32 + oy)*32 + ox] = v;
    }
    {
        unsigned int hp[8];
        #pragma unroll
        for (int k = 0; k < 8; ++k) hp[k] = packh2(vals[2*k], vals[2*k+1]);
        uint4* dp = (uint4*)(xh + (size_t)img*32768 + (size_t)n*32 + half*16);
        dp[0] = *(uint4*)&hp[0];
        dp[1] = *(uint4*)&hp[4];
    }
    {
        const int lane = threadIdx.x & 63;
        const int wsub = (t256 >> 6) & 1;
        #pragma unroll
        for (int j = 0; j < 16; ++j) {
            float v = vals[j];
            #pragma unroll
            for (int d = 32; d > 0; d >>= 1) v += __shfl_xor(v, d, 64);
            if (lane == 0)
                xmp[(((size_t)img*8 + strip)*2 + wsub)*32 + half*16 + j] = v * (1.f/1024.f);
        }
    }
}

// ---------------- FAT: blocks 0..7 = NTM recurrence; blocks 8.. = fused conv1+conv2 (z)
__global__ __launch_bounds__(512, 1) void fat_kernel(
    const float* __restrict__ xfeat, const __half* __restrict__ xh,
    const float* __restrict__ xmp,
    const __half* __restrict__ whhP, const __half* __restrict__ whrxP,
    const __half* __restrict__ wkP, const __half* __restrict__ weP,
    const __half* __restrict__ waP,
    const float* __restrict__ bk, const float* __restrict__ Wbeta,
    const float* __restrict__ bbeta, const float* __restrict__ bh,
    const float* __restrict__ Wg,
    float* __restrict__ wbuf, float* __restrict__ eag, float* __restrict__ lnst,
    const float* __restrict__ z_i, const unsigned int* __restrict__ c1w01,
    const float* __restrict__ c1w2, const float* __restrict__ c1b,
    const unsigned int* __restrict__ c2wP, const float* __restrict__ c2b,
    float* __restrict__ zfeat)
{
    __shared__ __align__(16) char smem[139264];

    if (blockIdx.x < 8) {
        // ======== NTM branch ========
        __builtin_amdgcn_s_setprio(1);
        __half* sWhh = (__half*)(smem);                    // 131072 B
        float (*sHbuf)[256] = (float(*)[256])(smem + 131072);
        __half (*sHh)[256] = (__half(*)[256])(smem + 133120);
        float* sK    = (float*)(smem + 134144);
        float* sXm   = (float*)(smem + 134272);
        float* sRedC = (float*)(smem + 136320);
        float* sR32  = (float*)(smem + 137344);
        float* sE    = (float*)(smem + 137472);
        float* sA    = (float*)(smem + 137600);
        float* sBk   = (float*)(smem + 137728);
        float* sBh   = (float*)(smem + 137856);
        float* sRedD = (float*)(smem + 138880);
        float* sRedL = (float*)(smem + 138912);

        const int b    = blockIdx.x;
        const int tid  = threadIdx.x;
        const int lane = tid & 63;
        const int wid  = tid >> 6;

        {
            const uint4* src = (const uint4*)whhP;
            uint4* dst = (uint4*)sWhh;
            for (int i2 = tid; i2 < 8192; i2 += 512) dst[i2] = src[i2];
        }
        if (tid < 256) { sBh[tid] = bh[tid]; sHbuf[0][tid] = 0.f; sHh[0][tid] = __float2half(0.f); }
        if (tid < 32)  { sBk[tid] = bk[tid]; sK[tid] = tanhf(bk[tid]); }
        if (tid < 512) {
            const int tt = tid >> 5, m = tid & 31;
            const float* pp = xmp + ((size_t)(b*16 + tt)*16)*32 + m;
            float s = 0.f;
            #pragma unroll
            for (int q = 0; q < 16; ++q) s += pp[q*32];
            sXm[tid] = s;
        }
        float4 wbeta4 = *(const float4*)&Wbeta[(size_t)lane*4];
        float4 wg4    = *(const float4*)&Wg[(size_t)lane*4];
        float bb = bbeta[0];

        const int mg = tid >> 4, jg = tid & 15;
        uint4 wk0, wk1, we0, we1, wa0, wa1;
        {
            const uint4* p;
            p = (const uint4*)(wkP + (size_t)(mg*16 + jg)*16); wk0 = p[0]; wk1 = p[1];
            p = (const uint4*)(weP + (size_t)(mg*16 + jg)*16); we0 = p[0]; we1 = p[1];
            p = (const uint4*)(waP + (size_t)(mg*16 + jg)*16); wa0 = p[0]; wa1 = p[1];
        }
        const int iD = tid >> 1, qD = tid & 1;
        uint4 wrx0, wrx1, wrx2, wrx3;
        {
            const uint4* p = (const uint4*)(whrxP + (size_t)iD*64 + qD*32);
            wrx0 = p[0]; wrx1 = p[1]; wrx2 = p[2]; wrx3 = p[3];
        }

        const int n0 = 2*tid;
        float c0[32], c1[32];

        {
            const float* x0 = xfeat + (size_t)(b*16)*32768;
            float sum = 0.f, ss = 0.f;
            #pragma unroll
            for (int m = 0; m < 32; ++m) {
                float2 v = *(const float2*)&x0[m*1024 + n0];
                c0[m] = v.x; c1[m] = v.y;
                sum += v.x + v.y; ss += v.x*v.x + v.y*v.y;
            }
            #pragma unroll
            for (int d = 32; d > 0; d >>= 1) { sum += __shfl_xor(sum, d, 64); ss += __shfl_xor(ss, d, 64); }
            if (lane == 0) { sRedL[wid] = sum; sRedL[8+wid] = ss; }
            __syncthreads();
            float S = 0.f, SS = 0.f;
            #pragma unroll
            for (int i = 0; i < 8; ++i) { S += sRedL[i]; SS += sRedL[8+i]; }
            float mu = S * (1.f/32768.f);
            float var = SS * (1.f/32768.f) - mu*mu;
            float rs = rsqrtf(var + 1e-5f);
            if (tid == 0) { lnst[b*2] = mu; lnst[b*2+1] = rs; }
            #pragma unroll
            for (int m = 0; m < 32; ++m) { c0[m] = (c0[m]-mu)*rs; c1[m] = (c1[m]-mu)*rs; }
        }

        uint4 xb[8];
        {
            const uint4* xrow = (const uint4*)(xh + (size_t)(b*16)*32768) + 8*tid;
            #pragma unroll
            for (int i = 0; i < 8; ++i) xb[i] = xrow[i];
        }
        __syncthreads();

        float betav = (bb > 20.f) ? bb : log1pf(expf(bb));
        float ex0 = 0.f, ex1 = 0.f, w0 = 0.f, w1 = 0.f;
        const int rm = ((lane&1)<<4)|((lane&2)<<2)|(lane&4)|((lane&8)>>2)|((lane&16)>>4);

        #pragma unroll 1
        for (int t = 0; t < 16; ++t) {
            const int cur = t & 1, nxt = cur ^ 1;

            // PH_A
            {
                float beta = betav;
                float dot0 = 0.f, dot1 = 0.f, cn20 = 0.f, cn21 = 0.f, kn2 = 0.f;
                #pragma unroll
                for (int q = 0; q < 8; ++q) {
                    float4 k4 = *(const float4*)&sK[4*q];
                    dot0 += c0[4*q]*k4.x + c0[4*q+1]*k4.y + c0[4*q+2]*k4.z + c0[4*q+3]*k4.w;
                    dot1 += c1[4*q]*k4.x + c1[4*q+1]*k4.y + c1[4*q+2]*k4.z + c1[4*q+3]*k4.w;
                    cn20 += c0[4*q]*c0[4*q] + c0[4*q+1]*c0[4*q+1] + c0[4*q+2]*c0[4*q+2] + c0[4*q+3]*c0[4*q+3];
                    cn21 += c1[4*q]*c1[4*q] + c1[4*q+1]*c1[4*q+1] + c1[4*q+2]*c1[4*q+2] + c1[4*q+3]*c1[4*q+3];
                    kn2  += k4.x*k4.x + k4.y*k4.y + k4.z*k4.z + k4.w*k4.w;
                }
                float kinv = 1.f / (sqrtf(kn2) + 1e-8f);
                float s0 = dot0 * kinv / (sqrtf(cn20) + 1e-8f);
                float s1 = dot1 * kinv / (sqrtf(cn21) + 1e-8f);
                ex0 = expf(beta * s0);
                ex1 = expf(beta * s1);
                float es = ex0 + ex1;
                #pragma unroll
                for (int d = 32; d > 0; d >>= 1) es += __shfl_xor(es, d, 64);
                if (lane == 0) sRedD[wid] = es;
                float v[32];
                #pragma unroll
                for (int m = 0; m < 32; ++m) v[m] = ex0*c0[m] + ex1*c1[m];
                #pragma unroll
                for (int i = 0; i < 16; ++i) { float sd = (lane&1)? v[i] : v[i+16]; float rc = __shfl_xor(sd, 1, 64); v[i] = ((lane&1)? v[i+16] : v[i]) + rc; }
                #pragma unroll
                for (int i = 0; i < 8; ++i)  { float sd = (lane&2)? v[i] : v[i+8];  float rc = __shfl_xor(sd, 2, 64); v[i] = ((lane&2)? v[i+8]  : v[i]) + rc; }
                #pragma unroll
                for (int i = 0; i < 4; ++i)  { float sd = (lane&4)? v[i] : v[i+4];  float rc = __shfl_xor(sd, 4, 64); v[i] = ((lane&4)? v[i+4]  : v[i]) + rc; }
                #pragma unroll
                for (int i = 0; i < 2; ++i)  { float sd = (lane&8)? v[i] : v[i+2];  float rc = __shfl_xor(sd, 8, 64); v[i] = ((lane&8)? v[i+2]  : v[i]) + rc; }
                { float sd = (lane&16)? v[0] : v[1]; float rc = __shfl_xor(sd, 16, 64); v[0] = ((lane&16)? v[1] : v[0]) + rc; }
                v[0] += __shfl_xor(v[0], 32, 64);
                if (lane < 32) sRedC[wid*32 + rm] = v[0];
            }
            __syncthreads();

            // PH_B
            {
                float den = sRedD[0]+sRedD[1]+sRedD[2]+sRedD[3]+sRedD[4]+sRedD[5]+sRedD[6]+sRedD[7];
                float inv = 1.f / den;
                w0 = ex0 * inv; w1 = ex1 * inv;
                *(float2*)&wbuf[(size_t)(b*16 + t)*1024 + n0] = make_float2(w0, w1);
                if (lane < 32) {
                    float r = 0.f;
                    #pragma unroll
                    for (int w = 0; w < 8; ++w) r += sRedC[w*32 + lane];
                    sR32[lane] = r * inv;
                }
                float s0 = 0.f, s1 = 0.f, s2 = 0.f, s3 = 0.f;
                #pragma unroll
                for (int k4 = 0; k4 < 4; ++k4) {
                    const int kb = 4*k4;
                    uint4 wv0 = *(const uint4*)&sWhh[(size_t)((qD*16 + kb+0)*256 + iD)*8];
                    uint4 hv0 = *(const uint4*)&sHh[cur][qD*128 + (kb+0)*8];
                    s0 = fdot2(wv0.x, hv0.x, s0); s0 = fdot2(wv0.y, hv0.y, s0);
                    s0 = fdot2(wv0.z, hv0.z, s0); s0 = fdot2(wv0.w, hv0.w, s0);
                    uint4 wv1 = *(const uint4*)&sWhh[(size_t)((qD*16 + kb+1)*256 + iD)*8];
                    uint4 hv1 = *(const uint4*)&sHh[cur][qD*128 + (kb+1)*8];
                    s1 = fdot2(wv1.x, hv1.x, s1); s1 = fdot2(wv1.y, hv1.y, s1);
                    s1 = fdot2(wv1.z, hv1.z, s1); s1 = fdot2(wv1.w, hv1.w, s1);
                    uint4 wv2 = *(const uint4*)&sWhh[(size_t)((qD*16 + kb+2)*256 + iD)*8];
                    uint4 hv2 = *(const uint4*)&sHh[cur][qD*128 + (kb+2)*8];
                    s2 = fdot2(wv2.x, hv2.x, s2); s2 = fdot2(wv2.y, hv2.y, s2);
                    s2 = fdot2(wv2.z, hv2.z, s2); s2 = fdot2(wv2.w, hv2.w, s2);
                    uint4 wv3 = *(const uint4*)&sWhh[(size_t)((qD*16 + kb+3)*256 + iD)*8];
                    uint4 hv3 = *(const uint4*)&sHh[cur][qD*128 + (kb+3)*8];
                    s3 = fdot2(wv3.x, hv3.x, s3); s3 = fdot2(wv3.y, hv3.y, s3);
                    s3 = fdot2(wv3.z, hv3.z, s3); s3 = fdot2(wv3.w, hv3.w, s3);
                }
                const float* rxsrc = qD ? &sXm[t*32] : sR32;
                {
                    const __half2* w2;
                    float4 va, vb;
                    va = *(const float4*)&rxsrc[0];  vb = *(const float4*)&rxsrc[4];
                    w2 = (const __half2*)&wrx0;
                    { float2 p0 = __half22float2(w2[0]); s0 += p0.x*va.x + p0.y*va.y;
                      float2 p1 = __half22float2(w2[1]); s0 += p1.x*va.z + p1.y*va.w;
                      float2 p2 = __half22float2(w2[2]); s0 += p2.x*vb.x + p2.y*vb.y;
                      float2 p3 = __half22float2(w2[3]); s0 += p3.x*vb.z + p3.y*vb.w; }
                    va = *(const float4*)&rxsrc[8];  vb = *(const float4*)&rxsrc[12];
                    w2 = (const __half2*)&wrx1;
                    { float2 p0 = __half22float2(w2[0]); s1 += p0.x*va.x + p0.y*va.y;
                      float2 p1 = __half22float2(w2[1]); s1 += p1.x*va.z + p1.y*va.w;
                      float2 p2 = __half22float2(w2[2]); s1 += p2.x*vb.x + p2.y*vb.y;
                      float2 p3 = __half22float2(w2[3]); s1 += p3.x*vb.z + p3.y*vb.w; }
                    va = *(const float4*)&rxsrc[16]; vb = *(const float4*)&rxsrc[20];
                    w2 = (const __half2*)&wrx2;
                    { float2 p0 = __half22float2(w2[0]); s2 += p0.x*va.x + p0.y*va.y;
                      float2 p1 = __half22float2(w2[1]); s2 += p1.x*va.z + p1.y*va.w;
                      float2 p2 = __half22float2(w2[2]); s2 += p2.x*vb.x + p2.y*vb.y;
                      float2 p3 = __half22float2(w2[3]); s2 += p3.x*vb.z + p3.y*vb.w; }
                    va = *(const float4*)&rxsrc[24]; vb = *(const float4*)&rxsrc[28];
                    w2 = (const __half2*)&wrx3;
                    { float2 p0 = __half22float2(w2[0]); s3 += p0.x*va.x + p0.y*va.y;
                      float2 p1 = __half22float2(w2[1]); s3 += p1.x*va.z + p1.y*va.w;
                      float2 p2 = __half22float2(w2[2]); s3 += p2.x*vb.x + p2.y*vb.y;
                      float2 p3 = __half22float2(w2[3]); s3 += p3.x*vb.z + p3.y*vb.w; }
                }
                float s = (s0 + s1) + (s2 + s3);
                s += __shfl_down(s, 1, 2);
                if (qD == 0) {
                    float hn = tanhf(s + sBh[iD]);
                    sHbuf[nxt][iD] = hn;
                    sHh[nxt][iD] = __float2half(hn);
                }
            }
            __syncthreads();

            // PH_C
            float gg;
            {
                uint4 h0 = *(const uint4*)&sHh[nxt][8*jg];
                uint4 h1 = *(const uint4*)&sHh[nxt][128 + 8*jg];
                float se0=0.f, se1=0.f, sa0=0.f, sa1=0.f, sk0=0.f, sk1=0.f;
                se0 = fdot2(we0.x, h0.x, se0); se1 = fdot2(we0.y, h0.y, se1);
                se0 = fdot2(we0.z, h0.z, se0); se1 = fdot2(we0.w, h0.w, se1);
                se0 = fdot2(we1.x, h1.x, se0); se1 = fdot2(we1.y, h1.y, se1);
                se0 = fdot2(we1.z, h1.z, se0); se1 = fdot2(we1.w, h1.w, se1);
                sa0 = fdot2(wa0.x, h0.x, sa0); sa1 = fdot2(wa0.y, h0.y, sa1);
                sa0 = fdot2(wa0.z, h0.z, sa0); sa1 = fdot2(wa0.w, h0.w, sa1);
                sa0 = fdot2(wa1.x, h1.x, sa0); sa1 = fdot2(wa1.y, h1.y, sa1);
                sa0 = fdot2(wa1.z, h1.z, sa0); sa1 = fdot2(wa1.w, h1.w, sa1);
                sk0 = fdot2(wk0.x, h0.x, sk0); sk1 = fdot2(wk0.y, h0.y, sk1);
                sk0 = fdot2(wk0.z, h0.z, sk0); sk1 = fdot2(wk0.w, h0.w, sk1);
                sk0 = fdot2(wk1.x, h1.x, sk0); sk1 = fdot2(wk1.y, h1.y, sk1);
                sk0 = fdot2(wk1.z, h1.z, sk0); sk1 = fdot2(wk1.w, h1.w, sk1);
                float se = se0 + se1, sa = sa0 + sa1, sk = sk0 + sk1;
                se += __shfl_down(se, 8, 16); sa += __shfl_down(sa, 8, 16); sk += __shfl_down(sk, 8, 16);
                se += __shfl_down(se, 4, 16); sa += __shfl_down(sa, 4, 16); sk += __shfl_down(sk, 4, 16);
                se += __shfl_down(se, 2, 16); sa += __shfl_down(sa, 2, 16); sk += __shfl_down(sk, 2, 16);
                se += __shfl_down(se, 1, 16); sa += __shfl_down(sa, 1, 16); sk += __shfl_down(sk, 1, 16);
                if (jg == 0) {
                    float e = 1.f/(1.f + expf(-se));
                    float a = tanhf(sa);
                    sE[mg] = e; sA[mg] = a;
                    sK[mg] = tanhf(sk + sBk[mg]);
                    eag[(size_t)(b*16 + t)*80 + mg]      = e;
                    eag[(size_t)(b*16 + t)*80 + 32 + mg] = a;
                }
                float4 h4 = *(const float4*)&sHbuf[nxt][lane*4];
                float pg = wg4.x*h4.x + wg4.y*h4.y + wg4.z*h4.z + wg4.w*h4.w;
                float pb = wbeta4.x*h4.x + wbeta4.y*h4.y + wbeta4.z*h4.z + wbeta4.w*h4.w;
                #pragma unroll
                for (int d = 32; d > 0; d >>= 1) {
                    pg += __shfl_xor(pg, d, 64);
                    pb += __shfl_xor(pb, d, 64);
                }
                gg = 1.f/(1.f + expf(-pg));
                float xbeta = pb + bb;
                betav = (xbeta > 20.f) ? xbeta : log1pf(expf(xbeta));
                if (tid == 0) eag[(size_t)(b*16 + t)*80 + 64] = gg;
            }
            __syncthreads();

            // PH_D
            {
                float omg = 1.f - gg;
                const __half* xp = (const __half*)xb;
                #pragma unroll
                for (int q = 0; q < 8; ++q) {
                    float4 e4 = *(const float4*)&sE[4*q];
                    float4 a4 = *(const float4*)&sA[4*q];
                    #pragma unroll
                    for (int r = 0; r < 4; ++r) {
                        int m = 4*q + r;
                        float e = (r==0)?e4.x:(r==1)?e4.y:(r==2)?e4.z:e4.w;
                        float a = (r==0)?a4.x:(r==1)?a4.y:(r==2)?a4.z:a4.w;
                        float x0v = __half2float(xp[m]);
                        float x1v = __half2float(xp[32 + m]);
                        c0[m] = omg*(c0[m]*(1.f - w0*e) + w0*a) + gg*x0v;
                        c1[m] = omg*(c1[m]*(1.f - w1*e) + w1*a) + gg*x1v;
                    }
                }
                if (t < 15) {
                    const uint4* xrow = (const uint4*)(xh + (size_t)(b*16 + t + 1)*32768) + 8*tid;
                    #pragma unroll
                    for (int i = 0; i < 8; ++i) xb[i] = xrow[i];
                }
            }
        }
    } else {
        // ======== fused conv1+conv2 (z): 2 tiles/block; weights staged in shared LDS ========
        const int team = threadIdx.x >> 8;
        const int t256 = threadIdx.x & 255;
        const int tile = (blockIdx.x - 8)*2 + team;   // 0..1023
        const int img  = tile >> 3;
        const int strip = tile & 7;
        unsigned int* sZ  = (unsigned int*)(smem + team*53072);           // [3][19][66]
        unsigned int* sC1 = (unsigned int*)(smem + team*53072 + 15048);   // [16][9][66]
        unsigned int* sW   = (unsigned int*)(smem + 106144);              // 6144 u32
        unsigned int* sw01 = (unsigned int*)(smem + 130720);              // 288
        float*        sw2  = (float*)(smem + 131872);                     // 288
        float*        sb2  = (float*)(smem + 133024);                     // 32
        float*        sb1  = (float*)(smem + 133152);                     // 32

        for (int i = threadIdx.x; i < 1536; i += 512)
            ((uint4*)sW)[i] = ((const uint4*)c2wP)[i];
        for (int i = threadIdx.x; i < 288; i += 512) { sw01[i] = c1w01[i]; sw2[i] = c1w2[i]; }
        if (threadIdx.x < 32) { sb2[threadIdx.x] = c2b[threadIdx.x]; sb1[threadIdx.x] = c1b[threadIdx.x]; }

        const int zrow0 = strip*16;
        for (int idx = t256; idx < 3762; idx += 256) {
            int ic = idx / (19*66);
            int rem = idx - ic*(19*66);
            int li = rem / 66;
            int x2 = rem - li*66;
            int iy = zrow0 + li;
            unsigned int v = 0;
            if (iy < 128 && x2 < 64) {
                float2 p = *(const float2*)&z_i[(((size_t)img*3 + ic)*128 + iy)*128 + 2*x2];
                v = packh2(p.x, p.y);
            }
            sZ[idx] = v;
        }
        for (int idx = t256; idx < 16*9*2; idx += 256) {
            int oc2 = idx / 18; int rem = idx - oc2*18; int li = rem >> 1; int c = 64 + (rem & 1);
            sC1[oc2*(9*66) + li*66 + c] = 0;
        }
        __syncthreads();
        for (int pos = t256; pos < 576; pos += 256) {
            int li = pos >> 6;
            int ox = pos & 63;
            unsigned int pa[9]; float px[9];
            #pragma unroll
            for (int ic = 0; ic < 3; ++ic)
                #pragma unroll
                for (int dy = 0; dy < 3; ++dy) {
                    int r = ic*3 + dy;
                    int rowb = ic*(19*66) + (2*li + dy)*66;
                    pa[r] = sZ[rowb + ox];
                    unsigned int u = sZ[rowb + ox + 1];
                    px[r] = __half2float(((const __half2*)&u)->x);
                }
            const bool phantom = (strip == 7) && (li == 8);
            #pragma unroll 4
            for (int oc2 = 0; oc2 < 16; ++oc2) {
                const int oca = 2*oc2, ocb = oca + 1;
                float acca = sb1[oca], accb = sb1[ocb];
                #pragma unroll
                for (int r = 0; r < 9; ++r) {
                    acca = fdot2(sw01[oca*9 + r], pa[r], acca);
                    acca += sw2[oca*9 + r] * px[r];
                    accb = fdot2(sw01[ocb*9 + r], pa[r], accb);
                    accb += sw2[ocb*9 + r] * px[r];
                }
                sC1[oc2*(9*66) + li*66 + ox] =
                    phantom ? 0u : packh2(fmaxf(acca, 0.f), fmaxf(accb, 0.f));
            }
        }
        __syncthreads();
        const int posl = t256 & 127;
        const int half = t256 >> 7;
        const int ly = posl >> 5;
        const int ox = posl & 31;
        float acc[16];
        #pragma unroll
        for (int j = 0; j < 16; ++j) acc[j] = 0.f;
        for (int ic2 = 0; ic2 < 16; ++ic2) {
            unsigned int patch[9];
            #pragma unroll
            for (int dy = 0; dy < 3; ++dy)
                #pragma unroll
                for (int dx = 0; dx < 3; ++dx)
                    patch[dy*3+dx] = sC1[ic2*(9*66) + (2*ly+dy)*66 + 2*ox + dx];
            const unsigned int* wbase = sW + (half*16 + ic2)*192;
            #pragma unroll
            for (int j = 0; j < 16; ++j) {
                const unsigned int* wr = wbase + j*12;
                uint4 wa = *(const uint4*)wr;
                uint4 wb = *(const uint4*)(wr + 4);
                unsigned int w8 = wr[8];
                float a = acc[j];
                a = fdot2(wa.x, patch[0], a); a = fdot2(wa.y, patch[1], a);
                a = fdot2(wa.z, patch[2], a); a = fdot2(wa.w, patch[3], a);
                a = fdot2(wb.x, patch[4], a); a = fdot2(wb.y, patch[5], a);
                a = fdot2(wb.z, patch[6], a); a = fdot2(wb.w, patch[7], a);
                a = fdot2(w8,  patch[8], a);
                acc[j] = a;
            }
        }
        const int oy = strip*4 + ly;
        #pragma unroll
        for (int j = 0; j < 16; ++j) {
            int oc = half*16 + j;
            zfeat[(((size_t)img*32 + oc)*32 + oy)*32 + ox] = fmaxf(acc[j] + sb2[oc], 0.f);
        }
    }
}

// ---------------- replay + forward FFT fused: block per (b,m) = 256 blocks, 256 thr
__global__ __launch_bounds__(256) void replay_fft_kernel(
    const float* __restrict__ xfeat, const float* __restrict__ wbuf,
    const float* __restrict__ eag, const float* __restrict__ lnst,
    const float* __restrict__ cosw, const float* __restrict__ twg,
    float* __restrict__ cfft)
{
    const int m = blockIdx.x & 31;
    const int b = blockIdx.x >> 5;
    const int tid = threadIdx.x;
    __shared__ __align__(16) float sY[32*36];
    __shared__ __align__(16) float sT[2048];
    __shared__ __align__(16) float sR[2048];
    {
        const float4* s4 = (const float4*)twg;
        float4* d4 = (float4*)sT;
        d4[tid]       = s4[tid];
        d4[256 + tid] = s4[256 + tid];
    }
    const int n0 = tid*4;
    float4 cw = *(const float4*)&cosw[n0];
    const float mu = lnst[b*2], rs = lnst[b*2+1];
    float c0v, c1v, c2v, c3v;
    {
        float4 x = *(const float4*)&xfeat[(size_t)(b*16)*32768 + (size_t)m*1024 + n0];
        c0v=(x.x-mu)*rs; c1v=(x.y-mu)*rs; c2v=(x.z-mu)*rs; c3v=(x.w-mu)*rs;
    }
    const int hj = tid >> 3;
    const int k0 = (tid & 7)*4;
    const int syoff = (tid>>3)*36 + (tid&7)*4;

    for (int t = 0; t < 16; ++t) {
        const size_t bt = (size_t)(b*16 + t);
        float4 w = *(const float4*)&wbuf[bt*1024 + n0];
        float e = eag[bt*80 + m];
        float a = eag[bt*80 + 32 + m];
        float g = eag[bt*80 + 64];
        float omg = 1.f - g;
        float4 xv = *(const float4*)&xfeat[bt*32768 + (size_t)m*1024 + n0];
        c0v = omg*(c0v*(1.f - w.x*e) + w.x*a) + g*xv.x;
        c1v = omg*(c1v*(1.f - w.y*e) + w.y*a) + g*xv.y;
        c2v = omg*(c2v*(1.f - w.z*e) + w.z*a) + g*xv.z;
        c3v = omg*(c3v*(1.f - w.w*e) + w.w*a) + g*xv.w;
        *(float4*)&sY[syoff] = make_float4(c0v*cw.x, c1v*cw.y, c2v*cw.z, c3v*cw.w);
        __syncthreads();
        // stage1: R[h][k] = sum_w y[h][w] * tw[w][k]
        float r0=0.f,i0=0.f,r1=0.f,i1=0.f,r2=0.f,i2=0.f,r3=0.f,i3=0.f;
        #pragma unroll
        for (int ww = 0; ww < 32; ++ww) {
            float y = sY[hj*36 + ww];
            float4 ta = *(const float4*)&sT[(ww*32 + k0)*2];
            float4 tb = *(const float4*)&sT[(ww*32 + k0)*2 + 4];
            r0 += y*ta.x; i0 += y*ta.y;
            r1 += y*ta.z; i1 += y*ta.w;
            r2 += y*tb.x; i2 += y*tb.y;
            r3 += y*tb.z; i3 += y*tb.w;
        }
        *(float4*)&sR[(hj*32 + k0)*2]     = make_float4(r0,i0,r1,i1);
        *(float4*)&sR[(hj*32 + k0)*2 + 4] = make_float4(r2,i2,r3,i3);
        __syncthreads();
        // stage2
        float fr0=0.f,fi0=0.f,fr1=0.f,fi1=0.f,fr2=0.f,fi2=0.f,fr3=0.f,fi3=0.f;
        #pragma unroll
        for (int h = 0; h < 32; ++h) {
            float2 wj = *(const float2*)&sT[(h*32 + hj)*2];
            float4 Ra = *(const float4*)&sR[(h*32 + k0)*2];
            float4 Rb = *(const float4*)&sR[(h*32 + k0)*2 + 4];
            fr0 += Ra.x*wj.x - Ra.y*wj.y;  fi0 += Ra.x*wj.y + Ra.y*wj.x;
            fr1 += Ra.z*wj.x - Ra.w*wj.y;  fi1 += Ra.z*wj.y + Ra.w*wj.x;
            fr2 += Rb.x*wj.x - Rb.y*wj.y;  fi2 += Rb.x*wj.y + Rb.y*wj.x;
            fr3 += Rb.z*wj.x - Rb.w*wj.y;  fi3 += Rb.z*wj.y + Rb.w*wj.x;
        }
        float* dp = cfft + (size_t)(bt*32 + m)*1088 + (size_t)(hj*17 + k0)*2;
        if (k0 < 16) {
            *(float2*)&dp[0] = make_float2(fr0, fi0);
            *(float2*)&dp[2] = make_float2(fr1, fi1);
            *(float2*)&dp[4] = make_float2(fr2, fi2);
            *(float2*)&dp[6] = make_float2(fr3, fi3);
        } else if (k0 == 16) {
            *(float2*)&dp[0] = make_float2(fr0, fi0);
        }
    }
}

// ---------------- rfft2 (z only): table-driven DFT, 4096 blocks
__global__ __launch_bounds__(256) void fft_fwd_kernel(const float* __restrict__ src0,
                                                      const float* __restrict__ cosw,
                                                      const float* __restrict__ twg,
                                                      float* __restrict__ dst0)
{
    const int img = blockIdx.x;
    const int tid = threadIdx.x;
    const float* src = src0 + (size_t)img*1024;
    float* dst = dst0 + (size_t)img*1088;

    __shared__ __align__(16) float sY[32*36];
    __shared__ __align__(16) float sT[2048];
    __shared__ __align__(16) float sR[2048];

    {
        const float4* s4 = (const float4*)twg;
        float4* d4 = (float4*)sT;
        d4[tid]       = s4[tid];
        d4[256 + tid] = s4[256 + tid];
    }
    {
        float4 v = *(const float4*)&src[tid*4];
        float4 c = *(const float4*)&cosw[tid*4];
        *(float4*)&sY[(tid>>3)*36 + (tid&7)*4] = make_float4(v.x*c.x, v.y*c.y, v.z*c.z, v.w*c.w);
    }
    __syncthreads();

    const int hj = tid >> 3;
    const int k0 = (tid & 7) * 4;

    float r0=0.f,i0=0.f,r1=0.f,i1=0.f,r2=0.f,i2=0.f,r3=0.f,i3=0.f;
    #pragma unroll
    for (int w = 0; w < 32; ++w) {
        float y = sY[hj*36 + w];
        float4 ta = *(const float4*)&sT[(w*32 + k0)*2];
        float4 tb = *(const float4*)&sT[(w*32 + k0)*2 + 4];
        r0 += y*ta.x; i0 += y*ta.y;
        r1 += y*ta.z; i1 += y*ta.w;
        r2 += y*tb.x; i2 += y*tb.y;
        r3 += y*tb.z; i3 += y*tb.w;
    }
    *(float4*)&sR[(hj*32 + k0)*2]     = make_float4(r0,i0,r1,i1);
    *(float4*)&sR[(hj*32 + k0)*2 + 4] = make_float4(r2,i2,r3,i3);
    __syncthreads();

    float fr0=0.f,fi0=0.f,fr1=0.f,fi1=0.f,fr2=0.f,fi2=0.f,fr3=0.f,fi3=0.f;
    #pragma unroll
    for (int h = 0; h < 32; ++h) {
        float2 wj = *(const float2*)&sT[(h*32 + hj)*2];
        float4 Ra = *(const float4*)&sR[(h*32 + k0)*2];
        float4 Rb = *(const float4*)&sR[(h*32 + k0)*2 + 4];
        fr0 += Ra.x*wj.x - Ra.y*wj.y;  fi0 += Ra.x*wj.y + Ra.y*wj.x;
        fr1 += Ra.z*wj.x - Ra.w*wj.y;  fi1 += Ra.z*wj.y + Ra.w*wj.x;
        fr2 += Rb.x*wj.x - Rb.y*wj.y;  fi2 += Rb.x*wj.y + Rb.y*wj.x;
        fr3 += Rb.z*wj.x - Rb.w*wj.y;  fi3 += Rb.z*wj.y + Rb.w*wj.x;
    }
    float* dp = dst + (size_t)(hj*17 + k0)*2;
    if (k0 < 16) {
        *(float2*)&dp[0] = make_float2(fr0, fi0);
        *(float2*)&dp[2] = make_float2(fr1, fi1);
        *(float2*)&dp[4] = make_float2(fr2, fi2);
        *(float2*)&dp[6] = make_float2(fr3, fi3);
    } else if (k0 == 16) {
        *(float2*)&dp[0] = make_float2(fr0, fi0);
    }
}

// ---------------- fused combine + irfft2; one block per bt
__global__ __launch_bounds__(256) void comb_ifft_kernel(const float* __restrict__ cfft,
                                                        const float* __restrict__ zfft,
                                                        const float* __restrict__ yf,
                                                        float* __restrict__ out)
{
    const int bt  = blockIdx.x;
    const int tid = threadIdx.x;
    __shared__ float sG[544*2];
    __shared__ float sS[544*2];
    __shared__ float ct[32], st[32];
    if (tid < 32) {
        float sv, cv;
        sincosf(TWOPI_32 * (float)tid, &sv, &cv);
        ct[tid] = cv; st[tid] = sv;
    }
    for (int idx = tid; idx < 544; idx += 256) {
        float kzz = 0.f, kxr = 0.f, kxi = 0.f;
        #pragma unroll 4
        for (int m = 0; m < 32; ++m) {
            size_t base = ((size_t)(bt*32 + m)*1088) + idx*2;
            float2 c = *(const float2*)&cfft[base];
            float2 z = *(const float2*)&zfft[base];
            kzz += c.x*c.x + c.y*c.y;
            kxr += z.x*c.x + z.y*c.y;
            kxi += z.y*c.x - z.x*c.y;
        }
        float den = 1.f / (kzz + 1e-4f);
        float2 y = *(const float2*)&yf[idx*2];
        float ar = y.x*den, ai = y.y*den;
        sG[idx*2]     = kxr*ar - kxi*ai;
        sG[idx*2 + 1] = kxr*ai + kxi*ar;
    }
    __syncthreads();
    for (int idx = tid; idx < 544; idx += 256) {
        int h = idx / 17;
        int k = idx - h*17;
        float re = 0.f, im = 0.f;
        #pragma unroll
        for (int j = 0; j < 32; ++j) {
            float gr = sG[(j*17+k)*2], gi = sG[(j*17+k)*2+1];
            int a = (h*j) & 31;
            float c = ct[a], s = st[a];
            re += gr*c - gi*s;
            im += gr*s + gi*c;
        }
        sS[(h*17+k)*2] = re; sS[(h*17+k)*2+1] = im;
    }
    __syncthreads();
    #pragma unroll
    for (int p = 0; p < 4; ++p) {
        int pos = p*256 + tid;
        int h = pos >> 5, wq = pos & 31;
        float acc = sS[(h*17)*2];
        #pragma unroll
        for (int k = 1; k < 16; ++k) {
            int a = (wq*k) & 31;
            acc += 2.f*(sS[(h*17+k)*2]*ct[a] - sS[(h*17+k)*2+1]*st[a]);
        }
        acc += sS[(h*17+16)*2] * ((wq & 1) ? -1.f : 1.f);
        out[(size_t)bt*1024 + pos] = acc * (1.f/1024.f);
    }
}

extern "C" void kernel_launch(void* const* d_in, const int* in_sizes, int n_in,
                              void* d_out, int out_size, void* d_ws, size_t ws_size,
                              hipStream_t stream)
{
    const float* x_i   = (const float*)d_in[0];
    const float* z_i   = (const float*)d_in[1];
    const float* c1w   = (const float*)d_in[2];
    const float* c1b   = (const float*)d_in[3];
    const float* c2w   = (const float*)d_in[4];
    const float* c2b   = (const float*)d_in[5];
    const float* Wk    = (const float*)d_in[6];
    const float* bk    = (const float*)d_in[7];
    const float* Wbeta = (const float*)d_in[8];
    const float* bbeta = (const float*)d_in[9];
    const float* Wh    = (const float*)d_in[10];
    const float* bh    = (const float*)d_in[11];
    const float* We    = (const float*)d_in[12];
    const float* Wa    = (const float*)d_in[13];
    const float* Wg    = (const float*)d_in[14];
    const float* cosw  = (const float*)d_in[15];
    const float* yf    = (const float*)d_in[16];
    float* out = (float*)d_out;
    float* ws  = (float*)d_ws;

    // workspace layout (floats)
    float*  xfeat = ws + 16777216;      // 4,194,304
    float*  zfeat = ws + 20971520;      // 4,194,304
    float*  cfft  = ws;                 // 4,456,448 f
    float*  zfft  = ws + 4456448;       // 4,456,448 f (ends 8,912,896)
    __half* xhb   = (__half*)(ws + 9000000);    // 4,194,304 halfs
    float*  wbuf  = ws + 11100000;      // 131,072 f
    float*  eag   = ws + 11240000;      // 10,240 f
    float*  lnstp = ws + 11251000;      // 16 f
    // prepack outputs + xmp in the dead gap [29,360,128 .. 29,499,392)
    __half* whhP  = (__half*)(ws + 29360128);
    __half* whrxP = (__half*)(ws + 29392896);
    __half* wkP   = (__half*)(ws + 29401088);
    __half* weP   = (__half*)(ws + 29405184);
    __half* waP   = (__half*)(ws + 29409280);
    float*  twg   = ws + 29413376;
    unsigned int* c2wP   = (unsigned int*)(ws + 29415424);  // 6,144 u32
    unsigned int* c1wP01 = (unsigned int*)(ws + 29421568);  // 288 u32
    float*  c1wP2 = ws + 29421856;      // 288 f -> ends 29,422,144
    float*  xmp   = ws + 29422144;      // 65,536 f -> ends 29,487,680 (< 29,499,392 OK)

    dim3 b256(256);
    prepack_kernel<<<33, b256, 0, stream>>>(Wh, Wk, We, Wa, c1w, c2w,
                                            whhP, whrxP, wkP, weP, waP, twg,
                                            c2wP, c1wP01, c1wP2);
    convx_kernel<<<512, 512, 0, stream>>>(x_i, c1wP01, c1wP2, c1b, c2wP, c2b,
                                          xfeat, xhb, xmp);
    fat_kernel<<<520, 512, 0, stream>>>(xfeat, xhb, xmp, whhP, whrxP, wkP, weP, waP,
                                        bk, Wbeta, bbeta, bh, Wg, wbuf, eag, lnstp,
                                        z_i, c1wP01, c1wP2, c1b, c2wP, c2b, zfeat);
    replay_fft_kernel<<<256, b256, 0, stream>>>(xfeat, wbuf, eag, lnstp, cosw, twg, cfft);
    fft_fwd_kernel<<<4096, b256, 0, stream>>>(zfeat, cosw, twg, zfft);
    comb_ifft_kernel<<<128, b256, 0, stream>>>(cfft, zfft, yf, out);
}

// Round 15
// 407.616 us; speedup vs baseline: 2.2065x; 1.0260x over previous
//
#include <hip/hip_runtime.h>
#include <hip/hip_fp16.h>
#include <math.h>

// B=8, T=16, IMG=128, CF=32, WO=HO=32, N=1024, M=32, DH=256
// conv SAME stride2: pad_lo=0, pad_hi=1 -> in_idx = 2*out + k

#define TWOPI_32 0.19634954084936207f  // 2*pi/32

typedef _Float16 __h2 __attribute__((ext_vector_type(2)));
__device__ __forceinline__ float fdot2(unsigned int w, unsigned int h, float acc) {
    union { unsigned int u; __h2 v; } a, b;
    a.u = w; b.u = h;
    return __builtin_amdgcn_fdot2(a.v, b.v, acc, false);
}
__device__ __forceinline__ unsigned int packh2(float a, float b) {
    __half2 h2 = __floats2half2_rn(a, b);
    return *(unsigned int*)&h2;
}

// helper: pack conv weights into block LDS from raw inputs (call with all block threads, NT = blockDim)
__device__ __forceinline__ void pack_conv_lds(
    const float* __restrict__ c1w, const float* __restrict__ c1b,
    const float* __restrict__ c2w, const float* __restrict__ c2b,
    unsigned int* sW, unsigned int* sw01, float* sw2, float* sb1, float* sb2, int NT)
{
    for (int i = threadIdx.x; i < 4608; i += NT) {
        int half = i / 2304;
        int rem  = i - half*2304;
        int ic2  = rem / 144;
        int r2   = rem - ic2*144;
        int j    = r2 / 9, q = r2 - j*9;
        int oc   = half*16 + j;
        sW[(half*16 + ic2)*192 + j*12 + q] =
            packh2(c2w[oc*288 + (2*ic2)*9 + q], c2w[oc*288 + (2*ic2+1)*9 + q]);
    }
    for (int i = threadIdx.x; i < 288; i += NT) {
        int oc = i / 9, r = i - oc*9;
        sw01[i] = packh2(c1w[oc*27 + r*3 + 0], c1w[oc*27 + r*3 + 1]);
        sw2[i]  = c1w[oc*27 + r*3 + 2];
    }
    if (threadIdx.x < 32) { sb1[threadIdx.x] = c1b[threadIdx.x]; sb2[threadIdx.x] = c2b[threadIdx.x]; }
}

// ---------------- convx: fused conv1+conv2 (x path) + (blocks 512+) NTM weight packs & twiddle
__global__ __launch_bounds__(512, 1) void convx_kernel(
    const float* __restrict__ x_i, const float* __restrict__ c1w,
    const float* __restrict__ c1b, const float* __restrict__ c2w,
    const float* __restrict__ c2b,
    const float* __restrict__ Wh, const float* __restrict__ Wk,
    const float* __restrict__ We, const float* __restrict__ Wa,
    float* __restrict__ xfeat, __half* __restrict__ xh, float* __restrict__ xmp,
    __half* __restrict__ whhP, __half* __restrict__ whrxP,
    __half* __restrict__ wkP, __half* __restrict__ weP, __half* __restrict__ waP,
    float* __restrict__ twg)
{
    __shared__ __align__(16) char smem[139264];
    if (blockIdx.x >= 512) {
        if (blockIdx.x < 528) {
            const int base = (blockIdx.x - 512)*512 + threadIdx.x;   // 0..8191
            #pragma unroll
            for (int r = 0; r < 8; ++r) {
                int idx = base*8 + r;
                int e = idx & 7, i = (idx >> 3) & 255, c = idx >> 11;
                int q = c >> 4, k = c & 15;
                whhP[idx] = __float2half(Wh[i*320 + q*128 + k*8 + e]);
            }
            #pragma unroll
            for (int r = 0; r < 2; ++r) {
                int idx = base*2 + r;
                int i = idx >> 6, s2 = idx & 63;
                whrxP[idx] = __float2half(Wh[i*320 + 256 + s2]);
            }
            {
                int idx = base;
                int m = idx >> 8, j = (idx >> 4) & 15, e = idx & 15;
                int col = (e < 8) ? (8*j + e) : (128 + 8*j + (e - 8));
                wkP[idx] = __float2half(Wk[m*256 + col]);
                weP[idx] = __float2half(We[m*256 + col]);
                waP[idx] = __float2half(Wa[m*256 + col]);
            }
        } else {
            for (int idx = threadIdx.x; idx < 1024; idx += 512) {
                int w = idx >> 5, k = idx & 31;
                float sv, cv;
                sincosf(TWOPI_32 * (float)((w*k) & 31), &sv, &cv);
                twg[idx*2]     = cv;
                twg[idx*2 + 1] = -sv;
            }
        }
        return;
    }
    const int team = threadIdx.x >> 8;
    const int t256 = threadIdx.x & 255;
    const int tile = blockIdx.x*2 + team;   // 0..1023
    const int img  = tile >> 3;
    const int strip = tile & 7;
    unsigned int* sZ  = (unsigned int*)(smem + team*53072);           // [3][19][66]
    unsigned int* sC1 = (unsigned int*)(smem + team*53072 + 15048);   // [16][9][66]
    unsigned int* sW   = (unsigned int*)(smem + 106144);              // 6144 u32
    unsigned int* sw01 = (unsigned int*)(smem + 130720);              // 288
    float*        sw2  = (float*)(smem + 131872);                     // 288
    float*        sb2  = (float*)(smem + 133024);                     // 32
    float*        sb1  = (float*)(smem + 133152);                     // 32

    pack_conv_lds(c1w, c1b, c2w, c2b, sW, sw01, sw2, sb1, sb2, 512);

    const int zrow0 = strip*16;
    for (int idx = t256; idx < 3762; idx += 256) {
        int ic = idx / (19*66);
        int rem = idx - ic*(19*66);
        int li = rem / 66;
        int x2 = rem - li*66;
        int iy = zrow0 + li;
        unsigned int v = 0;
        if (iy < 128 && x2 < 64) {
            float2 p = *(const float2*)&x_i[(((size_t)img*3 + ic)*128 + iy)*128 + 2*x2];
            v = packh2(p.x, p.y);
        }
        sZ[idx] = v;
    }
    for (int idx = t256; idx < 16*9*2; idx += 256) {
        int oc2 = idx / 18; int rem = idx - oc2*18; int li = rem >> 1; int c = 64 + (rem & 1);
        sC1[oc2*(9*66) + li*66 + c] = 0;
    }
    __syncthreads();
    // conv1: 9 rows x 64 cols (phantom row 64 at strip 7 -> 0)
    for (int pos = t256; pos < 576; pos += 256) {
        int li = pos >> 6;
        int ox = pos & 63;
        unsigned int pa[9]; float px[9];
        #pragma unroll
        for (int ic = 0; ic < 3; ++ic)
            #pragma unroll
            for (int dy = 0; dy < 3; ++dy) {
                int r = ic*3 + dy;
                int rowb = ic*(19*66) + (2*li + dy)*66;
                pa[r] = sZ[rowb + ox];
                unsigned int u = sZ[rowb + ox + 1];
                px[r] = __half2float(((const __half2*)&u)->x);
            }
        const bool phantom = (strip == 7) && (li == 8);
        #pragma unroll 4
        for (int oc2 = 0; oc2 < 16; ++oc2) {
            const int oca = 2*oc2, ocb = oca + 1;
            float acca = sb1[oca], accb = sb1[ocb];
            #pragma unroll
            for (int r = 0; r < 9; ++r) {
                acca = fdot2(sw01[oca*9 + r], pa[r], acca);
                acca += sw2[oca*9 + r] * px[r];
                accb = fdot2(sw01[ocb*9 + r], pa[r], accb);
                accb += sw2[ocb*9 + r] * px[r];
            }
            sC1[oc2*(9*66) + li*66 + ox] =
                phantom ? 0u : packh2(fmaxf(acca, 0.f), fmaxf(accb, 0.f));
        }
    }
    __syncthreads();
    // conv2: 4 rows x 32 cols x 32 oc; then emit xfeat/xh/xmp
    const int posl = t256 & 127;
    const int half = t256 >> 7;
    const int ly = posl >> 5;
    const int ox = posl & 31;
    float acc[16];
    #pragma unroll
    for (int j = 0; j < 16; ++j) acc[j] = 0.f;
    for (int ic2 = 0; ic2 < 16; ++ic2) {
        unsigned int patch[9];
        #pragma unroll
        for (int dy = 0; dy < 3; ++dy)
            #pragma unroll
            for (int dx = 0; dx < 3; ++dx)
                patch[dy*3+dx] = sC1[ic2*(9*66) + (2*ly+dy)*66 + 2*ox + dx];
        const unsigned int* wbase = sW + (half*16 + ic2)*192;
        #pragma unroll
        for (int j = 0; j < 16; ++j) {
            const unsigned int* wr = wbase + j*12;
            uint4 wa = *(const uint4*)wr;
            uint4 wb = *(const uint4*)(wr + 4);
            unsigned int w8 = wr[8];
            float a = acc[j];
            a = fdot2(wa.x, patch[0], a); a = fdot2(wa.y, patch[1], a);
            a = fdot2(wa.z, patch[2], a); a = fdot2(wa.w, patch[3], a);
            a = fdot2(wb.x, patch[4], a); a = fdot2(wb.y, patch[5], a);
            a = fdot2(wb.z, patch[6], a); a = fdot2(wb.w, patch[7], a);
            a = fdot2(w8,  patch[8], a);
            acc[j] = a;
        }
    }
    const int oy = strip*4 + ly;
    const int n  = oy*32 + ox;
    float vals[16];
    #pragma unroll
    for (int j = 0; j < 16; ++j) {
        int oc = half*16 + j;
        float v = fmaxf(acc[j] + sb2[oc], 0.f);
        vals[j] = v;
        xfeat[(((size_t)img*32 + oc)*32 + oy)*32 + ox] = v;
    }
    {
        unsigned int hp[8];
        #pragma unroll
        for (int k = 0; k < 8; ++k) hp[k] = packh2(vals[2*k], vals[2*k+1]);
        uint4* dp = (uint4*)(xh + (size_t)img*32768 + (size_t)n*32 + half*16);
        dp[0] = *(uint4*)&hp[0];
        dp[1] = *(uint4*)&hp[4];
    }
    {
        const int lane = threadIdx.x & 63;
        const int wsub = (t256 >> 6) & 1;
        #pragma unroll
        for (int j = 0; j < 16; ++j) {
            float v = vals[j];
            #pragma unroll
            for (int d = 32; d > 0; d >>= 1) v += __shfl_xor(v, d, 64);
            if (lane == 0)
                xmp[(((size_t)img*8 + strip)*2 + wsub)*32 + half*16 + j] = v * (1.f/1024.f);
        }
    }
}

// ---------------- FAT: blocks 0..7 = NTM recurrence; blocks 8.. = fused conv1+conv2 (z)
__global__ __launch_bounds__(512, 1) void fat_kernel(
    const float* __restrict__ xfeat, const __half* __restrict__ xh,
    const float* __restrict__ xmp,
    const __half* __restrict__ whhP, const __half* __restrict__ whrxP,
    const __half* __restrict__ wkP, const __half* __restrict__ weP,
    const __half* __restrict__ waP,
    const float* __restrict__ bk, const float* __restrict__ Wbeta,
    const float* __restrict__ bbeta, const float* __restrict__ bh,
    const float* __restrict__ Wg,
    float* __restrict__ wbuf, float* __restrict__ eag, float* __restrict__ lnst,
    const float* __restrict__ z_i, const float* __restrict__ c1w,
    const float* __restrict__ c1b, const float* __restrict__ c2w,
    const float* __restrict__ c2b,
    float* __restrict__ zfeat)
{
    __shared__ __align__(16) char smem[139264];

    if (blockIdx.x < 8) {
        // ======== NTM branch ========
        __builtin_amdgcn_s_setprio(1);
        __half* sWhh = (__half*)(smem);                    // 131072 B
        float (*sHbuf)[256] = (float(*)[256])(smem + 131072);
        __half (*sHh)[256] = (__half(*)[256])(smem + 133120);
        float* sK    = (float*)(smem + 134144);
        float* sXm   = (float*)(smem + 134272);
        float* sRedC = (float*)(smem + 136320);
        float* sR32  = (float*)(smem + 137344);
        float* sE    = (float*)(smem + 137472);
        float* sA    = (float*)(smem + 137600);
        float* sBk   = (float*)(smem + 137728);
        float* sBh   = (float*)(smem + 137856);
        float* sRedD = (float*)(smem + 138880);
        float* sRedL = (float*)(smem + 138912);

        const int b    = blockIdx.x;
        const int tid  = threadIdx.x;
        const int lane = tid & 63;
        const int wid  = tid >> 6;

        {
            const uint4* src = (const uint4*)whhP;
            uint4* dst = (uint4*)sWhh;
            for (int i2 = tid; i2 < 8192; i2 += 512) dst[i2] = src[i2];
        }
        if (tid < 256) { sBh[tid] = bh[tid]; sHbuf[0][tid] = 0.f; sHh[0][tid] = __float2half(0.f); }
        if (tid < 32)  { sBk[tid] = bk[tid]; sK[tid] = tanhf(bk[tid]); }
        if (tid < 512) {
            const int tt = tid >> 5, m = tid & 31;
            const float* pp = xmp + ((size_t)(b*16 + tt)*16)*32 + m;
            float s = 0.f;
            #pragma unroll
            for (int q = 0; q < 16; ++q) s += pp[q*32];
            sXm[tid] = s;
        }
        float4 wbeta4 = *(const float4*)&Wbeta[(size_t)lane*4];
        float4 wg4    = *(const float4*)&Wg[(size_t)lane*4];
        float bb = bbeta[0];

        const int mg = tid >> 4, jg = tid & 15;
        uint4 wk0, wk1, we0, we1, wa0, wa1;
        {
            const uint4* p;
            p = (const uint4*)(wkP + (size_t)(mg*16 + jg)*16); wk0 = p[0]; wk1 = p[1];
            p = (const uint4*)(weP + (size_t)(mg*16 + jg)*16); we0 = p[0]; we1 = p[1];
            p = (const uint4*)(waP + (size_t)(mg*16 + jg)*16); wa0 = p[0]; wa1 = p[1];
        }
        const int iD = tid >> 1, qD = tid & 1;
        uint4 wrx0, wrx1, wrx2, wrx3;
        {
            const uint4* p = (const uint4*)(whrxP + (size_t)iD*64 + qD*32);
            wrx0 = p[0]; wrx1 = p[1]; wrx2 = p[2]; wrx3 = p[3];
        }

        const int n0 = 2*tid;
        float c0[32], c1[32];

        {
            const float* x0 = xfeat + (size_t)(b*16)*32768;
            float sum = 0.f, ss = 0.f;
            #pragma unroll
            for (int m = 0; m < 32; ++m) {
                float2 v = *(const float2*)&x0[m*1024 + n0];
                c0[m] = v.x; c1[m] = v.y;
                sum += v.x + v.y; ss += v.x*v.x + v.y*v.y;
            }
            #pragma unroll
            for (int d = 32; d > 0; d >>= 1) { sum += __shfl_xor(sum, d, 64); ss += __shfl_xor(ss, d, 64); }
            if (lane == 0) { sRedL[wid] = sum; sRedL[8+wid] = ss; }
            __syncthreads();
            float S = 0.f, SS = 0.f;
            #pragma unroll
            for (int i = 0; i < 8; ++i) { S += sRedL[i]; SS += sRedL[8+i]; }
            float mu = S * (1.f/32768.f);
            float var = SS * (1.f/32768.f) - mu*mu;
            float rs = rsqrtf(var + 1e-5f);
            if (tid == 0) { lnst[b*2] = mu; lnst[b*2+1] = rs; }
            #pragma unroll
            for (int m = 0; m < 32; ++m) { c0[m] = (c0[m]-mu)*rs; c1[m] = (c1[m]-mu)*rs; }
        }

        uint4 xb[8];
        {
            const uint4* xrow = (const uint4*)(xh + (size_t)(b*16)*32768) + 8*tid;
            #pragma unroll
            for (int i = 0; i < 8; ++i) xb[i] = xrow[i];
        }
        __syncthreads();

        float betav = (bb > 20.f) ? bb : log1pf(expf(bb));
        float ex0 = 0.f, ex1 = 0.f, w0 = 0.f, w1 = 0.f;
        const int rm = ((lane&1)<<4)|((lane&2)<<2)|(lane&4)|((lane&8)>>2)|((lane&16)>>4);

        #pragma unroll 1
        for (int t = 0; t < 16; ++t) {
            const int cur = t & 1, nxt = cur ^ 1;

            // PH_A
            {
                float beta = betav;
                float dot0 = 0.f, dot1 = 0.f, cn20 = 0.f, cn21 = 0.f, kn2 = 0.f;
                #pragma unroll
                for (int q = 0; q < 8; ++q) {
                    float4 k4 = *(const float4*)&sK[4*q];
                    dot0 += c0[4*q]*k4.x + c0[4*q+1]*k4.y + c0[4*q+2]*k4.z + c0[4*q+3]*k4.w;
                    dot1 += c1[4*q]*k4.x + c1[4*q+1]*k4.y + c1[4*q+2]*k4.z + c1[4*q+3]*k4.w;
                    cn20 += c0[4*q]*c0[4*q] + c0[4*q+1]*c0[4*q+1] + c0[4*q+2]*c0[4*q+2] + c0[4*q+3]*c0[4*q+3];
                    cn21 += c1[4*q]*c1[4*q] + c1[4*q+1]*c1[4*q+1] + c1[4*q+2]*c1[4*q+2] + c1[4*q+3]*c1[4*q+3];
                    kn2  += k4.x*k4.x + k4.y*k4.y + k4.z*k4.z + k4.w*k4.w;
                }
                float kinv = 1.f / (sqrtf(kn2) + 1e-8f);
                float s0 = dot0 * kinv / (sqrtf(cn20) + 1e-8f);
                float s1 = dot1 * kinv / (sqrtf(cn21) + 1e-8f);
                ex0 = expf(beta * s0);
                ex1 = expf(beta * s1);
                float es = ex0 + ex1;
                #pragma unroll
                for (int d = 32; d > 0; d >>= 1) es += __shfl_xor(es, d, 64);
                if (lane == 0) sRedD[wid] = es;
                float v[32];
                #pragma unroll
                for (int m = 0; m < 32; ++m) v[m] = ex0*c0[m] + ex1*c1[m];
                #pragma unroll
                for (int i = 0; i < 16; ++i) { float sd = (lane&1)? v[i] : v[i+16]; float rc = __shfl_xor(sd, 1, 64); v[i] = ((lane&1)? v[i+16] : v[i]) + rc; }
                #pragma unroll
                for (int i = 0; i < 8; ++i)  { float sd = (lane&2)? v[i] : v[i+8];  float rc = __shfl_xor(sd, 2, 64); v[i] = ((lane&2)? v[i+8]  : v[i]) + rc; }
                #pragma unroll
                for (int i = 0; i < 4; ++i)  { float sd = (lane&4)? v[i] : v[i+4];  float rc = __shfl_xor(sd, 4, 64); v[i] = ((lane&4)? v[i+4]  : v[i]) + rc; }
                #pragma unroll
                for (int i = 0; i < 2; ++i)  { float sd = (lane&8)? v[i] : v[i+2];  float rc = __shfl_xor(sd, 8, 64); v[i] = ((lane&8)? v[i+2]  : v[i]) + rc; }
                { float sd = (lane&16)? v[0] : v[1]; float rc = __shfl_xor(sd, 16, 64); v[0] = ((lane&16)? v[1] : v[0]) + rc; }
                v[0] += __shfl_xor(v[0], 32, 64);
                if (lane < 32) sRedC[wid*32 + rm] = v[0];
            }
            __syncthreads();

            // PH_B
            {
                float den = sRedD[0]+sRedD[1]+sRedD[2]+sRedD[3]+sRedD[4]+sRedD[5]+sRedD[6]+sRedD[7];
                float inv = 1.f / den;
                w0 = ex0 * inv; w1 = ex1 * inv;
                *(float2*)&wbuf[(size_t)(b*16 + t)*1024 + n0] = make_float2(w0, w1);
                if (lane < 32) {
                    float r = 0.f;
                    #pragma unroll
                    for (int w = 0; w < 8; ++w) r += sRedC[w*32 + lane];
                    sR32[lane] = r * inv;
                }
                float s0 = 0.f, s1 = 0.f, s2 = 0.f, s3 = 0.f;
                #pragma unroll
                for (int k4 = 0; k4 < 4; ++k4) {
                    const int kb = 4*k4;
                    uint4 wv0 = *(const uint4*)&sWhh[(size_t)((qD*16 + kb+0)*256 + iD)*8];
                    uint4 hv0 = *(const uint4*)&sHh[cur][qD*128 + (kb+0)*8];
                    s0 = fdot2(wv0.x, hv0.x, s0); s0 = fdot2(wv0.y, hv0.y, s0);
                    s0 = fdot2(wv0.z, hv0.z, s0); s0 = fdot2(wv0.w, hv0.w, s0);
                    uint4 wv1 = *(const uint4*)&sWhh[(size_t)((qD*16 + kb+1)*256 + iD)*8];
                    uint4 hv1 = *(const uint4*)&sHh[cur][qD*128 + (kb+1)*8];
                    s1 = fdot2(wv1.x, hv1.x, s1); s1 = fdot2(wv1.y, hv1.y, s1);
                    s1 = fdot2(wv1.z, hv1.z, s1); s1 = fdot2(wv1.w, hv1.w, s1);
                    uint4 wv2 = *(const uint4*)&sWhh[(size_t)((qD*16 + kb+2)*256 + iD)*8];
                    uint4 hv2 = *(const uint4*)&sHh[cur][qD*128 + (kb+2)*8];
                    s2 = fdot2(wv2.x, hv2.x, s2); s2 = fdot2(wv2.y, hv2.y, s2);
                    s2 = fdot2(wv2.z, hv2.z, s2); s2 = fdot2(wv2.w, hv2.w, s2);
                    uint4 wv3 = *(const uint4*)&sWhh[(size_t)((qD*16 + kb+3)*256 + iD)*8];
                    uint4 hv3 = *(const uint4*)&sHh[cur][qD*128 + (kb+3)*8];
                    s3 = fdot2(wv3.x, hv3.x, s3); s3 = fdot2(wv3.y, hv3.y, s3);
                    s3 = fdot2(wv3.z, hv3.z, s3); s3 = fdot2(wv3.w, hv3.w, s3);
                }
                const float* rxsrc = qD ? &sXm[t*32] : sR32;
                {
                    const __half2* w2;
                    float4 va, vb;
                    va = *(const float4*)&rxsrc[0];  vb = *(const float4*)&rxsrc[4];
                    w2 = (const __half2*)&wrx0;
                    { float2 p0 = __half22float2(w2[0]); s0 += p0.x*va.x + p0.y*va.y;
                      float2 p1 = __half22float2(w2[1]); s0 += p1.x*va.z + p1.y*va.w;
                      float2 p2 = __half22float2(w2[2]); s0 += p2.x*vb.x + p2.y*vb.y;
                      float2 p3 = __half22float2(w2[3]); s0 += p3.x*vb.z + p3.y*vb.w; }
                    va = *(const float4*)&rxsrc[8];  vb = *(const float4*)&rxsrc[12];
                    w2 = (const __half2*)&wrx1;
                    { float2 p0 = __half22float2(w2[0]); s1 += p0.x*va.x + p0.y*va.y;
                      float2 p1 = __half22float2(w2[1]); s1 += p1.x*va.z + p1.y*va.w;
                      float2 p2 = __half22float2(w2[2]); s1 += p2.x*vb.x + p2.y*vb.y;
                      float2 p3 = __half22float2(w2[3]); s1 += p3.x*vb.z + p3.y*vb.w; }
                    va = *(const float4*)&rxsrc[16]; vb = *(const float4*)&rxsrc[20];
                    w2 = (const __half2*)&wrx2;
                    { float2 p0 = __half22float2(w2[0]); s2 += p0.x*va.x + p0.y*va.y;
                      float2 p1 = __half22float2(w2[1]); s2 += p1.x*va.z + p1.y*va.w;
                      float2 p2 = __half22float2(w2[2]); s2 += p2.x*vb.x + p2.y*vb.y;
                      float2 p3 = __half22float2(w2[3]); s2 += p3.x*vb.z + p3.y*vb.w; }
                    va = *(const float4*)&rxsrc[24]; vb = *(const float4*)&rxsrc[28];
                    w2 = (const __half2*)&wrx3;
                    { float2 p0 = __half22float2(w2[0]); s3 += p0.x*va.x + p0.y*va.y;
                      float2 p1 = __half22float2(w2[1]); s3 += p1.x*va.z + p1.y*va.w;
                      float2 p2 = __half22float2(w2[2]); s3 += p2.x*vb.x + p2.y*vb.y;
                      float2 p3 = __half22float2(w2[3]); s3 += p3.x*vb.z + p3.y*vb.w; }
                }
                float s = (s0 + s1) + (s2 + s3);
                s += __shfl_down(s, 1, 2);
                if (qD == 0) {
                    float hn = tanhf(s + sBh[iD]);
                    sHbuf[nxt][iD] = hn;
                    sHh[nxt][iD] = __float2half(hn);
                }
            }
            __syncthreads();

            // PH_C
            float gg;
            {
                uint4 h0 = *(const uint4*)&sHh[nxt][8*jg];
                uint4 h1 = *(const uint4*)&sHh[nxt][128 + 8*jg];
                float se0=0.f, se1=0.f, sa0=0.f, sa1=0.f, sk0=0.f, sk1=0.f;
                se0 = fdot2(we0.x, h0.x, se0); se1 = fdot2(we0.y, h0.y, se1);
                se0 = fdot2(we0.z, h0.z, se0); se1 = fdot2(we0.w, h0.w, se1);
                se0 = fdot2(we1.x, h1.x, se0); se1 = fdot2(we1.y, h1.y, se1);
                se0 = fdot2(we1.z, h1.z, se0); se1 = fdot2(we1.w, h1.w, se1);
                sa0 = fdot2(wa0.x, h0.x, sa0); sa1 = fdot2(wa0.y, h0.y, sa1);
                sa0 = fdot2(wa0.z, h0.z, sa0); sa1 = fdot2(wa0.w, h0.w, sa1);
                sa0 = fdot2(wa1.x, h1.x, sa0); sa1 = fdot2(wa1.y, h1.y, sa1);
                sa0 = fdot2(wa1.z, h1.z, sa0); sa1 = fdot2(wa1.w, h1.w, sa1);
                sk0 = fdot2(wk0.x, h0.x, sk0); sk1 = fdot2(wk0.y, h0.y, sk1);
                sk0 = fdot2(wk0.z, h0.z, sk0); sk1 = fdot2(wk0.w, h0.w, sk1);
                sk0 = fdot2(wk1.x, h1.x, sk0); sk1 = fdot2(wk1.y, h1.y, sk1);
                sk0 = fdot2(wk1.z, h1.z, sk0); sk1 = fdot2(wk1.w, h1.w, sk1);
                float se = se0 + se1, sa = sa0 + sa1, sk = sk0 + sk1;
                se += __shfl_down(se, 8, 16); sa += __shfl_down(sa, 8, 16); sk += __shfl_down(sk, 8, 16);
                se += __shfl_down(se, 4, 16); sa += __shfl_down(sa, 4, 16); sk += __shfl_down(sk, 4, 16);
                se += __shfl_down(se, 2, 16); sa += __shfl_down(sa, 2, 16); sk += __shfl_down(sk, 2, 16);
                se += __shfl_down(se, 1, 16); sa += __shfl_down(sa, 1, 16); sk += __shfl_down(sk, 1, 16);
                if (jg == 0) {
                    float e = 1.f/(1.f + expf(-se));
                    float a = tanhf(sa);
                    sE[mg] = e; sA[mg] = a;
                    sK[mg] = tanhf(sk + sBk[mg]);
                    eag[(size_t)(b*16 + t)*80 + mg]      = e;
                    eag[(size_t)(b*16 + t)*80 + 32 + mg] = a;
                }
                float4 h4 = *(const float4*)&sHbuf[nxt][lane*4];
                float pg = wg4.x*h4.x + wg4.y*h4.y + wg4.z*h4.z + wg4.w*h4.w;
                float pb = wbeta4.x*h4.x + wbeta4.y*h4.y + wbeta4.z*h4.z + wbeta4.w*h4.w;
                #pragma unroll
                for (int d = 32; d > 0; d >>= 1) {
                    pg += __shfl_xor(pg, d, 64);
                    pb += __shfl_xor(pb, d, 64);
                }
                gg = 1.f/(1.f + expf(-pg));
                float xbeta = pb + bb;
                betav = (xbeta > 20.f) ? xbeta : log1pf(expf(xbeta));
                if (tid == 0) eag[(size_t)(b*16 + t)*80 + 64] = gg;
            }
            __syncthreads();

            // PH_D
            {
                float omg = 1.f - gg;
                const __half* xp = (const __half*)xb;
                #pragma unroll
                for (int q = 0; q < 8; ++q) {
                    float4 e4 = *(const float4*)&sE[4*q];
                    float4 a4 = *(const float4*)&sA[4*q];
                    #pragma unroll
                    for (int r = 0; r < 4; ++r) {
                        int m = 4*q + r;
                        float e = (r==0)?e4.x:(r==1)?e4.y:(r==2)?e4.z:e4.w;
                        float a = (r==0)?a4.x:(r==1)?a4.y:(r==2)?a4.z:a4.w;
                        float x0v = __half2float(xp[m]);
                        float x1v = __half2float(xp[32 + m]);
                        c0[m] = omg*(c0[m]*(1.f - w0*e) + w0*a) + gg*x0v;
                        c1[m] = omg*(c1[m]*(1.f - w1*e) + w1*a) + gg*x1v;
                    }
                }
                if (t < 15) {
                    const uint4* xrow = (const uint4*)(xh + (size_t)(b*16 + t + 1)*32768) + 8*tid;
                    #pragma unroll
                    for (int i = 0; i < 8; ++i) xb[i] = xrow[i];
                }
            }
        }
    } else {
        // ======== fused conv1+conv2 (z): 2 tiles/block; weights packed into LDS from raw ========
        const int team = threadIdx.x >> 8;
        const int t256 = threadIdx.x & 255;
        const int tile = (blockIdx.x - 8)*2 + team;   // 0..1023
        const int img  = tile >> 3;
        const int strip = tile & 7;
        unsigned int* sZ  = (unsigned int*)(smem + team*53072);           // [3][19][66]
        unsigned int* sC1 = (unsigned int*)(smem + team*53072 + 15048);   // [16][9][66]
        unsigned int* sW   = (unsigned int*)(smem + 106144);              // 6144 u32
        unsigned int* sw01 = (unsigned int*)(smem + 130720);              // 288
        float*        sw2  = (float*)(smem + 131872);                     // 288
        float*        sb2  = (float*)(smem + 133024);                     // 32
        float*        sb1  = (float*)(smem + 133152);                     // 32

        pack_conv_lds(c1w, c1b, c2w, c2b, sW, sw01, sw2, sb1, sb2, 512);

        const int zrow0 = strip*16;
        for (int idx = t256; idx < 3762; idx += 256) {
            int ic = idx / (19*66);
            int rem = idx - ic*(19*66);
            int li = rem / 66;
            int x2 = rem - li*66;
            int iy = zrow0 + li;
            unsigned int v = 0;
            if (iy < 128 && x2 < 64) {
                float2 p = *(const float2*)&z_i[(((size_t)img*3 + ic)*128 + iy)*128 + 2*x2];
                v = packh2(p.x, p.y);
            }
            sZ[idx] = v;
        }
        for (int idx = t256; idx < 16*9*2; idx += 256) {
            int oc2 = idx / 18; int rem = idx - oc2*18; int li = rem >> 1; int c = 64 + (rem & 1);
            sC1[oc2*(9*66) + li*66 + c] = 0;
        }
        __syncthreads();
        for (int pos = t256; pos < 576; pos += 256) {
            int li = pos >> 6;
            int ox = pos & 63;
            unsigned int pa[9]; float px[9];
            #pragma unroll
            for (int ic = 0; ic < 3; ++ic)
                #pragma unroll
                for (int dy = 0; dy < 3; ++dy) {
                    int r = ic*3 + dy;
                    int rowb = ic*(19*66) + (2*li + dy)*66;
                    pa[r] = sZ[rowb + ox];
                    unsigned int u = sZ[rowb + ox + 1];
                    px[r] = __half2float(((const __half2*)&u)->x);
                }
            const bool phantom = (strip == 7) && (li == 8);
            #pragma unroll 4
            for (int oc2 = 0; oc2 < 16; ++oc2) {
                const int oca = 2*oc2, ocb = oca + 1;
                float acca = sb1[oca], accb = sb1[ocb];
                #pragma unroll
                for (int r = 0; r < 9; ++r) {
                    acca = fdot2(sw01[oca*9 + r], pa[r], acca);
                    acca += sw2[oca*9 + r] * px[r];
                    accb = fdot2(sw01[ocb*9 + r], pa[r], accb);
                    accb += sw2[ocb*9 + r] * px[r];
                }
                sC1[oc2*(9*66) + li*66 + ox] =
                    phantom ? 0u : packh2(fmaxf(acca, 0.f), fmaxf(accb, 0.f));
            }
        }
        __syncthreads();
        const int posl = t256 & 127;
        const int half = t256 >> 7;
        const int ly = posl >> 5;
        const int ox = posl & 31;
        float acc[16];
        #pragma unroll
        for (int j = 0; j < 16; ++j) acc[j] = 0.f;
        for (int ic2 = 0; ic2 < 16; ++ic2) {
            unsigned int patch[9];
            #pragma unroll
            for (int dy = 0; dy < 3; ++dy)
                #pragma unroll
                for (int dx = 0; dx < 3; ++dx)
                    patch[dy*3+dx] = sC1[ic2*(9*66) + (2*ly+dy)*66 + 2*ox + dx];
            const unsigned int* wbase = sW + (half*16 + ic2)*192;
            #pragma unroll
            for (int j = 0; j < 16; ++j) {
                const unsigned int* wr = wbase + j*12;
                uint4 wa = *(const uint4*)wr;
                uint4 wb = *(const uint4*)(wr + 4);
                unsigned int w8 = wr[8];
                float a = acc[j];
                a = fdot2(wa.x, patch[0], a); a = fdot2(wa.y, patch[1], a);
                a = fdot2(wa.z, patch[2], a); a = fdot2(wa.w, patch[3], a);
                a = fdot2(wb.x, patch[4], a); a = fdot2(wb.y, patch[5], a);
                a = fdot2(wb.z, patch[6], a); a = fdot2(wb.w, patch[7], a);
                a = fdot2(w8,  patch[8], a);
                acc[j] = a;
            }
        }
        const int oy = strip*4 + ly;
        #pragma unroll
        for (int j = 0; j < 16; ++j) {
            int oc = half*16 + j;
            zfeat[(((size_t)img*32 + oc)*32 + oy)*32 + ox] = fmaxf(acc[j] + sb2[oc], 0.f);
        }
    }
}

// ---------------- replay + forward FFT fused: block per (b,m) = 256 blocks, 256 thr
__global__ __launch_bounds__(256) void replay_fft_kernel(
    const float* __restrict__ xfeat, const float* __restrict__ wbuf,
    const float* __restrict__ eag, const float* __restrict__ lnst,
    const float* __restrict__ cosw, const float* __restrict__ twg,
    float* __restrict__ cfft)
{
    const int m = blockIdx.x & 31;
    const int b = blockIdx.x >> 5;
    const int tid = threadIdx.x;
    __shared__ __align__(16) float sY[32*36];
    __shared__ __align__(16) float sT[2048];
    __shared__ __align__(16) float sR[2048];
    {
        const float4* s4 = (const float4*)twg;
        float4* d4 = (float4*)sT;
        d4[tid]       = s4[tid];
        d4[256 + tid] = s4[256 + tid];
    }
    const int n0 = tid*4;
    float4 cw = *(const float4*)&cosw[n0];
    const float mu = lnst[b*2], rs = lnst[b*2+1];
    float c0v, c1v, c2v, c3v;
    {
        float4 x = *(const float4*)&xfeat[(size_t)(b*16)*32768 + (size_t)m*1024 + n0];
        c0v=(x.x-mu)*rs; c1v=(x.y-mu)*rs; c2v=(x.z-mu)*rs; c3v=(x.w-mu)*rs;
    }
    const int hj = tid >> 3;
    const int k0 = (tid & 7)*4;
    const int syoff = (tid>>3)*36 + (tid&7)*4;

    for (int t = 0; t < 16; ++t) {
        const size_t bt = (size_t)(b*16 + t);
        float4 w = *(const float4*)&wbuf[bt*1024 + n0];
        float e = eag[bt*80 + m];
        float a = eag[bt*80 + 32 + m];
        float g = eag[bt*80 + 64];
        float omg = 1.f - g;
        float4 xv = *(const float4*)&xfeat[bt*32768 + (size_t)m*1024 + n0];
        c0v = omg*(c0v*(1.f - w.x*e) + w.x*a) + g*xv.x;
        c1v = omg*(c1v*(1.f - w.y*e) + w.y*a) + g*xv.y;
        c2v = omg*(c2v*(1.f - w.z*e) + w.z*a) + g*xv.z;
        c3v = omg*(c3v*(1.f - w.w*e) + w.w*a) + g*xv.w;
        *(float4*)&sY[syoff] = make_float4(c0v*cw.x, c1v*cw.y, c2v*cw.z, c3v*cw.w);
        __syncthreads();
        float r0=0.f,i0=0.f,r1=0.f,i1=0.f,r2=0.f,i2=0.f,r3=0.f,i3=0.f;
        #pragma unroll
        for (int ww = 0; ww < 32; ++ww) {
            float y = sY[hj*36 + ww];
            float4 ta = *(const float4*)&sT[(ww*32 + k0)*2];
            float4 tb = *(const float4*)&sT[(ww*32 + k0)*2 + 4];
            r0 += y*ta.x; i0 += y*ta.y;
            r1 += y*ta.z; i1 += y*ta.w;
            r2 += y*tb.x; i2 += y*tb.y;
            r3 += y*tb.z; i3 += y*tb.w;
        }
        *(float4*)&sR[(hj*32 + k0)*2]     = make_float4(r0,i0,r1,i1);
        *(float4*)&sR[(hj*32 + k0)*2 + 4] = make_float4(r2,i2,r3,i3);
        __syncthreads();
        float fr0=0.f,fi0=0.f,fr1=0.f,fi1=0.f,fr2=0.f,fi2=0.f,fr3=0.f,fi3=0.f;
        #pragma unroll
        for (int h = 0; h < 32; ++h) {
            float2 wj = *(const float2*)&sT[(h*32 + hj)*2];
            float4 Ra = *(const float4*)&sR[(h*32 + k0)*2];
            float4 Rb = *(const float4*)&sR[(h*32 + k0)*2 + 4];
            fr0 += Ra.x*wj.x - Ra.y*wj.y;  fi0 += Ra.x*wj.y + Ra.y*wj.x;
            fr1 += Ra.z*wj.x - Ra.w*wj.y;  fi1 += Ra.z*wj.y + Ra.w*wj.x;
            fr2 += Rb.x*wj.x - Rb.y*wj.y;  fi2 += Rb.x*wj.y + Rb.y*wj.x;
            fr3 += Rb.z*wj.x - Rb.w*wj.y;  fi3 += Rb.z*wj.y + Rb.w*wj.x;
        }
        float* dp = cfft + (size_t)(bt*32 + m)*1088 + (size_t)(hj*17 + k0)*2;
        if (k0 < 16) {
            *(float2*)&dp[0] = make_float2(fr0, fi0);
            *(float2*)&dp[2] = make_float2(fr1, fi1);
            *(float2*)&dp[4] = make_float2(fr2, fi2);
            *(float2*)&dp[6] = make_float2(fr3, fi3);
        } else if (k0 == 16) {
            *(float2*)&dp[0] = make_float2(fr0, fi0);
        }
    }
}

// ---------------- rfft2 (z only): table-driven DFT, 4096 blocks
__global__ __launch_bounds__(256) void fft_fwd_kernel(const float* __restrict__ src0,
                                                      const float* __restrict__ cosw,
                                                      const float* __restrict__ twg,
                                                      float* __restrict__ dst0)
{
    const int img = blockIdx.x;
    const int tid = threadIdx.x;
    const float* src = src0 + (size_t)img*1024;
    float* dst = dst0 + (size_t)img*1088;

    __shared__ __align__(16) float sY[32*36];
    __shared__ __align__(16) float sT[2048];
    __shared__ __align__(16) float sR[2048];

    {
        const float4* s4 = (const float4*)twg;
        float4* d4 = (float4*)sT;
        d4[tid]       = s4[tid];
        d4[256 + tid] = s4[256 + tid];
    }
    {
        float4 v = *(const float4*)&src[tid*4];
        float4 c = *(const float4*)&cosw[tid*4];
        *(float4*)&sY[(tid>>3)*36 + (tid&7)*4] = make_float4(v.x*c.x, v.y*c.y, v.z*c.z, v.w*c.w);
    }
    __syncthreads();

    const int hj = tid >> 3;
    const int k0 = (tid & 7) * 4;

    float r0=0.f,i0=0.f,r1=0.f,i1=0.f,r2=0.f,i2=0.f,r3=0.f,i3=0.f;
    #pragma unroll
    for (int w = 0; w < 32; ++w) {
        float y = sY[hj*36 + w];
        float4 ta = *(const float4*)&sT[(w*32 + k0)*2];
        float4 tb = *(const float4*)&sT[(w*32 + k0)*2 + 4];
        r0 += y*ta.x; i0 += y*ta.y;
        r1 += y*ta.z; i1 += y*ta.w;
        r2 += y*tb.x; i2 += y*tb.y;
        r3 += y*tb.z; i3 += y*tb.w;
    }
    *(float4*)&sR[(hj*32 + k0)*2]     = make_float4(r0,i0,r1,i1);
    *(float4*)&sR[(hj*32 + k0)*2 + 4] = make_float4(r2,i2,r3,i3);
    __syncthreads();

    float fr0=0.f,fi0=0.f,fr1=0.f,fi1=0.f,fr2=0.f,fi2=0.f,fr3=0.f,fi3=0.f;
    #pragma unroll
    for (int h = 0; h < 32; ++h) {
        float2 wj = *(const float2*)&sT[(h*32 + hj)*2];
        float4 Ra = *(const float4*)&sR[(h*32 + k0)*2];
        float4 Rb = *(const float4*)&sR[(h*32 + k0)*2 + 4];
        fr0 += Ra.x*wj.x - Ra.y*wj.y;  fi0 += Ra.x*wj.y + Ra.y*wj.x;
        fr1 += Ra.z*wj.x - Ra.w*wj.y;  fi1 += Ra.z*wj.y + Ra.w*wj.x;
        fr2 += Rb.x*wj.x - Rb.y*wj.y;  fi2 += Rb.x*wj.y + Rb.y*wj.x;
        fr3 += Rb.z*wj.x - Rb.w*wj.y;  fi3 += Rb.z*wj.y + Rb.w*wj.x;
    }
    float* dp = dst + (size_t)(hj*17 + k0)*2;
    if (k0 < 16) {
        *(float2*)&dp[0] = make_float2(fr0, fi0);
        *(float2*)&dp[2] = make_float2(fr1, fi1);
        *(float2*)&dp[4] = make_float2(fr2, fi2);
        *(float2*)&dp[6] = make_float2(fr3, fi3);
    } else if (k0 == 16) {
        *(float2*)&dp[0] = make_float2(fr0, fi0);
    }
}

// ---------------- fused combine + irfft2; one block per bt, 512 threads
__global__ __launch_bounds__(512) void comb_ifft_kernel(const float* __restrict__ cfft,
                                                        const float* __restrict__ zfft,
                                                        const float* __restrict__ yf,
                                                        float* __restrict__ out)
{
    const int bt  = blockIdx.x;
    const int tid = threadIdx.x;
    __shared__ float sG[544*2];
    __shared__ float sS[544*2];
    __shared__ float ct[32], st[32];
    if (tid < 32) {
        float sv, cv;
        sincosf(TWOPI_32 * (float)tid, &sv, &cv);
        ct[tid] = cv; st[tid] = sv;
    }
    for (int idx = tid; idx < 544; idx += 512) {
        float kzz = 0.f, kxr = 0.f, kxi = 0.f;
        #pragma unroll 4
        for (int m = 0; m < 32; ++m) {
            size_t base = ((size_t)(bt*32 + m)*1088) + idx*2;
            float2 c = *(const float2*)&cfft[base];
            float2 z = *(const float2*)&zfft[base];
            kzz += c.x*c.x + c.y*c.y;
            kxr += z.x*c.x + z.y*c.y;
            kxi += z.y*c.x - z.x*c.y;
        }
        float den = 1.f / (kzz + 1e-4f);
        float2 y = *(const float2*)&yf[idx*2];
        float ar = y.x*den, ai = y.y*den;
        sG[idx*2]     = kxr*ar - kxi*ai;
        sG[idx*2 + 1] = kxr*ai + kxi*ar;
    }
    __syncthreads();
    for (int idx = tid; idx < 544; idx += 512) {
        int h = idx / 17;
        int k = idx - h*17;
        float re = 0.f, im = 0.f;
        #pragma unroll
        for (int j = 0; j < 32; ++j) {
            float gr = sG[(j*17+k)*2], gi = sG[(j*17+k)*2+1];
            int a = (h*j) & 31;
            float c = ct[a], s = st[a];
            re += gr*c - gi*s;
            im += gr*s + gi*c;
        }
        sS[(h*17+k)*2] = re; sS[(h*17+k)*2+1] = im;
    }
    __syncthreads();
    #pragma unroll
    for (int p = 0; p < 2; ++p) {
        int pos = p*512 + tid;
        int h = pos >> 5, wq = pos & 31;
        float acc = sS[(h*17)*2];
        #pragma unroll
        for (int k = 1; k < 16; ++k) {
            int a = (wq*k) & 31;
            acc += 2.f*(sS[(h*17+k)*2]*ct[a] - sS[(h*17+k)*2+1]*st[a]);
        }
        acc += sS[(h*17+16)*2] * ((wq & 1) ? -1.f : 1.f);
        out[(size_t)bt*1024 + pos] = acc * (1.f/1024.f);
    }
}

extern "C" void kernel_launch(void* const* d_in, const int* in_sizes, int n_in,
                              void* d_out, int out_size, void* d_ws, size_t ws_size,
                              hipStream_t stream)
{
    const float* x_i   = (const float*)d_in[0];
    const float* z_i   = (const float*)d_in[1];
    const float* c1w   = (const float*)d_in[2];
    const float* c1b   = (const float*)d_in[3];
    const float* c2w   = (const float*)d_in[4];
    const float* c2b   = (const float*)d_in[5];
    const float* Wk    = (const float*)d_in[6];
    const float* bk    = (const float*)d_in[7];
    const float* Wbeta = (const float*)d_in[8];
    const float* bbeta = (const float*)d_in[9];
    const float* Wh    = (const float*)d_in[10];
    const float* bh    = (const float*)d_in[11];
    const float* We    = (const float*)d_in[12];
    const float* Wa    = (const float*)d_in[13];
    const float* Wg    = (const float*)d_in[14];
    const float* cosw  = (const float*)d_in[15];
    const float* yf    = (const float*)d_in[16];
    float* out = (float*)d_out;
    float* ws  = (float*)d_ws;

    // workspace layout (floats)
    float*  xfeat = ws + 16777216;      // 4,194,304
    float*  zfeat = ws + 20971520;      // 4,194,304
    float*  cfft  = ws;                 // 4,456,448 f
    float*  zfft  = ws + 4456448;       // 4,456,448 f (ends 8,912,896)
    __half* xhb   = (__half*)(ws + 9000000);    // 4,194,304 halfs
    float*  wbuf  = ws + 11100000;      // 131,072 f
    float*  eag   = ws + 11240000;      // 10,240 f
    float*  lnstp = ws + 11251000;      // 16 f
    // pack outputs + xmp in the dead gap [29,360,128 .. 29,499,392)
    __half* whhP  = (__half*)(ws + 29360128);
    __half* whrxP = (__half*)(ws + 29392896);
    __half* wkP   = (__half*)(ws + 29401088);
    __half* weP   = (__half*)(ws + 29405184);
    __half* waP   = (__half*)(ws + 29409280);
    float*  twg   = ws + 29413376;      // 2,048 f -> ends 29,415,424
    float*  xmp   = ws + 29422144;      // 65,536 f -> ends 29,487,680 (< 29,499,392 OK)

    dim3 b256(256);
    convx_kernel<<<529, 512, 0, stream>>>(x_i, c1w, c1b, c2w, c2b, Wh, Wk, We, Wa,
                                          xfeat, xhb, xmp,
                                          whhP, whrxP, wkP, weP, waP, twg);
    fat_kernel<<<520, 512, 0, stream>>>(xfeat, xhb, xmp, whhP, whrxP, wkP, weP, waP,
                                        bk, Wbeta, bbeta, bh, Wg, wbuf, eag, lnstp,
                                        z_i, c1w, c1b, c2w, c2b, zfeat);
    replay_fft_kernel<<<256, b256, 0, stream>>>(xfeat, wbuf, eag, lnstp, cosw, twg, cfft);
    fft_fwd_kernel<<<4096, b256, 0, stream>>>(zfeat, cosw, twg, zfft);
    comb_ifft_kernel<<<128, 512, 0, stream>>>(cfft, zfft, yf, out);
}

// Round 16
// 404.012 us; speedup vs baseline: 2.2262x; 1.0089x over previous
//
#include <hip/hip_runtime.h>
#include <hip/hip_fp16.h>
#include <math.h>

// B=8, T=16, IMG=128, CF=32, WO=HO=32, N=1024, M=32, DH=256
// conv SAME stride2: pad_lo=0, pad_hi=1 -> in_idx = 2*out + k

#define TWOPI_32 0.19634954084936207f  // 2*pi/32

typedef _Float16 __h2 __attribute__((ext_vector_type(2)));
__device__ __forceinline__ float fdot2(unsigned int w, unsigned int h, float acc) {
    union { unsigned int u; __h2 v; } a, b;
    a.u = w; b.u = h;
    return __builtin_amdgcn_fdot2(a.v, b.v, acc, false);
}
__device__ __forceinline__ unsigned int packh2(float a, float b) {
    __half2 h2 = __floats2half2_rn(a, b);
    return *(unsigned int*)&h2;
}

// helper: pack conv weights into block LDS from raw inputs
__device__ __forceinline__ void pack_conv_lds(
    const float* __restrict__ c1w, const float* __restrict__ c1b,
    const float* __restrict__ c2w, const float* __restrict__ c2b,
    unsigned int* sW, unsigned int* sw01, float* sw2, float* sb1, float* sb2, int NT)
{
    for (int i = threadIdx.x; i < 4608; i += NT) {
        int half = i / 2304;
        int rem  = i - half*2304;
        int ic2  = rem / 144;
        int r2   = rem - ic2*144;
        int j    = r2 / 9, q = r2 - j*9;
        int oc   = half*16 + j;
        sW[(half*16 + ic2)*192 + j*12 + q] =
            packh2(c2w[oc*288 + (2*ic2)*9 + q], c2w[oc*288 + (2*ic2+1)*9 + q]);
    }
    for (int i = threadIdx.x; i < 288; i += NT) {
        int oc = i / 9, r = i - oc*9;
        sw01[i] = packh2(c1w[oc*27 + r*3 + 0], c1w[oc*27 + r*3 + 1]);
        sw2[i]  = c1w[oc*27 + r*3 + 2];
    }
    if (threadIdx.x < 32) { sb1[threadIdx.x] = c1b[threadIdx.x]; sb2[threadIdx.x] = c2b[threadIdx.x]; }
}

// ---------------- convx: fused conv1+conv2 (x path) + (blocks 512+) NTM weight packs & twiddle
__global__ __launch_bounds__(512, 1) void convx_kernel(
    const float* __restrict__ x_i, const float* __restrict__ c1w,
    const float* __restrict__ c1b, const float* __restrict__ c2w,
    const float* __restrict__ c2b,
    const float* __restrict__ Wh, const float* __restrict__ Wk,
    const float* __restrict__ We, const float* __restrict__ Wa,
    float* __restrict__ xfeat, __half* __restrict__ xh, float* __restrict__ xmp,
    __half* __restrict__ whhP, __half* __restrict__ whrxP,
    __half* __restrict__ wkP, __half* __restrict__ weP, __half* __restrict__ waP,
    float* __restrict__ twg)
{
    __shared__ __align__(16) char smem[139264];
    if (blockIdx.x >= 512) {
        if (blockIdx.x < 528) {
            const int base = (blockIdx.x - 512)*512 + threadIdx.x;   // 0..8191
            #pragma unroll
            for (int r = 0; r < 8; ++r) {
                int idx = base*8 + r;
                int e = idx & 7, i = (idx >> 3) & 255, c = idx >> 11;
                int q = c >> 4, k = c & 15;
                whhP[idx] = __float2half(Wh[i*320 + q*128 + k*8 + e]);
            }
            #pragma unroll
            for (int r = 0; r < 2; ++r) {
                int idx = base*2 + r;
                int i = idx >> 6, s2 = idx & 63;
                whrxP[idx] = __float2half(Wh[i*320 + 256 + s2]);
            }
            {
                int idx = base;
                int m = idx >> 8, j = (idx >> 4) & 15, e = idx & 15;
                int col = (e < 8) ? (8*j + e) : (128 + 8*j + (e - 8));
                wkP[idx] = __float2half(Wk[m*256 + col]);
                weP[idx] = __float2half(We[m*256 + col]);
                waP[idx] = __float2half(Wa[m*256 + col]);
            }
        } else {
            for (int idx = threadIdx.x; idx < 1024; idx += 512) {
                int w = idx >> 5, k = idx & 31;
                float sv, cv;
                sincosf(TWOPI_32 * (float)((w*k) & 31), &sv, &cv);
                twg[idx*2]     = cv;
                twg[idx*2 + 1] = -sv;
            }
        }
        return;
    }
    const int team = threadIdx.x >> 8;
    const int t256 = threadIdx.x & 255;
    const int tile = blockIdx.x*2 + team;   // 0..1023
    const int img  = tile >> 3;
    const int strip = tile & 7;
    unsigned int* sZ  = (unsigned int*)(smem + team*53072);           // [3][19][66]
    unsigned int* sC1 = (unsigned int*)(smem + team*53072 + 15048);   // [16][9][66]
    unsigned int* sW   = (unsigned int*)(smem + 106144);              // 6144 u32
    unsigned int* sw01 = (unsigned int*)(smem + 130720);              // 288
    float*        sw2  = (float*)(smem + 131872);                     // 288
    float*        sb2  = (float*)(smem + 133024);                     // 32
    float*        sb1  = (float*)(smem + 133152);                     // 32

    pack_conv_lds(c1w, c1b, c2w, c2b, sW, sw01, sw2, sb1, sb2, 512);

    const int zrow0 = strip*16;
    for (int idx = t256; idx < 3762; idx += 256) {
        int ic = idx / (19*66);
        int rem = idx - ic*(19*66);
        int li = rem / 66;
        int x2 = rem - li*66;
        int iy = zrow0 + li;
        unsigned int v = 0;
        if (iy < 128 && x2 < 64) {
            float2 p = *(const float2*)&x_i[(((size_t)img*3 + ic)*128 + iy)*128 + 2*x2];
            v = packh2(p.x, p.y);
        }
        sZ[idx] = v;
    }
    for (int idx = t256; idx < 16*9*2; idx += 256) {
        int oc2 = idx / 18; int rem = idx - oc2*18; int li = rem >> 1; int c = 64 + (rem & 1);
        sC1[oc2*(9*66) + li*66 + c] = 0;
    }
    __syncthreads();
    // conv1: 9 rows x 64 cols (phantom row 64 at strip 7 -> 0)
    for (int pos = t256; pos < 576; pos += 256) {
        int li = pos >> 6;
        int ox = pos & 63;
        unsigned int pa[9]; float px[9];
        #pragma unroll
        for (int ic = 0; ic < 3; ++ic)
            #pragma unroll
            for (int dy = 0; dy < 3; ++dy) {
                int r = ic*3 + dy;
                int rowb = ic*(19*66) + (2*li + dy)*66;
                pa[r] = sZ[rowb + ox];
                unsigned int u = sZ[rowb + ox + 1];
                px[r] = __half2float(((const __half2*)&u)->x);
            }
        const bool phantom = (strip == 7) && (li == 8);
        #pragma unroll 4
        for (int oc2 = 0; oc2 < 16; ++oc2) {
            const int oca = 2*oc2, ocb = oca + 1;
            float acca = sb1[oca], accb = sb1[ocb];
            #pragma unroll
            for (int r = 0; r < 9; ++r) {
                acca = fdot2(sw01[oca*9 + r], pa[r], acca);
                acca += sw2[oca*9 + r] * px[r];
                accb = fdot2(sw01[ocb*9 + r], pa[r], accb);
                accb += sw2[ocb*9 + r] * px[r];
            }
            sC1[oc2*(9*66) + li*66 + ox] =
                phantom ? 0u : packh2(fmaxf(acca, 0.f), fmaxf(accb, 0.f));
        }
    }
    __syncthreads();
    // conv2: 4 rows x 32 cols x 32 oc; then emit xfeat/xh/xmp
    const int posl = t256 & 127;
    const int half = t256 >> 7;
    const int ly = posl >> 5;
    const int ox = posl & 31;
    float acc[16];
    #pragma unroll
    for (int j = 0; j < 16; ++j) acc[j] = 0.f;
    for (int ic2 = 0; ic2 < 16; ++ic2) {
        unsigned int patch[9];
        #pragma unroll
        for (int dy = 0; dy < 3; ++dy)
            #pragma unroll
            for (int dx = 0; dx < 3; ++dx)
                patch[dy*3+dx] = sC1[ic2*(9*66) + (2*ly+dy)*66 + 2*ox + dx];
        const unsigned int* wbase = sW + (half*16 + ic2)*192;
        #pragma unroll
        for (int j = 0; j < 16; ++j) {
            const unsigned int* wr = wbase + j*12;
            uint4 wa = *(const uint4*)wr;
            uint4 wb = *(const uint4*)(wr + 4);
            unsigned int w8 = wr[8];
            float a = acc[j];
            a = fdot2(wa.x, patch[0], a); a = fdot2(wa.y, patch[1], a);
            a = fdot2(wa.z, patch[2], a); a = fdot2(wa.w, patch[3], a);
            a = fdot2(wb.x, patch[4], a); a = fdot2(wb.y, patch[5], a);
            a = fdot2(wb.z, patch[6], a); a = fdot2(wb.w, patch[7], a);
            a = fdot2(w8,  patch[8], a);
            acc[j] = a;
        }
    }
    const int oy = strip*4 + ly;
    const int n  = oy*32 + ox;
    float vals[16];
    #pragma unroll
    for (int j = 0; j < 16; ++j) {
        int oc = half*16 + j;
        float v = fmaxf(acc[j] + sb2[oc], 0.f);
        vals[j] = v;
        xfeat[(((size_t)img*32 + oc)*32 + oy)*32 + ox] = v;
    }
    {
        unsigned int hp[8];
        #pragma unroll
        for (int k = 0; k < 8; ++k) hp[k] = packh2(vals[2*k], vals[2*k+1]);
        uint4* dp = (uint4*)(xh + (size_t)img*32768 + (size_t)n*32 + half*16);
        dp[0] = *(uint4*)&hp[0];
        dp[1] = *(uint4*)&hp[4];
    }
    {
        const int lane = threadIdx.x & 63;
        const int wsub = (t256 >> 6) & 1;
        #pragma unroll
        for (int j = 0; j < 16; ++j) {
            float v = vals[j];
            #pragma unroll
            for (int d = 32; d > 0; d >>= 1) v += __shfl_xor(v, d, 64);
            if (lane == 0)
                xmp[(((size_t)img*8 + strip)*2 + wsub)*32 + half*16 + j] = v * (1.f/1024.f);
        }
    }
}

// ---------------- FAT: blocks 0..7 = NTM recurrence; blocks 8.. = fused conv1+conv2 (z)
__global__ __launch_bounds__(512, 1) void fat_kernel(
    const float* __restrict__ xfeat, const __half* __restrict__ xh,
    const float* __restrict__ xmp,
    const __half* __restrict__ whhP, const __half* __restrict__ whrxP,
    const __half* __restrict__ wkP, const __half* __restrict__ weP,
    const __half* __restrict__ waP,
    const float* __restrict__ bk, const float* __restrict__ Wbeta,
    const float* __restrict__ bbeta, const float* __restrict__ bh,
    const float* __restrict__ Wg,
    float* __restrict__ wbuf, float* __restrict__ eag, float* __restrict__ lnst,
    const float* __restrict__ z_i, const float* __restrict__ c1w,
    const float* __restrict__ c1b, const float* __restrict__ c2w,
    const float* __restrict__ c2b,
    float* __restrict__ zfeat)
{
    __shared__ __align__(16) char smem[139264];

    if (blockIdx.x < 8) {
        // ======== NTM branch ========
        __builtin_amdgcn_s_setprio(1);
        __half* sWhh = (__half*)(smem);                    // 131072 B
        float (*sHbuf)[256] = (float(*)[256])(smem + 131072);
        __half (*sHh)[256] = (__half(*)[256])(smem + 133120);
        float* sK    = (float*)(smem + 134144);
        float* sXm   = (float*)(smem + 134272);
        float* sRedC = (float*)(smem + 136320);
        float* sR32  = (float*)(smem + 137344);
        float* sE    = (float*)(smem + 137472);
        float* sA    = (float*)(smem + 137600);
        float* sBk   = (float*)(smem + 137728);
        float* sBh   = (float*)(smem + 137856);
        float* sRedD = (float*)(smem + 138880);
        float* sRedL = (float*)(smem + 138912);

        const int b    = blockIdx.x;
        const int tid  = threadIdx.x;
        const int lane = tid & 63;
        const int wid  = tid >> 6;

        {
            const uint4* src = (const uint4*)whhP;
            uint4* dst = (uint4*)sWhh;
            for (int i2 = tid; i2 < 8192; i2 += 512) dst[i2] = src[i2];
        }
        if (tid < 256) { sBh[tid] = bh[tid]; sHbuf[0][tid] = 0.f; sHh[0][tid] = __float2half(0.f); }
        if (tid < 32)  { sBk[tid] = bk[tid]; sK[tid] = tanhf(bk[tid]); }
        if (tid < 512) {
            const int tt = tid >> 5, m = tid & 31;
            const float* pp = xmp + ((size_t)(b*16 + tt)*16)*32 + m;
            float s = 0.f;
            #pragma unroll
            for (int q = 0; q < 16; ++q) s += pp[q*32];
            sXm[tid] = s;
        }
        float4 wbeta4 = *(const float4*)&Wbeta[(size_t)lane*4];
        float4 wg4    = *(const float4*)&Wg[(size_t)lane*4];
        float bb = bbeta[0];

        const int mg = tid >> 4, jg = tid & 15;
        uint4 wk0, wk1, we0, we1, wa0, wa1;
        {
            const uint4* p;
            p = (const uint4*)(wkP + (size_t)(mg*16 + jg)*16); wk0 = p[0]; wk1 = p[1];
            p = (const uint4*)(weP + (size_t)(mg*16 + jg)*16); we0 = p[0]; we1 = p[1];
            p = (const uint4*)(waP + (size_t)(mg*16 + jg)*16); wa0 = p[0]; wa1 = p[1];
        }
        const int iD = tid >> 1, qD = tid & 1;
        uint4 wrx0, wrx1, wrx2, wrx3;
        {
            const uint4* p = (const uint4*)(whrxP + (size_t)iD*64 + qD*32);
            wrx0 = p[0]; wrx1 = p[1]; wrx2 = p[2]; wrx3 = p[3];
        }

        const int n0 = 2*tid;
        float c0[32], c1[32];

        {
            const float* x0 = xfeat + (size_t)(b*16)*32768;
            float sum = 0.f, ss = 0.f;
            #pragma unroll
            for (int m = 0; m < 32; ++m) {
                float2 v = *(const float2*)&x0[m*1024 + n0];
                c0[m] = v.x; c1[m] = v.y;
                sum += v.x + v.y; ss += v.x*v.x + v.y*v.y;
            }
            #pragma unroll
            for (int d = 32; d > 0; d >>= 1) { sum += __shfl_xor(sum, d, 64); ss += __shfl_xor(ss, d, 64); }
            if (lane == 0) { sRedL[wid] = sum; sRedL[8+wid] = ss; }
            __syncthreads();
            float S = 0.f, SS = 0.f;
            #pragma unroll
            for (int i = 0; i < 8; ++i) { S += sRedL[i]; SS += sRedL[8+i]; }
            float mu = S * (1.f/32768.f);
            float var = SS * (1.f/32768.f) - mu*mu;
            float rs = rsqrtf(var + 1e-5f);
            if (tid == 0) { lnst[b*2] = mu; lnst[b*2+1] = rs; }
            #pragma unroll
            for (int m = 0; m < 32; ++m) { c0[m] = (c0[m]-mu)*rs; c1[m] = (c1[m]-mu)*rs; }
        }

        uint4 xb[8];
        {
            const uint4* xrow = (const uint4*)(xh + (size_t)(b*16)*32768) + 8*tid;
            #pragma unroll
            for (int i = 0; i < 8; ++i) xb[i] = xrow[i];
        }
        __syncthreads();

        float betav = (bb > 20.f) ? bb : log1pf(expf(bb));
        float ex0 = 0.f, ex1 = 0.f, w0 = 0.f, w1 = 0.f;
        const int rm = ((lane&1)<<4)|((lane&2)<<2)|(lane&4)|((lane&8)>>2)|((lane&16)>>4);

        #pragma unroll 1
        for (int t = 0; t < 16; ++t) {
            const int cur = t & 1, nxt = cur ^ 1;

            // PH_A
            {
                float beta = betav;
                float dot0 = 0.f, dot1 = 0.f, cn20 = 0.f, cn21 = 0.f, kn2 = 0.f;
                #pragma unroll
                for (int q = 0; q < 8; ++q) {
                    float4 k4 = *(const float4*)&sK[4*q];
                    dot0 += c0[4*q]*k4.x + c0[4*q+1]*k4.y + c0[4*q+2]*k4.z + c0[4*q+3]*k4.w;
                    dot1 += c1[4*q]*k4.x + c1[4*q+1]*k4.y + c1[4*q+2]*k4.z + c1[4*q+3]*k4.w;
                    cn20 += c0[4*q]*c0[4*q] + c0[4*q+1]*c0[4*q+1] + c0[4*q+2]*c0[4*q+2] + c0[4*q+3]*c0[4*q+3];
                    cn21 += c1[4*q]*c1[4*q] + c1[4*q+1]*c1[4*q+1] + c1[4*q+2]*c1[4*q+2] + c1[4*q+3]*c1[4*q+3];
                    kn2  += k4.x*k4.x + k4.y*k4.y + k4.z*k4.z + k4.w*k4.w;
                }
                float kinv = 1.f / (sqrtf(kn2) + 1e-8f);
                float s0 = dot0 * kinv / (sqrtf(cn20) + 1e-8f);
                float s1 = dot1 * kinv / (sqrtf(cn21) + 1e-8f);
                ex0 = expf(beta * s0);
                ex1 = expf(beta * s1);
                float es = ex0 + ex1;
                #pragma unroll
                for (int d = 32; d > 0; d >>= 1) es += __shfl_xor(es, d, 64);
                if (lane == 0) sRedD[wid] = es;
                float v[32];
                #pragma unroll
                for (int m = 0; m < 32; ++m) v[m] = ex0*c0[m] + ex1*c1[m];
                #pragma unroll
                for (int i = 0; i < 16; ++i) { float sd = (lane&1)? v[i] : v[i+16]; float rc = __shfl_xor(sd, 1, 64); v[i] = ((lane&1)? v[i+16] : v[i]) + rc; }
                #pragma unroll
                for (int i = 0; i < 8; ++i)  { float sd = (lane&2)? v[i] : v[i+8];  float rc = __shfl_xor(sd, 2, 64); v[i] = ((lane&2)? v[i+8]  : v[i]) + rc; }
                #pragma unroll
                for (int i = 0; i < 4; ++i)  { float sd = (lane&4)? v[i] : v[i+4];  float rc = __shfl_xor(sd, 4, 64); v[i] = ((lane&4)? v[i+4]  : v[i]) + rc; }
                #pragma unroll
                for (int i = 0; i < 2; ++i)  { float sd = (lane&8)? v[i] : v[i+2];  float rc = __shfl_xor(sd, 8, 64); v[i] = ((lane&8)? v[i+2]  : v[i]) + rc; }
                { float sd = (lane&16)? v[0] : v[1]; float rc = __shfl_xor(sd, 16, 64); v[0] = ((lane&16)? v[1] : v[0]) + rc; }
                v[0] += __shfl_xor(v[0], 32, 64);
                if (lane < 32) sRedC[wid*32 + rm] = v[0];
            }
            __syncthreads();

            // PH_B
            {
                float den = sRedD[0]+sRedD[1]+sRedD[2]+sRedD[3]+sRedD[4]+sRedD[5]+sRedD[6]+sRedD[7];
                float inv = 1.f / den;
                w0 = ex0 * inv; w1 = ex1 * inv;
                *(float2*)&wbuf[(size_t)(b*16 + t)*1024 + n0] = make_float2(w0, w1);
                if (lane < 32) {
                    float r = 0.f;
                    #pragma unroll
                    for (int w = 0; w < 8; ++w) r += sRedC[w*32 + lane];
                    sR32[lane] = r * inv;
                }
                float s0 = 0.f, s1 = 0.f, s2 = 0.f, s3 = 0.f;
                #pragma unroll
                for (int k4 = 0; k4 < 4; ++k4) {
                    const int kb = 4*k4;
                    uint4 wv0 = *(const uint4*)&sWhh[(size_t)((qD*16 + kb+0)*256 + iD)*8];
                    uint4 hv0 = *(const uint4*)&sHh[cur][qD*128 + (kb+0)*8];
                    s0 = fdot2(wv0.x, hv0.x, s0); s0 = fdot2(wv0.y, hv0.y, s0);
                    s0 = fdot2(wv0.z, hv0.z, s0); s0 = fdot2(wv0.w, hv0.w, s0);
                    uint4 wv1 = *(const uint4*)&sWhh[(size_t)((qD*16 + kb+1)*256 + iD)*8];
                    uint4 hv1 = *(const uint4*)&sHh[cur][qD*128 + (kb+1)*8];
                    s1 = fdot2(wv1.x, hv1.x, s1); s1 = fdot2(wv1.y, hv1.y, s1);
                    s1 = fdot2(wv1.z, hv1.z, s1); s1 = fdot2(wv1.w, hv1.w, s1);
                    uint4 wv2 = *(const uint4*)&sWhh[(size_t)((qD*16 + kb+2)*256 + iD)*8];
                    uint4 hv2 = *(const uint4*)&sHh[cur][qD*128 + (kb+2)*8];
                    s2 = fdot2(wv2.x, hv2.x, s2); s2 = fdot2(wv2.y, hv2.y, s2);
                    s2 = fdot2(wv2.z, hv2.z, s2); s2 = fdot2(wv2.w, hv2.w, s2);
                    uint4 wv3 = *(const uint4*)&sWhh[(size_t)((qD*16 + kb+3)*256 + iD)*8];
                    uint4 hv3 = *(const uint4*)&sHh[cur][qD*128 + (kb+3)*8];
                    s3 = fdot2(wv3.x, hv3.x, s3); s3 = fdot2(wv3.y, hv3.y, s3);
                    s3 = fdot2(wv3.z, hv3.z, s3); s3 = fdot2(wv3.w, hv3.w, s3);
                }
                const float* rxsrc = qD ? &sXm[t*32] : sR32;
                {
                    const __half2* w2;
                    float4 va, vb;
                    va = *(const float4*)&rxsrc[0];  vb = *(const float4*)&rxsrc[4];
                    w2 = (const __half2*)&wrx0;
                    { float2 p0 = __half22float2(w2[0]); s0 += p0.x*va.x + p0.y*va.y;
                      float2 p1 = __half22float2(w2[1]); s0 += p1.x*va.z + p1.y*va.w;
                      float2 p2 = __half22float2(w2[2]); s0 += p2.x*vb.x + p2.y*vb.y;
                      float2 p3 = __half22float2(w2[3]); s0 += p3.x*vb.z + p3.y*vb.w; }
                    va = *(const float4*)&rxsrc[8];  vb = *(const float4*)&rxsrc[12];
                    w2 = (const __half2*)&wrx1;
                    { float2 p0 = __half22float2(w2[0]); s1 += p0.x*va.x + p0.y*va.y;
                      float2 p1 = __half22float2(w2[1]); s1 += p1.x*va.z + p1.y*va.w;
                      float2 p2 = __half22float2(w2[2]); s1 += p2.x*vb.x + p2.y*vb.y;
                      float2 p3 = __half22float2(w2[3]); s1 += p3.x*vb.z + p3.y*vb.w; }
                    va = *(const float4*)&rxsrc[16]; vb = *(const float4*)&rxsrc[20];
                    w2 = (const __half2*)&wrx2;
                    { float2 p0 = __half22float2(w2[0]); s2 += p0.x*va.x + p0.y*va.y;
                      float2 p1 = __half22float2(w2[1]); s2 += p1.x*va.z + p1.y*va.w;
                      float2 p2 = __half22float2(w2[2]); s2 += p2.x*vb.x + p2.y*vb.y;
                      float2 p3 = __half22float2(w2[3]); s2 += p3.x*vb.z + p3.y*vb.w; }
                    va = *(const float4*)&rxsrc[24]; vb = *(const float4*)&rxsrc[28];
                    w2 = (const __half2*)&wrx3;
                    { float2 p0 = __half22float2(w2[0]); s3 += p0.x*va.x + p0.y*va.y;
                      float2 p1 = __half22float2(w2[1]); s3 += p1.x*va.z + p1.y*va.w;
                      float2 p2 = __half22float2(w2[2]); s3 += p2.x*vb.x + p2.y*vb.y;
                      float2 p3 = __half22float2(w2[3]); s3 += p3.x*vb.z + p3.y*vb.w; }
                }
                float s = (s0 + s1) + (s2 + s3);
                s += __shfl_down(s, 1, 2);
                if (qD == 0) {
                    float hn = tanhf(s + sBh[iD]);
                    sHbuf[nxt][iD] = hn;
                    sHh[nxt][iD] = __float2half(hn);
                }
            }
            __syncthreads();

            // PH_C
            float gg;
            {
                uint4 h0 = *(const uint4*)&sHh[nxt][8*jg];
                uint4 h1 = *(const uint4*)&sHh[nxt][128 + 8*jg];
                float se0=0.f, se1=0.f, sa0=0.f, sa1=0.f, sk0=0.f, sk1=0.f;
                se0 = fdot2(we0.x, h0.x, se0); se1 = fdot2(we0.y, h0.y, se1);
                se0 = fdot2(we0.z, h0.z, se0); se1 = fdot2(we0.w, h0.w, se1);
                se0 = fdot2(we1.x, h1.x, se0); se1 = fdot2(we1.y, h1.y, se1);
                se0 = fdot2(we1.z, h1.z, se0); se1 = fdot2(we1.w, h1.w, se1);
                sa0 = fdot2(wa0.x, h0.x, sa0); sa1 = fdot2(wa0.y, h0.y, sa1);
                sa0 = fdot2(wa0.z, h0.z, sa0); sa1 = fdot2(wa0.w, h0.w, sa1);
                sa0 = fdot2(wa1.x, h1.x, sa0); sa1 = fdot2(wa1.y, h1.y, sa1);
                sa0 = fdot2(wa1.z, h1.z, sa0); sa1 = fdot2(wa1.w, h1.w, sa1);
                sk0 = fdot2(wk0.x, h0.x, sk0); sk1 = fdot2(wk0.y, h0.y, sk1);
                sk0 = fdot2(wk0.z, h0.z, sk0); sk1 = fdot2(wk0.w, h0.w, sk1);
                sk0 = fdot2(wk1.x, h1.x, sk0); sk1 = fdot2(wk1.y, h1.y, sk1);
                sk0 = fdot2(wk1.z, h1.z, sk0); sk1 = fdot2(wk1.w, h1.w, sk1);
                float se = se0 + se1, sa = sa0 + sa1, sk = sk0 + sk1;
                se += __shfl_down(se, 8, 16); sa += __shfl_down(sa, 8, 16); sk += __shfl_down(sk, 8, 16);
                se += __shfl_down(se, 4, 16); sa += __shfl_down(sa, 4, 16); sk += __shfl_down(sk, 4, 16);
                se += __shfl_down(se, 2, 16); sa += __shfl_down(sa, 2, 16); sk += __shfl_down(sk, 2, 16);
                se += __shfl_down(se, 1, 16); sa += __shfl_down(sa, 1, 16); sk += __shfl_down(sk, 1, 16);
                if (jg == 0) {
                    float e = 1.f/(1.f + expf(-se));
                    float a = tanhf(sa);
                    sE[mg] = e; sA[mg] = a;
                    sK[mg] = tanhf(sk + sBk[mg]);
                    eag[(size_t)(b*16 + t)*80 + mg]      = e;
                    eag[(size_t)(b*16 + t)*80 + 32 + mg] = a;
                }
                float4 h4 = *(const float4*)&sHbuf[nxt][lane*4];
                float pg = wg4.x*h4.x + wg4.y*h4.y + wg4.z*h4.z + wg4.w*h4.w;
                float pb = wbeta4.x*h4.x + wbeta4.y*h4.y + wbeta4.z*h4.z + wbeta4.w*h4.w;
                #pragma unroll
                for (int d = 32; d > 0; d >>= 1) {
                    pg += __shfl_xor(pg, d, 64);
                    pb += __shfl_xor(pb, d, 64);
                }
                gg = 1.f/(1.f + expf(-pg));
                float xbeta = pb + bb;
                betav = (xbeta > 20.f) ? xbeta : log1pf(expf(xbeta));
                if (tid == 0) eag[(size_t)(b*16 + t)*80 + 64] = gg;
            }
            __syncthreads();

            // PH_D
            {
                float omg = 1.f - gg;
                const __half* xp = (const __half*)xb;
                #pragma unroll
                for (int q = 0; q < 8; ++q) {
                    float4 e4 = *(const float4*)&sE[4*q];
                    float4 a4 = *(const float4*)&sA[4*q];
                    #pragma unroll
                    for (int r = 0; r < 4; ++r) {
                        int m = 4*q + r;
                        float e = (r==0)?e4.x:(r==1)?e4.y:(r==2)?e4.z:e4.w;
                        float a = (r==0)?a4.x:(r==1)?a4.y:(r==2)?a4.z:a4.w;
                        float x0v = __half2float(xp[m]);
                        float x1v = __half2float(xp[32 + m]);
                        c0[m] = omg*(c0[m]*(1.f - w0*e) + w0*a) + gg*x0v;
                        c1[m] = omg*(c1[m]*(1.f - w1*e) + w1*a) + gg*x1v;
                    }
                }
                if (t < 15) {
                    const uint4* xrow = (const uint4*)(xh + (size_t)(b*16 + t + 1)*32768) + 8*tid;
                    #pragma unroll
                    for (int i = 0; i < 8; ++i) xb[i] = xrow[i];
                }
            }
        }
    } else {
        // ======== fused conv1+conv2 (z): 2 tiles/block; weights packed into LDS from raw ========
        const int team = threadIdx.x >> 8;
        const int t256 = threadIdx.x & 255;
        const int tile = (blockIdx.x - 8)*2 + team;   // 0..1023
        const int img  = tile >> 3;
        const int strip = tile & 7;
        unsigned int* sZ  = (unsigned int*)(smem + team*53072);           // [3][19][66]
        unsigned int* sC1 = (unsigned int*)(smem + team*53072 + 15048);   // [16][9][66]
        unsigned int* sW   = (unsigned int*)(smem + 106144);              // 6144 u32
        unsigned int* sw01 = (unsigned int*)(smem + 130720);              // 288
        float*        sw2  = (float*)(smem + 131872);                     // 288
        float*        sb2  = (float*)(smem + 133024);                     // 32
        float*        sb1  = (float*)(smem + 133152);                     // 32

        pack_conv_lds(c1w, c1b, c2w, c2b, sW, sw01, sw2, sb1, sb2, 512);

        const int zrow0 = strip*16;
        for (int idx = t256; idx < 3762; idx += 256) {
            int ic = idx / (19*66);
            int rem = idx - ic*(19*66);
            int li = rem / 66;
            int x2 = rem - li*66;
            int iy = zrow0 + li;
            unsigned int v = 0;
            if (iy < 128 && x2 < 64) {
                float2 p = *(const float2*)&z_i[(((size_t)img*3 + ic)*128 + iy)*128 + 2*x2];
                v = packh2(p.x, p.y);
            }
            sZ[idx] = v;
        }
        for (int idx = t256; idx < 16*9*2; idx += 256) {
            int oc2 = idx / 18; int rem = idx - oc2*18; int li = rem >> 1; int c = 64 + (rem & 1);
            sC1[oc2*(9*66) + li*66 + c] = 0;
        }
        __syncthreads();
        for (int pos = t256; pos < 576; pos += 256) {
            int li = pos >> 6;
            int ox = pos & 63;
            unsigned int pa[9]; float px[9];
            #pragma unroll
            for (int ic = 0; ic < 3; ++ic)
                #pragma unroll
                for (int dy = 0; dy < 3; ++dy) {
                    int r = ic*3 + dy;
                    int rowb = ic*(19*66) + (2*li + dy)*66;
                    pa[r] = sZ[rowb + ox];
                    unsigned int u = sZ[rowb + ox + 1];
                    px[r] = __half2float(((const __half2*)&u)->x);
                }
            const bool phantom = (strip == 7) && (li == 8);
            #pragma unroll 4
            for (int oc2 = 0; oc2 < 16; ++oc2) {
                const int oca = 2*oc2, ocb = oca + 1;
                float acca = sb1[oca], accb = sb1[ocb];
                #pragma unroll
                for (int r = 0; r < 9; ++r) {
                    acca = fdot2(sw01[oca*9 + r], pa[r], acca);
                    acca += sw2[oca*9 + r] * px[r];
                    accb = fdot2(sw01[ocb*9 + r], pa[r], accb);
                    accb += sw2[ocb*9 + r] * px[r];
                }
                sC1[oc2*(9*66) + li*66 + ox] =
                    phantom ? 0u : packh2(fmaxf(acca, 0.f), fmaxf(accb, 0.f));
            }
        }
        __syncthreads();
        const int posl = t256 & 127;
        const int half = t256 >> 7;
        const int ly = posl >> 5;
        const int ox = posl & 31;
        float acc[16];
        #pragma unroll
        for (int j = 0; j < 16; ++j) acc[j] = 0.f;
        for (int ic2 = 0; ic2 < 16; ++ic2) {
            unsigned int patch[9];
            #pragma unroll
            for (int dy = 0; dy < 3; ++dy)
                #pragma unroll
                for (int dx = 0; dx < 3; ++dx)
                    patch[dy*3+dx] = sC1[ic2*(9*66) + (2*ly+dy)*66 + 2*ox + dx];
            const unsigned int* wbase = sW + (half*16 + ic2)*192;
            #pragma unroll
            for (int j = 0; j < 16; ++j) {
                const unsigned int* wr = wbase + j*12;
                uint4 wa = *(const uint4*)wr;
                uint4 wb = *(const uint4*)(wr + 4);
                unsigned int w8 = wr[8];
                float a = acc[j];
                a = fdot2(wa.x, patch[0], a); a = fdot2(wa.y, patch[1], a);
                a = fdot2(wa.z, patch[2], a); a = fdot2(wa.w, patch[3], a);
                a = fdot2(wb.x, patch[4], a); a = fdot2(wb.y, patch[5], a);
                a = fdot2(wb.z, patch[6], a); a = fdot2(wb.w, patch[7], a);
                a = fdot2(w8,  patch[8], a);
                acc[j] = a;
            }
        }
        const int oy = strip*4 + ly;
        #pragma unroll
        for (int j = 0; j < 16; ++j) {
            int oc = half*16 + j;
            zfeat[(((size_t)img*32 + oc)*32 + oy)*32 + ox] = fmaxf(acc[j] + sb2[oc], 0.f);
        }
    }
}

// ---------------- TAIL: blocks 0..255 = replay+FFT(c); blocks 256..4351 = FFT(z)
__global__ __launch_bounds__(256) void tail_kernel(
    const float* __restrict__ xfeat, const float* __restrict__ wbuf,
    const float* __restrict__ eag, const float* __restrict__ lnst,
    const float* __restrict__ zfeat,
    const float* __restrict__ cosw, const float* __restrict__ twg,
    float* __restrict__ cfft, float* __restrict__ zfft)
{
    const int tid = threadIdx.x;
    __shared__ __align__(16) float sY[32*36];
    __shared__ __align__(16) float sT[2048];
    __shared__ __align__(16) float sR[2048];
    {
        const float4* s4 = (const float4*)twg;
        float4* d4 = (float4*)sT;
        d4[tid]       = s4[tid];
        d4[256 + tid] = s4[256 + tid];
    }
    const int hj = tid >> 3;
    const int k0 = (tid & 7)*4;

    if (blockIdx.x < 256) {
        // ---- replay + FFT(c)
        const int m = blockIdx.x & 31;
        const int b = blockIdx.x >> 5;
        const int n0 = tid*4;
        float4 cw = *(const float4*)&cosw[n0];
        const float mu = lnst[b*2], rs = lnst[b*2+1];
        float c0v, c1v, c2v, c3v;
        {
            float4 x = *(const float4*)&xfeat[(size_t)(b*16)*32768 + (size_t)m*1024 + n0];
            c0v=(x.x-mu)*rs; c1v=(x.y-mu)*rs; c2v=(x.z-mu)*rs; c3v=(x.w-mu)*rs;
        }
        const int syoff = (tid>>3)*36 + (tid&7)*4;

        for (int t = 0; t < 16; ++t) {
            const size_t bt = (size_t)(b*16 + t);
            float4 w = *(const float4*)&wbuf[bt*1024 + n0];
            float e = eag[bt*80 + m];
            float a = eag[bt*80 + 32 + m];
            float g = eag[bt*80 + 64];
            float omg = 1.f - g;
            float4 xv = *(const float4*)&xfeat[bt*32768 + (size_t)m*1024 + n0];
            c0v = omg*(c0v*(1.f - w.x*e) + w.x*a) + g*xv.x;
            c1v = omg*(c1v*(1.f - w.y*e) + w.y*a) + g*xv.y;
            c2v = omg*(c2v*(1.f - w.z*e) + w.z*a) + g*xv.z;
            c3v = omg*(c3v*(1.f - w.w*e) + w.w*a) + g*xv.w;
            *(float4*)&sY[syoff] = make_float4(c0v*cw.x, c1v*cw.y, c2v*cw.z, c3v*cw.w);
            __syncthreads();
            float r0=0.f,i0=0.f,r1=0.f,i1=0.f,r2=0.f,i2=0.f,r3=0.f,i3=0.f;
            #pragma unroll
            for (int ww = 0; ww < 32; ++ww) {
                float y = sY[hj*36 + ww];
                float4 ta = *(const float4*)&sT[(ww*32 + k0)*2];
                float4 tb = *(const float4*)&sT[(ww*32 + k0)*2 + 4];
                r0 += y*ta.x; i0 += y*ta.y;
                r1 += y*ta.z; i1 += y*ta.w;
                r2 += y*tb.x; i2 += y*tb.y;
                r3 += y*tb.z; i3 += y*tb.w;
            }
            *(float4*)&sR[(hj*32 + k0)*2]     = make_float4(r0,i0,r1,i1);
            *(float4*)&sR[(hj*32 + k0)*2 + 4] = make_float4(r2,i2,r3,i3);
            __syncthreads();
            float fr0=0.f,fi0=0.f,fr1=0.f,fi1=0.f,fr2=0.f,fi2=0.f,fr3=0.f,fi3=0.f;
            #pragma unroll
            for (int h = 0; h < 32; ++h) {
                float2 wj = *(const float2*)&sT[(h*32 + hj)*2];
                float4 Ra = *(const float4*)&sR[(h*32 + k0)*2];
                float4 Rb = *(const float4*)&sR[(h*32 + k0)*2 + 4];
                fr0 += Ra.x*wj.x - Ra.y*wj.y;  fi0 += Ra.x*wj.y + Ra.y*wj.x;
                fr1 += Ra.z*wj.x - Ra.w*wj.y;  fi1 += Ra.z*wj.y + Ra.w*wj.x;
                fr2 += Rb.x*wj.x - Rb.y*wj.y;  fi2 += Rb.x*wj.y + Rb.y*wj.x;
                fr3 += Rb.z*wj.x - Rb.w*wj.y;  fi3 += Rb.z*wj.y + Rb.w*wj.x;
            }
            float* dp = cfft + (size_t)(bt*32 + m)*1088 + (size_t)(hj*17 + k0)*2;
            if (k0 < 16) {
                *(float2*)&dp[0] = make_float2(fr0, fi0);
                *(float2*)&dp[2] = make_float2(fr1, fi1);
                *(float2*)&dp[4] = make_float2(fr2, fi2);
                *(float2*)&dp[6] = make_float2(fr3, fi3);
            } else if (k0 == 16) {
                *(float2*)&dp[0] = make_float2(fr0, fi0);
            }
        }
    } else {
        // ---- FFT(z): one image per block
        const int img = blockIdx.x - 256;
        const float* src = zfeat + (size_t)img*1024;
        float* dst = zfft + (size_t)img*1088;
        {
            float4 v = *(const float4*)&src[tid*4];
            float4 c = *(const float4*)&cosw[tid*4];
            *(float4*)&sY[(tid>>3)*36 + (tid&7)*4] = make_float4(v.x*c.x, v.y*c.y, v.z*c.z, v.w*c.w);
        }
        __syncthreads();
        float r0=0.f,i0=0.f,r1=0.f,i1=0.f,r2=0.f,i2=0.f,r3=0.f,i3=0.f;
        #pragma unroll
        for (int w = 0; w < 32; ++w) {
            float y = sY[hj*36 + w];
            float4 ta = *(const float4*)&sT[(w*32 + k0)*2];
            float4 tb = *(const float4*)&sT[(w*32 + k0)*2 + 4];
            r0 += y*ta.x; i0 += y*ta.y;
            r1 += y*ta.z; i1 += y*ta.w;
            r2 += y*tb.x; i2 += y*tb.y;
            r3 += y*tb.z; i3 += y*tb.w;
        }
        *(float4*)&sR[(hj*32 + k0)*2]     = make_float4(r0,i0,r1,i1);
        *(float4*)&sR[(hj*32 + k0)*2 + 4] = make_float4(r2,i2,r3,i3);
        __syncthreads();
        float fr0=0.f,fi0=0.f,fr1=0.f,fi1=0.f,fr2=0.f,fi2=0.f,fr3=0.f,fi3=0.f;
        #pragma unroll
        for (int h = 0; h < 32; ++h) {
            float2 wj = *(const float2*)&sT[(h*32 + hj)*2];
            float4 Ra = *(const float4*)&sR[(h*32 + k0)*2];
            float4 Rb = *(const float4*)&sR[(h*32 + k0)*2 + 4];
            fr0 += Ra.x*wj.x - Ra.y*wj.y;  fi0 += Ra.x*wj.y + Ra.y*wj.x;
            fr1 += Ra.z*wj.x - Ra.w*wj.y;  fi1 += Ra.z*wj.y + Ra.w*wj.x;
            fr2 += Rb.x*wj.x - Rb.y*wj.y;  fi2 += Rb.x*wj.y + Rb.y*wj.x;
            fr3 += Rb.z*wj.x - Rb.w*wj.y;  fi3 += Rb.z*wj.y + Rb.w*wj.x;
        }
        float* dp = dst + (size_t)(hj*17 + k0)*2;
        if (k0 < 16) {
            *(float2*)&dp[0] = make_float2(fr0, fi0);
            *(float2*)&dp[2] = make_float2(fr1, fi1);
            *(float2*)&dp[4] = make_float2(fr2, fi2);
            *(float2*)&dp[6] = make_float2(fr3, fi3);
        } else if (k0 == 16) {
            *(float2*)&dp[0] = make_float2(fr0, fi0);
        }
    }
}

// ---------------- fused combine + irfft2; one block per bt, 512 threads
__global__ __launch_bounds__(512) void comb_ifft_kernel(const float* __restrict__ cfft,
                                                        const float* __restrict__ zfft,
                                                        const float* __restrict__ yf,
                                                        float* __restrict__ out)
{
    const int bt  = blockIdx.x;
    const int tid = threadIdx.x;
    __shared__ float sG[544*2];
    __shared__ float sS[544*2];
    __shared__ float ct[32], st[32];
    if (tid < 32) {
        float sv, cv;
        sincosf(TWOPI_32 * (float)tid, &sv, &cv);
        ct[tid] = cv; st[tid] = sv;
    }
    for (int idx = tid; idx < 544; idx += 512) {
        float kzz = 0.f, kxr = 0.f, kxi = 0.f;
        #pragma unroll 4
        for (int m = 0; m < 32; ++m) {
            size_t base = ((size_t)(bt*32 + m)*1088) + idx*2;
            float2 c = *(const float2*)&cfft[base];
            float2 z = *(const float2*)&zfft[base];
            kzz += c.x*c.x + c.y*c.y;
            kxr += z.x*c.x + z.y*c.y;
            kxi += z.y*c.x - z.x*c.y;
        }
        float den = 1.f / (kzz + 1e-4f);
        float2 y = *(const float2*)&yf[idx*2];
        float ar = y.x*den, ai = y.y*den;
        sG[idx*2]     = kxr*ar - kxi*ai;
        sG[idx*2 + 1] = kxr*ai + kxi*ar;
    }
    __syncthreads();
    for (int idx = tid; idx < 544; idx += 512) {
        int h = idx / 17;
        int k = idx - h*17;
        float re = 0.f, im = 0.f;
        #pragma unroll
        for (int j = 0; j < 32; ++j) {
            float gr = sG[(j*17+k)*2], gi = sG[(j*17+k)*2+1];
            int a = (h*j) & 31;
            float c = ct[a], s = st[a];
            re += gr*c - gi*s;
            im += gr*s + gi*c;
        }
        sS[(h*17+k)*2] = re; sS[(h*17+k)*2+1] = im;
    }
    __syncthreads();
    #pragma unroll
    for (int p = 0; p < 2; ++p) {
        int pos = p*512 + tid;
        int h = pos >> 5, wq = pos & 31;
        float acc = sS[(h*17)*2];
        #pragma unroll
        for (int k = 1; k < 16; ++k) {
            int a = (wq*k) & 31;
            acc += 2.f*(sS[(h*17+k)*2]*ct[a] - sS[(h*17+k)*2+1]*st[a]);
        }
        acc += sS[(h*17+16)*2] * ((wq & 1) ? -1.f : 1.f);
        out[(size_t)bt*1024 + pos] = acc * (1.f/1024.f);
    }
}

extern "C" void kernel_launch(void* const* d_in, const int* in_sizes, int n_in,
                              void* d_out, int out_size, void* d_ws, size_t ws_size,
                              hipStream_t stream)
{
    const float* x_i   = (const float*)d_in[0];
    const float* z_i   = (const float*)d_in[1];
    const float* c1w   = (const float*)d_in[2];
    const float* c1b   = (const float*)d_in[3];
    const float* c2w   = (const float*)d_in[4];
    const float* c2b   = (const float*)d_in[5];
    const float* Wk    = (const float*)d_in[6];
    const float* bk    = (const float*)d_in[7];
    const float* Wbeta = (const float*)d_in[8];
    const float* bbeta = (const float*)d_in[9];
    const float* Wh    = (const float*)d_in[10];
    const float* bh    = (const float*)d_in[11];
    const float* We    = (const float*)d_in[12];
    const float* Wa    = (const float*)d_in[13];
    const float* Wg    = (const float*)d_in[14];
    const float* cosw  = (const float*)d_in[15];
    const float* yf    = (const float*)d_in[16];
    float* out = (float*)d_out;
    float* ws  = (float*)d_ws;

    // workspace layout (floats)
    float*  xfeat = ws + 16777216;      // 4,194,304
    float*  zfeat = ws + 20971520;      // 4,194,304
    float*  cfft  = ws;                 // 4,456,448 f
    float*  zfft  = ws + 4456448;       // 4,456,448 f (ends 8,912,896)
    __half* xhb   = (__half*)(ws + 9000000);    // 4,194,304 halfs
    float*  wbuf  = ws + 11100000;      // 131,072 f
    float*  eag   = ws + 11240000;      // 10,240 f
    float*  lnstp = ws + 11251000;      // 16 f
    // pack outputs + xmp in the dead gap [29,360,128 .. 29,499,392)
    __half* whhP  = (__half*)(ws + 29360128);
    __half* whrxP = (__half*)(ws + 29392896);
    __half* wkP   = (__half*)(ws + 29401088);
    __half* weP   = (__half*)(ws + 29405184);
    __half* waP   = (__half*)(ws + 29409280);
    float*  twg   = ws + 29413376;      // 2,048 f -> ends 29,415,424
    float*  xmp   = ws + 29422144;      // 65,536 f -> ends 29,487,680 (< 29,499,392 OK)

    dim3 b256(256);
    convx_kernel<<<529, 512, 0, stream>>>(x_i, c1w, c1b, c2w, c2b, Wh, Wk, We, Wa,
                                          xfeat, xhb, xmp,
                                          whhP, whrxP, wkP, weP, waP, twg);
    fat_kernel<<<520, 512, 0, stream>>>(xfeat, xhb, xmp, whhP, whrxP, wkP, weP, waP,
                                        bk, Wbeta, bbeta, bh, Wg, wbuf, eag, lnstp,
                                        z_i, c1w, c1b, c2w, c2b, zfeat);
    tail_kernel<<<4352, b256, 0, stream>>>(xfeat, wbuf, eag, lnstp, zfeat,
                                           cosw, twg, cfft, zfft);
    comb_ifft_kernel<<<128, 512, 0, stream>>>(cfft, zfft, yf, out);
}